// Round 12
// baseline (542.968 us; speedup 1.0000x reference)
//
#include <hip/hip_runtime.h>
#include <hip/hip_bf16.h>

// GATFusionBlockPosOnly: B=8, N=1024, D=256, 8 GAT heads, 4 CA heads.
// Round 21:
//  - R20 landed (533us). #1: k_mattn5 L1 80us, MfmaUtil 17 / VALU 41 / Occ 38.
//    V fragment loads issued after barrier right before MFMA -> L2 round trip
//    (~200cy) on critical path every iter; only 16 waves/CU to hide it.
//  - k_mattn5: software-pipelined V prefetch — load chunk k+1's fragments into
//    registers BEFORE P-build of chunk k (independent of barrier); consume the
//    previous set after the barrier. +32 VGPR (60->~92, still 16 waves/CU).

#define BB 8
#define NN 1024
#define DD 256
#define HG 8
#define HC 4
#define BN (BB*NN)

typedef unsigned short u16;
typedef unsigned int u32;
typedef unsigned char u8;
typedef __attribute__((ext_vector_type(8))) short s8v;   // 8 bf16
typedef __attribute__((ext_vector_type(4))) float f4v;   // 4 fp32 acc
#define MFMA(a,b,c) __builtin_amdgcn_mfma_f32_16x16x32_bf16((a),(b),(c),0,0,0)

__device__ __forceinline__ u16 f2b(float x){
  union{ float f; unsigned u; } a; a.f = x;
  unsigned r = a.u + 0x7fff + ((a.u>>16)&1);
  return (u16)(r>>16);
}
__device__ __forceinline__ float b2f(u16 b){ return __uint_as_float(((unsigned)b)<<16); }
__device__ __forceinline__ float4 ld4bf(const u16* p){
  uint2 u = *(const uint2*)p;
  float4 r;
  r.x=__uint_as_float(u.x<<16); r.y=__uint_as_float(u.x&0xffff0000u);
  r.z=__uint_as_float(u.y<<16); r.w=__uint_as_float(u.y&0xffff0000u);
  return r;
}
__device__ __forceinline__ void load8(const float* p, float* v){
  float4 a=*(const float4*)p, b=*(const float4*)(p+4);
  v[0]=a.x;v[1]=a.y;v[2]=a.z;v[3]=a.w;v[4]=b.x;v[5]=b.y;v[6]=b.z;v[7]=b.w;
}
__device__ __forceinline__ float wredsum(float v){
  #pragma unroll
  for(int o=32;o>0;o>>=1) v += __shfl_xor(v,o);
  return v;
}
__device__ __forceinline__ float wredmax(float v){
  #pragma unroll
  for(int o=32;o>0;o>>=1) v = fmaxf(v,__shfl_xor(v,o));
  return v;
}
__device__ __forceinline__ float eluf(float x){ return x>0.f ? x : __expf(x)-1.f; }
__device__ __forceinline__ float leakyf(float z){ return z>=0.f ? z : 0.2f*z; }
__device__ __forceinline__ float exp0(float a){ return __expf(fminf(a, 0.f)); }
__device__ __forceinline__ float flushf(float v){ return (fabsf(v) < 1.0e30f) ? v : 0.f; }
__device__ __forceinline__ u32 pk2(float lo, float hi){
  u32 r;
  asm("v_cvt_pk_bf16_f32 %0, %1, %2" : "=v"(r) : "v"(lo), "v"(hi));
  return r;
}

// packed index for element (col, m) of the attention-V pack:  b=m>>10, kk=m&1023
__device__ __forceinline__ size_t packIdx(int col, int row){
  int kk = row & 1023;
  return ((((size_t)(col>>4))*8 + (row>>10))*32 + (kk>>5))*512
       + (size_t)(((((kk>>3)&3)*16) + (col&15))*8 + (kk&7));
}

// fragment-pack: element (row, k) of a [rows][KK] operand -> fragment order.
__device__ __forceinline__ size_t gpK(int row, int k, int KK){
  return (size_t)(row>>4)*((size_t)16*KK) + (size_t)(k>>5)*512
       + (size_t)(((((k>>3)&3)*16) + (row&15))*8 + (k&7));
}

// ---------- fp32 -> (hi,lo) bf16 split, packed output (gpK, KK=256) ----------
__global__ __launch_bounds__(256) void k_split(const float* __restrict__ X, u16* __restrict__ H, u16* __restrict__ Lo){
  size_t i = ((size_t)blockIdx.x*256 + threadIdx.x)*8;
  float v[8]; load8(X+i, v);
  u16 hh[8], ll[8];
  #pragma unroll
  for (int j=0;j<8;j++){ hh[j]=f2b(v[j]); ll[j]=f2b(v[j]-b2f(hh[j])); }
  int row = (int)(i>>8), col = (int)(i&255);
  size_t off = gpK(row, col, 256);
  *(uint4*)(H+off)=*(uint4*)&hh[0];
  *(uint4*)(Lo+off)=*(uint4*)&ll[0];
}

// ---------- transpose fp32 [R][C] -> bf16; pkKK=0: row-major [C][R]; else gpK packed ----------
__global__ __launch_bounds__(256) void k_transpose(const float* __restrict__ S, u16* __restrict__ D,
                                                   int R, int sliceElems, int pkKK){
  __shared__ float tl[64][65];
  const float* src = S + (size_t)blockIdx.z*sliceElems;
  u16* dst = D + (size_t)blockIdx.z*sliceElems;
  int C = gridDim.x*64;
  int bx=blockIdx.x*64, by=blockIdx.y*64;
  int tid=threadIdx.x, r=tid>>2, c0=(tid&3)*16;
  #pragma unroll
  for (int i=0;i<16;i+=4){
    float4 v = *(const float4*)(src + (size_t)(by+r)*C + bx + c0 + i);
    tl[r][c0+i]=v.x; tl[r][c0+i+1]=v.y; tl[r][c0+i+2]=v.z; tl[r][c0+i+3]=v.w;
  }
  __syncthreads();
  u16 tmp[16];
  #pragma unroll
  for (int i=0;i<16;i++) tmp[i] = f2b(tl[c0+i][r]);
  if (pkKK){
    *(uint4*)(dst + gpK(bx+r, by+c0,     pkKK)) = *(uint4*)&tmp[0];
    *(uint4*)(dst + gpK(bx+r, by+c0+8,   pkKK)) = *(uint4*)&tmp[8];
  } else {
    *(uint4*)(dst + (size_t)(bx+r)*R + by + c0)     = *(uint4*)&tmp[0];
    *(uint4*)(dst + (size_t)(bx+r)*R + by + c0 + 8) = *(uint4*)&tmp[8];
  }
}

// ---------- 4x 256x256 transposes, PACKED (gpK 256) output; grid (4,4,4) ----------
__global__ __launch_bounds__(256) void k_transpose4(const float* __restrict__ Sa, const float* __restrict__ Sb,
    const float* __restrict__ Sc, const float* __restrict__ Sd, u16* __restrict__ D){
  __shared__ float tl[64][65];
  const float* src = blockIdx.z==0 ? Sa : blockIdx.z==1 ? Sb : blockIdx.z==2 ? Sc : Sd;
  u16* dst = D + (size_t)blockIdx.z*65536;
  int bx=blockIdx.x*64, by=blockIdx.y*64;
  int tid=threadIdx.x, r=tid>>2, c0=(tid&3)*16;
  #pragma unroll
  for (int i=0;i<16;i+=4){
    float4 v = *(const float4*)(src + (size_t)(by+r)*256 + bx + c0 + i);
    tl[r][c0+i]=v.x; tl[r][c0+i+1]=v.y; tl[r][c0+i+2]=v.z; tl[r][c0+i+3]=v.w;
  }
  __syncthreads();
  u16 tmp[16];
  #pragma unroll
  for (int i=0;i<16;i++) tmp[i] = f2b(tl[c0+i][r]);
  *(uint4*)(dst + gpK(bx+r, by+c0,   256)) = *(uint4*)&tmp[0];
  *(uint4*)(dst + gpK(bx+r, by+c0+8, 256)) = *(uint4*)&tmp[8];
}

// ---------- transpose + split: fp32 [256][256] -> hi/lo bf16 PACKED (gpK 256) ----------
__global__ __launch_bounds__(256) void k_transp_split(const float* __restrict__ S, u16* __restrict__ DH, u16* __restrict__ DL){
  __shared__ float tl[64][65];
  int bx=blockIdx.x*64, by=blockIdx.y*64;
  int tid=threadIdx.x, r=tid>>2, c0=(tid&3)*16;
  #pragma unroll
  for (int i=0;i<16;i+=4){
    float4 v = *(const float4*)(S + (size_t)(by+r)*256 + bx + c0 + i);
    tl[r][c0+i]=v.x; tl[r][c0+i+1]=v.y; tl[r][c0+i+2]=v.z; tl[r][c0+i+3]=v.w;
  }
  __syncthreads();
  u16 th[16], tll[16];
  #pragma unroll
  for (int i=0;i<16;i++){
    float v = tl[c0+i][r];
    th[i]=f2b(v); tll[i]=f2b(v - b2f(th[i]));
  }
  size_t o0 = gpK(bx+r, by+c0,   256);
  size_t o1 = gpK(bx+r, by+c0+8, 256);
  *(uint4*)(DH + o0) = *(uint4*)&th[0];
  *(uint4*)(DH + o1) = *(uint4*)&th[8];
  *(uint4*)(DL + o0) = *(uint4*)&tll[0];
  *(uint4*)(DL + o1) = *(uint4*)&tll[8];
}

// ---------- pos_query ----------
__global__ __launch_bounds__(256) void k_posq(const float* __restrict__ x, const int* __restrict__ mask,
                                              float* __restrict__ pq, float* __restrict__ cnt){
  int b = blockIdx.x, chunk = blockIdx.y;
  int d = threadIdx.x;
  int n0 = chunk*64;
  float acc = 0.f; float c = 0.f;
  for (int i=0;i<64;i++){
    int n = n0+i;
    if (mask[b*NN+n]==1){ acc += x[((size_t)(b*NN+n))*DD + d]; c += 1.f; }
  }
  atomicAdd(&pq[b*DD+d], acc);
  if (d==0) atomicAdd(&cnt[b], c);
}

__global__ __launch_bounds__(256) void k_sq(const float* __restrict__ pq, const float* __restrict__ cnt,
                                            const float* __restrict__ Wq, float* __restrict__ sq){
  int b = blockIdx.x, e = threadIdx.x;
  float inv = 1.f / fmaxf(cnt[b], 1.f);
  float acc=0.f;
  for (int d0=0; d0<DD; d0++) acc += (pq[b*DD+d0]*inv) * Wq[d0*DD+e];
  sq[b*DD+e] = acc;
}

// ---------- sigmoid + threshold from folded dot ----------
__global__ __launch_bounds__(256) void k_simsel2(const float* __restrict__ pdot,
                                                 float* __restrict__ simOut, u8* __restrict__ sel8){
  int r = blockIdx.x*256 + threadIdx.x;
  float s = pdot[r] * 0.0625f;
  float sim = 1.f/(1.f+expf(-s));
  simOut[r] = sim;
  sel8[r] = (sim > 0.97f) ? 1 : 0;
}

// ---------- no-LDS MFMA GEMM: out[8192, OC] = A[8192,KK] @ BT[OC,KK]^T ----------
// APK: A fragment-packed (gpK, KK). BPK: BT fragment-packed (gpK, ldB total K; kOff = K start).
// EPI: 0=C fp32, 1=C+=, 2=residual+gamma, 3=O bf16,
//      7=Pk pack + s1/s2 fold (head=colBase>>8), 8=Pk pack + s1/s2 fold (single head)
template<int EPI, int APK, int BPK>
__global__ __launch_bounds__(256) void k_mgemm(const u16* __restrict__ A, const u16* __restrict__ BT,
    int KK, int ldB, int kOff, float* __restrict__ C, const float* __restrict__ Xres,
    const float* __restrict__ gamma, u16* __restrict__ O, u16* __restrict__ Pk,
    const float* __restrict__ A1, const float* __restrict__ A2,
    float* __restrict__ s1g, float* __restrict__ s2g){
  int tid=threadIdx.x, w=tid>>6, lane=tid&63, L=lane&15, q=lane>>4;
  int OC = gridDim.x<<6;
  int colBase=blockIdx.x<<6, rowBase=blockIdx.y<<6;
  const u16* ap;
  if constexpr (APK) ap = A + (size_t)((rowBase>>4)+w)*((size_t)16*KK) + (size_t)lane*8;
  else               ap = A + (size_t)(rowBase + w*16 + L)*KK + q*8;
  const u16* bp[4];
  #pragma unroll
  for (int t=0;t<4;t++){
    if constexpr (BPK) bp[t] = BT + (size_t)((colBase>>4)+t)*((size_t)16*ldB) + (size_t)(kOff>>5)*512 + (size_t)lane*8;
    else               bp[t] = BT + (size_t)(colBase + t*16 + L)*ldB + q*8 + kOff;
  }
  f4v z4={0.f,0.f,0.f,0.f};
  f4v acc[4]={z4,z4,z4,z4};
  int nk = KK>>5;
  for (int kc=0;kc<nk;kc++){
    s8v a0;
    if constexpr (APK) a0 = *(const s8v*)(ap + (size_t)kc*512);
    else               a0 = *(const s8v*)(ap + kc*32);
    #pragma unroll
    for (int t=0;t<4;t++){
      s8v bt;
      if constexpr (BPK) bt = *(const s8v*)(bp[t] + (size_t)kc*512);
      else               bt = *(const s8v*)(bp[t] + kc*32);
      acc[t]=MFMA(a0,bt,acc[t]);
    }
  }
  if constexpr (EPI<=3){
    #pragma unroll
    for (int t=0;t<4;t++){
      int col = colBase + t*16 + L;
      #pragma unroll
      for (int reg=0;reg<4;reg++){
        int row = rowBase + w*16 + q*4 + reg;
        size_t off = (size_t)row*OC + col;
        float v = acc[t][reg];
        if constexpr (EPI==0){ C[off] = v; }
        else if constexpr (EPI==1){ C[off] += v; }
        else if constexpr (EPI==2){ C[off] = flushf(Xres[off] + gamma[col]*v); }
        else { O[off] = f2b(v); }
      }
    }
  } else {
    // s1/s2 fold
    float s1p[4]={0.f,0.f,0.f,0.f}, s2p[4]={0.f,0.f,0.f,0.f};
    #pragma unroll
    for (int t=0;t<4;t++){
      int col = colBase + t*16 + L;
      float a1v = A1[col], a2v = A2[col];
      #pragma unroll
      for (int reg=0;reg<4;reg++){
        float v = acc[t][reg];
        s1p[reg] += v*a1v;
        s2p[reg] += v*a2v;
      }
    }
    #pragma unroll
    for (int off=1;off<16;off<<=1)
      #pragma unroll
      for (int reg=0;reg<4;reg++){
        s1p[reg] += __shfl_xor(s1p[reg],off);
        s2p[reg] += __shfl_xor(s2p[reg],off);
      }
    if (L==0){
      int sOff = (EPI==7) ? (colBase>>8)*BN : 0;
      #pragma unroll
      for (int reg=0;reg<4;reg++){
        int row = rowBase + w*16 + q*4 + reg;
        atomicAdd(&s1g[sOff+row], s1p[reg]);
        atomicAdd(&s2g[sOff+row], s2p[reg]);
      }
    }
    // coalesced pack store (16B per lane, 8 consecutive rows of one column)
    int pq_ = q&1;
    int m0 = rowBase + w*16 + (q>>1)*8;
    #pragma unroll
    for (int tp=0;tp<2;tp++){
      f4v accA = acc[2*tp], accB = acc[2*tp+1];
      f4v mine   = pq_ ? accB : accA;
      f4v theirs = pq_ ? accA : accB;
      u32 k0 = pk2(mine[0],  mine[1]);
      u32 k1 = pk2(mine[2],  mine[3]);
      u32 s0 = pk2(theirs[0],theirs[1]);
      u32 s1 = pk2(theirs[2],theirs[3]);
      u32 r0 = (u32)__shfl_xor((int)s0,16);
      u32 r1 = (u32)__shfl_xor((int)s1,16);
      uint4 val = pq_==0 ? make_uint4(k0,k1,r0,r1) : make_uint4(r0,r1,k0,k1);
      int t = 2*tp + pq_;
      int col = colBase + t*16 + L;
      *(uint4*)(Pk + packIdx(col, m0)) = val;
    }
  }
}

// ---------- fused q/k/v projections, packed A (gpK 256) and B (gpK 256) ----------
__global__ __launch_bounds__(256) void k_mgemm3(const u16* __restrict__ Aq, const u16* __restrict__ Akv,
    const u16* __restrict__ BT0, u16* __restrict__ O0){
  int tid=threadIdx.x, w=tid>>6, lane=tid&63, L=lane&15, q=lane>>4;
  const u16* A = blockIdx.z==0 ? Aq : Akv;
  const u16* BT = BT0 + (size_t)blockIdx.z*65536;
  u16* O = O0 + (size_t)blockIdx.z*2097152;
  int colBase=blockIdx.x<<6, rowBase=blockIdx.y<<6;
  const u16* ap = A + (size_t)((rowBase>>4)+w)*4096 + (size_t)lane*8;
  f4v z4={0.f,0.f,0.f,0.f};
  f4v acc[4]={z4,z4,z4,z4};
  #pragma unroll
  for (int kc=0;kc<8;kc++){
    s8v a0 = *(const s8v*)(ap + kc*512);
    #pragma unroll
    for (int t=0;t<4;t++){
      s8v bt = *(const s8v*)(BT + (size_t)((colBase>>4)+t)*4096 + (size_t)kc*512 + (size_t)lane*8);
      acc[t]=MFMA(a0,bt,acc[t]);
    }
  }
  #pragma unroll
  for (int t=0;t<4;t++){
    int col = colBase + t*16 + L;
    #pragma unroll
    for (int reg=0;reg<4;reg++){
      int row = rowBase + w*16 + q*4 + reg;
      O[(size_t)row*256 + col] = f2b(acc[t][reg]);
    }
  }
}

// ---------- split (3-term) MFMA GEMM, packed A and B (gpK 256): KK=256, OC=256 ----------
// EPI 4: hi/lo bf16 gram-packed out.  EPI 5: sq-dot fold -> pdot.
template<int EPI>
__global__ __launch_bounds__(256) void k_msgemm(const u16* __restrict__ Ah, const u16* __restrict__ Al,
    const u16* __restrict__ Bh, const u16* __restrict__ Bl,
    float* __restrict__ C, u16* __restrict__ Oh, u16* __restrict__ Ol,
    const float* __restrict__ sq, float* __restrict__ pdot){
  int tid=threadIdx.x, w=tid>>6, lane=tid&63, L=lane&15, q=lane>>4;
  int colBase=blockIdx.x<<6, rowBase=blockIdx.y<<6;
  const u16* ahp = Ah + (size_t)((rowBase>>4)+w)*4096 + (size_t)lane*8;
  const u16* alp = Al + (size_t)((rowBase>>4)+w)*4096 + (size_t)lane*8;
  f4v z4={0.f,0.f,0.f,0.f};
  f4v acc[4]={z4,z4,z4,z4};
  #pragma unroll
  for (int kc=0;kc<8;kc++){
    s8v ah=*(const s8v*)(ahp + kc*512), al=*(const s8v*)(alp + kc*512);
    #pragma unroll
    for (int t=0;t<4;t++){
      size_t boff = (size_t)((colBase>>4)+t)*4096 + (size_t)kc*512 + (size_t)lane*8;
      s8v bh=*(const s8v*)(Bh + boff);
      s8v bl=*(const s8v*)(Bl + boff);
      acc[t]=MFMA(ah,bh,acc[t]);
      acc[t]=MFMA(ah,bl,acc[t]);
      acc[t]=MFMA(al,bh,acc[t]);
    }
  }
  if constexpr (EPI==5){
    int b = rowBase>>10;
    float pp[4]={0.f,0.f,0.f,0.f};
    #pragma unroll
    for (int t=0;t<4;t++){
      int col = colBase + t*16 + L;
      float qv = sq[b*256 + col];
      #pragma unroll
      for (int reg=0;reg<4;reg++) pp[reg] += acc[t][reg]*qv;
    }
    #pragma unroll
    for (int off=1;off<16;off<<=1)
      #pragma unroll
      for (int reg=0;reg<4;reg++) pp[reg] += __shfl_xor(pp[reg],off);
    if (L==0){
      #pragma unroll
      for (int reg=0;reg<4;reg++){
        int row = rowBase + w*16 + q*4 + reg;
        atomicAdd(&pdot[row], pp[reg]);
      }
    }
  } else {
    #pragma unroll
    for (int t=0;t<4;t++){
      int col = colBase + t*16 + L;
      #pragma unroll
      for (int reg=0;reg<4;reg++){
        int row = rowBase + w*16 + q*4 + reg;
        float v = acc[t][reg];
        if constexpr (EPI==0){ C[(size_t)row*256 + col] = v; }
        else {
          size_t off = gpK(row, col, 256);
          u16 h = f2b(v); Oh[off]=h; Ol[off]=f2b(v - b2f(h));
        }
      }
    }
  }
}

// ---------- gram + bitpack v2: packed fragments, symmetric tile enumeration ----------
__global__ __launch_bounds__(256) void k_mconnect2(const u16* __restrict__ fahP, const u16* __restrict__ falP,
    const u8* __restrict__ sel8, u32* __restrict__ conn){
  __shared__ u8 sg[64][64];
  __shared__ u8 selI[64], selJ[64];
  int tid=threadIdx.x, w=tid>>6, lane=tid&63, L=lane&15, q=lane>>4;
  int b=blockIdx.z;
  int p=blockIdx.x;
  int i = (int)((sqrtf(8.f*p+1.f)-1.f)*0.5f);
  while ((i+1)*(i+2)/2 <= p) i++;
  while (i*(i+1)/2 > p) i--;
  int j = p - i*(i+1)/2;          // i >= j, both 0..15
  if (tid < 64)        selI[tid]     = sel8[b*NN + i*64 + tid];
  else if (tid < 128)  selJ[tid-64]  = sel8[b*NN + j*64 + (tid-64)];
  const u16* ah0 = fahP + ((size_t)(b*64 + i*4 + w))*4096 + (size_t)lane*8;
  const u16* al0 = falP + ((size_t)(b*64 + i*4 + w))*4096 + (size_t)lane*8;
  const u16* bh0 = fahP + ((size_t)(b*64 + j*4))*4096 + (size_t)lane*8;
  const u16* bl0 = falP + ((size_t)(b*64 + j*4))*4096 + (size_t)lane*8;
  f4v z4={0.f,0.f,0.f,0.f};
  f4v acc[4]={z4,z4,z4,z4};
  #pragma unroll
  for (int kc=0;kc<8;kc++){
    s8v ah = *(const s8v*)(ah0 + kc*512);
    s8v al = *(const s8v*)(al0 + kc*512);
    #pragma unroll
    for (int t=0;t<4;t++){
      s8v bh = *(const s8v*)(bh0 + (size_t)t*4096 + kc*512);
      s8v bl = *(const s8v*)(bl0 + (size_t)t*4096 + kc*512);
      acc[t]=MFMA(ah,bh,acc[t]);
      acc[t]=MFMA(ah,bl,acc[t]);
      acc[t]=MFMA(al,bh,acc[t]);
    }
  }
  #pragma unroll
  for (int t=0;t<4;t++)
    #pragma unroll
    for (int reg=0;reg<4;reg++)
      sg[w*16 + q*4 + reg][t*16 + L] = acc[t][reg] > 0.f;
  __syncthreads();
  int row=(tid&127)>>1, ww=tid&1;
  if (tid<128){
    u32 word=0;
    if (selI[row]){
      #pragma unroll 8
      for (int jj=0;jj<32;jj++)
        if (sg[row][ww*32+jj] && selJ[ww*32+jj]) word |= (1u<<jj);
    }
    conn[((size_t)b*NN + i*64+row)*32 + j*2 + ww] = word;
  } else if (i != j){
    u32 word=0;
    if (selJ[row]){
      #pragma unroll 8
      for (int jj=0;jj<32;jj++)
        if (sg[ww*32+jj][row] && selI[ww*32+jj]) word |= (1u<<jj);
    }
    conn[((size_t)b*NN + j*64+row)*32 + i*2 + ww] = word;
  }
}

// ---------- row max of s2 over connected m ----------
__global__ __launch_bounds__(256) void k_rowmax(const float* __restrict__ s2a,
    const u32* __restrict__ conn, float* __restrict__ M2a){
  int h = blockIdx.y;
  int r = blockIdx.x*4 + (threadIdx.x>>6);
  int lane = threadIdx.x&63;
  int b = r>>10;
  const float* s2p = s2a + h*BN + b*NN;
  float mx = -3.0e38f;
  #pragma unroll
  for (int t=0;t<16;t++){
    int m = lane + t*64;
    u32 wd = conn[(size_t)r*32 + (m>>5)];
    if ((wd>>(m&31))&1u) mx = fmaxf(mx, s2p[m]);
  }
  mx = wredmax(mx);
  if (lane==0) M2a[h*BN+r] = mx;
}

// ---------- MFMA GAT attention v7: P shared via LDS, V prefetched one chunk ahead ----------
// PKO: 0 = row-major output (stride oStride); else fragment-packed gpK(row,col,PKO).
template<int CT, bool SWZ, int PKO>
__global__ __launch_bounds__(256,4) void k_mattn5(const float* __restrict__ s1a, const float* __restrict__ s2a,
    const float* __restrict__ M2a, const u32* __restrict__ conn,
    const u16* __restrict__ P, int headMul, u16* __restrict__ Out, int oStride){
  __shared__ __align__(16) u16 Pb[2][4][512];
  __shared__ float Srow[64];
  int tid=threadIdx.x, w=tid>>6, lane=tid&63, L=lane&15, q=lane>>4;
  int h, rowBlk;
  if constexpr (SWZ){ h = blockIdx.y & 7; rowBlk = (blockIdx.y>>3) + (blockIdx.z<<4); }
  else             { h = blockIdx.z;     rowBlk = blockIdx.y; }
  int rowBase = rowBlk*64;
  int hOff = h*headMul, sOff = h*BN;
  int b = rowBase>>10;
  size_t bOff = (size_t)b*NN;
  int r = rowBase + w*16 + L;             // own row for P-build
  float s1v = s1a[sOff+r];
  float rmv = leakyf(s1v + M2a[sOff+r]);
  const float* s2p = s2a + sOff + bOff;
  const u32* cp = conn + (size_t)r*32;
  int tile0 = blockIdx.x*(4*CT) + w*CT;   // first col-tile owned by this wave
  const u16* vp = P + (size_t)((hOff>>4) + tile0)*131072 + (size_t)b*16384 + (size_t)lane*8;
  f4v z4={0.f,0.f,0.f,0.f};
  f4v acc[4][CT];
  #pragma unroll
  for (int g=0;g<4;g++)
    #pragma unroll
    for (int t=0;t<CT;t++) acc[g][t]=z4;
  float sumP = 0.f;
  // prologue: prefetch chunk 0's V fragments
  s8v vf[CT];
  #pragma unroll
  for (int t=0;t<CT;t++) vf[t] = *(const s8v*)(vp + (size_t)t*131072);
  for (int k0=0;k0<NN;k0+=32){
    int cur=(k0>>5)&1;
    u32 cw = cp[k0>>5];
    // issue next chunk's V loads NOW — they complete under P-build + barrier
    s8v vfn[CT];
    bool have = (k0+32)<NN;
    if (have){
      const u16* vk = vp + (size_t)((k0>>5)+1)*512;
      #pragma unroll
      for (int t=0;t<CT;t++) vfn[t] = *(const s8v*)(vk + (size_t)t*131072);
    }
    float4 sA = *(const float4*)(s2p + k0 + q*8);
    float4 sB = *(const float4*)(s2p + k0 + q*8 + 4);
    float s2v[8] = {sA.x,sA.y,sA.z,sA.w,sB.x,sB.y,sB.z,sB.w};
    float p[8];
    #pragma unroll
    for (int j=0;j<8;j++){
      float z = s1v + s2v[j];
      float ev = fmaxf(z, 0.2f*z);                      // leaky = max(z, 0.2z)
      ev = ((cw>>(q*8+j))&1u) ? ev : -9.0e15f;          // mask BEFORE exp (uniform rows!)
      p[j] = __expf(fminf(ev - rmv, 0.f));
      sumP += p[j];
    }
    union{ s8v v; u32 u[4]; } pk;
    #pragma unroll
    for (int jj=0;jj<4;jj++)
      pk.u[jj] = pk2(p[2*jj], p[2*jj+1]);
    *(s8v*)&Pb[cur][w][lane*8] = pk.v;    // ds_write_b128, contiguous
    __syncthreads();                       // all P fragments for this chunk visible
    s8v pa[4];
    #pragma unroll
    for (int g=0;g<4;g++) pa[g] = *(const s8v*)&Pb[cur][g][lane*8];
    #pragma unroll
    for (int t=0;t<CT;t++)
      #pragma unroll
      for (int g=0;g<4;g++) acc[g][t] = MFMA(pa[g], vf[t], acc[g][t]);
    if (have){
      #pragma unroll
      for (int t=0;t<CT;t++) vf[t] = vfn[t];
    }
  }
  sumP += __shfl_xor(sumP,16);
  sumP += __shfl_xor(sumP,32);
  if (lane<16) Srow[w*16+lane] = sumP;
  __syncthreads();
  #pragma unroll
  for (int g=0;g<4;g++){
    float4 sv = *(const float4*)&Srow[g*16 + q*4];
    float rsi[4] = {1.f/sv.x, 1.f/sv.y, 1.f/sv.z, 1.f/sv.w};
    #pragma unroll
    for (int t=0;t<CT;t++){
      int col = hOff + (tile0+t)*16 + L;
      #pragma unroll
      for (int reg=0;reg<4;reg++){
        int row = rowBase + g*16 + q*4 + reg;
        float ov = eluf(acc[g][t][reg]*rsi[reg]);
        if constexpr (PKO) Out[gpK(row, col, PKO)] = f2b(ov);
        else               Out[(size_t)row*oStride + col] = f2b(ov);
      }
    }
  }
}

// ---------- LayerNorms (packed gpK-256 output) ----------
__global__ __launch_bounds__(256) void k_ln_x(const float* __restrict__ x, const float* __restrict__ g,
                                              const float* __restrict__ bb, u16* __restrict__ out){
  int r = blockIdx.x*4 + (threadIdx.x>>6);
  int lane=threadIdx.x&63;
  float4 v = *(const float4*)(x + (size_t)r*DD + lane*4);
  float s = v.x+v.y+v.z+v.w;
  float s2 = v.x*v.x+v.y*v.y+v.z*v.z+v.w*v.w;
  s = wredsum(s); s2 = wredsum(s2);
  float mean = s*(1.f/256.f);
  float var = s2*(1.f/256.f) - mean*mean;
  float rstd = rsqrtf(var + 1e-5f);
  float4 gv = *(const float4*)(g+lane*4), bv = *(const float4*)(bb+lane*4);
  u16 t[4];
  t[0]=f2b((v.x-mean)*rstd*gv.x+bv.x); t[1]=f2b((v.y-mean)*rstd*gv.y+bv.y);
  t[2]=f2b((v.z-mean)*rstd*gv.z+bv.z); t[3]=f2b((v.w-mean)*rstd*gv.w+bv.w);
  *(uint2*)(out + gpK(r, lane*4, 256)) = *(uint2*)&t[0];
}

__global__ __launch_bounds__(256) void k_ln_kv(const u16* __restrict__ gout, const float* __restrict__ pe,
    const u8* __restrict__ sel8, const float* __restrict__ g, const float* __restrict__ bb,
    u16* __restrict__ out){
  int r = blockIdx.x*4 + (threadIdx.x>>6);
  int lane=threadIdx.x&63;
  int n = r & 1023;
  float4 v = make_float4(0.f,0.f,0.f,0.f);
  if (sel8[r]){
    float4 gv = ld4bf(gout + (size_t)r*DD + lane*4);
    float4 pv = *(const float4*)(pe + (size_t)n*DD + lane*4);
    v = make_float4(gv.x+pv.x, gv.y+pv.y, gv.z+pv.z, gv.w+pv.w);
  }
  float s = v.x+v.y+v.z+v.w;
  float s2 = v.x*v.x+v.y*v.y+v.z*v.z+v.w*v.w;
  s = wredsum(s); s2 = wredsum(s2);
  float mean = s*(1.f/256.f);
  float var = s2*(1.f/256.f) - mean*mean;
  float rstd = rsqrtf(var + 1e-5f);
  float4 gv = *(const float4*)(g+lane*4), bv = *(const float4*)(bb+lane*4);
  u16 t[4];
  t[0]=f2b((v.x-mean)*rstd*gv.x+bv.x); t[1]=f2b((v.y-mean)*rstd*gv.y+bv.y);
  t[2]=f2b((v.z-mean)*rstd*gv.z+bv.z); t[3]=f2b((v.w-mean)*rstd*gv.w+bv.w);
  *(uint2*)(out + gpK(r, lane*4, 256)) = *(uint2*)&t[0];
}

// ---------- CA attention, fused flash-style; Ob written fragment-packed (gpK 256) ----------
__global__ __launch_bounds__(256) void k_mca_av2(const u16* __restrict__ q, const u16* __restrict__ k,
    const u16* __restrict__ v, const u8* __restrict__ sel8, u16* __restrict__ O){
  __shared__ __align__(16) u16 Qls[64][72];
  __shared__ __align__(16) u16 KP[64][72];
  __shared__ __align__(16) u16 Vt[64][72];
  int tid=threadIdx.x;
  int w = tid>>6, lane = tid&63, L = lane&15, qd = lane>>4;
  int b=blockIdx.z, h=blockIdx.y, rowBase=blockIdx.x*64;
  size_t bOff = (size_t)b*NN;
  {
    int r=tid>>2, c0=(tid&3)*16;
    size_t base = (bOff + rowBase + r)*(size_t)DD + h*64 + c0;
    *(uint4*)&Qls[r][c0]   = *(const uint4*)(q + base);
    *(uint4*)&Qls[r][c0+8] = *(const uint4*)(q + base + 8);
  }
  float rm[4], sp[4];
  #pragma unroll
  for (int reg=0;reg<4;reg++){ rm[reg] = -3.0e38f; sp[reg] = 0.f; }
  f4v zero = {0.f,0.f,0.f,0.f};
  f4v acc[4] = {zero,zero,zero,zero};
  int svm = tid&63, svd0 = (tid>>6)*16;
  for (int m0=0;m0<NN;m0+=64){
    __syncthreads();
    {
      int r=tid>>2, c0=(tid&3)*16;
      size_t base = (bOff + m0 + r)*(size_t)DD + h*64 + c0;
      *(uint4*)&KP[r][c0]   = *(const uint4*)(k + base);
      *(uint4*)&KP[r][c0+8] = *(const uint4*)(k + base + 8);
      size_t vb_ = (bOff + m0 + svm)*(size_t)DD + h*64 + svd0;
      uint4 u0 = *(const uint4*)(v + vb_);
      uint4 u1 = *(const uint4*)(v + vb_ + 8);
      u16 tmp[16];
      *(uint4*)&tmp[0]=u0; *(uint4*)&tmp[8]=u1;
      #pragma unroll
      for (int i=0;i<16;i++) Vt[svd0+i][svm] = tmp[i];
    }
    __syncthreads();
    f4v sa[4] = {zero,zero,zero,zero};
    #pragma unroll
    for (int kc=0;kc<64;kc+=32){
      s8v af = *(const s8v*)&Qls[w*16 + L][kc + qd*8];
      #pragma unroll
      for (int t=0;t<4;t++){
        s8v bfr = *(const s8v*)&KP[t*16 + L][kc + qd*8];
        sa[t] = MFMA(af, bfr, sa[t]);
      }
    }
    __syncthreads();
    // online-softmax update (row-consistent max via L-group reduce)
    float vals[4][4];
    float tmax[4];
    #pragma unroll
    for (int reg=0;reg<4;reg++) tmax[reg] = -3.0e38f;
    #pragma unroll
    for (int t=0;t<4;t++){
      int m = m0 + t*16 + L;
      bool sl = sel8[b*NN+m];
      #pragma unroll
      for (int reg=0;reg<4;reg++){
        float val = sl ? sa[t][reg]*0.125f : -1.0e9f;
        vals[t][reg] = val;
        tmax[reg] = fmaxf(tmax[reg], val);
      }
    }
    #pragma unroll
    for (int off=1;off<16;off<<=1)
      #pragma unroll
      for (int reg=0;reg<4;reg++) tmax[reg] = fmaxf(tmax[reg], __shfl_xor(tmax[reg],off));
    float sc[4];
    #pragma unroll
    for (int reg=0;reg<4;reg++){
      float nm = fmaxf(rm[reg], tmax[reg]);
      sc[reg] = exp0(rm[reg] - nm);
      rm[reg] = nm;
      sp[reg] *= sc[reg];
    }
    #pragma unroll
    for (int t=0;t<4;t++){
      #pragma unroll
      for (int reg=0;reg<4;reg++){
        float pv = exp0(vals[t][reg] - rm[reg]);
        sp[reg] += pv;
        KP[w*16 + qd*4 + reg][t*16 + L] = f2b(pv);
      }
    }
    #pragma unroll
    for (int t=0;t<4;t++)
      #pragma unroll
      for (int reg=0;reg<4;reg++) acc[t][reg] *= sc[reg];
    __syncthreads();
    #pragma unroll
    for (int mc=0;mc<64;mc+=32){
      s8v pf = *(const s8v*)&KP[w*16 + L][mc + qd*8];
      #pragma unroll
      for (int t=0;t<4;t++){
        s8v vf = *(const s8v*)&Vt[t*16 + L][mc + qd*8];
        acc[t] = MFMA(pf, vf, acc[t]);
      }
    }
  }
  #pragma unroll
  for (int off=1;off<16;off<<=1)
    #pragma unroll
    for (int reg=0;reg<4;reg++) sp[reg] += __shfl_xor(sp[reg],off);
  float ri[4];
  #pragma unroll
  for (int reg=0;reg<4;reg++) ri[reg] = 1.f/sp[reg];
  #pragma unroll
  for (int t=0;t<4;t++){
    int col = h*64 + t*16 + L;
    #pragma unroll
    for (int reg=0;reg<4;reg++){
      int row = (int)bOff + rowBase + w*16 + qd*4 + reg;
      O[gpK(row, col, 256)] = f2b(acc[t][reg]*ri[reg]);
    }
  }
}

extern "C" void kernel_launch(void* const* d_in, const int* in_sizes, int n_in,
                              void* d_out, int out_size, void* d_ws, size_t ws_size,
                              hipStream_t stream) {
  (void)in_sizes; (void)n_in; (void)out_size;
  const float* x      = (const float*)d_in[0];
  const int*   mask   = (const int*  )d_in[1];
  const float* pe     = (const float*)d_in[2];
  const float* sim_Wx = (const float*)d_in[3];
  const float* sim_Wq = (const float*)d_in[4];
  const float* adj_W  = (const float*)d_in[5];
  const float* gat_W  = (const float*)d_in[6];
  const float* gat_a1 = (const float*)d_in[7];
  const float* gat_a2 = (const float*)d_in[8];
  const float* gat_Wo = (const float*)d_in[9];
  const float* gat_ao1= (const float*)d_in[10];
  const float* gat_ao2= (const float*)d_in[11];
  const float* ln3_g  = (const float*)d_in[12];
  const float* ln3_b  = (const float*)d_in[13];
  const float* ln4_g  = (const float*)d_in[14];
  const float* ln4_b  = (const float*)d_in[15];
  const float* ca_Wq  = (const float*)d_in[16];
  const float* ca_Wk  = (const float*)d_in[17];
  const float* ca_Wv  = (const float*)d_in[18];
  const float* ca_Wp  = (const float*)d_in[19];
  const float* gamma  = (const float*)d_in[20];
  float* out    = (float*)d_out;
  float* simOut = out + (size_t)BN*DD;

  const size_t MB = 1024*1024;
  bool big = ws_size >= 98*MB;
  char* W = (char*)d_ws;
  float* pq   = (float*)W;
  float* cnt  = pq + 2048;
  float* sq   = cnt + 16;
  float* s1a  = (float*)(W + 64*1024);
  float* s2a  = (float*)(W + 320*1024);
  float* M2a  = (float*)(W + 576*1024);
  float* pdot = (float*)(W + 1216*1024);
  u8*    sel8 = (u8*)(W + 1400*1024);
  u32*   conn = (u32*)(W + 2*MB);
  u16*   WT0  = (u16*)(W + 3*MB);
  u16*   WoT  = (u16*)(W + 4*MB);
  u16*   WQT  = (u16*)(W + 5*MB);
  u16*   WPT  = WQT + 3*65536;
  u16*   sWxh = (u16*)(W + 5*MB + 512*1024);
  u16*   sWxl = sWxh + 65536;
  u16*   aWh  = sWxl + 65536;
  u16*   aWl  = aWh + 65536;
  u16*   xh   = (u16*)(W + 6*MB);
  u16*   xl   = (u16*)(W + 10*MB);
  float* S0   = (float*)(W + 14*MB);
  u16*   fah  = (u16*)(W + 22*MB);
  u16*   fal  = (u16*)(W + 26*MB);
  u16*   T2   = (u16*)(W + 30*MB);

  // prep (everything fragment-packed)
  k_split<<<BN*DD/2048,256,0,stream>>>(x, xh, xl);
  k_transpose<<<dim3(4,4,HG),256,0,stream>>>(gat_W, WT0, 256, 65536, 256);
  k_transpose<<<dim3(4,32,1),256,0,stream>>>(gat_Wo, WoT, 2048, 0, 2048);
  k_transpose4<<<dim3(4,4,4),256,0,stream>>>(ca_Wq, ca_Wk, ca_Wv, ca_Wp, WQT);
  k_transp_split<<<dim3(4,4,1),256,0,stream>>>(sim_Wx, sWxh, sWxl);
  k_transp_split<<<dim3(4,4,1),256,0,stream>>>(adj_W, aWh, aWl);

  hipMemsetAsync(pq, 0, (2048+16)*sizeof(float), stream);
  hipMemsetAsync(pdot, 0, BN*sizeof(float), stream);
  k_posq<<<dim3(BB,16),256,0,stream>>>(x, mask, pq, cnt);
  k_sq<<<BB,256,0,stream>>>(pq, cnt, sim_Wq, sq);
  k_msgemm<5><<<dim3(4,128),256,0,stream>>>(xh, xl, sWxh, sWxl, nullptr, nullptr, nullptr, sq, pdot); // y-dot fold
  k_simsel2<<<BN/256,256,0,stream>>>(pdot, simOut, sel8);
  k_msgemm<4><<<dim3(4,128),256,0,stream>>>(xh, xl, aWh, aWl, nullptr, fah, fal, nullptr, nullptr);   // fa gram-packed
  k_mconnect2<<<dim3(136,1,BB),256,0,stream>>>(fah, fal, sel8, conn);

  if (big){
    u16* WhP   = (u16*)(W + 66*MB);   // attention-packed Wh_cat, 32MB
    u16* htcat = (u16*)(W + 34*MB);   // fragment-packed (gpK 2048) ht_cat, 32MB
    u16* S0P   = (u16*)(W + 22*MB);   // attention-packed Who, 4MB (fah dead after mconnect)
    u16* qx = (u16*)(W + 34*MB);      // after htcat consumed
    u16* kv = (u16*)(W + 38*MB);
    u16* qb = (u16*)(W + 42*MB);
    u16* vb = (u16*)(W + 50*MB);
    u16* Ob = (u16*)(W + 54*MB);

    hipMemsetAsync(s1a, 0, 512*1024, stream);  // s1a(256K) + s2a(256K) contiguous
    k_mgemm<7,1,1><<<dim3(32,128),256,0,stream>>>(xh, WT0, 256, 256, 0, nullptr, nullptr, nullptr, nullptr,
                                                  WhP, gat_a1, gat_a2, s1a, s2a);  // WhP pack + s1s2 fold
    k_rowmax<<<dim3(BN/4,HG),256,0,stream>>>(s2a, conn, M2a);
    k_mattn5<4,true,2048><<<dim3(1,128,HG),256,0,stream>>>(s1a, s2a, M2a, conn, WhP, 256, htcat, 2048);
    hipMemsetAsync(s1a, 0, BN*sizeof(float), stream);
    hipMemsetAsync(s2a, 0, BN*sizeof(float), stream);
    k_mgemm<8,1,1><<<dim3(4,128),256,0,stream>>>(htcat, WoT, 2048, 2048, 0, nullptr, nullptr, nullptr, nullptr,
                                                 S0P, gat_ao1, gat_ao2, s1a, s2a);  // S0P pack + s1s2 fold
    k_rowmax<<<dim3(BN/4,1),256,0,stream>>>(s2a, conn, M2a);
    k_mattn5<1,false,0><<<dim3(4,128,1),256,0,stream>>>(s1a, s2a, M2a, conn, S0P, 0, T2, 256);  // gout

    k_ln_x<<<BN/4,256,0,stream>>>(x, ln3_g, ln3_b, qx);
    k_ln_kv<<<BN/4,256,0,stream>>>(T2, pe, sel8, ln4_g, ln4_b, kv);
    k_mgemm3<<<dim3(4,128,3),256,0,stream>>>(qx, kv, WQT, qb);     // qb,kb,vb (stride 4MB)
    k_mca_av2<<<dim3(16,HC,BB),256,0,stream>>>(qb, qb + 2097152, vb, sel8, Ob);
    k_mgemm<2,1,1><<<dim3(4,128),256,0,stream>>>(Ob, WPT, 256, 256, 0, out, x, gamma, nullptr, nullptr,
                                                 nullptr, nullptr, nullptr, nullptr);
  } else {
    // small-ws fallback: per-head loop, packed kernels (rarely taken)
    u16* T0 = fah;
    u16* T1 = fal;
    u16* S0b = (u16*)S0;
    hipMemsetAsync(s1a, 0, 512*1024, stream);
    for (int h=0;h<HG;h++){
      hipMemsetAsync(s1a, 0, BN*sizeof(float), stream);
      hipMemsetAsync(s2a, 0, BN*sizeof(float), stream);
      k_mgemm<8,1,1><<<dim3(4,128),256,0,stream>>>(xh, WT0 + (size_t)h*65536, 256, 256, 0,
                                                   nullptr, nullptr, nullptr, nullptr, T0,
                                                   gat_a1 + h*DD, gat_a2 + h*DD, s1a, s2a);
      k_rowmax<<<dim3(BN/4,1),256,0,stream>>>(s2a, conn, M2a);
      k_mattn5<1,false,0><<<dim3(4,128,1),256,0,stream>>>(s1a, s2a, M2a, conn, T0, 0, T1, 256);
      k_mgemm<1,0,1><<<dim3(4,128),256,0,stream>>>(T1, WoT, 256, 2048, h*256, S0, nullptr, nullptr, nullptr, nullptr,
                                                   nullptr, nullptr, nullptr, nullptr);
    }
    hipMemsetAsync(s1a, 0, BN*sizeof(float), stream);
    hipMemsetAsync(s2a, 0, BN*sizeof(float), stream);
    k_mattn5<1,false,0><<<dim3(4,128,1),256,0,stream>>>(s1a, s2a, M2a, conn, (u16*)S0, 0, T2, 256);
    k_ln_x<<<BN/4,256,0,stream>>>(x, ln3_g, ln3_b, T1);
    k_ln_kv<<<BN/4,256,0,stream>>>(T2, pe, sel8, ln4_g, ln4_b, T0);
    k_mgemm3<<<dim3(4,128,3),256,0,stream>>>(T1, T0, WQT, S0b);
    k_mca_av2<<<dim3(16,HC,BB),256,0,stream>>>(S0b, S0b + 2097152, S0b + 4194304, sel8, T0);
    k_mgemm<2,1,1><<<dim3(4,128),256,0,stream>>>(T0, WPT, 256, 256, 0, out, x, gamma, nullptr, nullptr,
                                                 nullptr, nullptr, nullptr, nullptr);
  }
}

// Round 13
// 510.267 us; speedup vs baseline: 1.0641x; 1.0641x over previous
//
#include <hip/hip_runtime.h>
#include <hip/hip_bf16.h>

// GATFusionBlockPosOnly: B=8, N=1024, D=256, 8 GAT heads, 4 CA heads.
// Round 22:
//  - R21 post-mortem: double-buffered V prefetch (vf+vfn, +32 VGPR) SPILLED —
//    FETCH +5MB / WRITE +11MB scratch traffic, 80->92us. Reverted.
//  - Single-copy early issue instead: load chunk k's V fragments at TOP of
//    iteration k (before P-build), consume after barrier. Same 16 VGPRs as the
//    late load; live range covers P-build (~140cy) + barrier -> L2 latency hidden
//    with zero extra registers.

#define BB 8
#define NN 1024
#define DD 256
#define HG 8
#define HC 4
#define BN (BB*NN)

typedef unsigned short u16;
typedef unsigned int u32;
typedef unsigned char u8;
typedef __attribute__((ext_vector_type(8))) short s8v;   // 8 bf16
typedef __attribute__((ext_vector_type(4))) float f4v;   // 4 fp32 acc
#define MFMA(a,b,c) __builtin_amdgcn_mfma_f32_16x16x32_bf16((a),(b),(c),0,0,0)

__device__ __forceinline__ u16 f2b(float x){
  union{ float f; unsigned u; } a; a.f = x;
  unsigned r = a.u + 0x7fff + ((a.u>>16)&1);
  return (u16)(r>>16);
}
__device__ __forceinline__ float b2f(u16 b){ return __uint_as_float(((unsigned)b)<<16); }
__device__ __forceinline__ float4 ld4bf(const u16* p){
  uint2 u = *(const uint2*)p;
  float4 r;
  r.x=__uint_as_float(u.x<<16); r.y=__uint_as_float(u.x&0xffff0000u);
  r.z=__uint_as_float(u.y<<16); r.w=__uint_as_float(u.y&0xffff0000u);
  return r;
}
__device__ __forceinline__ void load8(const float* p, float* v){
  float4 a=*(const float4*)p, b=*(const float4*)(p+4);
  v[0]=a.x;v[1]=a.y;v[2]=a.z;v[3]=a.w;v[4]=b.x;v[5]=b.y;v[6]=b.z;v[7]=b.w;
}
__device__ __forceinline__ float wredsum(float v){
  #pragma unroll
  for(int o=32;o>0;o>>=1) v += __shfl_xor(v,o);
  return v;
}
__device__ __forceinline__ float wredmax(float v){
  #pragma unroll
  for(int o=32;o>0;o>>=1) v = fmaxf(v,__shfl_xor(v,o));
  return v;
}
__device__ __forceinline__ float eluf(float x){ return x>0.f ? x : __expf(x)-1.f; }
__device__ __forceinline__ float leakyf(float z){ return z>=0.f ? z : 0.2f*z; }
__device__ __forceinline__ float exp0(float a){ return __expf(fminf(a, 0.f)); }
__device__ __forceinline__ float flushf(float v){ return (fabsf(v) < 1.0e30f) ? v : 0.f; }
__device__ __forceinline__ u32 pk2(float lo, float hi){
  u32 r;
  asm("v_cvt_pk_bf16_f32 %0, %1, %2" : "=v"(r) : "v"(lo), "v"(hi));
  return r;
}

// packed index for element (col, m) of the attention-V pack:  b=m>>10, kk=m&1023
__device__ __forceinline__ size_t packIdx(int col, int row){
  int kk = row & 1023;
  return ((((size_t)(col>>4))*8 + (row>>10))*32 + (kk>>5))*512
       + (size_t)(((((kk>>3)&3)*16) + (col&15))*8 + (kk&7));
}

// fragment-pack: element (row, k) of a [rows][KK] operand -> fragment order.
__device__ __forceinline__ size_t gpK(int row, int k, int KK){
  return (size_t)(row>>4)*((size_t)16*KK) + (size_t)(k>>5)*512
       + (size_t)(((((k>>3)&3)*16) + (row&15))*8 + (k&7));
}

// ---------- fp32 -> (hi,lo) bf16 split, packed output (gpK, KK=256) ----------
__global__ __launch_bounds__(256) void k_split(const float* __restrict__ X, u16* __restrict__ H, u16* __restrict__ Lo){
  size_t i = ((size_t)blockIdx.x*256 + threadIdx.x)*8;
  float v[8]; load8(X+i, v);
  u16 hh[8], ll[8];
  #pragma unroll
  for (int j=0;j<8;j++){ hh[j]=f2b(v[j]); ll[j]=f2b(v[j]-b2f(hh[j])); }
  int row = (int)(i>>8), col = (int)(i&255);
  size_t off = gpK(row, col, 256);
  *(uint4*)(H+off)=*(uint4*)&hh[0];
  *(uint4*)(Lo+off)=*(uint4*)&ll[0];
}

// ---------- transpose fp32 [R][C] -> bf16; pkKK=0: row-major [C][R]; else gpK packed ----------
__global__ __launch_bounds__(256) void k_transpose(const float* __restrict__ S, u16* __restrict__ D,
                                                   int R, int sliceElems, int pkKK){
  __shared__ float tl[64][65];
  const float* src = S + (size_t)blockIdx.z*sliceElems;
  u16* dst = D + (size_t)blockIdx.z*sliceElems;
  int C = gridDim.x*64;
  int bx=blockIdx.x*64, by=blockIdx.y*64;
  int tid=threadIdx.x, r=tid>>2, c0=(tid&3)*16;
  #pragma unroll
  for (int i=0;i<16;i+=4){
    float4 v = *(const float4*)(src + (size_t)(by+r)*C + bx + c0 + i);
    tl[r][c0+i]=v.x; tl[r][c0+i+1]=v.y; tl[r][c0+i+2]=v.z; tl[r][c0+i+3]=v.w;
  }
  __syncthreads();
  u16 tmp[16];
  #pragma unroll
  for (int i=0;i<16;i++) tmp[i] = f2b(tl[c0+i][r]);
  if (pkKK){
    *(uint4*)(dst + gpK(bx+r, by+c0,     pkKK)) = *(uint4*)&tmp[0];
    *(uint4*)(dst + gpK(bx+r, by+c0+8,   pkKK)) = *(uint4*)&tmp[8];
  } else {
    *(uint4*)(dst + (size_t)(bx+r)*R + by + c0)     = *(uint4*)&tmp[0];
    *(uint4*)(dst + (size_t)(bx+r)*R + by + c0 + 8) = *(uint4*)&tmp[8];
  }
}

// ---------- 4x 256x256 transposes, PACKED (gpK 256) output; grid (4,4,4) ----------
__global__ __launch_bounds__(256) void k_transpose4(const float* __restrict__ Sa, const float* __restrict__ Sb,
    const float* __restrict__ Sc, const float* __restrict__ Sd, u16* __restrict__ D){
  __shared__ float tl[64][65];
  const float* src = blockIdx.z==0 ? Sa : blockIdx.z==1 ? Sb : blockIdx.z==2 ? Sc : Sd;
  u16* dst = D + (size_t)blockIdx.z*65536;
  int bx=blockIdx.x*64, by=blockIdx.y*64;
  int tid=threadIdx.x, r=tid>>2, c0=(tid&3)*16;
  #pragma unroll
  for (int i=0;i<16;i+=4){
    float4 v = *(const float4*)(src + (size_t)(by+r)*256 + bx + c0 + i);
    tl[r][c0+i]=v.x; tl[r][c0+i+1]=v.y; tl[r][c0+i+2]=v.z; tl[r][c0+i+3]=v.w;
  }
  __syncthreads();
  u16 tmp[16];
  #pragma unroll
  for (int i=0;i<16;i++) tmp[i] = f2b(tl[c0+i][r]);
  *(uint4*)(dst + gpK(bx+r, by+c0,   256)) = *(uint4*)&tmp[0];
  *(uint4*)(dst + gpK(bx+r, by+c0+8, 256)) = *(uint4*)&tmp[8];
}

// ---------- transpose + split: fp32 [256][256] -> hi/lo bf16 PACKED (gpK 256) ----------
__global__ __launch_bounds__(256) void k_transp_split(const float* __restrict__ S, u16* __restrict__ DH, u16* __restrict__ DL){
  __shared__ float tl[64][65];
  int bx=blockIdx.x*64, by=blockIdx.y*64;
  int tid=threadIdx.x, r=tid>>2, c0=(tid&3)*16;
  #pragma unroll
  for (int i=0;i<16;i+=4){
    float4 v = *(const float4*)(S + (size_t)(by+r)*256 + bx + c0 + i);
    tl[r][c0+i]=v.x; tl[r][c0+i+1]=v.y; tl[r][c0+i+2]=v.z; tl[r][c0+i+3]=v.w;
  }
  __syncthreads();
  u16 th[16], tll[16];
  #pragma unroll
  for (int i=0;i<16;i++){
    float v = tl[c0+i][r];
    th[i]=f2b(v); tll[i]=f2b(v - b2f(th[i]));
  }
  size_t o0 = gpK(bx+r, by+c0,   256);
  size_t o1 = gpK(bx+r, by+c0+8, 256);
  *(uint4*)(DH + o0) = *(uint4*)&th[0];
  *(uint4*)(DH + o1) = *(uint4*)&th[8];
  *(uint4*)(DL + o0) = *(uint4*)&tll[0];
  *(uint4*)(DL + o1) = *(uint4*)&tll[8];
}

// ---------- pos_query ----------
__global__ __launch_bounds__(256) void k_posq(const float* __restrict__ x, const int* __restrict__ mask,
                                              float* __restrict__ pq, float* __restrict__ cnt){
  int b = blockIdx.x, chunk = blockIdx.y;
  int d = threadIdx.x;
  int n0 = chunk*64;
  float acc = 0.f; float c = 0.f;
  for (int i=0;i<64;i++){
    int n = n0+i;
    if (mask[b*NN+n]==1){ acc += x[((size_t)(b*NN+n))*DD + d]; c += 1.f; }
  }
  atomicAdd(&pq[b*DD+d], acc);
  if (d==0) atomicAdd(&cnt[b], c);
}

__global__ __launch_bounds__(256) void k_sq(const float* __restrict__ pq, const float* __restrict__ cnt,
                                            const float* __restrict__ Wq, float* __restrict__ sq){
  int b = blockIdx.x, e = threadIdx.x;
  float inv = 1.f / fmaxf(cnt[b], 1.f);
  float acc=0.f;
  for (int d0=0; d0<DD; d0++) acc += (pq[b*DD+d0]*inv) * Wq[d0*DD+e];
  sq[b*DD+e] = acc;
}

// ---------- sigmoid + threshold from folded dot ----------
__global__ __launch_bounds__(256) void k_simsel2(const float* __restrict__ pdot,
                                                 float* __restrict__ simOut, u8* __restrict__ sel8){
  int r = blockIdx.x*256 + threadIdx.x;
  float s = pdot[r] * 0.0625f;
  float sim = 1.f/(1.f+expf(-s));
  simOut[r] = sim;
  sel8[r] = (sim > 0.97f) ? 1 : 0;
}

// ---------- no-LDS MFMA GEMM: out[8192, OC] = A[8192,KK] @ BT[OC,KK]^T ----------
// APK: A fragment-packed (gpK, KK). BPK: BT fragment-packed (gpK, ldB total K; kOff = K start).
// EPI: 0=C fp32, 1=C+=, 2=residual+gamma, 3=O bf16,
//      7=Pk pack + s1/s2 fold (head=colBase>>8), 8=Pk pack + s1/s2 fold (single head)
template<int EPI, int APK, int BPK>
__global__ __launch_bounds__(256) void k_mgemm(const u16* __restrict__ A, const u16* __restrict__ BT,
    int KK, int ldB, int kOff, float* __restrict__ C, const float* __restrict__ Xres,
    const float* __restrict__ gamma, u16* __restrict__ O, u16* __restrict__ Pk,
    const float* __restrict__ A1, const float* __restrict__ A2,
    float* __restrict__ s1g, float* __restrict__ s2g){
  int tid=threadIdx.x, w=tid>>6, lane=tid&63, L=lane&15, q=lane>>4;
  int OC = gridDim.x<<6;
  int colBase=blockIdx.x<<6, rowBase=blockIdx.y<<6;
  const u16* ap;
  if constexpr (APK) ap = A + (size_t)((rowBase>>4)+w)*((size_t)16*KK) + (size_t)lane*8;
  else               ap = A + (size_t)(rowBase + w*16 + L)*KK + q*8;
  const u16* bp[4];
  #pragma unroll
  for (int t=0;t<4;t++){
    if constexpr (BPK) bp[t] = BT + (size_t)((colBase>>4)+t)*((size_t)16*ldB) + (size_t)(kOff>>5)*512 + (size_t)lane*8;
    else               bp[t] = BT + (size_t)(colBase + t*16 + L)*ldB + q*8 + kOff;
  }
  f4v z4={0.f,0.f,0.f,0.f};
  f4v acc[4]={z4,z4,z4,z4};
  int nk = KK>>5;
  for (int kc=0;kc<nk;kc++){
    s8v a0;
    if constexpr (APK) a0 = *(const s8v*)(ap + (size_t)kc*512);
    else               a0 = *(const s8v*)(ap + kc*32);
    #pragma unroll
    for (int t=0;t<4;t++){
      s8v bt;
      if constexpr (BPK) bt = *(const s8v*)(bp[t] + (size_t)kc*512);
      else               bt = *(const s8v*)(bp[t] + kc*32);
      acc[t]=MFMA(a0,bt,acc[t]);
    }
  }
  if constexpr (EPI<=3){
    #pragma unroll
    for (int t=0;t<4;t++){
      int col = colBase + t*16 + L;
      #pragma unroll
      for (int reg=0;reg<4;reg++){
        int row = rowBase + w*16 + q*4 + reg;
        size_t off = (size_t)row*OC + col;
        float v = acc[t][reg];
        if constexpr (EPI==0){ C[off] = v; }
        else if constexpr (EPI==1){ C[off] += v; }
        else if constexpr (EPI==2){ C[off] = flushf(Xres[off] + gamma[col]*v); }
        else { O[off] = f2b(v); }
      }
    }
  } else {
    // s1/s2 fold
    float s1p[4]={0.f,0.f,0.f,0.f}, s2p[4]={0.f,0.f,0.f,0.f};
    #pragma unroll
    for (int t=0;t<4;t++){
      int col = colBase + t*16 + L;
      float a1v = A1[col], a2v = A2[col];
      #pragma unroll
      for (int reg=0;reg<4;reg++){
        float v = acc[t][reg];
        s1p[reg] += v*a1v;
        s2p[reg] += v*a2v;
      }
    }
    #pragma unroll
    for (int off=1;off<16;off<<=1)
      #pragma unroll
      for (int reg=0;reg<4;reg++){
        s1p[reg] += __shfl_xor(s1p[reg],off);
        s2p[reg] += __shfl_xor(s2p[reg],off);
      }
    if (L==0){
      int sOff = (EPI==7) ? (colBase>>8)*BN : 0;
      #pragma unroll
      for (int reg=0;reg<4;reg++){
        int row = rowBase + w*16 + q*4 + reg;
        atomicAdd(&s1g[sOff+row], s1p[reg]);
        atomicAdd(&s2g[sOff+row], s2p[reg]);
      }
    }
    // coalesced pack store (16B per lane, 8 consecutive rows of one column)
    int pq_ = q&1;
    int m0 = rowBase + w*16 + (q>>1)*8;
    #pragma unroll
    for (int tp=0;tp<2;tp++){
      f4v accA = acc[2*tp], accB = acc[2*tp+1];
      f4v mine   = pq_ ? accB : accA;
      f4v theirs = pq_ ? accA : accB;
      u32 k0 = pk2(mine[0],  mine[1]);
      u32 k1 = pk2(mine[2],  mine[3]);
      u32 s0 = pk2(theirs[0],theirs[1]);
      u32 s1 = pk2(theirs[2],theirs[3]);
      u32 r0 = (u32)__shfl_xor((int)s0,16);
      u32 r1 = (u32)__shfl_xor((int)s1,16);
      uint4 val = pq_==0 ? make_uint4(k0,k1,r0,r1) : make_uint4(r0,r1,k0,k1);
      int t = 2*tp + pq_;
      int col = colBase + t*16 + L;
      *(uint4*)(Pk + packIdx(col, m0)) = val;
    }
  }
}

// ---------- fused q/k/v projections, packed A (gpK 256) and B (gpK 256) ----------
__global__ __launch_bounds__(256) void k_mgemm3(const u16* __restrict__ Aq, const u16* __restrict__ Akv,
    const u16* __restrict__ BT0, u16* __restrict__ O0){
  int tid=threadIdx.x, w=tid>>6, lane=tid&63, L=lane&15, q=lane>>4;
  const u16* A = blockIdx.z==0 ? Aq : Akv;
  const u16* BT = BT0 + (size_t)blockIdx.z*65536;
  u16* O = O0 + (size_t)blockIdx.z*2097152;
  int colBase=blockIdx.x<<6, rowBase=blockIdx.y<<6;
  const u16* ap = A + (size_t)((rowBase>>4)+w)*4096 + (size_t)lane*8;
  f4v z4={0.f,0.f,0.f,0.f};
  f4v acc[4]={z4,z4,z4,z4};
  #pragma unroll
  for (int kc=0;kc<8;kc++){
    s8v a0 = *(const s8v*)(ap + kc*512);
    #pragma unroll
    for (int t=0;t<4;t++){
      s8v bt = *(const s8v*)(BT + (size_t)((colBase>>4)+t)*4096 + (size_t)kc*512 + (size_t)lane*8);
      acc[t]=MFMA(a0,bt,acc[t]);
    }
  }
  #pragma unroll
  for (int t=0;t<4;t++){
    int col = colBase + t*16 + L;
    #pragma unroll
    for (int reg=0;reg<4;reg++){
      int row = rowBase + w*16 + q*4 + reg;
      O[(size_t)row*256 + col] = f2b(acc[t][reg]);
    }
  }
}

// ---------- split (3-term) MFMA GEMM, packed A and B (gpK 256): KK=256, OC=256 ----------
// EPI 4: hi/lo bf16 gram-packed out.  EPI 5: sq-dot fold -> pdot.
template<int EPI>
__global__ __launch_bounds__(256) void k_msgemm(const u16* __restrict__ Ah, const u16* __restrict__ Al,
    const u16* __restrict__ Bh, const u16* __restrict__ Bl,
    float* __restrict__ C, u16* __restrict__ Oh, u16* __restrict__ Ol,
    const float* __restrict__ sq, float* __restrict__ pdot){
  int tid=threadIdx.x, w=tid>>6, lane=tid&63, L=lane&15, q=lane>>4;
  int colBase=blockIdx.x<<6, rowBase=blockIdx.y<<6;
  const u16* ahp = Ah + (size_t)((rowBase>>4)+w)*4096 + (size_t)lane*8;
  const u16* alp = Al + (size_t)((rowBase>>4)+w)*4096 + (size_t)lane*8;
  f4v z4={0.f,0.f,0.f,0.f};
  f4v acc[4]={z4,z4,z4,z4};
  #pragma unroll
  for (int kc=0;kc<8;kc++){
    s8v ah=*(const s8v*)(ahp + kc*512), al=*(const s8v*)(alp + kc*512);
    #pragma unroll
    for (int t=0;t<4;t++){
      size_t boff = (size_t)((colBase>>4)+t)*4096 + (size_t)kc*512 + (size_t)lane*8;
      s8v bh=*(const s8v*)(Bh + boff);
      s8v bl=*(const s8v*)(Bl + boff);
      acc[t]=MFMA(ah,bh,acc[t]);
      acc[t]=MFMA(ah,bl,acc[t]);
      acc[t]=MFMA(al,bh,acc[t]);
    }
  }
  if constexpr (EPI==5){
    int b = rowBase>>10;
    float pp[4]={0.f,0.f,0.f,0.f};
    #pragma unroll
    for (int t=0;t<4;t++){
      int col = colBase + t*16 + L;
      float qv = sq[b*256 + col];
      #pragma unroll
      for (int reg=0;reg<4;reg++) pp[reg] += acc[t][reg]*qv;
    }
    #pragma unroll
    for (int off=1;off<16;off<<=1)
      #pragma unroll
      for (int reg=0;reg<4;reg++) pp[reg] += __shfl_xor(pp[reg],off);
    if (L==0){
      #pragma unroll
      for (int reg=0;reg<4;reg++){
        int row = rowBase + w*16 + q*4 + reg;
        atomicAdd(&pdot[row], pp[reg]);
      }
    }
  } else {
    #pragma unroll
    for (int t=0;t<4;t++){
      int col = colBase + t*16 + L;
      #pragma unroll
      for (int reg=0;reg<4;reg++){
        int row = rowBase + w*16 + q*4 + reg;
        float v = acc[t][reg];
        if constexpr (EPI==0){ C[(size_t)row*256 + col] = v; }
        else {
          size_t off = gpK(row, col, 256);
          u16 h = f2b(v); Oh[off]=h; Ol[off]=f2b(v - b2f(h));
        }
      }
    }
  }
}

// ---------- gram + bitpack v2: packed fragments, symmetric tile enumeration ----------
__global__ __launch_bounds__(256) void k_mconnect2(const u16* __restrict__ fahP, const u16* __restrict__ falP,
    const u8* __restrict__ sel8, u32* __restrict__ conn){
  __shared__ u8 sg[64][64];
  __shared__ u8 selI[64], selJ[64];
  int tid=threadIdx.x, w=tid>>6, lane=tid&63, L=lane&15, q=lane>>4;
  int b=blockIdx.z;
  int p=blockIdx.x;
  int i = (int)((sqrtf(8.f*p+1.f)-1.f)*0.5f);
  while ((i+1)*(i+2)/2 <= p) i++;
  while (i*(i+1)/2 > p) i--;
  int j = p - i*(i+1)/2;          // i >= j, both 0..15
  if (tid < 64)        selI[tid]     = sel8[b*NN + i*64 + tid];
  else if (tid < 128)  selJ[tid-64]  = sel8[b*NN + j*64 + (tid-64)];
  const u16* ah0 = fahP + ((size_t)(b*64 + i*4 + w))*4096 + (size_t)lane*8;
  const u16* al0 = falP + ((size_t)(b*64 + i*4 + w))*4096 + (size_t)lane*8;
  const u16* bh0 = fahP + ((size_t)(b*64 + j*4))*4096 + (size_t)lane*8;
  const u16* bl0 = falP + ((size_t)(b*64 + j*4))*4096 + (size_t)lane*8;
  f4v z4={0.f,0.f,0.f,0.f};
  f4v acc[4]={z4,z4,z4,z4};
  #pragma unroll
  for (int kc=0;kc<8;kc++){
    s8v ah = *(const s8v*)(ah0 + kc*512);
    s8v al = *(const s8v*)(al0 + kc*512);
    #pragma unroll
    for (int t=0;t<4;t++){
      s8v bh = *(const s8v*)(bh0 + (size_t)t*4096 + kc*512);
      s8v bl = *(const s8v*)(bl0 + (size_t)t*4096 + kc*512);
      acc[t]=MFMA(ah,bh,acc[t]);
      acc[t]=MFMA(ah,bl,acc[t]);
      acc[t]=MFMA(al,bh,acc[t]);
    }
  }
  #pragma unroll
  for (int t=0;t<4;t++)
    #pragma unroll
    for (int reg=0;reg<4;reg++)
      sg[w*16 + q*4 + reg][t*16 + L] = acc[t][reg] > 0.f;
  __syncthreads();
  int row=(tid&127)>>1, ww=tid&1;
  if (tid<128){
    u32 word=0;
    if (selI[row]){
      #pragma unroll 8
      for (int jj=0;jj<32;jj++)
        if (sg[row][ww*32+jj] && selJ[ww*32+jj]) word |= (1u<<jj);
    }
    conn[((size_t)b*NN + i*64+row)*32 + j*2 + ww] = word;
  } else if (i != j){
    u32 word=0;
    if (selJ[row]){
      #pragma unroll 8
      for (int jj=0;jj<32;jj++)
        if (sg[ww*32+jj][row] && selI[ww*32+jj]) word |= (1u<<jj);
    }
    conn[((size_t)b*NN + j*64+row)*32 + i*2 + ww] = word;
  }
}

// ---------- row max of s2 over connected m ----------
__global__ __launch_bounds__(256) void k_rowmax(const float* __restrict__ s2a,
    const u32* __restrict__ conn, float* __restrict__ M2a){
  int h = blockIdx.y;
  int r = blockIdx.x*4 + (threadIdx.x>>6);
  int lane = threadIdx.x&63;
  int b = r>>10;
  const float* s2p = s2a + h*BN + b*NN;
  float mx = -3.0e38f;
  #pragma unroll
  for (int t=0;t<16;t++){
    int m = lane + t*64;
    u32 wd = conn[(size_t)r*32 + (m>>5)];
    if ((wd>>(m&31))&1u) mx = fmaxf(mx, s2p[m]);
  }
  mx = wredmax(mx);
  if (lane==0) M2a[h*BN+r] = mx;
}

// ---------- MFMA GAT attention v8: P shared via LDS; V loaded EARLY (single copy) ----------
// PKO: 0 = row-major output (stride oStride); else fragment-packed gpK(row,col,PKO).
template<int CT, bool SWZ, int PKO>
__global__ __launch_bounds__(256,4) void k_mattn5(const float* __restrict__ s1a, const float* __restrict__ s2a,
    const float* __restrict__ M2a, const u32* __restrict__ conn,
    const u16* __restrict__ P, int headMul, u16* __restrict__ Out, int oStride){
  __shared__ __align__(16) u16 Pb[2][4][512];
  __shared__ float Srow[64];
  int tid=threadIdx.x, w=tid>>6, lane=tid&63, L=lane&15, q=lane>>4;
  int h, rowBlk;
  if constexpr (SWZ){ h = blockIdx.y & 7; rowBlk = (blockIdx.y>>3) + (blockIdx.z<<4); }
  else             { h = blockIdx.z;     rowBlk = blockIdx.y; }
  int rowBase = rowBlk*64;
  int hOff = h*headMul, sOff = h*BN;
  int b = rowBase>>10;
  size_t bOff = (size_t)b*NN;
  int r = rowBase + w*16 + L;             // own row for P-build
  float s1v = s1a[sOff+r];
  float rmv = leakyf(s1v + M2a[sOff+r]);
  const float* s2p = s2a + sOff + bOff;
  const u32* cp = conn + (size_t)r*32;
  int tile0 = blockIdx.x*(4*CT) + w*CT;   // first col-tile owned by this wave
  const u16* vp = P + (size_t)((hOff>>4) + tile0)*131072 + (size_t)b*16384 + (size_t)lane*8;
  f4v z4={0.f,0.f,0.f,0.f};
  f4v acc[4][CT];
  #pragma unroll
  for (int g=0;g<4;g++)
    #pragma unroll
    for (int t=0;t<CT;t++) acc[g][t]=z4;
  float sumP = 0.f;
  for (int k0=0;k0<NN;k0+=32){
    int cur=(k0>>5)&1;
    u32 cw = cp[k0>>5];
    // issue THIS chunk's V loads first — latency hidden under P-build + barrier
    s8v vf[CT];
    {
      const u16* vk = vp + (size_t)(k0>>5)*512;
      #pragma unroll
      for (int t=0;t<CT;t++) vf[t] = *(const s8v*)(vk + (size_t)t*131072);
    }
    float4 sA = *(const float4*)(s2p + k0 + q*8);
    float4 sB = *(const float4*)(s2p + k0 + q*8 + 4);
    float s2v[8] = {sA.x,sA.y,sA.z,sA.w,sB.x,sB.y,sB.z,sB.w};
    float p[8];
    #pragma unroll
    for (int j=0;j<8;j++){
      float z = s1v + s2v[j];
      float ev = fmaxf(z, 0.2f*z);                      // leaky = max(z, 0.2z)
      ev = ((cw>>(q*8+j))&1u) ? ev : -9.0e15f;          // mask BEFORE exp (uniform rows!)
      p[j] = __expf(fminf(ev - rmv, 0.f));
      sumP += p[j];
    }
    union{ s8v v; u32 u[4]; } pk;
    #pragma unroll
    for (int jj=0;jj<4;jj++)
      pk.u[jj] = pk2(p[2*jj], p[2*jj+1]);
    *(s8v*)&Pb[cur][w][lane*8] = pk.v;    // ds_write_b128, contiguous
    __syncthreads();                       // all P fragments for this chunk visible
    s8v pa[4];
    #pragma unroll
    for (int g=0;g<4;g++) pa[g] = *(const s8v*)&Pb[cur][g][lane*8];
    #pragma unroll
    for (int t=0;t<CT;t++)
      #pragma unroll
      for (int g=0;g<4;g++) acc[g][t] = MFMA(pa[g], vf[t], acc[g][t]);
  }
  sumP += __shfl_xor(sumP,16);
  sumP += __shfl_xor(sumP,32);
  if (lane<16) Srow[w*16+lane] = sumP;
  __syncthreads();
  #pragma unroll
  for (int g=0;g<4;g++){
    float4 sv = *(const float4*)&Srow[g*16 + q*4];
    float rsi[4] = {1.f/sv.x, 1.f/sv.y, 1.f/sv.z, 1.f/sv.w};
    #pragma unroll
    for (int t=0;t<CT;t++){
      int col = hOff + (tile0+t)*16 + L;
      #pragma unroll
      for (int reg=0;reg<4;reg++){
        int row = rowBase + g*16 + q*4 + reg;
        float ov = eluf(acc[g][t][reg]*rsi[reg]);
        if constexpr (PKO) Out[gpK(row, col, PKO)] = f2b(ov);
        else               Out[(size_t)row*oStride + col] = f2b(ov);
      }
    }
  }
}

// ---------- LayerNorms (packed gpK-256 output) ----------
__global__ __launch_bounds__(256) void k_ln_x(const float* __restrict__ x, const float* __restrict__ g,
                                              const float* __restrict__ bb, u16* __restrict__ out){
  int r = blockIdx.x*4 + (threadIdx.x>>6);
  int lane=threadIdx.x&63;
  float4 v = *(const float4*)(x + (size_t)r*DD + lane*4);
  float s = v.x+v.y+v.z+v.w;
  float s2 = v.x*v.x+v.y*v.y+v.z*v.z+v.w*v.w;
  s = wredsum(s); s2 = wredsum(s2);
  float mean = s*(1.f/256.f);
  float var = s2*(1.f/256.f) - mean*mean;
  float rstd = rsqrtf(var + 1e-5f);
  float4 gv = *(const float4*)(g+lane*4), bv = *(const float4*)(bb+lane*4);
  u16 t[4];
  t[0]=f2b((v.x-mean)*rstd*gv.x+bv.x); t[1]=f2b((v.y-mean)*rstd*gv.y+bv.y);
  t[2]=f2b((v.z-mean)*rstd*gv.z+bv.z); t[3]=f2b((v.w-mean)*rstd*gv.w+bv.w);
  *(uint2*)(out + gpK(r, lane*4, 256)) = *(uint2*)&t[0];
}

__global__ __launch_bounds__(256) void k_ln_kv(const u16* __restrict__ gout, const float* __restrict__ pe,
    const u8* __restrict__ sel8, const float* __restrict__ g, const float* __restrict__ bb,
    u16* __restrict__ out){
  int r = blockIdx.x*4 + (threadIdx.x>>6);
  int lane=threadIdx.x&63;
  int n = r & 1023;
  float4 v = make_float4(0.f,0.f,0.f,0.f);
  if (sel8[r]){
    float4 gv = ld4bf(gout + (size_t)r*DD + lane*4);
    float4 pv = *(const float4*)(pe + (size_t)n*DD + lane*4);
    v = make_float4(gv.x+pv.x, gv.y+pv.y, gv.z+pv.z, gv.w+pv.w);
  }
  float s = v.x+v.y+v.z+v.w;
  float s2 = v.x*v.x+v.y*v.y+v.z*v.z+v.w*v.w;
  s = wredsum(s); s2 = wredsum(s2);
  float mean = s*(1.f/256.f);
  float var = s2*(1.f/256.f) - mean*mean;
  float rstd = rsqrtf(var + 1e-5f);
  float4 gv = *(const float4*)(g+lane*4), bv = *(const float4*)(bb+lane*4);
  u16 t[4];
  t[0]=f2b((v.x-mean)*rstd*gv.x+bv.x); t[1]=f2b((v.y-mean)*rstd*gv.y+bv.y);
  t[2]=f2b((v.z-mean)*rstd*gv.z+bv.z); t[3]=f2b((v.w-mean)*rstd*gv.w+bv.w);
  *(uint2*)(out + gpK(r, lane*4, 256)) = *(uint2*)&t[0];
}

// ---------- CA attention, fused flash-style; Ob written fragment-packed (gpK 256) ----------
__global__ __launch_bounds__(256) void k_mca_av2(const u16* __restrict__ q, const u16* __restrict__ k,
    const u16* __restrict__ v, const u8* __restrict__ sel8, u16* __restrict__ O){
  __shared__ __align__(16) u16 Qls[64][72];
  __shared__ __align__(16) u16 KP[64][72];
  __shared__ __align__(16) u16 Vt[64][72];
  int tid=threadIdx.x;
  int w = tid>>6, lane = tid&63, L = lane&15, qd = lane>>4;
  int b=blockIdx.z, h=blockIdx.y, rowBase=blockIdx.x*64;
  size_t bOff = (size_t)b*NN;
  {
    int r=tid>>2, c0=(tid&3)*16;
    size_t base = (bOff + rowBase + r)*(size_t)DD + h*64 + c0;
    *(uint4*)&Qls[r][c0]   = *(const uint4*)(q + base);
    *(uint4*)&Qls[r][c0+8] = *(const uint4*)(q + base + 8);
  }
  float rm[4], sp[4];
  #pragma unroll
  for (int reg=0;reg<4;reg++){ rm[reg] = -3.0e38f; sp[reg] = 0.f; }
  f4v zero = {0.f,0.f,0.f,0.f};
  f4v acc[4] = {zero,zero,zero,zero};
  int svm = tid&63, svd0 = (tid>>6)*16;
  for (int m0=0;m0<NN;m0+=64){
    __syncthreads();
    {
      int r=tid>>2, c0=(tid&3)*16;
      size_t base = (bOff + m0 + r)*(size_t)DD + h*64 + c0;
      *(uint4*)&KP[r][c0]   = *(const uint4*)(k + base);
      *(uint4*)&KP[r][c0+8] = *(const uint4*)(k + base + 8);
      size_t vb_ = (bOff + m0 + svm)*(size_t)DD + h*64 + svd0;
      uint4 u0 = *(const uint4*)(v + vb_);
      uint4 u1 = *(const uint4*)(v + vb_ + 8);
      u16 tmp[16];
      *(uint4*)&tmp[0]=u0; *(uint4*)&tmp[8]=u1;
      #pragma unroll
      for (int i=0;i<16;i++) Vt[svd0+i][svm] = tmp[i];
    }
    __syncthreads();
    f4v sa[4] = {zero,zero,zero,zero};
    #pragma unroll
    for (int kc=0;kc<64;kc+=32){
      s8v af = *(const s8v*)&Qls[w*16 + L][kc + qd*8];
      #pragma unroll
      for (int t=0;t<4;t++){
        s8v bfr = *(const s8v*)&KP[t*16 + L][kc + qd*8];
        sa[t] = MFMA(af, bfr, sa[t]);
      }
    }
    __syncthreads();
    // online-softmax update (row-consistent max via L-group reduce)
    float vals[4][4];
    float tmax[4];
    #pragma unroll
    for (int reg=0;reg<4;reg++) tmax[reg] = -3.0e38f;
    #pragma unroll
    for (int t=0;t<4;t++){
      int m = m0 + t*16 + L;
      bool sl = sel8[b*NN+m];
      #pragma unroll
      for (int reg=0;reg<4;reg++){
        float val = sl ? sa[t][reg]*0.125f : -1.0e9f;
        vals[t][reg] = val;
        tmax[reg] = fmaxf(tmax[reg], val);
      }
    }
    #pragma unroll
    for (int off=1;off<16;off<<=1)
      #pragma unroll
      for (int reg=0;reg<4;reg++) tmax[reg] = fmaxf(tmax[reg], __shfl_xor(tmax[reg],off));
    float sc[4];
    #pragma unroll
    for (int reg=0;reg<4;reg++){
      float nm = fmaxf(rm[reg], tmax[reg]);
      sc[reg] = exp0(rm[reg] - nm);
      rm[reg] = nm;
      sp[reg] *= sc[reg];
    }
    #pragma unroll
    for (int t=0;t<4;t++){
      #pragma unroll
      for (int reg=0;reg<4;reg++){
        float pv = exp0(vals[t][reg] - rm[reg]);
        sp[reg] += pv;
        KP[w*16 + qd*4 + reg][t*16 + L] = f2b(pv);
      }
    }
    #pragma unroll
    for (int t=0;t<4;t++)
      #pragma unroll
      for (int reg=0;reg<4;reg++) acc[t][reg] *= sc[reg];
    __syncthreads();
    #pragma unroll
    for (int mc=0;mc<64;mc+=32){
      s8v pf = *(const s8v*)&KP[w*16 + L][mc + qd*8];
      #pragma unroll
      for (int t=0;t<4;t++){
        s8v vf = *(const s8v*)&Vt[t*16 + L][mc + qd*8];
        acc[t] = MFMA(pf, vf, acc[t]);
      }
    }
  }
  #pragma unroll
  for (int off=1;off<16;off<<=1)
    #pragma unroll
    for (int reg=0;reg<4;reg++) sp[reg] += __shfl_xor(sp[reg],off);
  float ri[4];
  #pragma unroll
  for (int reg=0;reg<4;reg++) ri[reg] = 1.f/sp[reg];
  #pragma unroll
  for (int t=0;t<4;t++){
    int col = h*64 + t*16 + L;
    #pragma unroll
    for (int reg=0;reg<4;reg++){
      int row = (int)bOff + rowBase + w*16 + qd*4 + reg;
      O[gpK(row, col, 256)] = f2b(acc[t][reg]*ri[reg]);
    }
  }
}

extern "C" void kernel_launch(void* const* d_in, const int* in_sizes, int n_in,
                              void* d_out, int out_size, void* d_ws, size_t ws_size,
                              hipStream_t stream) {
  (void)in_sizes; (void)n_in; (void)out_size;
  const float* x      = (const float*)d_in[0];
  const int*   mask   = (const int*  )d_in[1];
  const float* pe     = (const float*)d_in[2];
  const float* sim_Wx = (const float*)d_in[3];
  const float* sim_Wq = (const float*)d_in[4];
  const float* adj_W  = (const float*)d_in[5];
  const float* gat_W  = (const float*)d_in[6];
  const float* gat_a1 = (const float*)d_in[7];
  const float* gat_a2 = (const float*)d_in[8];
  const float* gat_Wo = (const float*)d_in[9];
  const float* gat_ao1= (const float*)d_in[10];
  const float* gat_ao2= (const float*)d_in[11];
  const float* ln3_g  = (const float*)d_in[12];
  const float* ln3_b  = (const float*)d_in[13];
  const float* ln4_g  = (const float*)d_in[14];
  const float* ln4_b  = (const float*)d_in[15];
  const float* ca_Wq  = (const float*)d_in[16];
  const float* ca_Wk  = (const float*)d_in[17];
  const float* ca_Wv  = (const float*)d_in[18];
  const float* ca_Wp  = (const float*)d_in[19];
  const float* gamma  = (const float*)d_in[20];
  float* out    = (float*)d_out;
  float* simOut = out + (size_t)BN*DD;

  const size_t MB = 1024*1024;
  bool big = ws_size >= 98*MB;
  char* W = (char*)d_ws;
  float* pq   = (float*)W;
  float* cnt  = pq + 2048;
  float* sq   = cnt + 16;
  float* s1a  = (float*)(W + 64*1024);
  float* s2a  = (float*)(W + 320*1024);
  float* M2a  = (float*)(W + 576*1024);
  float* pdot = (float*)(W + 1216*1024);
  u8*    sel8 = (u8*)(W + 1400*1024);
  u32*   conn = (u32*)(W + 2*MB);
  u16*   WT0  = (u16*)(W + 3*MB);
  u16*   WoT  = (u16*)(W + 4*MB);
  u16*   WQT  = (u16*)(W + 5*MB);
  u16*   WPT  = WQT + 3*65536;
  u16*   sWxh = (u16*)(W + 5*MB + 512*1024);
  u16*   sWxl = sWxh + 65536;
  u16*   aWh  = sWxl + 65536;
  u16*   aWl  = aWh + 65536;
  u16*   xh   = (u16*)(W + 6*MB);
  u16*   xl   = (u16*)(W + 10*MB);
  float* S0   = (float*)(W + 14*MB);
  u16*   fah  = (u16*)(W + 22*MB);
  u16*   fal  = (u16*)(W + 26*MB);
  u16*   T2   = (u16*)(W + 30*MB);

  // prep (everything fragment-packed)
  k_split<<<BN*DD/2048,256,0,stream>>>(x, xh, xl);
  k_transpose<<<dim3(4,4,HG),256,0,stream>>>(gat_W, WT0, 256, 65536, 256);
  k_transpose<<<dim3(4,32,1),256,0,stream>>>(gat_Wo, WoT, 2048, 0, 2048);
  k_transpose4<<<dim3(4,4,4),256,0,stream>>>(ca_Wq, ca_Wk, ca_Wv, ca_Wp, WQT);
  k_transp_split<<<dim3(4,4,1),256,0,stream>>>(sim_Wx, sWxh, sWxl);
  k_transp_split<<<dim3(4,4,1),256,0,stream>>>(adj_W, aWh, aWl);

  hipMemsetAsync(pq, 0, (2048+16)*sizeof(float), stream);
  hipMemsetAsync(pdot, 0, BN*sizeof(float), stream);
  k_posq<<<dim3(BB,16),256,0,stream>>>(x, mask, pq, cnt);
  k_sq<<<BB,256,0,stream>>>(pq, cnt, sim_Wq, sq);
  k_msgemm<5><<<dim3(4,128),256,0,stream>>>(xh, xl, sWxh, sWxl, nullptr, nullptr, nullptr, sq, pdot); // y-dot fold
  k_simsel2<<<BN/256,256,0,stream>>>(pdot, simOut, sel8);
  k_msgemm<4><<<dim3(4,128),256,0,stream>>>(xh, xl, aWh, aWl, nullptr, fah, fal, nullptr, nullptr);   // fa gram-packed
  k_mconnect2<<<dim3(136,1,BB),256,0,stream>>>(fah, fal, sel8, conn);

  if (big){
    u16* WhP   = (u16*)(W + 66*MB);   // attention-packed Wh_cat, 32MB
    u16* htcat = (u16*)(W + 34*MB);   // fragment-packed (gpK 2048) ht_cat, 32MB
    u16* S0P   = (u16*)(W + 22*MB);   // attention-packed Who, 4MB (fah dead after mconnect)
    u16* qx = (u16*)(W + 34*MB);      // after htcat consumed
    u16* kv = (u16*)(W + 38*MB);
    u16* qb = (u16*)(W + 42*MB);
    u16* vb = (u16*)(W + 50*MB);
    u16* Ob = (u16*)(W + 54*MB);

    hipMemsetAsync(s1a, 0, 512*1024, stream);  // s1a(256K) + s2a(256K) contiguous
    k_mgemm<7,1,1><<<dim3(32,128),256,0,stream>>>(xh, WT0, 256, 256, 0, nullptr, nullptr, nullptr, nullptr,
                                                  WhP, gat_a1, gat_a2, s1a, s2a);  // WhP pack + s1s2 fold
    k_rowmax<<<dim3(BN/4,HG),256,0,stream>>>(s2a, conn, M2a);
    k_mattn5<4,true,2048><<<dim3(1,128,HG),256,0,stream>>>(s1a, s2a, M2a, conn, WhP, 256, htcat, 2048);
    hipMemsetAsync(s1a, 0, BN*sizeof(float), stream);
    hipMemsetAsync(s2a, 0, BN*sizeof(float), stream);
    k_mgemm<8,1,1><<<dim3(4,128),256,0,stream>>>(htcat, WoT, 2048, 2048, 0, nullptr, nullptr, nullptr, nullptr,
                                                 S0P, gat_ao1, gat_ao2, s1a, s2a);  // S0P pack + s1s2 fold
    k_rowmax<<<dim3(BN/4,1),256,0,stream>>>(s2a, conn, M2a);
    k_mattn5<1,false,0><<<dim3(4,128,1),256,0,stream>>>(s1a, s2a, M2a, conn, S0P, 0, T2, 256);  // gout

    k_ln_x<<<BN/4,256,0,stream>>>(x, ln3_g, ln3_b, qx);
    k_ln_kv<<<BN/4,256,0,stream>>>(T2, pe, sel8, ln4_g, ln4_b, kv);
    k_mgemm3<<<dim3(4,128,3),256,0,stream>>>(qx, kv, WQT, qb);     // qb,kb,vb (stride 4MB)
    k_mca_av2<<<dim3(16,HC,BB),256,0,stream>>>(qb, qb + 2097152, vb, sel8, Ob);
    k_mgemm<2,1,1><<<dim3(4,128),256,0,stream>>>(Ob, WPT, 256, 256, 0, out, x, gamma, nullptr, nullptr,
                                                 nullptr, nullptr, nullptr, nullptr);
  } else {
    // small-ws fallback: per-head loop, packed kernels (rarely taken)
    u16* T0 = fah;
    u16* T1 = fal;
    u16* S0b = (u16*)S0;
    hipMemsetAsync(s1a, 0, 512*1024, stream);
    for (int h=0;h<HG;h++){
      hipMemsetAsync(s1a, 0, BN*sizeof(float), stream);
      hipMemsetAsync(s2a, 0, BN*sizeof(float), stream);
      k_mgemm<8,1,1><<<dim3(4,128),256,0,stream>>>(xh, WT0 + (size_t)h*65536, 256, 256, 0,
                                                   nullptr, nullptr, nullptr, nullptr, T0,
                                                   gat_a1 + h*DD, gat_a2 + h*DD, s1a, s2a);
      k_rowmax<<<dim3(BN/4,1),256,0,stream>>>(s2a, conn, M2a);
      k_mattn5<1,false,0><<<dim3(4,128,1),256,0,stream>>>(s1a, s2a, M2a, conn, T0, 0, T1, 256);
      k_mgemm<1,0,1><<<dim3(4,128),256,0,stream>>>(T1, WoT, 256, 2048, h*256, S0, nullptr, nullptr, nullptr, nullptr,
                                                   nullptr, nullptr, nullptr, nullptr);
    }
    hipMemsetAsync(s1a, 0, BN*sizeof(float), stream);
    hipMemsetAsync(s2a, 0, BN*sizeof(float), stream);
    k_mattn5<1,false,0><<<dim3(4,128,1),256,0,stream>>>(s1a, s2a, M2a, conn, (u16*)S0, 0, T2, 256);
    k_ln_x<<<BN/4,256,0,stream>>>(x, ln3_g, ln3_b, T1);
    k_ln_kv<<<BN/4,256,0,stream>>>(T2, pe, sel8, ln4_g, ln4_b, T0);
    k_mgemm3<<<dim3(4,128,3),256,0,stream>>>(T1, T0, WQT, S0b);
    k_mca_av2<<<dim3(16,HC,BB),256,0,stream>>>(S0b, S0b + 2097152, S0b + 4194304, sel8, T0);
    k_mgemm<2,1,1><<<dim3(4,128),256,0,stream>>>(T0, WPT, 256, 256, 0, out, x, gamma, nullptr, nullptr,
                                                 nullptr, nullptr, nullptr, nullptr);
  }
}

// Round 14
// 467.964 us; speedup vs baseline: 1.1603x; 1.0904x over previous
//
#include <hip/hip_runtime.h>
#include <hip/hip_bf16.h>

// GATFusionBlockPosOnly: B=8, N=1024, D=256, 8 GAT heads, 4 CA heads.
// Round 23:
//  - R22 landed (510us). #1: k_mgemm<8,1,1> (Who, KK=2048) 74us at 993 GB/s /
//    Occ 20 — latency-bound: 512 blocks = 2 waves/SIMD, runtime-bound kc loop
//    pipelines ~1 deep.
//  - k_mgemm<EPI,APK,BPK,UNR>: batch UNR iterations' loads before the MFMAs.
//    UNR=4 only on the two block-limited 512-block GEMMs (<8> Who, <2> final
//    CA) where VGPR growth is free (grid-capped at 2 blocks/CU); UNR=1
//    elsewhere (R21 spill lesson: never add registers where occupancy pays).

#define BB 8
#define NN 1024
#define DD 256
#define HG 8
#define HC 4
#define BN (BB*NN)

typedef unsigned short u16;
typedef unsigned int u32;
typedef unsigned char u8;
typedef __attribute__((ext_vector_type(8))) short s8v;   // 8 bf16
typedef __attribute__((ext_vector_type(4))) float f4v;   // 4 fp32 acc
#define MFMA(a,b,c) __builtin_amdgcn_mfma_f32_16x16x32_bf16((a),(b),(c),0,0,0)

__device__ __forceinline__ u16 f2b(float x){
  union{ float f; unsigned u; } a; a.f = x;
  unsigned r = a.u + 0x7fff + ((a.u>>16)&1);
  return (u16)(r>>16);
}
__device__ __forceinline__ float b2f(u16 b){ return __uint_as_float(((unsigned)b)<<16); }
__device__ __forceinline__ float4 ld4bf(const u16* p){
  uint2 u = *(const uint2*)p;
  float4 r;
  r.x=__uint_as_float(u.x<<16); r.y=__uint_as_float(u.x&0xffff0000u);
  r.z=__uint_as_float(u.y<<16); r.w=__uint_as_float(u.y&0xffff0000u);
  return r;
}
__device__ __forceinline__ void load8(const float* p, float* v){
  float4 a=*(const float4*)p, b=*(const float4*)(p+4);
  v[0]=a.x;v[1]=a.y;v[2]=a.z;v[3]=a.w;v[4]=b.x;v[5]=b.y;v[6]=b.z;v[7]=b.w;
}
__device__ __forceinline__ float wredsum(float v){
  #pragma unroll
  for(int o=32;o>0;o>>=1) v += __shfl_xor(v,o);
  return v;
}
__device__ __forceinline__ float wredmax(float v){
  #pragma unroll
  for(int o=32;o>0;o>>=1) v = fmaxf(v,__shfl_xor(v,o));
  return v;
}
__device__ __forceinline__ float eluf(float x){ return x>0.f ? x : __expf(x)-1.f; }
__device__ __forceinline__ float leakyf(float z){ return z>=0.f ? z : 0.2f*z; }
__device__ __forceinline__ float exp0(float a){ return __expf(fminf(a, 0.f)); }
__device__ __forceinline__ float flushf(float v){ return (fabsf(v) < 1.0e30f) ? v : 0.f; }
__device__ __forceinline__ u32 pk2(float lo, float hi){
  u32 r;
  asm("v_cvt_pk_bf16_f32 %0, %1, %2" : "=v"(r) : "v"(lo), "v"(hi));
  return r;
}

// packed index for element (col, m) of the attention-V pack:  b=m>>10, kk=m&1023
__device__ __forceinline__ size_t packIdx(int col, int row){
  int kk = row & 1023;
  return ((((size_t)(col>>4))*8 + (row>>10))*32 + (kk>>5))*512
       + (size_t)(((((kk>>3)&3)*16) + (col&15))*8 + (kk&7));
}

// fragment-pack: element (row, k) of a [rows][KK] operand -> fragment order.
__device__ __forceinline__ size_t gpK(int row, int k, int KK){
  return (size_t)(row>>4)*((size_t)16*KK) + (size_t)(k>>5)*512
       + (size_t)(((((k>>3)&3)*16) + (row&15))*8 + (k&7));
}

// ---------- fp32 -> (hi,lo) bf16 split, packed output (gpK, KK=256) ----------
__global__ __launch_bounds__(256) void k_split(const float* __restrict__ X, u16* __restrict__ H, u16* __restrict__ Lo){
  size_t i = ((size_t)blockIdx.x*256 + threadIdx.x)*8;
  float v[8]; load8(X+i, v);
  u16 hh[8], ll[8];
  #pragma unroll
  for (int j=0;j<8;j++){ hh[j]=f2b(v[j]); ll[j]=f2b(v[j]-b2f(hh[j])); }
  int row = (int)(i>>8), col = (int)(i&255);
  size_t off = gpK(row, col, 256);
  *(uint4*)(H+off)=*(uint4*)&hh[0];
  *(uint4*)(Lo+off)=*(uint4*)&ll[0];
}

// ---------- transpose fp32 [R][C] -> bf16; pkKK=0: row-major [C][R]; else gpK packed ----------
__global__ __launch_bounds__(256) void k_transpose(const float* __restrict__ S, u16* __restrict__ D,
                                                   int R, int sliceElems, int pkKK){
  __shared__ float tl[64][65];
  const float* src = S + (size_t)blockIdx.z*sliceElems;
  u16* dst = D + (size_t)blockIdx.z*sliceElems;
  int C = gridDim.x*64;
  int bx=blockIdx.x*64, by=blockIdx.y*64;
  int tid=threadIdx.x, r=tid>>2, c0=(tid&3)*16;
  #pragma unroll
  for (int i=0;i<16;i+=4){
    float4 v = *(const float4*)(src + (size_t)(by+r)*C + bx + c0 + i);
    tl[r][c0+i]=v.x; tl[r][c0+i+1]=v.y; tl[r][c0+i+2]=v.z; tl[r][c0+i+3]=v.w;
  }
  __syncthreads();
  u16 tmp[16];
  #pragma unroll
  for (int i=0;i<16;i++) tmp[i] = f2b(tl[c0+i][r]);
  if (pkKK){
    *(uint4*)(dst + gpK(bx+r, by+c0,     pkKK)) = *(uint4*)&tmp[0];
    *(uint4*)(dst + gpK(bx+r, by+c0+8,   pkKK)) = *(uint4*)&tmp[8];
  } else {
    *(uint4*)(dst + (size_t)(bx+r)*R + by + c0)     = *(uint4*)&tmp[0];
    *(uint4*)(dst + (size_t)(bx+r)*R + by + c0 + 8) = *(uint4*)&tmp[8];
  }
}

// ---------- 4x 256x256 transposes, PACKED (gpK 256) output; grid (4,4,4) ----------
__global__ __launch_bounds__(256) void k_transpose4(const float* __restrict__ Sa, const float* __restrict__ Sb,
    const float* __restrict__ Sc, const float* __restrict__ Sd, u16* __restrict__ D){
  __shared__ float tl[64][65];
  const float* src = blockIdx.z==0 ? Sa : blockIdx.z==1 ? Sb : blockIdx.z==2 ? Sc : Sd;
  u16* dst = D + (size_t)blockIdx.z*65536;
  int bx=blockIdx.x*64, by=blockIdx.y*64;
  int tid=threadIdx.x, r=tid>>2, c0=(tid&3)*16;
  #pragma unroll
  for (int i=0;i<16;i+=4){
    float4 v = *(const float4*)(src + (size_t)(by+r)*256 + bx + c0 + i);
    tl[r][c0+i]=v.x; tl[r][c0+i+1]=v.y; tl[r][c0+i+2]=v.z; tl[r][c0+i+3]=v.w;
  }
  __syncthreads();
  u16 tmp[16];
  #pragma unroll
  for (int i=0;i<16;i++) tmp[i] = f2b(tl[c0+i][r]);
  *(uint4*)(dst + gpK(bx+r, by+c0,   256)) = *(uint4*)&tmp[0];
  *(uint4*)(dst + gpK(bx+r, by+c0+8, 256)) = *(uint4*)&tmp[8];
}

// ---------- transpose + split: fp32 [256][256] -> hi/lo bf16 PACKED (gpK 256) ----------
__global__ __launch_bounds__(256) void k_transp_split(const float* __restrict__ S, u16* __restrict__ DH, u16* __restrict__ DL){
  __shared__ float tl[64][65];
  int bx=blockIdx.x*64, by=blockIdx.y*64;
  int tid=threadIdx.x, r=tid>>2, c0=(tid&3)*16;
  #pragma unroll
  for (int i=0;i<16;i+=4){
    float4 v = *(const float4*)(S + (size_t)(by+r)*256 + bx + c0 + i);
    tl[r][c0+i]=v.x; tl[r][c0+i+1]=v.y; tl[r][c0+i+2]=v.z; tl[r][c0+i+3]=v.w;
  }
  __syncthreads();
  u16 th[16], tll[16];
  #pragma unroll
  for (int i=0;i<16;i++){
    float v = tl[c0+i][r];
    th[i]=f2b(v); tll[i]=f2b(v - b2f(th[i]));
  }
  size_t o0 = gpK(bx+r, by+c0,   256);
  size_t o1 = gpK(bx+r, by+c0+8, 256);
  *(uint4*)(DH + o0) = *(uint4*)&th[0];
  *(uint4*)(DH + o1) = *(uint4*)&th[8];
  *(uint4*)(DL + o0) = *(uint4*)&tll[0];
  *(uint4*)(DL + o1) = *(uint4*)&tll[8];
}

// ---------- pos_query ----------
__global__ __launch_bounds__(256) void k_posq(const float* __restrict__ x, const int* __restrict__ mask,
                                              float* __restrict__ pq, float* __restrict__ cnt){
  int b = blockIdx.x, chunk = blockIdx.y;
  int d = threadIdx.x;
  int n0 = chunk*64;
  float acc = 0.f; float c = 0.f;
  for (int i=0;i<64;i++){
    int n = n0+i;
    if (mask[b*NN+n]==1){ acc += x[((size_t)(b*NN+n))*DD + d]; c += 1.f; }
  }
  atomicAdd(&pq[b*DD+d], acc);
  if (d==0) atomicAdd(&cnt[b], c);
}

__global__ __launch_bounds__(256) void k_sq(const float* __restrict__ pq, const float* __restrict__ cnt,
                                            const float* __restrict__ Wq, float* __restrict__ sq){
  int b = blockIdx.x, e = threadIdx.x;
  float inv = 1.f / fmaxf(cnt[b], 1.f);
  float acc=0.f;
  for (int d0=0; d0<DD; d0++) acc += (pq[b*DD+d0]*inv) * Wq[d0*DD+e];
  sq[b*DD+e] = acc;
}

// ---------- sigmoid + threshold from folded dot ----------
__global__ __launch_bounds__(256) void k_simsel2(const float* __restrict__ pdot,
                                                 float* __restrict__ simOut, u8* __restrict__ sel8){
  int r = blockIdx.x*256 + threadIdx.x;
  float s = pdot[r] * 0.0625f;
  float sim = 1.f/(1.f+expf(-s));
  simOut[r] = sim;
  sel8[r] = (sim > 0.97f) ? 1 : 0;
}

// ---------- no-LDS MFMA GEMM: out[8192, OC] = A[8192,KK] @ BT[OC,KK]^T ----------
// APK: A fragment-packed (gpK, KK). BPK: BT fragment-packed (gpK, ldB total K; kOff = K start).
// UNR: load-batch depth (use >1 only on block-limited grids; R21 spill lesson).
// EPI: 0=C fp32, 1=C+=, 2=residual+gamma, 3=O bf16,
//      7=Pk pack + s1/s2 fold (head=colBase>>8), 8=Pk pack + s1/s2 fold (single head)
template<int EPI, int APK, int BPK, int UNR=1>
__global__ __launch_bounds__(256) void k_mgemm(const u16* __restrict__ A, const u16* __restrict__ BT,
    int KK, int ldB, int kOff, float* __restrict__ C, const float* __restrict__ Xres,
    const float* __restrict__ gamma, u16* __restrict__ O, u16* __restrict__ Pk,
    const float* __restrict__ A1, const float* __restrict__ A2,
    float* __restrict__ s1g, float* __restrict__ s2g){
  int tid=threadIdx.x, w=tid>>6, lane=tid&63, L=lane&15, q=lane>>4;
  int OC = gridDim.x<<6;
  int colBase=blockIdx.x<<6, rowBase=blockIdx.y<<6;
  const u16* ap;
  if constexpr (APK) ap = A + (size_t)((rowBase>>4)+w)*((size_t)16*KK) + (size_t)lane*8;
  else               ap = A + (size_t)(rowBase + w*16 + L)*KK + q*8;
  const u16* bp[4];
  #pragma unroll
  for (int t=0;t<4;t++){
    if constexpr (BPK) bp[t] = BT + (size_t)((colBase>>4)+t)*((size_t)16*ldB) + (size_t)(kOff>>5)*512 + (size_t)lane*8;
    else               bp[t] = BT + (size_t)(colBase + t*16 + L)*ldB + q*8 + kOff;
  }
  f4v z4={0.f,0.f,0.f,0.f};
  f4v acc[4]={z4,z4,z4,z4};
  int nk = KK>>5;
  for (int kc0=0;kc0<nk;kc0+=UNR){
    s8v a0[UNR], bt[UNR][4];
    #pragma unroll
    for (int u=0;u<UNR;u++){
      int kc = kc0 + u;
      if constexpr (APK) a0[u] = *(const s8v*)(ap + (size_t)kc*512);
      else               a0[u] = *(const s8v*)(ap + kc*32);
      #pragma unroll
      for (int t=0;t<4;t++){
        if constexpr (BPK) bt[u][t] = *(const s8v*)(bp[t] + (size_t)kc*512);
        else               bt[u][t] = *(const s8v*)(bp[t] + kc*32);
      }
    }
    #pragma unroll
    for (int u=0;u<UNR;u++)
      #pragma unroll
      for (int t=0;t<4;t++)
        acc[t]=MFMA(a0[u],bt[u][t],acc[t]);
  }
  if constexpr (EPI<=3){
    #pragma unroll
    for (int t=0;t<4;t++){
      int col = colBase + t*16 + L;
      #pragma unroll
      for (int reg=0;reg<4;reg++){
        int row = rowBase + w*16 + q*4 + reg;
        size_t off = (size_t)row*OC + col;
        float v = acc[t][reg];
        if constexpr (EPI==0){ C[off] = v; }
        else if constexpr (EPI==1){ C[off] += v; }
        else if constexpr (EPI==2){ C[off] = flushf(Xres[off] + gamma[col]*v); }
        else { O[off] = f2b(v); }
      }
    }
  } else {
    // s1/s2 fold
    float s1p[4]={0.f,0.f,0.f,0.f}, s2p[4]={0.f,0.f,0.f,0.f};
    #pragma unroll
    for (int t=0;t<4;t++){
      int col = colBase + t*16 + L;
      float a1v = A1[col], a2v = A2[col];
      #pragma unroll
      for (int reg=0;reg<4;reg++){
        float v = acc[t][reg];
        s1p[reg] += v*a1v;
        s2p[reg] += v*a2v;
      }
    }
    #pragma unroll
    for (int off=1;off<16;off<<=1)
      #pragma unroll
      for (int reg=0;reg<4;reg++){
        s1p[reg] += __shfl_xor(s1p[reg],off);
        s2p[reg] += __shfl_xor(s2p[reg],off);
      }
    if (L==0){
      int sOff = (EPI==7) ? (colBase>>8)*BN : 0;
      #pragma unroll
      for (int reg=0;reg<4;reg++){
        int row = rowBase + w*16 + q*4 + reg;
        atomicAdd(&s1g[sOff+row], s1p[reg]);
        atomicAdd(&s2g[sOff+row], s2p[reg]);
      }
    }
    // coalesced pack store (16B per lane, 8 consecutive rows of one column)
    int pq_ = q&1;
    int m0 = rowBase + w*16 + (q>>1)*8;
    #pragma unroll
    for (int tp=0;tp<2;tp++){
      f4v accA = acc[2*tp], accB = acc[2*tp+1];
      f4v mine   = pq_ ? accB : accA;
      f4v theirs = pq_ ? accA : accB;
      u32 k0 = pk2(mine[0],  mine[1]);
      u32 k1 = pk2(mine[2],  mine[3]);
      u32 s0 = pk2(theirs[0],theirs[1]);
      u32 s1 = pk2(theirs[2],theirs[3]);
      u32 r0 = (u32)__shfl_xor((int)s0,16);
      u32 r1 = (u32)__shfl_xor((int)s1,16);
      uint4 val = pq_==0 ? make_uint4(k0,k1,r0,r1) : make_uint4(r0,r1,k0,k1);
      int t = 2*tp + pq_;
      int col = colBase + t*16 + L;
      *(uint4*)(Pk + packIdx(col, m0)) = val;
    }
  }
}

// ---------- fused q/k/v projections, packed A (gpK 256) and B (gpK 256) ----------
__global__ __launch_bounds__(256) void k_mgemm3(const u16* __restrict__ Aq, const u16* __restrict__ Akv,
    const u16* __restrict__ BT0, u16* __restrict__ O0){
  int tid=threadIdx.x, w=tid>>6, lane=tid&63, L=lane&15, q=lane>>4;
  const u16* A = blockIdx.z==0 ? Aq : Akv;
  const u16* BT = BT0 + (size_t)blockIdx.z*65536;
  u16* O = O0 + (size_t)blockIdx.z*2097152;
  int colBase=blockIdx.x<<6, rowBase=blockIdx.y<<6;
  const u16* ap = A + (size_t)((rowBase>>4)+w)*4096 + (size_t)lane*8;
  f4v z4={0.f,0.f,0.f,0.f};
  f4v acc[4]={z4,z4,z4,z4};
  #pragma unroll
  for (int kc=0;kc<8;kc++){
    s8v a0 = *(const s8v*)(ap + kc*512);
    #pragma unroll
    for (int t=0;t<4;t++){
      s8v bt = *(const s8v*)(BT + (size_t)((colBase>>4)+t)*4096 + (size_t)kc*512 + (size_t)lane*8);
      acc[t]=MFMA(a0,bt,acc[t]);
    }
  }
  #pragma unroll
  for (int t=0;t<4;t++){
    int col = colBase + t*16 + L;
    #pragma unroll
    for (int reg=0;reg<4;reg++){
      int row = rowBase + w*16 + q*4 + reg;
      O[(size_t)row*256 + col] = f2b(acc[t][reg]);
    }
  }
}

// ---------- split (3-term) MFMA GEMM, packed A and B (gpK 256): KK=256, OC=256 ----------
// EPI 4: hi/lo bf16 gram-packed out.  EPI 5: sq-dot fold -> pdot.
template<int EPI>
__global__ __launch_bounds__(256) void k_msgemm(const u16* __restrict__ Ah, const u16* __restrict__ Al,
    const u16* __restrict__ Bh, const u16* __restrict__ Bl,
    float* __restrict__ C, u16* __restrict__ Oh, u16* __restrict__ Ol,
    const float* __restrict__ sq, float* __restrict__ pdot){
  int tid=threadIdx.x, w=tid>>6, lane=tid&63, L=lane&15, q=lane>>4;
  int colBase=blockIdx.x<<6, rowBase=blockIdx.y<<6;
  const u16* ahp = Ah + (size_t)((rowBase>>4)+w)*4096 + (size_t)lane*8;
  const u16* alp = Al + (size_t)((rowBase>>4)+w)*4096 + (size_t)lane*8;
  f4v z4={0.f,0.f,0.f,0.f};
  f4v acc[4]={z4,z4,z4,z4};
  #pragma unroll
  for (int kc=0;kc<8;kc++){
    s8v ah=*(const s8v*)(ahp + kc*512), al=*(const s8v*)(alp + kc*512);
    #pragma unroll
    for (int t=0;t<4;t++){
      size_t boff = (size_t)((colBase>>4)+t)*4096 + (size_t)kc*512 + (size_t)lane*8;
      s8v bh=*(const s8v*)(Bh + boff);
      s8v bl=*(const s8v*)(Bl + boff);
      acc[t]=MFMA(ah,bh,acc[t]);
      acc[t]=MFMA(ah,bl,acc[t]);
      acc[t]=MFMA(al,bh,acc[t]);
    }
  }
  if constexpr (EPI==5){
    int b = rowBase>>10;
    float pp[4]={0.f,0.f,0.f,0.f};
    #pragma unroll
    for (int t=0;t<4;t++){
      int col = colBase + t*16 + L;
      float qv = sq[b*256 + col];
      #pragma unroll
      for (int reg=0;reg<4;reg++) pp[reg] += acc[t][reg]*qv;
    }
    #pragma unroll
    for (int off=1;off<16;off<<=1)
      #pragma unroll
      for (int reg=0;reg<4;reg++) pp[reg] += __shfl_xor(pp[reg],off);
    if (L==0){
      #pragma unroll
      for (int reg=0;reg<4;reg++){
        int row = rowBase + w*16 + q*4 + reg;
        atomicAdd(&pdot[row], pp[reg]);
      }
    }
  } else {
    #pragma unroll
    for (int t=0;t<4;t++){
      int col = colBase + t*16 + L;
      #pragma unroll
      for (int reg=0;reg<4;reg++){
        int row = rowBase + w*16 + q*4 + reg;
        float v = acc[t][reg];
        if constexpr (EPI==0){ C[(size_t)row*256 + col] = v; }
        else {
          size_t off = gpK(row, col, 256);
          u16 h = f2b(v); Oh[off]=h; Ol[off]=f2b(v - b2f(h));
        }
      }
    }
  }
}

// ---------- gram + bitpack v2: packed fragments, symmetric tile enumeration ----------
__global__ __launch_bounds__(256) void k_mconnect2(const u16* __restrict__ fahP, const u16* __restrict__ falP,
    const u8* __restrict__ sel8, u32* __restrict__ conn){
  __shared__ u8 sg[64][64];
  __shared__ u8 selI[64], selJ[64];
  int tid=threadIdx.x, w=tid>>6, lane=tid&63, L=lane&15, q=lane>>4;
  int b=blockIdx.z;
  int p=blockIdx.x;
  int i = (int)((sqrtf(8.f*p+1.f)-1.f)*0.5f);
  while ((i+1)*(i+2)/2 <= p) i++;
  while (i*(i+1)/2 > p) i--;
  int j = p - i*(i+1)/2;          // i >= j, both 0..15
  if (tid < 64)        selI[tid]     = sel8[b*NN + i*64 + tid];
  else if (tid < 128)  selJ[tid-64]  = sel8[b*NN + j*64 + (tid-64)];
  const u16* ah0 = fahP + ((size_t)(b*64 + i*4 + w))*4096 + (size_t)lane*8;
  const u16* al0 = falP + ((size_t)(b*64 + i*4 + w))*4096 + (size_t)lane*8;
  const u16* bh0 = fahP + ((size_t)(b*64 + j*4))*4096 + (size_t)lane*8;
  const u16* bl0 = falP + ((size_t)(b*64 + j*4))*4096 + (size_t)lane*8;
  f4v z4={0.f,0.f,0.f,0.f};
  f4v acc[4]={z4,z4,z4,z4};
  #pragma unroll
  for (int kc=0;kc<8;kc++){
    s8v ah = *(const s8v*)(ah0 + kc*512);
    s8v al = *(const s8v*)(al0 + kc*512);
    #pragma unroll
    for (int t=0;t<4;t++){
      s8v bh = *(const s8v*)(bh0 + (size_t)t*4096 + kc*512);
      s8v bl = *(const s8v*)(bl0 + (size_t)t*4096 + kc*512);
      acc[t]=MFMA(ah,bh,acc[t]);
      acc[t]=MFMA(ah,bl,acc[t]);
      acc[t]=MFMA(al,bh,acc[t]);
    }
  }
  #pragma unroll
  for (int t=0;t<4;t++)
    #pragma unroll
    for (int reg=0;reg<4;reg++)
      sg[w*16 + q*4 + reg][t*16 + L] = acc[t][reg] > 0.f;
  __syncthreads();
  int row=(tid&127)>>1, ww=tid&1;
  if (tid<128){
    u32 word=0;
    if (selI[row]){
      #pragma unroll 8
      for (int jj=0;jj<32;jj++)
        if (sg[row][ww*32+jj] && selJ[ww*32+jj]) word |= (1u<<jj);
    }
    conn[((size_t)b*NN + i*64+row)*32 + j*2 + ww] = word;
  } else if (i != j){
    u32 word=0;
    if (selJ[row]){
      #pragma unroll 8
      for (int jj=0;jj<32;jj++)
        if (sg[ww*32+jj][row] && selI[ww*32+jj]) word |= (1u<<jj);
    }
    conn[((size_t)b*NN + j*64+row)*32 + i*2 + ww] = word;
  }
}

// ---------- row max of s2 over connected m ----------
__global__ __launch_bounds__(256) void k_rowmax(const float* __restrict__ s2a,
    const u32* __restrict__ conn, float* __restrict__ M2a){
  int h = blockIdx.y;
  int r = blockIdx.x*4 + (threadIdx.x>>6);
  int lane = threadIdx.x&63;
  int b = r>>10;
  const float* s2p = s2a + h*BN + b*NN;
  float mx = -3.0e38f;
  #pragma unroll
  for (int t=0;t<16;t++){
    int m = lane + t*64;
    u32 wd = conn[(size_t)r*32 + (m>>5)];
    if ((wd>>(m&31))&1u) mx = fmaxf(mx, s2p[m]);
  }
  mx = wredmax(mx);
  if (lane==0) M2a[h*BN+r] = mx;
}

// ---------- MFMA GAT attention v8: P shared via LDS; V loaded EARLY (single copy) ----------
// PKO: 0 = row-major output (stride oStride); else fragment-packed gpK(row,col,PKO).
template<int CT, bool SWZ, int PKO>
__global__ __launch_bounds__(256,4) void k_mattn5(const float* __restrict__ s1a, const float* __restrict__ s2a,
    const float* __restrict__ M2a, const u32* __restrict__ conn,
    const u16* __restrict__ P, int headMul, u16* __restrict__ Out, int oStride){
  __shared__ __align__(16) u16 Pb[2][4][512];
  __shared__ float Srow[64];
  int tid=threadIdx.x, w=tid>>6, lane=tid&63, L=lane&15, q=lane>>4;
  int h, rowBlk;
  if constexpr (SWZ){ h = blockIdx.y & 7; rowBlk = (blockIdx.y>>3) + (blockIdx.z<<4); }
  else             { h = blockIdx.z;     rowBlk = blockIdx.y; }
  int rowBase = rowBlk*64;
  int hOff = h*headMul, sOff = h*BN;
  int b = rowBase>>10;
  size_t bOff = (size_t)b*NN;
  int r = rowBase + w*16 + L;             // own row for P-build
  float s1v = s1a[sOff+r];
  float rmv = leakyf(s1v + M2a[sOff+r]);
  const float* s2p = s2a + sOff + bOff;
  const u32* cp = conn + (size_t)r*32;
  int tile0 = blockIdx.x*(4*CT) + w*CT;   // first col-tile owned by this wave
  const u16* vp = P + (size_t)((hOff>>4) + tile0)*131072 + (size_t)b*16384 + (size_t)lane*8;
  f4v z4={0.f,0.f,0.f,0.f};
  f4v acc[4][CT];
  #pragma unroll
  for (int g=0;g<4;g++)
    #pragma unroll
    for (int t=0;t<CT;t++) acc[g][t]=z4;
  float sumP = 0.f;
  for (int k0=0;k0<NN;k0+=32){
    int cur=(k0>>5)&1;
    u32 cw = cp[k0>>5];
    // issue THIS chunk's V loads first — latency hidden under P-build + barrier
    s8v vf[CT];
    {
      const u16* vk = vp + (size_t)(k0>>5)*512;
      #pragma unroll
      for (int t=0;t<CT;t++) vf[t] = *(const s8v*)(vk + (size_t)t*131072);
    }
    float4 sA = *(const float4*)(s2p + k0 + q*8);
    float4 sB = *(const float4*)(s2p + k0 + q*8 + 4);
    float s2v[8] = {sA.x,sA.y,sA.z,sA.w,sB.x,sB.y,sB.z,sB.w};
    float p[8];
    #pragma unroll
    for (int j=0;j<8;j++){
      float z = s1v + s2v[j];
      float ev = fmaxf(z, 0.2f*z);                      // leaky = max(z, 0.2z)
      ev = ((cw>>(q*8+j))&1u) ? ev : -9.0e15f;          // mask BEFORE exp (uniform rows!)
      p[j] = __expf(fminf(ev - rmv, 0.f));
      sumP += p[j];
    }
    union{ s8v v; u32 u[4]; } pk;
    #pragma unroll
    for (int jj=0;jj<4;jj++)
      pk.u[jj] = pk2(p[2*jj], p[2*jj+1]);
    *(s8v*)&Pb[cur][w][lane*8] = pk.v;    // ds_write_b128, contiguous
    __syncthreads();                       // all P fragments for this chunk visible
    s8v pa[4];
    #pragma unroll
    for (int g=0;g<4;g++) pa[g] = *(const s8v*)&Pb[cur][g][lane*8];
    #pragma unroll
    for (int t=0;t<CT;t++)
      #pragma unroll
      for (int g=0;g<4;g++) acc[g][t] = MFMA(pa[g], vf[t], acc[g][t]);
  }
  sumP += __shfl_xor(sumP,16);
  sumP += __shfl_xor(sumP,32);
  if (lane<16) Srow[w*16+lane] = sumP;
  __syncthreads();
  #pragma unroll
  for (int g=0;g<4;g++){
    float4 sv = *(const float4*)&Srow[g*16 + q*4];
    float rsi[4] = {1.f/sv.x, 1.f/sv.y, 1.f/sv.z, 1.f/sv.w};
    #pragma unroll
    for (int t=0;t<CT;t++){
      int col = hOff + (tile0+t)*16 + L;
      #pragma unroll
      for (int reg=0;reg<4;reg++){
        int row = rowBase + g*16 + q*4 + reg;
        float ov = eluf(acc[g][t][reg]*rsi[reg]);
        if constexpr (PKO) Out[gpK(row, col, PKO)] = f2b(ov);
        else               Out[(size_t)row*oStride + col] = f2b(ov);
      }
    }
  }
}

// ---------- LayerNorms (packed gpK-256 output) ----------
__global__ __launch_bounds__(256) void k_ln_x(const float* __restrict__ x, const float* __restrict__ g,
                                              const float* __restrict__ bb, u16* __restrict__ out){
  int r = blockIdx.x*4 + (threadIdx.x>>6);
  int lane=threadIdx.x&63;
  float4 v = *(const float4*)(x + (size_t)r*DD + lane*4);
  float s = v.x+v.y+v.z+v.w;
  float s2 = v.x*v.x+v.y*v.y+v.z*v.z+v.w*v.w;
  s = wredsum(s); s2 = wredsum(s2);
  float mean = s*(1.f/256.f);
  float var = s2*(1.f/256.f) - mean*mean;
  float rstd = rsqrtf(var + 1e-5f);
  float4 gv = *(const float4*)(g+lane*4), bv = *(const float4*)(bb+lane*4);
  u16 t[4];
  t[0]=f2b((v.x-mean)*rstd*gv.x+bv.x); t[1]=f2b((v.y-mean)*rstd*gv.y+bv.y);
  t[2]=f2b((v.z-mean)*rstd*gv.z+bv.z); t[3]=f2b((v.w-mean)*rstd*gv.w+bv.w);
  *(uint2*)(out + gpK(r, lane*4, 256)) = *(uint2*)&t[0];
}

__global__ __launch_bounds__(256) void k_ln_kv(const u16* __restrict__ gout, const float* __restrict__ pe,
    const u8* __restrict__ sel8, const float* __restrict__ g, const float* __restrict__ bb,
    u16* __restrict__ out){
  int r = blockIdx.x*4 + (threadIdx.x>>6);
  int lane=threadIdx.x&63;
  int n = r & 1023;
  float4 v = make_float4(0.f,0.f,0.f,0.f);
  if (sel8[r]){
    float4 gv = ld4bf(gout + (size_t)r*DD + lane*4);
    float4 pv = *(const float4*)(pe + (size_t)n*DD + lane*4);
    v = make_float4(gv.x+pv.x, gv.y+pv.y, gv.z+pv.z, gv.w+pv.w);
  }
  float s = v.x+v.y+v.z+v.w;
  float s2 = v.x*v.x+v.y*v.y+v.z*v.z+v.w*v.w;
  s = wredsum(s); s2 = wredsum(s2);
  float mean = s*(1.f/256.f);
  float var = s2*(1.f/256.f) - mean*mean;
  float rstd = rsqrtf(var + 1e-5f);
  float4 gv = *(const float4*)(g+lane*4), bv = *(const float4*)(bb+lane*4);
  u16 t[4];
  t[0]=f2b((v.x-mean)*rstd*gv.x+bv.x); t[1]=f2b((v.y-mean)*rstd*gv.y+bv.y);
  t[2]=f2b((v.z-mean)*rstd*gv.z+bv.z); t[3]=f2b((v.w-mean)*rstd*gv.w+bv.w);
  *(uint2*)(out + gpK(r, lane*4, 256)) = *(uint2*)&t[0];
}

// ---------- CA attention, fused flash-style; Ob written fragment-packed (gpK 256) ----------
__global__ __launch_bounds__(256) void k_mca_av2(const u16* __restrict__ q, const u16* __restrict__ k,
    const u16* __restrict__ v, const u8* __restrict__ sel8, u16* __restrict__ O){
  __shared__ __align__(16) u16 Qls[64][72];
  __shared__ __align__(16) u16 KP[64][72];
  __shared__ __align__(16) u16 Vt[64][72];
  int tid=threadIdx.x;
  int w = tid>>6, lane = tid&63, L = lane&15, qd = lane>>4;
  int b=blockIdx.z, h=blockIdx.y, rowBase=blockIdx.x*64;
  size_t bOff = (size_t)b*NN;
  {
    int r=tid>>2, c0=(tid&3)*16;
    size_t base = (bOff + rowBase + r)*(size_t)DD + h*64 + c0;
    *(uint4*)&Qls[r][c0]   = *(const uint4*)(q + base);
    *(uint4*)&Qls[r][c0+8] = *(const uint4*)(q + base + 8);
  }
  float rm[4], sp[4];
  #pragma unroll
  for (int reg=0;reg<4;reg++){ rm[reg] = -3.0e38f; sp[reg] = 0.f; }
  f4v zero = {0.f,0.f,0.f,0.f};
  f4v acc[4] = {zero,zero,zero,zero};
  int svm = tid&63, svd0 = (tid>>6)*16;
  for (int m0=0;m0<NN;m0+=64){
    __syncthreads();
    {
      int r=tid>>2, c0=(tid&3)*16;
      size_t base = (bOff + m0 + r)*(size_t)DD + h*64 + c0;
      *(uint4*)&KP[r][c0]   = *(const uint4*)(k + base);
      *(uint4*)&KP[r][c0+8] = *(const uint4*)(k + base + 8);
      size_t vb_ = (bOff + m0 + svm)*(size_t)DD + h*64 + svd0;
      uint4 u0 = *(const uint4*)(v + vb_);
      uint4 u1 = *(const uint4*)(v + vb_ + 8);
      u16 tmp[16];
      *(uint4*)&tmp[0]=u0; *(uint4*)&tmp[8]=u1;
      #pragma unroll
      for (int i=0;i<16;i++) Vt[svd0+i][svm] = tmp[i];
    }
    __syncthreads();
    f4v sa[4] = {zero,zero,zero,zero};
    #pragma unroll
    for (int kc=0;kc<64;kc+=32){
      s8v af = *(const s8v*)&Qls[w*16 + L][kc + qd*8];
      #pragma unroll
      for (int t=0;t<4;t++){
        s8v bfr = *(const s8v*)&KP[t*16 + L][kc + qd*8];
        sa[t] = MFMA(af, bfr, sa[t]);
      }
    }
    __syncthreads();
    // online-softmax update (row-consistent max via L-group reduce)
    float vals[4][4];
    float tmax[4];
    #pragma unroll
    for (int reg=0;reg<4;reg++) tmax[reg] = -3.0e38f;
    #pragma unroll
    for (int t=0;t<4;t++){
      int m = m0 + t*16 + L;
      bool sl = sel8[b*NN+m];
      #pragma unroll
      for (int reg=0;reg<4;reg++){
        float val = sl ? sa[t][reg]*0.125f : -1.0e9f;
        vals[t][reg] = val;
        tmax[reg] = fmaxf(tmax[reg], val);
      }
    }
    #pragma unroll
    for (int off=1;off<16;off<<=1)
      #pragma unroll
      for (int reg=0;reg<4;reg++) tmax[reg] = fmaxf(tmax[reg], __shfl_xor(tmax[reg],off));
    float sc[4];
    #pragma unroll
    for (int reg=0;reg<4;reg++){
      float nm = fmaxf(rm[reg], tmax[reg]);
      sc[reg] = exp0(rm[reg] - nm);
      rm[reg] = nm;
      sp[reg] *= sc[reg];
    }
    #pragma unroll
    for (int t=0;t<4;t++){
      #pragma unroll
      for (int reg=0;reg<4;reg++){
        float pv = exp0(vals[t][reg] - rm[reg]);
        sp[reg] += pv;
        KP[w*16 + qd*4 + reg][t*16 + L] = f2b(pv);
      }
    }
    #pragma unroll
    for (int t=0;t<4;t++)
      #pragma unroll
      for (int reg=0;reg<4;reg++) acc[t][reg] *= sc[reg];
    __syncthreads();
    #pragma unroll
    for (int mc=0;mc<64;mc+=32){
      s8v pf = *(const s8v*)&KP[w*16 + L][mc + qd*8];
      #pragma unroll
      for (int t=0;t<4;t++){
        s8v vf = *(const s8v*)&Vt[t*16 + L][mc + qd*8];
        acc[t] = MFMA(pf, vf, acc[t]);
      }
    }
  }
  #pragma unroll
  for (int off=1;off<16;off<<=1)
    #pragma unroll
    for (int reg=0;reg<4;reg++) sp[reg] += __shfl_xor(sp[reg],off);
  float ri[4];
  #pragma unroll
  for (int reg=0;reg<4;reg++) ri[reg] = 1.f/sp[reg];
  #pragma unroll
  for (int t=0;t<4;t++){
    int col = h*64 + t*16 + L;
    #pragma unroll
    for (int reg=0;reg<4;reg++){
      int row = (int)bOff + rowBase + w*16 + qd*4 + reg;
      O[gpK(row, col, 256)] = f2b(acc[t][reg]*ri[reg]);
    }
  }
}

extern "C" void kernel_launch(void* const* d_in, const int* in_sizes, int n_in,
                              void* d_out, int out_size, void* d_ws, size_t ws_size,
                              hipStream_t stream) {
  (void)in_sizes; (void)n_in; (void)out_size;
  const float* x      = (const float*)d_in[0];
  const int*   mask   = (const int*  )d_in[1];
  const float* pe     = (const float*)d_in[2];
  const float* sim_Wx = (const float*)d_in[3];
  const float* sim_Wq = (const float*)d_in[4];
  const float* adj_W  = (const float*)d_in[5];
  const float* gat_W  = (const float*)d_in[6];
  const float* gat_a1 = (const float*)d_in[7];
  const float* gat_a2 = (const float*)d_in[8];
  const float* gat_Wo = (const float*)d_in[9];
  const float* gat_ao1= (const float*)d_in[10];
  const float* gat_ao2= (const float*)d_in[11];
  const float* ln3_g  = (const float*)d_in[12];
  const float* ln3_b  = (const float*)d_in[13];
  const float* ln4_g  = (const float*)d_in[14];
  const float* ln4_b  = (const float*)d_in[15];
  const float* ca_Wq  = (const float*)d_in[16];
  const float* ca_Wk  = (const float*)d_in[17];
  const float* ca_Wv  = (const float*)d_in[18];
  const float* ca_Wp  = (const float*)d_in[19];
  const float* gamma  = (const float*)d_in[20];
  float* out    = (float*)d_out;
  float* simOut = out + (size_t)BN*DD;

  const size_t MB = 1024*1024;
  bool big = ws_size >= 98*MB;
  char* W = (char*)d_ws;
  float* pq   = (float*)W;
  float* cnt  = pq + 2048;
  float* sq   = cnt + 16;
  float* s1a  = (float*)(W + 64*1024);
  float* s2a  = (float*)(W + 320*1024);
  float* M2a  = (float*)(W + 576*1024);
  float* pdot = (float*)(W + 1216*1024);
  u8*    sel8 = (u8*)(W + 1400*1024);
  u32*   conn = (u32*)(W + 2*MB);
  u16*   WT0  = (u16*)(W + 3*MB);
  u16*   WoT  = (u16*)(W + 4*MB);
  u16*   WQT  = (u16*)(W + 5*MB);
  u16*   WPT  = WQT + 3*65536;
  u16*   sWxh = (u16*)(W + 5*MB + 512*1024);
  u16*   sWxl = sWxh + 65536;
  u16*   aWh  = sWxl + 65536;
  u16*   aWl  = aWh + 65536;
  u16*   xh   = (u16*)(W + 6*MB);
  u16*   xl   = (u16*)(W + 10*MB);
  float* S0   = (float*)(W + 14*MB);
  u16*   fah  = (u16*)(W + 22*MB);
  u16*   fal  = (u16*)(W + 26*MB);
  u16*   T2   = (u16*)(W + 30*MB);

  // prep (everything fragment-packed)
  k_split<<<BN*DD/2048,256,0,stream>>>(x, xh, xl);
  k_transpose<<<dim3(4,4,HG),256,0,stream>>>(gat_W, WT0, 256, 65536, 256);
  k_transpose<<<dim3(4,32,1),256,0,stream>>>(gat_Wo, WoT, 2048, 0, 2048);
  k_transpose4<<<dim3(4,4,4),256,0,stream>>>(ca_Wq, ca_Wk, ca_Wv, ca_Wp, WQT);
  k_transp_split<<<dim3(4,4,1),256,0,stream>>>(sim_Wx, sWxh, sWxl);
  k_transp_split<<<dim3(4,4,1),256,0,stream>>>(adj_W, aWh, aWl);

  hipMemsetAsync(pq, 0, (2048+16)*sizeof(float), stream);
  hipMemsetAsync(pdot, 0, BN*sizeof(float), stream);
  k_posq<<<dim3(BB,16),256,0,stream>>>(x, mask, pq, cnt);
  k_sq<<<BB,256,0,stream>>>(pq, cnt, sim_Wq, sq);
  k_msgemm<5><<<dim3(4,128),256,0,stream>>>(xh, xl, sWxh, sWxl, nullptr, nullptr, nullptr, sq, pdot); // y-dot fold
  k_simsel2<<<BN/256,256,0,stream>>>(pdot, simOut, sel8);
  k_msgemm<4><<<dim3(4,128),256,0,stream>>>(xh, xl, aWh, aWl, nullptr, fah, fal, nullptr, nullptr);   // fa gram-packed
  k_mconnect2<<<dim3(136,1,BB),256,0,stream>>>(fah, fal, sel8, conn);

  if (big){
    u16* WhP   = (u16*)(W + 66*MB);   // attention-packed Wh_cat, 32MB
    u16* htcat = (u16*)(W + 34*MB);   // fragment-packed (gpK 2048) ht_cat, 32MB
    u16* S0P   = (u16*)(W + 22*MB);   // attention-packed Who, 4MB (fah dead after mconnect)
    u16* qx = (u16*)(W + 34*MB);      // after htcat consumed
    u16* kv = (u16*)(W + 38*MB);
    u16* qb = (u16*)(W + 42*MB);
    u16* vb = (u16*)(W + 50*MB);
    u16* Ob = (u16*)(W + 54*MB);

    hipMemsetAsync(s1a, 0, 512*1024, stream);  // s1a(256K) + s2a(256K) contiguous
    k_mgemm<7,1,1><<<dim3(32,128),256,0,stream>>>(xh, WT0, 256, 256, 0, nullptr, nullptr, nullptr, nullptr,
                                                  WhP, gat_a1, gat_a2, s1a, s2a);  // WhP pack + s1s2 fold
    k_rowmax<<<dim3(BN/4,HG),256,0,stream>>>(s2a, conn, M2a);
    k_mattn5<4,true,2048><<<dim3(1,128,HG),256,0,stream>>>(s1a, s2a, M2a, conn, WhP, 256, htcat, 2048);
    hipMemsetAsync(s1a, 0, BN*sizeof(float), stream);
    hipMemsetAsync(s2a, 0, BN*sizeof(float), stream);
    k_mgemm<8,1,1,4><<<dim3(4,128),256,0,stream>>>(htcat, WoT, 2048, 2048, 0, nullptr, nullptr, nullptr, nullptr,
                                                   S0P, gat_ao1, gat_ao2, s1a, s2a);  // S0P pack + s1s2 fold
    k_rowmax<<<dim3(BN/4,1),256,0,stream>>>(s2a, conn, M2a);
    k_mattn5<1,false,0><<<dim3(4,128,1),256,0,stream>>>(s1a, s2a, M2a, conn, S0P, 0, T2, 256);  // gout

    k_ln_x<<<BN/4,256,0,stream>>>(x, ln3_g, ln3_b, qx);
    k_ln_kv<<<BN/4,256,0,stream>>>(T2, pe, sel8, ln4_g, ln4_b, kv);
    k_mgemm3<<<dim3(4,128,3),256,0,stream>>>(qx, kv, WQT, qb);     // qb,kb,vb (stride 4MB)
    k_mca_av2<<<dim3(16,HC,BB),256,0,stream>>>(qb, qb + 2097152, vb, sel8, Ob);
    k_mgemm<2,1,1,4><<<dim3(4,128),256,0,stream>>>(Ob, WPT, 256, 256, 0, out, x, gamma, nullptr, nullptr,
                                                   nullptr, nullptr, nullptr, nullptr);
  } else {
    // small-ws fallback: per-head loop, packed kernels (rarely taken)
    u16* T0 = fah;
    u16* T1 = fal;
    u16* S0b = (u16*)S0;
    hipMemsetAsync(s1a, 0, 512*1024, stream);
    for (int h=0;h<HG;h++){
      hipMemsetAsync(s1a, 0, BN*sizeof(float), stream);
      hipMemsetAsync(s2a, 0, BN*sizeof(float), stream);
      k_mgemm<8,1,1><<<dim3(4,128),256,0,stream>>>(xh, WT0 + (size_t)h*65536, 256, 256, 0,
                                                   nullptr, nullptr, nullptr, nullptr, T0,
                                                   gat_a1 + h*DD, gat_a2 + h*DD, s1a, s2a);
      k_rowmax<<<dim3(BN/4,1),256,0,stream>>>(s2a, conn, M2a);
      k_mattn5<1,false,0><<<dim3(4,128,1),256,0,stream>>>(s1a, s2a, M2a, conn, T0, 0, T1, 256);
      k_mgemm<1,0,1><<<dim3(4,128),256,0,stream>>>(T1, WoT, 256, 2048, h*256, S0, nullptr, nullptr, nullptr, nullptr,
                                                   nullptr, nullptr, nullptr, nullptr);
    }
    hipMemsetAsync(s1a, 0, BN*sizeof(float), stream);
    hipMemsetAsync(s2a, 0, BN*sizeof(float), stream);
    k_mattn5<1,false,0><<<dim3(4,128,1),256,0,stream>>>(s1a, s2a, M2a, conn, (u16*)S0, 0, T2, 256);
    k_ln_x<<<BN/4,256,0,stream>>>(x, ln3_g, ln3_b, T1);
    k_ln_kv<<<BN/4,256,0,stream>>>(T2, pe, sel8, ln4_g, ln4_b, T0);
    k_mgemm3<<<dim3(4,128,3),256,0,stream>>>(T1, T0, WQT, S0b);
    k_mca_av2<<<dim3(16,HC,BB),256,0,stream>>>(S0b, S0b + 2097152, S0b + 4194304, sel8, T0);
    k_mgemm<2,1,1><<<dim3(4,128),256,0,stream>>>(T0, WPT, 256, 256, 0, out, x, gamma, nullptr, nullptr,
                                                 nullptr, nullptr, nullptr, nullptr);
  }
}

// Round 15
// 462.897 us; speedup vs baseline: 1.1730x; 1.0109x over previous
//
#include <hip/hip_runtime.h>
#include <hip/hip_bf16.h>

// GATFusionBlockPosOnly: B=8, N=1024, D=256, 8 GAT heads, 4 CA heads.
// Round 24:
//  - R23 landed (468us). #1 k_mattn5 L1 63us (VALU 53, ~75% busy) — leaving it.
//  - Target invisible #2: k_mca_av2 still stages K/V/Q via LDS with 4 barriers
//    per 64-m iter. mgemm3 now emits qb/kb gpK-packed and vb packIdx-packed ->
//    all QK^T/PV fragments are direct contiguous 16B loads.
//  - k_mca_av3: P transpose is INTRA-WAVE (own 16-row slice) -> private per-wave
//    LDS slice, ZERO __syncthreads. K/V fragments issued early (R22 pattern).
//    Online-softmax math bit-identical.

#define BB 8
#define NN 1024
#define DD 256
#define HG 8
#define HC 4
#define BN (BB*NN)

typedef unsigned short u16;
typedef unsigned int u32;
typedef unsigned char u8;
typedef __attribute__((ext_vector_type(8))) short s8v;   // 8 bf16
typedef __attribute__((ext_vector_type(4))) float f4v;   // 4 fp32 acc
#define MFMA(a,b,c) __builtin_amdgcn_mfma_f32_16x16x32_bf16((a),(b),(c),0,0,0)

__device__ __forceinline__ u16 f2b(float x){
  union{ float f; unsigned u; } a; a.f = x;
  unsigned r = a.u + 0x7fff + ((a.u>>16)&1);
  return (u16)(r>>16);
}
__device__ __forceinline__ float b2f(u16 b){ return __uint_as_float(((unsigned)b)<<16); }
__device__ __forceinline__ float4 ld4bf(const u16* p){
  uint2 u = *(const uint2*)p;
  float4 r;
  r.x=__uint_as_float(u.x<<16); r.y=__uint_as_float(u.x&0xffff0000u);
  r.z=__uint_as_float(u.y<<16); r.w=__uint_as_float(u.y&0xffff0000u);
  return r;
}
__device__ __forceinline__ void load8(const float* p, float* v){
  float4 a=*(const float4*)p, b=*(const float4*)(p+4);
  v[0]=a.x;v[1]=a.y;v[2]=a.z;v[3]=a.w;v[4]=b.x;v[5]=b.y;v[6]=b.z;v[7]=b.w;
}
__device__ __forceinline__ float wredsum(float v){
  #pragma unroll
  for(int o=32;o>0;o>>=1) v += __shfl_xor(v,o);
  return v;
}
__device__ __forceinline__ float wredmax(float v){
  #pragma unroll
  for(int o=32;o>0;o>>=1) v = fmaxf(v,__shfl_xor(v,o));
  return v;
}
__device__ __forceinline__ float eluf(float x){ return x>0.f ? x : __expf(x)-1.f; }
__device__ __forceinline__ float leakyf(float z){ return z>=0.f ? z : 0.2f*z; }
__device__ __forceinline__ float exp0(float a){ return __expf(fminf(a, 0.f)); }
__device__ __forceinline__ float flushf(float v){ return (fabsf(v) < 1.0e30f) ? v : 0.f; }
__device__ __forceinline__ u32 pk2(float lo, float hi){
  u32 r;
  asm("v_cvt_pk_bf16_f32 %0, %1, %2" : "=v"(r) : "v"(lo), "v"(hi));
  return r;
}

// packed index for element (col, m) of the attention-V pack:  b=m>>10, kk=m&1023
__device__ __forceinline__ size_t packIdx(int col, int row){
  int kk = row & 1023;
  return ((((size_t)(col>>4))*8 + (row>>10))*32 + (kk>>5))*512
       + (size_t)(((((kk>>3)&3)*16) + (col&15))*8 + (kk&7));
}

// fragment-pack: element (row, k) of a [rows][KK] operand -> fragment order.
__device__ __forceinline__ size_t gpK(int row, int k, int KK){
  return (size_t)(row>>4)*((size_t)16*KK) + (size_t)(k>>5)*512
       + (size_t)(((((k>>3)&3)*16) + (row&15))*8 + (k&7));
}

// ---------- fp32 -> (hi,lo) bf16 split, packed output (gpK, KK=256) ----------
__global__ __launch_bounds__(256) void k_split(const float* __restrict__ X, u16* __restrict__ H, u16* __restrict__ Lo){
  size_t i = ((size_t)blockIdx.x*256 + threadIdx.x)*8;
  float v[8]; load8(X+i, v);
  u16 hh[8], ll[8];
  #pragma unroll
  for (int j=0;j<8;j++){ hh[j]=f2b(v[j]); ll[j]=f2b(v[j]-b2f(hh[j])); }
  int row = (int)(i>>8), col = (int)(i&255);
  size_t off = gpK(row, col, 256);
  *(uint4*)(H+off)=*(uint4*)&hh[0];
  *(uint4*)(Lo+off)=*(uint4*)&ll[0];
}

// ---------- transpose fp32 [R][C] -> bf16; pkKK=0: row-major [C][R]; else gpK packed ----------
__global__ __launch_bounds__(256) void k_transpose(const float* __restrict__ S, u16* __restrict__ D,
                                                   int R, int sliceElems, int pkKK){
  __shared__ float tl[64][65];
  const float* src = S + (size_t)blockIdx.z*sliceElems;
  u16* dst = D + (size_t)blockIdx.z*sliceElems;
  int C = gridDim.x*64;
  int bx=blockIdx.x*64, by=blockIdx.y*64;
  int tid=threadIdx.x, r=tid>>2, c0=(tid&3)*16;
  #pragma unroll
  for (int i=0;i<16;i+=4){
    float4 v = *(const float4*)(src + (size_t)(by+r)*C + bx + c0 + i);
    tl[r][c0+i]=v.x; tl[r][c0+i+1]=v.y; tl[r][c0+i+2]=v.z; tl[r][c0+i+3]=v.w;
  }
  __syncthreads();
  u16 tmp[16];
  #pragma unroll
  for (int i=0;i<16;i++) tmp[i] = f2b(tl[c0+i][r]);
  if (pkKK){
    *(uint4*)(dst + gpK(bx+r, by+c0,     pkKK)) = *(uint4*)&tmp[0];
    *(uint4*)(dst + gpK(bx+r, by+c0+8,   pkKK)) = *(uint4*)&tmp[8];
  } else {
    *(uint4*)(dst + (size_t)(bx+r)*R + by + c0)     = *(uint4*)&tmp[0];
    *(uint4*)(dst + (size_t)(bx+r)*R + by + c0 + 8) = *(uint4*)&tmp[8];
  }
}

// ---------- 4x 256x256 transposes, PACKED (gpK 256) output; grid (4,4,4) ----------
__global__ __launch_bounds__(256) void k_transpose4(const float* __restrict__ Sa, const float* __restrict__ Sb,
    const float* __restrict__ Sc, const float* __restrict__ Sd, u16* __restrict__ D){
  __shared__ float tl[64][65];
  const float* src = blockIdx.z==0 ? Sa : blockIdx.z==1 ? Sb : blockIdx.z==2 ? Sc : Sd;
  u16* dst = D + (size_t)blockIdx.z*65536;
  int bx=blockIdx.x*64, by=blockIdx.y*64;
  int tid=threadIdx.x, r=tid>>2, c0=(tid&3)*16;
  #pragma unroll
  for (int i=0;i<16;i+=4){
    float4 v = *(const float4*)(src + (size_t)(by+r)*256 + bx + c0 + i);
    tl[r][c0+i]=v.x; tl[r][c0+i+1]=v.y; tl[r][c0+i+2]=v.z; tl[r][c0+i+3]=v.w;
  }
  __syncthreads();
  u16 tmp[16];
  #pragma unroll
  for (int i=0;i<16;i++) tmp[i] = f2b(tl[c0+i][r]);
  *(uint4*)(dst + gpK(bx+r, by+c0,   256)) = *(uint4*)&tmp[0];
  *(uint4*)(dst + gpK(bx+r, by+c0+8, 256)) = *(uint4*)&tmp[8];
}

// ---------- transpose + split: fp32 [256][256] -> hi/lo bf16 PACKED (gpK 256) ----------
__global__ __launch_bounds__(256) void k_transp_split(const float* __restrict__ S, u16* __restrict__ DH, u16* __restrict__ DL){
  __shared__ float tl[64][65];
  int bx=blockIdx.x*64, by=blockIdx.y*64;
  int tid=threadIdx.x, r=tid>>2, c0=(tid&3)*16;
  #pragma unroll
  for (int i=0;i<16;i+=4){
    float4 v = *(const float4*)(S + (size_t)(by+r)*256 + bx + c0 + i);
    tl[r][c0+i]=v.x; tl[r][c0+i+1]=v.y; tl[r][c0+i+2]=v.z; tl[r][c0+i+3]=v.w;
  }
  __syncthreads();
  u16 th[16], tll[16];
  #pragma unroll
  for (int i=0;i<16;i++){
    float v = tl[c0+i][r];
    th[i]=f2b(v); tll[i]=f2b(v - b2f(th[i]));
  }
  size_t o0 = gpK(bx+r, by+c0,   256);
  size_t o1 = gpK(bx+r, by+c0+8, 256);
  *(uint4*)(DH + o0) = *(uint4*)&th[0];
  *(uint4*)(DH + o1) = *(uint4*)&th[8];
  *(uint4*)(DL + o0) = *(uint4*)&tll[0];
  *(uint4*)(DL + o1) = *(uint4*)&tll[8];
}

// ---------- pos_query ----------
__global__ __launch_bounds__(256) void k_posq(const float* __restrict__ x, const int* __restrict__ mask,
                                              float* __restrict__ pq, float* __restrict__ cnt){
  int b = blockIdx.x, chunk = blockIdx.y;
  int d = threadIdx.x;
  int n0 = chunk*64;
  float acc = 0.f; float c = 0.f;
  for (int i=0;i<64;i++){
    int n = n0+i;
    if (mask[b*NN+n]==1){ acc += x[((size_t)(b*NN+n))*DD + d]; c += 1.f; }
  }
  atomicAdd(&pq[b*DD+d], acc);
  if (d==0) atomicAdd(&cnt[b], c);
}

__global__ __launch_bounds__(256) void k_sq(const float* __restrict__ pq, const float* __restrict__ cnt,
                                            const float* __restrict__ Wq, float* __restrict__ sq){
  int b = blockIdx.x, e = threadIdx.x;
  float inv = 1.f / fmaxf(cnt[b], 1.f);
  float acc=0.f;
  for (int d0=0; d0<DD; d0++) acc += (pq[b*DD+d0]*inv) * Wq[d0*DD+e];
  sq[b*DD+e] = acc;
}

// ---------- sigmoid + threshold from folded dot ----------
__global__ __launch_bounds__(256) void k_simsel2(const float* __restrict__ pdot,
                                                 float* __restrict__ simOut, u8* __restrict__ sel8){
  int r = blockIdx.x*256 + threadIdx.x;
  float s = pdot[r] * 0.0625f;
  float sim = 1.f/(1.f+expf(-s));
  simOut[r] = sim;
  sel8[r] = (sim > 0.97f) ? 1 : 0;
}

// ---------- no-LDS MFMA GEMM: out[8192, OC] = A[8192,KK] @ BT[OC,KK]^T ----------
// APK: A fragment-packed (gpK, KK). BPK: BT fragment-packed (gpK, ldB total K; kOff = K start).
// UNR: load-batch depth (use >1 only on block-limited grids; R21 spill lesson).
// EPI: 0=C fp32, 1=C+=, 2=residual+gamma, 3=O bf16,
//      7=Pk pack + s1/s2 fold (head=colBase>>8), 8=Pk pack + s1/s2 fold (single head)
template<int EPI, int APK, int BPK, int UNR=1>
__global__ __launch_bounds__(256) void k_mgemm(const u16* __restrict__ A, const u16* __restrict__ BT,
    int KK, int ldB, int kOff, float* __restrict__ C, const float* __restrict__ Xres,
    const float* __restrict__ gamma, u16* __restrict__ O, u16* __restrict__ Pk,
    const float* __restrict__ A1, const float* __restrict__ A2,
    float* __restrict__ s1g, float* __restrict__ s2g){
  int tid=threadIdx.x, w=tid>>6, lane=tid&63, L=lane&15, q=lane>>4;
  int OC = gridDim.x<<6;
  int colBase=blockIdx.x<<6, rowBase=blockIdx.y<<6;
  const u16* ap;
  if constexpr (APK) ap = A + (size_t)((rowBase>>4)+w)*((size_t)16*KK) + (size_t)lane*8;
  else               ap = A + (size_t)(rowBase + w*16 + L)*KK + q*8;
  const u16* bp[4];
  #pragma unroll
  for (int t=0;t<4;t++){
    if constexpr (BPK) bp[t] = BT + (size_t)((colBase>>4)+t)*((size_t)16*ldB) + (size_t)(kOff>>5)*512 + (size_t)lane*8;
    else               bp[t] = BT + (size_t)(colBase + t*16 + L)*ldB + q*8 + kOff;
  }
  f4v z4={0.f,0.f,0.f,0.f};
  f4v acc[4]={z4,z4,z4,z4};
  int nk = KK>>5;
  for (int kc0=0;kc0<nk;kc0+=UNR){
    s8v a0[UNR], bt[UNR][4];
    #pragma unroll
    for (int u=0;u<UNR;u++){
      int kc = kc0 + u;
      if constexpr (APK) a0[u] = *(const s8v*)(ap + (size_t)kc*512);
      else               a0[u] = *(const s8v*)(ap + kc*32);
      #pragma unroll
      for (int t=0;t<4;t++){
        if constexpr (BPK) bt[u][t] = *(const s8v*)(bp[t] + (size_t)kc*512);
        else               bt[u][t] = *(const s8v*)(bp[t] + kc*32);
      }
    }
    #pragma unroll
    for (int u=0;u<UNR;u++)
      #pragma unroll
      for (int t=0;t<4;t++)
        acc[t]=MFMA(a0[u],bt[u][t],acc[t]);
  }
  if constexpr (EPI<=3){
    #pragma unroll
    for (int t=0;t<4;t++){
      int col = colBase + t*16 + L;
      #pragma unroll
      for (int reg=0;reg<4;reg++){
        int row = rowBase + w*16 + q*4 + reg;
        size_t off = (size_t)row*OC + col;
        float v = acc[t][reg];
        if constexpr (EPI==0){ C[off] = v; }
        else if constexpr (EPI==1){ C[off] += v; }
        else if constexpr (EPI==2){ C[off] = flushf(Xres[off] + gamma[col]*v); }
        else { O[off] = f2b(v); }
      }
    }
  } else {
    // s1/s2 fold
    float s1p[4]={0.f,0.f,0.f,0.f}, s2p[4]={0.f,0.f,0.f,0.f};
    #pragma unroll
    for (int t=0;t<4;t++){
      int col = colBase + t*16 + L;
      float a1v = A1[col], a2v = A2[col];
      #pragma unroll
      for (int reg=0;reg<4;reg++){
        float v = acc[t][reg];
        s1p[reg] += v*a1v;
        s2p[reg] += v*a2v;
      }
    }
    #pragma unroll
    for (int off=1;off<16;off<<=1)
      #pragma unroll
      for (int reg=0;reg<4;reg++){
        s1p[reg] += __shfl_xor(s1p[reg],off);
        s2p[reg] += __shfl_xor(s2p[reg],off);
      }
    if (L==0){
      int sOff = (EPI==7) ? (colBase>>8)*BN : 0;
      #pragma unroll
      for (int reg=0;reg<4;reg++){
        int row = rowBase + w*16 + q*4 + reg;
        atomicAdd(&s1g[sOff+row], s1p[reg]);
        atomicAdd(&s2g[sOff+row], s2p[reg]);
      }
    }
    // coalesced pack store (16B per lane, 8 consecutive rows of one column)
    int pq_ = q&1;
    int m0 = rowBase + w*16 + (q>>1)*8;
    #pragma unroll
    for (int tp=0;tp<2;tp++){
      f4v accA = acc[2*tp], accB = acc[2*tp+1];
      f4v mine   = pq_ ? accB : accA;
      f4v theirs = pq_ ? accA : accB;
      u32 k0 = pk2(mine[0],  mine[1]);
      u32 k1 = pk2(mine[2],  mine[3]);
      u32 s0 = pk2(theirs[0],theirs[1]);
      u32 s1 = pk2(theirs[2],theirs[3]);
      u32 r0 = (u32)__shfl_xor((int)s0,16);
      u32 r1 = (u32)__shfl_xor((int)s1,16);
      uint4 val = pq_==0 ? make_uint4(k0,k1,r0,r1) : make_uint4(r0,r1,k0,k1);
      int t = 2*tp + pq_;
      int col = colBase + t*16 + L;
      *(uint4*)(Pk + packIdx(col, m0)) = val;
    }
  }
}

// ---------- fused q/k/v projections, packed A+B (gpK 256); outputs packed:
// z=0 (q) and z=1 (k): gpK(row,col,256); z=2 (v): packIdx(col,row) ----------
__global__ __launch_bounds__(256) void k_mgemm3(const u16* __restrict__ Aq, const u16* __restrict__ Akv,
    const u16* __restrict__ BT0, u16* __restrict__ O0){
  int tid=threadIdx.x, w=tid>>6, lane=tid&63, L=lane&15, q=lane>>4;
  const u16* A = blockIdx.z==0 ? Aq : Akv;
  const u16* BT = BT0 + (size_t)blockIdx.z*65536;
  u16* O = O0 + (size_t)blockIdx.z*2097152;
  int colBase=blockIdx.x<<6, rowBase=blockIdx.y<<6;
  const u16* ap = A + (size_t)((rowBase>>4)+w)*4096 + (size_t)lane*8;
  f4v z4={0.f,0.f,0.f,0.f};
  f4v acc[4]={z4,z4,z4,z4};
  #pragma unroll
  for (int kc=0;kc<8;kc++){
    s8v a0 = *(const s8v*)(ap + kc*512);
    #pragma unroll
    for (int t=0;t<4;t++){
      s8v bt = *(const s8v*)(BT + (size_t)((colBase>>4)+t)*4096 + (size_t)kc*512 + (size_t)lane*8);
      acc[t]=MFMA(a0,bt,acc[t]);
    }
  }
  bool isV = (blockIdx.z==2);
  #pragma unroll
  for (int t=0;t<4;t++){
    int col = colBase + t*16 + L;
    #pragma unroll
    for (int reg=0;reg<4;reg++){
      int row = rowBase + w*16 + q*4 + reg;
      u16 hv = f2b(acc[t][reg]);
      if (isV) O[packIdx(col, row)] = hv;
      else     O[gpK(row, col, 256)] = hv;
    }
  }
}

// ---------- split (3-term) MFMA GEMM, packed A and B (gpK 256): KK=256, OC=256 ----------
// EPI 4: hi/lo bf16 gram-packed out.  EPI 5: sq-dot fold -> pdot.
template<int EPI>
__global__ __launch_bounds__(256) void k_msgemm(const u16* __restrict__ Ah, const u16* __restrict__ Al,
    const u16* __restrict__ Bh, const u16* __restrict__ Bl,
    float* __restrict__ C, u16* __restrict__ Oh, u16* __restrict__ Ol,
    const float* __restrict__ sq, float* __restrict__ pdot){
  int tid=threadIdx.x, w=tid>>6, lane=tid&63, L=lane&15, q=lane>>4;
  int colBase=blockIdx.x<<6, rowBase=blockIdx.y<<6;
  const u16* ahp = Ah + (size_t)((rowBase>>4)+w)*4096 + (size_t)lane*8;
  const u16* alp = Al + (size_t)((rowBase>>4)+w)*4096 + (size_t)lane*8;
  f4v z4={0.f,0.f,0.f,0.f};
  f4v acc[4]={z4,z4,z4,z4};
  #pragma unroll
  for (int kc=0;kc<8;kc++){
    s8v ah=*(const s8v*)(ahp + kc*512), al=*(const s8v*)(alp + kc*512);
    #pragma unroll
    for (int t=0;t<4;t++){
      size_t boff = (size_t)((colBase>>4)+t)*4096 + (size_t)kc*512 + (size_t)lane*8;
      s8v bh=*(const s8v*)(Bh + boff);
      s8v bl=*(const s8v*)(Bl + boff);
      acc[t]=MFMA(ah,bh,acc[t]);
      acc[t]=MFMA(ah,bl,acc[t]);
      acc[t]=MFMA(al,bh,acc[t]);
    }
  }
  if constexpr (EPI==5){
    int b = rowBase>>10;
    float pp[4]={0.f,0.f,0.f,0.f};
    #pragma unroll
    for (int t=0;t<4;t++){
      int col = colBase + t*16 + L;
      float qv = sq[b*256 + col];
      #pragma unroll
      for (int reg=0;reg<4;reg++) pp[reg] += acc[t][reg]*qv;
    }
    #pragma unroll
    for (int off=1;off<16;off<<=1)
      #pragma unroll
      for (int reg=0;reg<4;reg++) pp[reg] += __shfl_xor(pp[reg],off);
    if (L==0){
      #pragma unroll
      for (int reg=0;reg<4;reg++){
        int row = rowBase + w*16 + q*4 + reg;
        atomicAdd(&pdot[row], pp[reg]);
      }
    }
  } else {
    #pragma unroll
    for (int t=0;t<4;t++){
      int col = colBase + t*16 + L;
      #pragma unroll
      for (int reg=0;reg<4;reg++){
        int row = rowBase + w*16 + q*4 + reg;
        float v = acc[t][reg];
        if constexpr (EPI==0){ C[(size_t)row*256 + col] = v; }
        else {
          size_t off = gpK(row, col, 256);
          u16 h = f2b(v); Oh[off]=h; Ol[off]=f2b(v - b2f(h));
        }
      }
    }
  }
}

// ---------- gram + bitpack v2: packed fragments, symmetric tile enumeration ----------
__global__ __launch_bounds__(256) void k_mconnect2(const u16* __restrict__ fahP, const u16* __restrict__ falP,
    const u8* __restrict__ sel8, u32* __restrict__ conn){
  __shared__ u8 sg[64][64];
  __shared__ u8 selI[64], selJ[64];
  int tid=threadIdx.x, w=tid>>6, lane=tid&63, L=lane&15, q=lane>>4;
  int b=blockIdx.z;
  int p=blockIdx.x;
  int i = (int)((sqrtf(8.f*p+1.f)-1.f)*0.5f);
  while ((i+1)*(i+2)/2 <= p) i++;
  while (i*(i+1)/2 > p) i--;
  int j = p - i*(i+1)/2;          // i >= j, both 0..15
  if (tid < 64)        selI[tid]     = sel8[b*NN + i*64 + tid];
  else if (tid < 128)  selJ[tid-64]  = sel8[b*NN + j*64 + (tid-64)];
  const u16* ah0 = fahP + ((size_t)(b*64 + i*4 + w))*4096 + (size_t)lane*8;
  const u16* al0 = falP + ((size_t)(b*64 + i*4 + w))*4096 + (size_t)lane*8;
  const u16* bh0 = fahP + ((size_t)(b*64 + j*4))*4096 + (size_t)lane*8;
  const u16* bl0 = falP + ((size_t)(b*64 + j*4))*4096 + (size_t)lane*8;
  f4v z4={0.f,0.f,0.f,0.f};
  f4v acc[4]={z4,z4,z4,z4};
  #pragma unroll
  for (int kc=0;kc<8;kc++){
    s8v ah = *(const s8v*)(ah0 + kc*512);
    s8v al = *(const s8v*)(al0 + kc*512);
    #pragma unroll
    for (int t=0;t<4;t++){
      s8v bh = *(const s8v*)(bh0 + (size_t)t*4096 + kc*512);
      s8v bl = *(const s8v*)(bl0 + (size_t)t*4096 + kc*512);
      acc[t]=MFMA(ah,bh,acc[t]);
      acc[t]=MFMA(ah,bl,acc[t]);
      acc[t]=MFMA(al,bh,acc[t]);
    }
  }
  #pragma unroll
  for (int t=0;t<4;t++)
    #pragma unroll
    for (int reg=0;reg<4;reg++)
      sg[w*16 + q*4 + reg][t*16 + L] = acc[t][reg] > 0.f;
  __syncthreads();
  int row=(tid&127)>>1, ww=tid&1;
  if (tid<128){
    u32 word=0;
    if (selI[row]){
      #pragma unroll 8
      for (int jj=0;jj<32;jj++)
        if (sg[row][ww*32+jj] && selJ[ww*32+jj]) word |= (1u<<jj);
    }
    conn[((size_t)b*NN + i*64+row)*32 + j*2 + ww] = word;
  } else if (i != j){
    u32 word=0;
    if (selJ[row]){
      #pragma unroll 8
      for (int jj=0;jj<32;jj++)
        if (sg[ww*32+jj][row] && selI[ww*32+jj]) word |= (1u<<jj);
    }
    conn[((size_t)b*NN + j*64+row)*32 + i*2 + ww] = word;
  }
}

// ---------- row max of s2 over connected m ----------
__global__ __launch_bounds__(256) void k_rowmax(const float* __restrict__ s2a,
    const u32* __restrict__ conn, float* __restrict__ M2a){
  int h = blockIdx.y;
  int r = blockIdx.x*4 + (threadIdx.x>>6);
  int lane = threadIdx.x&63;
  int b = r>>10;
  const float* s2p = s2a + h*BN + b*NN;
  float mx = -3.0e38f;
  #pragma unroll
  for (int t=0;t<16;t++){
    int m = lane + t*64;
    u32 wd = conn[(size_t)r*32 + (m>>5)];
    if ((wd>>(m&31))&1u) mx = fmaxf(mx, s2p[m]);
  }
  mx = wredmax(mx);
  if (lane==0) M2a[h*BN+r] = mx;
}

// ---------- MFMA GAT attention v8: P shared via LDS; V loaded EARLY (single copy) ----------
// PKO: 0 = row-major output (stride oStride); else fragment-packed gpK(row,col,PKO).
template<int CT, bool SWZ, int PKO>
__global__ __launch_bounds__(256,4) void k_mattn5(const float* __restrict__ s1a, const float* __restrict__ s2a,
    const float* __restrict__ M2a, const u32* __restrict__ conn,
    const u16* __restrict__ P, int headMul, u16* __restrict__ Out, int oStride){
  __shared__ __align__(16) u16 Pb[2][4][512];
  __shared__ float Srow[64];
  int tid=threadIdx.x, w=tid>>6, lane=tid&63, L=lane&15, q=lane>>4;
  int h, rowBlk;
  if constexpr (SWZ){ h = blockIdx.y & 7; rowBlk = (blockIdx.y>>3) + (blockIdx.z<<4); }
  else             { h = blockIdx.z;     rowBlk = blockIdx.y; }
  int rowBase = rowBlk*64;
  int hOff = h*headMul, sOff = h*BN;
  int b = rowBase>>10;
  size_t bOff = (size_t)b*NN;
  int r = rowBase + w*16 + L;             // own row for P-build
  float s1v = s1a[sOff+r];
  float rmv = leakyf(s1v + M2a[sOff+r]);
  const float* s2p = s2a + sOff + bOff;
  const u32* cp = conn + (size_t)r*32;
  int tile0 = blockIdx.x*(4*CT) + w*CT;   // first col-tile owned by this wave
  const u16* vp = P + (size_t)((hOff>>4) + tile0)*131072 + (size_t)b*16384 + (size_t)lane*8;
  f4v z4={0.f,0.f,0.f,0.f};
  f4v acc[4][CT];
  #pragma unroll
  for (int g=0;g<4;g++)
    #pragma unroll
    for (int t=0;t<CT;t++) acc[g][t]=z4;
  float sumP = 0.f;
  for (int k0=0;k0<NN;k0+=32){
    int cur=(k0>>5)&1;
    u32 cw = cp[k0>>5];
    // issue THIS chunk's V loads first — latency hidden under P-build + barrier
    s8v vf[CT];
    {
      const u16* vk = vp + (size_t)(k0>>5)*512;
      #pragma unroll
      for (int t=0;t<CT;t++) vf[t] = *(const s8v*)(vk + (size_t)t*131072);
    }
    float4 sA = *(const float4*)(s2p + k0 + q*8);
    float4 sB = *(const float4*)(s2p + k0 + q*8 + 4);
    float s2v[8] = {sA.x,sA.y,sA.z,sA.w,sB.x,sB.y,sB.z,sB.w};
    float p[8];
    #pragma unroll
    for (int j=0;j<8;j++){
      float z = s1v + s2v[j];
      float ev = fmaxf(z, 0.2f*z);                      // leaky = max(z, 0.2z)
      ev = ((cw>>(q*8+j))&1u) ? ev : -9.0e15f;          // mask BEFORE exp (uniform rows!)
      p[j] = __expf(fminf(ev - rmv, 0.f));
      sumP += p[j];
    }
    union{ s8v v; u32 u[4]; } pk;
    #pragma unroll
    for (int jj=0;jj<4;jj++)
      pk.u[jj] = pk2(p[2*jj], p[2*jj+1]);
    *(s8v*)&Pb[cur][w][lane*8] = pk.v;    // ds_write_b128, contiguous
    __syncthreads();                       // all P fragments for this chunk visible
    s8v pa[4];
    #pragma unroll
    for (int g=0;g<4;g++) pa[g] = *(const s8v*)&Pb[cur][g][lane*8];
    #pragma unroll
    for (int t=0;t<CT;t++)
      #pragma unroll
      for (int g=0;g<4;g++) acc[g][t] = MFMA(pa[g], vf[t], acc[g][t]);
  }
  sumP += __shfl_xor(sumP,16);
  sumP += __shfl_xor(sumP,32);
  if (lane<16) Srow[w*16+lane] = sumP;
  __syncthreads();
  #pragma unroll
  for (int g=0;g<4;g++){
    float4 sv = *(const float4*)&Srow[g*16 + q*4];
    float rsi[4] = {1.f/sv.x, 1.f/sv.y, 1.f/sv.z, 1.f/sv.w};
    #pragma unroll
    for (int t=0;t<CT;t++){
      int col = hOff + (tile0+t)*16 + L;
      #pragma unroll
      for (int reg=0;reg<4;reg++){
        int row = rowBase + g*16 + q*4 + reg;
        float ov = eluf(acc[g][t][reg]*rsi[reg]);
        if constexpr (PKO) Out[gpK(row, col, PKO)] = f2b(ov);
        else               Out[(size_t)row*oStride + col] = f2b(ov);
      }
    }
  }
}

// ---------- LayerNorms (packed gpK-256 output) ----------
__global__ __launch_bounds__(256) void k_ln_x(const float* __restrict__ x, const float* __restrict__ g,
                                              const float* __restrict__ bb, u16* __restrict__ out){
  int r = blockIdx.x*4 + (threadIdx.x>>6);
  int lane=threadIdx.x&63;
  float4 v = *(const float4*)(x + (size_t)r*DD + lane*4);
  float s = v.x+v.y+v.z+v.w;
  float s2 = v.x*v.x+v.y*v.y+v.z*v.z+v.w*v.w;
  s = wredsum(s); s2 = wredsum(s2);
  float mean = s*(1.f/256.f);
  float var = s2*(1.f/256.f) - mean*mean;
  float rstd = rsqrtf(var + 1e-5f);
  float4 gv = *(const float4*)(g+lane*4), bv = *(const float4*)(bb+lane*4);
  u16 t[4];
  t[0]=f2b((v.x-mean)*rstd*gv.x+bv.x); t[1]=f2b((v.y-mean)*rstd*gv.y+bv.y);
  t[2]=f2b((v.z-mean)*rstd*gv.z+bv.z); t[3]=f2b((v.w-mean)*rstd*gv.w+bv.w);
  *(uint2*)(out + gpK(r, lane*4, 256)) = *(uint2*)&t[0];
}

__global__ __launch_bounds__(256) void k_ln_kv(const u16* __restrict__ gout, const float* __restrict__ pe,
    const u8* __restrict__ sel8, const float* __restrict__ g, const float* __restrict__ bb,
    u16* __restrict__ out){
  int r = blockIdx.x*4 + (threadIdx.x>>6);
  int lane=threadIdx.x&63;
  int n = r & 1023;
  float4 v = make_float4(0.f,0.f,0.f,0.f);
  if (sel8[r]){
    float4 gv = ld4bf(gout + (size_t)r*DD + lane*4);
    float4 pv = *(const float4*)(pe + (size_t)n*DD + lane*4);
    v = make_float4(gv.x+pv.x, gv.y+pv.y, gv.z+pv.z, gv.w+pv.w);
  }
  float s = v.x+v.y+v.z+v.w;
  float s2 = v.x*v.x+v.y*v.y+v.z*v.z+v.w*v.w;
  s = wredsum(s); s2 = wredsum(s2);
  float mean = s*(1.f/256.f);
  float var = s2*(1.f/256.f) - mean*mean;
  float rstd = rsqrtf(var + 1e-5f);
  float4 gv = *(const float4*)(g+lane*4), bv = *(const float4*)(bb+lane*4);
  u16 t[4];
  t[0]=f2b((v.x-mean)*rstd*gv.x+bv.x); t[1]=f2b((v.y-mean)*rstd*gv.y+bv.y);
  t[2]=f2b((v.z-mean)*rstd*gv.z+bv.z); t[3]=f2b((v.w-mean)*rstd*gv.w+bv.w);
  *(uint2*)(out + gpK(r, lane*4, 256)) = *(uint2*)&t[0];
}

// ---------- CA attention v3: barrier-free flash; direct fragment loads ----------
// q,k: gpK-packed (KK=256). v: packIdx-packed. O: gpK-packed. P transpose is
// intra-wave via a private per-wave LDS slice -> ZERO __syncthreads.
__global__ __launch_bounds__(256) void k_mca_av3(const u16* __restrict__ q, const u16* __restrict__ k,
    const u16* __restrict__ v, const u8* __restrict__ sel8, u16* __restrict__ O){
  __shared__ __align__(16) u16 Pw[4][16][72];
  int tid=threadIdx.x;
  int w = tid>>6, lane = tid&63, L = lane&15, qd = lane>>4;
  int b=blockIdx.z, h=blockIdx.y, rowBase=blockIdx.x*64;
  size_t bOff = (size_t)b*NN;
  // Q A-fragments (2 k-chunks covering this head's 64 dims)
  const u16* qbase = q + (size_t)((bOff + rowBase + w*16)>>4)*4096 + (size_t)lane*8;
  s8v af0 = *(const s8v*)(qbase + (size_t)(h*2+0)*512);
  s8v af1 = *(const s8v*)(qbase + (size_t)(h*2+1)*512);
  float rm[4], sp[4];
  #pragma unroll
  for (int reg=0;reg<4;reg++){ rm[reg] = -3.0e38f; sp[reg] = 0.f; }
  f4v zero = {0.f,0.f,0.f,0.f};
  f4v acc[4] = {zero,zero,zero,zero};
  for (int m0=0;m0<NN;m0+=64){
    // K B-fragments (issued early)
    s8v bt[4][2];
    #pragma unroll
    for (int t=0;t<4;t++){
      const u16* kb = k + (size_t)((bOff + m0 + t*16)>>4)*4096 + (size_t)lane*8;
      bt[t][0] = *(const s8v*)(kb + (size_t)(h*2+0)*512);
      bt[t][1] = *(const s8v*)(kb + (size_t)(h*2+1)*512);
    }
    // V B-fragments (issued early, consumed after softmax)
    s8v vf[4][2];
    #pragma unroll
    for (int t=0;t<4;t++){
      const u16* vb = v + (size_t)(((h*4+t)*8 + b)*32 + (m0>>5))*512 + (size_t)lane*8;
      vf[t][0] = *(const s8v*)vb;
      vf[t][1] = *(const s8v*)(vb + 512);
    }
    f4v sa[4] = {zero,zero,zero,zero};
    #pragma unroll
    for (int t=0;t<4;t++){
      sa[t] = MFMA(af0, bt[t][0], sa[t]);
      sa[t] = MFMA(af1, bt[t][1], sa[t]);
    }
    // online-softmax update (row-consistent max via L-group reduce) — unchanged math
    float vals[4][4];
    float tmax[4];
    #pragma unroll
    for (int reg=0;reg<4;reg++) tmax[reg] = -3.0e38f;
    #pragma unroll
    for (int t=0;t<4;t++){
      int m = m0 + t*16 + L;
      bool sl = sel8[b*NN+m];
      #pragma unroll
      for (int reg=0;reg<4;reg++){
        float val = sl ? sa[t][reg]*0.125f : -1.0e9f;
        vals[t][reg] = val;
        tmax[reg] = fmaxf(tmax[reg], val);
      }
    }
    #pragma unroll
    for (int off=1;off<16;off<<=1)
      #pragma unroll
      for (int reg=0;reg<4;reg++) tmax[reg] = fmaxf(tmax[reg], __shfl_xor(tmax[reg],off));
    float sc[4];
    #pragma unroll
    for (int reg=0;reg<4;reg++){
      float nm = fmaxf(rm[reg], tmax[reg]);
      sc[reg] = exp0(rm[reg] - nm);
      rm[reg] = nm;
      sp[reg] *= sc[reg];
    }
    #pragma unroll
    for (int t=0;t<4;t++){
      #pragma unroll
      for (int reg=0;reg<4;reg++){
        float pv = exp0(vals[t][reg] - rm[reg]);
        sp[reg] += pv;
        Pw[w][qd*4 + reg][t*16 + L] = f2b(pv);   // intra-wave slice, no barrier
      }
    }
    #pragma unroll
    for (int t=0;t<4;t++)
      #pragma unroll
      for (int reg=0;reg<4;reg++) acc[t][reg] *= sc[reg];
    #pragma unroll
    for (int mc2=0;mc2<2;mc2++){
      s8v pf = *(const s8v*)&Pw[w][L][mc2*32 + qd*8];
      #pragma unroll
      for (int t=0;t<4;t++)
        acc[t] = MFMA(pf, vf[t][mc2], acc[t]);
    }
  }
  #pragma unroll
  for (int off=1;off<16;off<<=1)
    #pragma unroll
    for (int reg=0;reg<4;reg++) sp[reg] += __shfl_xor(sp[reg],off);
  float ri[4];
  #pragma unroll
  for (int reg=0;reg<4;reg++) ri[reg] = 1.f/sp[reg];
  #pragma unroll
  for (int t=0;t<4;t++){
    int col = h*64 + t*16 + L;
    #pragma unroll
    for (int reg=0;reg<4;reg++){
      int row = (int)bOff + rowBase + w*16 + qd*4 + reg;
      O[gpK(row, col, 256)] = f2b(acc[t][reg]*ri[reg]);
    }
  }
}

extern "C" void kernel_launch(void* const* d_in, const int* in_sizes, int n_in,
                              void* d_out, int out_size, void* d_ws, size_t ws_size,
                              hipStream_t stream) {
  (void)in_sizes; (void)n_in; (void)out_size;
  const float* x      = (const float*)d_in[0];
  const int*   mask   = (const int*  )d_in[1];
  const float* pe     = (const float*)d_in[2];
  const float* sim_Wx = (const float*)d_in[3];
  const float* sim_Wq = (const float*)d_in[4];
  const float* adj_W  = (const float*)d_in[5];
  const float* gat_W  = (const float*)d_in[6];
  const float* gat_a1 = (const float*)d_in[7];
  const float* gat_a2 = (const float*)d_in[8];
  const float* gat_Wo = (const float*)d_in[9];
  const float* gat_ao1= (const float*)d_in[10];
  const float* gat_ao2= (const float*)d_in[11];
  const float* ln3_g  = (const float*)d_in[12];
  const float* ln3_b  = (const float*)d_in[13];
  const float* ln4_g  = (const float*)d_in[14];
  const float* ln4_b  = (const float*)d_in[15];
  const float* ca_Wq  = (const float*)d_in[16];
  const float* ca_Wk  = (const float*)d_in[17];
  const float* ca_Wv  = (const float*)d_in[18];
  const float* ca_Wp  = (const float*)d_in[19];
  const float* gamma  = (const float*)d_in[20];
  float* out    = (float*)d_out;
  float* simOut = out + (size_t)BN*DD;

  const size_t MB = 1024*1024;
  bool big = ws_size >= 98*MB;
  char* W = (char*)d_ws;
  float* pq   = (float*)W;
  float* cnt  = pq + 2048;
  float* sq   = cnt + 16;
  float* s1a  = (float*)(W + 64*1024);
  float* s2a  = (float*)(W + 320*1024);
  float* M2a  = (float*)(W + 576*1024);
  float* pdot = (float*)(W + 1216*1024);
  u8*    sel8 = (u8*)(W + 1400*1024);
  u32*   conn = (u32*)(W + 2*MB);
  u16*   WT0  = (u16*)(W + 3*MB);
  u16*   WoT  = (u16*)(W + 4*MB);
  u16*   WQT  = (u16*)(W + 5*MB);
  u16*   WPT  = WQT + 3*65536;
  u16*   sWxh = (u16*)(W + 5*MB + 512*1024);
  u16*   sWxl = sWxh + 65536;
  u16*   aWh  = sWxl + 65536;
  u16*   aWl  = aWh + 65536;
  u16*   xh   = (u16*)(W + 6*MB);
  u16*   xl   = (u16*)(W + 10*MB);
  float* S0   = (float*)(W + 14*MB);
  u16*   fah  = (u16*)(W + 22*MB);
  u16*   fal  = (u16*)(W + 26*MB);
  u16*   T2   = (u16*)(W + 30*MB);

  // prep (everything fragment-packed)
  k_split<<<BN*DD/2048,256,0,stream>>>(x, xh, xl);
  k_transpose<<<dim3(4,4,HG),256,0,stream>>>(gat_W, WT0, 256, 65536, 256);
  k_transpose<<<dim3(4,32,1),256,0,stream>>>(gat_Wo, WoT, 2048, 0, 2048);
  k_transpose4<<<dim3(4,4,4),256,0,stream>>>(ca_Wq, ca_Wk, ca_Wv, ca_Wp, WQT);
  k_transp_split<<<dim3(4,4,1),256,0,stream>>>(sim_Wx, sWxh, sWxl);
  k_transp_split<<<dim3(4,4,1),256,0,stream>>>(adj_W, aWh, aWl);

  hipMemsetAsync(pq, 0, (2048+16)*sizeof(float), stream);
  hipMemsetAsync(pdot, 0, BN*sizeof(float), stream);
  k_posq<<<dim3(BB,16),256,0,stream>>>(x, mask, pq, cnt);
  k_sq<<<BB,256,0,stream>>>(pq, cnt, sim_Wq, sq);
  k_msgemm<5><<<dim3(4,128),256,0,stream>>>(xh, xl, sWxh, sWxl, nullptr, nullptr, nullptr, sq, pdot); // y-dot fold
  k_simsel2<<<BN/256,256,0,stream>>>(pdot, simOut, sel8);
  k_msgemm<4><<<dim3(4,128),256,0,stream>>>(xh, xl, aWh, aWl, nullptr, fah, fal, nullptr, nullptr);   // fa gram-packed
  k_mconnect2<<<dim3(136,1,BB),256,0,stream>>>(fah, fal, sel8, conn);

  if (big){
    u16* WhP   = (u16*)(W + 66*MB);   // attention-packed Wh_cat, 32MB
    u16* htcat = (u16*)(W + 34*MB);   // fragment-packed (gpK 2048) ht_cat, 32MB
    u16* S0P   = (u16*)(W + 22*MB);   // attention-packed Who, 4MB (fah dead after mconnect)
    u16* qx = (u16*)(W + 34*MB);      // after htcat consumed
    u16* kv = (u16*)(W + 38*MB);
    u16* qb = (u16*)(W + 42*MB);
    u16* vb = (u16*)(W + 50*MB);
    u16* Ob = (u16*)(W + 54*MB);

    hipMemsetAsync(s1a, 0, 512*1024, stream);  // s1a(256K) + s2a(256K) contiguous
    k_mgemm<7,1,1><<<dim3(32,128),256,0,stream>>>(xh, WT0, 256, 256, 0, nullptr, nullptr, nullptr, nullptr,
                                                  WhP, gat_a1, gat_a2, s1a, s2a);  // WhP pack + s1s2 fold
    k_rowmax<<<dim3(BN/4,HG),256,0,stream>>>(s2a, conn, M2a);
    k_mattn5<4,true,2048><<<dim3(1,128,HG),256,0,stream>>>(s1a, s2a, M2a, conn, WhP, 256, htcat, 2048);
    hipMemsetAsync(s1a, 0, BN*sizeof(float), stream);
    hipMemsetAsync(s2a, 0, BN*sizeof(float), stream);
    k_mgemm<8,1,1,4><<<dim3(4,128),256,0,stream>>>(htcat, WoT, 2048, 2048, 0, nullptr, nullptr, nullptr, nullptr,
                                                   S0P, gat_ao1, gat_ao2, s1a, s2a);  // S0P pack + s1s2 fold
    k_rowmax<<<dim3(BN/4,1),256,0,stream>>>(s2a, conn, M2a);
    k_mattn5<1,false,0><<<dim3(4,128,1),256,0,stream>>>(s1a, s2a, M2a, conn, S0P, 0, T2, 256);  // gout

    k_ln_x<<<BN/4,256,0,stream>>>(x, ln3_g, ln3_b, qx);
    k_ln_kv<<<BN/4,256,0,stream>>>(T2, pe, sel8, ln4_g, ln4_b, kv);
    k_mgemm3<<<dim3(4,128,3),256,0,stream>>>(qx, kv, WQT, qb);     // qb,kb gpK; vb packIdx
    k_mca_av3<<<dim3(16,HC,BB),256,0,stream>>>(qb, qb + 2097152, vb, sel8, Ob);
    k_mgemm<2,1,1,4><<<dim3(4,128),256,0,stream>>>(Ob, WPT, 256, 256, 0, out, x, gamma, nullptr, nullptr,
                                                   nullptr, nullptr, nullptr, nullptr);
  } else {
    // small-ws fallback: per-head loop, packed kernels (rarely taken)
    u16* T0 = fah;
    u16* T1 = fal;
    u16* S0b = (u16*)S0;
    hipMemsetAsync(s1a, 0, 512*1024, stream);
    for (int h=0;h<HG;h++){
      hipMemsetAsync(s1a, 0, BN*sizeof(float), stream);
      hipMemsetAsync(s2a, 0, BN*sizeof(float), stream);
      k_mgemm<8,1,1><<<dim3(4,128),256,0,stream>>>(xh, WT0 + (size_t)h*65536, 256, 256, 0,
                                                   nullptr, nullptr, nullptr, nullptr, T0,
                                                   gat_a1 + h*DD, gat_a2 + h*DD, s1a, s2a);
      k_rowmax<<<dim3(BN/4,1),256,0,stream>>>(s2a, conn, M2a);
      k_mattn5<1,false,0><<<dim3(4,128,1),256,0,stream>>>(s1a, s2a, M2a, conn, T0, 0, T1, 256);
      k_mgemm<1,0,1><<<dim3(4,128),256,0,stream>>>(T1, WoT, 256, 2048, h*256, S0, nullptr, nullptr, nullptr, nullptr,
                                                   nullptr, nullptr, nullptr, nullptr);
    }
    hipMemsetAsync(s1a, 0, BN*sizeof(float), stream);
    hipMemsetAsync(s2a, 0, BN*sizeof(float), stream);
    k_mattn5<1,false,0><<<dim3(4,128,1),256,0,stream>>>(s1a, s2a, M2a, conn, (u16*)S0, 0, T2, 256);
    k_ln_x<<<BN/4,256,0,stream>>>(x, ln3_g, ln3_b, T1);
    k_ln_kv<<<BN/4,256,0,stream>>>(T2, pe, sel8, ln4_g, ln4_b, T0);
    k_mgemm3<<<dim3(4,128,3),256,0,stream>>>(T1, T0, WQT, S0b);
    k_mca_av3<<<dim3(16,HC,BB),256,0,stream>>>(S0b, S0b + 2097152, S0b + 4194304, sel8, T0);
    k_mgemm<2,1,1><<<dim3(4,128),256,0,stream>>>(T0, WPT, 256, 256, 0, out, x, gamma, nullptr, nullptr,
                                                 nullptr, nullptr, nullptr, nullptr);
  }
}

// Round 16
// 446.899 us; speedup vs baseline: 1.2150x; 1.0358x over previous
//
#include <hip/hip_runtime.h>
#include <hip/hip_bf16.h>

// GATFusionBlockPosOnly: B=8, N=1024, D=256, 8 GAT heads, 4 CA heads.
// Round 25:
//  - R24 landed (463us). #1 k_mattn5 L1 62us (Mfma 22 / VALU 55, 77% busy).
//  - exp2 prescale: leaky commutes with positive scale -> fold a1/a2 * log2(e)
//    in mgemm<7/8> epilogue; mattn5 inner exp becomes bare v_exp_f32 (2^x).
//    Masked constants scale-agnostic (0 / uniform rows preserved). rowmax is
//    max (scale-invariant).
//  - k_posq: 128 blocks/64-iter -> 512 blocks/16-iter (latency).
//  - k_sq: 8 blocks/256-iter -> 128 blocks/16-iter, atomic accumulate (sq
//    added to the zeroing memset).

#define BB 8
#define NN 1024
#define DD 256
#define HG 8
#define HC 4
#define BN (BB*NN)
#define LOG2E 1.44269504088896f

typedef unsigned short u16;
typedef unsigned int u32;
typedef unsigned char u8;
typedef __attribute__((ext_vector_type(8))) short s8v;   // 8 bf16
typedef __attribute__((ext_vector_type(4))) float f4v;   // 4 fp32 acc
#define MFMA(a,b,c) __builtin_amdgcn_mfma_f32_16x16x32_bf16((a),(b),(c),0,0,0)

__device__ __forceinline__ u16 f2b(float x){
  union{ float f; unsigned u; } a; a.f = x;
  unsigned r = a.u + 0x7fff + ((a.u>>16)&1);
  return (u16)(r>>16);
}
__device__ __forceinline__ float b2f(u16 b){ return __uint_as_float(((unsigned)b)<<16); }
__device__ __forceinline__ float4 ld4bf(const u16* p){
  uint2 u = *(const uint2*)p;
  float4 r;
  r.x=__uint_as_float(u.x<<16); r.y=__uint_as_float(u.x&0xffff0000u);
  r.z=__uint_as_float(u.y<<16); r.w=__uint_as_float(u.y&0xffff0000u);
  return r;
}
__device__ __forceinline__ void load8(const float* p, float* v){
  float4 a=*(const float4*)p, b=*(const float4*)(p+4);
  v[0]=a.x;v[1]=a.y;v[2]=a.z;v[3]=a.w;v[4]=b.x;v[5]=b.y;v[6]=b.z;v[7]=b.w;
}
__device__ __forceinline__ float wredsum(float v){
  #pragma unroll
  for(int o=32;o>0;o>>=1) v += __shfl_xor(v,o);
  return v;
}
__device__ __forceinline__ float wredmax(float v){
  #pragma unroll
  for(int o=32;o>0;o>>=1) v = fmaxf(v,__shfl_xor(v,o));
  return v;
}
__device__ __forceinline__ float eluf(float x){ return x>0.f ? x : __expf(x)-1.f; }
__device__ __forceinline__ float leakyf(float z){ return z>=0.f ? z : 0.2f*z; }
__device__ __forceinline__ float exp0(float a){ return __expf(fminf(a, 0.f)); }
__device__ __forceinline__ float exp2z(float a){   // 2^min(a,0), bare v_exp
  float x = fminf(a, 0.f), r;
  asm("v_exp_f32 %0, %1" : "=v"(r) : "v"(x));
  return r;
}
__device__ __forceinline__ float flushf(float v){ return (fabsf(v) < 1.0e30f) ? v : 0.f; }
__device__ __forceinline__ u32 pk2(float lo, float hi){
  u32 r;
  asm("v_cvt_pk_bf16_f32 %0, %1, %2" : "=v"(r) : "v"(lo), "v"(hi));
  return r;
}

// packed index for element (col, m) of the attention-V pack:  b=m>>10, kk=m&1023
__device__ __forceinline__ size_t packIdx(int col, int row){
  int kk = row & 1023;
  return ((((size_t)(col>>4))*8 + (row>>10))*32 + (kk>>5))*512
       + (size_t)(((((kk>>3)&3)*16) + (col&15))*8 + (kk&7));
}

// fragment-pack: element (row, k) of a [rows][KK] operand -> fragment order.
__device__ __forceinline__ size_t gpK(int row, int k, int KK){
  return (size_t)(row>>4)*((size_t)16*KK) + (size_t)(k>>5)*512
       + (size_t)(((((k>>3)&3)*16) + (row&15))*8 + (k&7));
}

// ---------- fp32 -> (hi,lo) bf16 split, packed output (gpK, KK=256) ----------
__global__ __launch_bounds__(256) void k_split(const float* __restrict__ X, u16* __restrict__ H, u16* __restrict__ Lo){
  size_t i = ((size_t)blockIdx.x*256 + threadIdx.x)*8;
  float v[8]; load8(X+i, v);
  u16 hh[8], ll[8];
  #pragma unroll
  for (int j=0;j<8;j++){ hh[j]=f2b(v[j]); ll[j]=f2b(v[j]-b2f(hh[j])); }
  int row = (int)(i>>8), col = (int)(i&255);
  size_t off = gpK(row, col, 256);
  *(uint4*)(H+off)=*(uint4*)&hh[0];
  *(uint4*)(Lo+off)=*(uint4*)&ll[0];
}

// ---------- transpose fp32 [R][C] -> bf16; pkKK=0: row-major [C][R]; else gpK packed ----------
__global__ __launch_bounds__(256) void k_transpose(const float* __restrict__ S, u16* __restrict__ D,
                                                   int R, int sliceElems, int pkKK){
  __shared__ float tl[64][65];
  const float* src = S + (size_t)blockIdx.z*sliceElems;
  u16* dst = D + (size_t)blockIdx.z*sliceElems;
  int C = gridDim.x*64;
  int bx=blockIdx.x*64, by=blockIdx.y*64;
  int tid=threadIdx.x, r=tid>>2, c0=(tid&3)*16;
  #pragma unroll
  for (int i=0;i<16;i+=4){
    float4 v = *(const float4*)(src + (size_t)(by+r)*C + bx + c0 + i);
    tl[r][c0+i]=v.x; tl[r][c0+i+1]=v.y; tl[r][c0+i+2]=v.z; tl[r][c0+i+3]=v.w;
  }
  __syncthreads();
  u16 tmp[16];
  #pragma unroll
  for (int i=0;i<16;i++) tmp[i] = f2b(tl[c0+i][r]);
  if (pkKK){
    *(uint4*)(dst + gpK(bx+r, by+c0,     pkKK)) = *(uint4*)&tmp[0];
    *(uint4*)(dst + gpK(bx+r, by+c0+8,   pkKK)) = *(uint4*)&tmp[8];
  } else {
    *(uint4*)(dst + (size_t)(bx+r)*R + by + c0)     = *(uint4*)&tmp[0];
    *(uint4*)(dst + (size_t)(bx+r)*R + by + c0 + 8) = *(uint4*)&tmp[8];
  }
}

// ---------- 4x 256x256 transposes, PACKED (gpK 256) output; grid (4,4,4) ----------
__global__ __launch_bounds__(256) void k_transpose4(const float* __restrict__ Sa, const float* __restrict__ Sb,
    const float* __restrict__ Sc, const float* __restrict__ Sd, u16* __restrict__ D){
  __shared__ float tl[64][65];
  const float* src = blockIdx.z==0 ? Sa : blockIdx.z==1 ? Sb : blockIdx.z==2 ? Sc : Sd;
  u16* dst = D + (size_t)blockIdx.z*65536;
  int bx=blockIdx.x*64, by=blockIdx.y*64;
  int tid=threadIdx.x, r=tid>>2, c0=(tid&3)*16;
  #pragma unroll
  for (int i=0;i<16;i+=4){
    float4 v = *(const float4*)(src + (size_t)(by+r)*256 + bx + c0 + i);
    tl[r][c0+i]=v.x; tl[r][c0+i+1]=v.y; tl[r][c0+i+2]=v.z; tl[r][c0+i+3]=v.w;
  }
  __syncthreads();
  u16 tmp[16];
  #pragma unroll
  for (int i=0;i<16;i++) tmp[i] = f2b(tl[c0+i][r]);
  *(uint4*)(dst + gpK(bx+r, by+c0,   256)) = *(uint4*)&tmp[0];
  *(uint4*)(dst + gpK(bx+r, by+c0+8, 256)) = *(uint4*)&tmp[8];
}

// ---------- transpose + split: fp32 [256][256] -> hi/lo bf16 PACKED (gpK 256) ----------
__global__ __launch_bounds__(256) void k_transp_split(const float* __restrict__ S, u16* __restrict__ DH, u16* __restrict__ DL){
  __shared__ float tl[64][65];
  int bx=blockIdx.x*64, by=blockIdx.y*64;
  int tid=threadIdx.x, r=tid>>2, c0=(tid&3)*16;
  #pragma unroll
  for (int i=0;i<16;i+=4){
    float4 v = *(const float4*)(S + (size_t)(by+r)*256 + bx + c0 + i);
    tl[r][c0+i]=v.x; tl[r][c0+i+1]=v.y; tl[r][c0+i+2]=v.z; tl[r][c0+i+3]=v.w;
  }
  __syncthreads();
  u16 th[16], tll[16];
  #pragma unroll
  for (int i=0;i<16;i++){
    float v = tl[c0+i][r];
    th[i]=f2b(v); tll[i]=f2b(v - b2f(th[i]));
  }
  size_t o0 = gpK(bx+r, by+c0,   256);
  size_t o1 = gpK(bx+r, by+c0+8, 256);
  *(uint4*)(DH + o0) = *(uint4*)&th[0];
  *(uint4*)(DH + o1) = *(uint4*)&th[8];
  *(uint4*)(DL + o0) = *(uint4*)&tll[0];
  *(uint4*)(DL + o1) = *(uint4*)&tll[8];
}

// ---------- pos_query: grid (BB, 64), 16 rows per block ----------
__global__ __launch_bounds__(256) void k_posq(const float* __restrict__ x, const int* __restrict__ mask,
                                              float* __restrict__ pq, float* __restrict__ cnt){
  int b = blockIdx.x, chunk = blockIdx.y;
  int d = threadIdx.x;
  int n0 = chunk*16;
  float acc = 0.f; float c = 0.f;
  for (int i=0;i<16;i++){
    int n = n0+i;
    if (mask[b*NN+n]==1){ acc += x[((size_t)(b*NN+n))*DD + d]; c += 1.f; }
  }
  atomicAdd(&pq[b*DD+d], acc);
  if (d==0) atomicAdd(&cnt[b], c);
}

// ---------- sq: grid (BB, 16), 16 d-rows per block, atomic accumulate ----------
__global__ __launch_bounds__(256) void k_sq(const float* __restrict__ pq, const float* __restrict__ cnt,
                                            const float* __restrict__ Wq, float* __restrict__ sq){
  int b = blockIdx.x, dq = blockIdx.y;
  int e = threadIdx.x;
  float inv = 1.f / fmaxf(cnt[b], 1.f);
  float acc=0.f;
  for (int i=0;i<16;i++){
    int d0 = dq*16 + i;
    acc += pq[b*DD+d0] * Wq[d0*DD+e];
  }
  atomicAdd(&sq[b*DD+e], acc*inv);
}

// ---------- sigmoid + threshold from folded dot ----------
__global__ __launch_bounds__(256) void k_simsel2(const float* __restrict__ pdot,
                                                 float* __restrict__ simOut, u8* __restrict__ sel8){
  int r = blockIdx.x*256 + threadIdx.x;
  float s = pdot[r] * 0.0625f;
  float sim = 1.f/(1.f+expf(-s));
  simOut[r] = sim;
  sel8[r] = (sim > 0.97f) ? 1 : 0;
}

// ---------- no-LDS MFMA GEMM: out[8192, OC] = A[8192,KK] @ BT[OC,KK]^T ----------
// APK: A fragment-packed (gpK, KK). BPK: BT fragment-packed (gpK, ldB total K; kOff = K start).
// UNR: load-batch depth (use >1 only on block-limited grids; R21 spill lesson).
// EPI: 0=C fp32, 1=C+=, 2=residual+gamma, 3=O bf16,
//      7=Pk pack + s1/s2 fold (head=colBase>>8), 8=Pk pack + s1/s2 fold (single head)
// EPI 7/8: a1/a2 prescaled by LOG2E so consumers use bare 2^x.
template<int EPI, int APK, int BPK, int UNR=1>
__global__ __launch_bounds__(256) void k_mgemm(const u16* __restrict__ A, const u16* __restrict__ BT,
    int KK, int ldB, int kOff, float* __restrict__ C, const float* __restrict__ Xres,
    const float* __restrict__ gamma, u16* __restrict__ O, u16* __restrict__ Pk,
    const float* __restrict__ A1, const float* __restrict__ A2,
    float* __restrict__ s1g, float* __restrict__ s2g){
  int tid=threadIdx.x, w=tid>>6, lane=tid&63, L=lane&15, q=lane>>4;
  int OC = gridDim.x<<6;
  int colBase=blockIdx.x<<6, rowBase=blockIdx.y<<6;
  const u16* ap;
  if constexpr (APK) ap = A + (size_t)((rowBase>>4)+w)*((size_t)16*KK) + (size_t)lane*8;
  else               ap = A + (size_t)(rowBase + w*16 + L)*KK + q*8;
  const u16* bp[4];
  #pragma unroll
  for (int t=0;t<4;t++){
    if constexpr (BPK) bp[t] = BT + (size_t)((colBase>>4)+t)*((size_t)16*ldB) + (size_t)(kOff>>5)*512 + (size_t)lane*8;
    else               bp[t] = BT + (size_t)(colBase + t*16 + L)*ldB + q*8 + kOff;
  }
  f4v z4={0.f,0.f,0.f,0.f};
  f4v acc[4]={z4,z4,z4,z4};
  int nk = KK>>5;
  for (int kc0=0;kc0<nk;kc0+=UNR){
    s8v a0[UNR], bt[UNR][4];
    #pragma unroll
    for (int u=0;u<UNR;u++){
      int kc = kc0 + u;
      if constexpr (APK) a0[u] = *(const s8v*)(ap + (size_t)kc*512);
      else               a0[u] = *(const s8v*)(ap + kc*32);
      #pragma unroll
      for (int t=0;t<4;t++){
        if constexpr (BPK) bt[u][t] = *(const s8v*)(bp[t] + (size_t)kc*512);
        else               bt[u][t] = *(const s8v*)(bp[t] + kc*32);
      }
    }
    #pragma unroll
    for (int u=0;u<UNR;u++)
      #pragma unroll
      for (int t=0;t<4;t++)
        acc[t]=MFMA(a0[u],bt[u][t],acc[t]);
  }
  if constexpr (EPI<=3){
    #pragma unroll
    for (int t=0;t<4;t++){
      int col = colBase + t*16 + L;
      #pragma unroll
      for (int reg=0;reg<4;reg++){
        int row = rowBase + w*16 + q*4 + reg;
        size_t off = (size_t)row*OC + col;
        float v = acc[t][reg];
        if constexpr (EPI==0){ C[off] = v; }
        else if constexpr (EPI==1){ C[off] += v; }
        else if constexpr (EPI==2){ C[off] = flushf(Xres[off] + gamma[col]*v); }
        else { O[off] = f2b(v); }
      }
    }
  } else {
    // s1/s2 fold (prescaled by LOG2E for exp2 consumers)
    float s1p[4]={0.f,0.f,0.f,0.f}, s2p[4]={0.f,0.f,0.f,0.f};
    #pragma unroll
    for (int t=0;t<4;t++){
      int col = colBase + t*16 + L;
      float a1v = A1[col]*LOG2E, a2v = A2[col]*LOG2E;
      #pragma unroll
      for (int reg=0;reg<4;reg++){
        float v = acc[t][reg];
        s1p[reg] += v*a1v;
        s2p[reg] += v*a2v;
      }
    }
    #pragma unroll
    for (int off=1;off<16;off<<=1)
      #pragma unroll
      for (int reg=0;reg<4;reg++){
        s1p[reg] += __shfl_xor(s1p[reg],off);
        s2p[reg] += __shfl_xor(s2p[reg],off);
      }
    if (L==0){
      int sOff = (EPI==7) ? (colBase>>8)*BN : 0;
      #pragma unroll
      for (int reg=0;reg<4;reg++){
        int row = rowBase + w*16 + q*4 + reg;
        atomicAdd(&s1g[sOff+row], s1p[reg]);
        atomicAdd(&s2g[sOff+row], s2p[reg]);
      }
    }
    // coalesced pack store (16B per lane, 8 consecutive rows of one column)
    int pq_ = q&1;
    int m0 = rowBase + w*16 + (q>>1)*8;
    #pragma unroll
    for (int tp=0;tp<2;tp++){
      f4v accA = acc[2*tp], accB = acc[2*tp+1];
      f4v mine   = pq_ ? accB : accA;
      f4v theirs = pq_ ? accA : accB;
      u32 k0 = pk2(mine[0],  mine[1]);
      u32 k1 = pk2(mine[2],  mine[3]);
      u32 s0 = pk2(theirs[0],theirs[1]);
      u32 s1 = pk2(theirs[2],theirs[3]);
      u32 r0 = (u32)__shfl_xor((int)s0,16);
      u32 r1 = (u32)__shfl_xor((int)s1,16);
      uint4 val = pq_==0 ? make_uint4(k0,k1,r0,r1) : make_uint4(r0,r1,k0,k1);
      int t = 2*tp + pq_;
      int col = colBase + t*16 + L;
      *(uint4*)(Pk + packIdx(col, m0)) = val;
    }
  }
}

// ---------- fused q/k/v projections, packed A+B (gpK 256); outputs packed:
// z=0 (q) and z=1 (k): gpK(row,col,256); z=2 (v): packIdx(col,row) ----------
__global__ __launch_bounds__(256) void k_mgemm3(const u16* __restrict__ Aq, const u16* __restrict__ Akv,
    const u16* __restrict__ BT0, u16* __restrict__ O0){
  int tid=threadIdx.x, w=tid>>6, lane=tid&63, L=lane&15, q=lane>>4;
  const u16* A = blockIdx.z==0 ? Aq : Akv;
  const u16* BT = BT0 + (size_t)blockIdx.z*65536;
  u16* O = O0 + (size_t)blockIdx.z*2097152;
  int colBase=blockIdx.x<<6, rowBase=blockIdx.y<<6;
  const u16* ap = A + (size_t)((rowBase>>4)+w)*4096 + (size_t)lane*8;
  f4v z4={0.f,0.f,0.f,0.f};
  f4v acc[4]={z4,z4,z4,z4};
  #pragma unroll
  for (int kc=0;kc<8;kc++){
    s8v a0 = *(const s8v*)(ap + kc*512);
    #pragma unroll
    for (int t=0;t<4;t++){
      s8v bt = *(const s8v*)(BT + (size_t)((colBase>>4)+t)*4096 + (size_t)kc*512 + (size_t)lane*8);
      acc[t]=MFMA(a0,bt,acc[t]);
    }
  }
  bool isV = (blockIdx.z==2);
  #pragma unroll
  for (int t=0;t<4;t++){
    int col = colBase + t*16 + L;
    #pragma unroll
    for (int reg=0;reg<4;reg++){
      int row = rowBase + w*16 + q*4 + reg;
      u16 hv = f2b(acc[t][reg]);
      if (isV) O[packIdx(col, row)] = hv;
      else     O[gpK(row, col, 256)] = hv;
    }
  }
}

// ---------- split (3-term) MFMA GEMM, packed A and B (gpK 256): KK=256, OC=256 ----------
// EPI 4: hi/lo bf16 gram-packed out.  EPI 5: sq-dot fold -> pdot.
template<int EPI>
__global__ __launch_bounds__(256) void k_msgemm(const u16* __restrict__ Ah, const u16* __restrict__ Al,
    const u16* __restrict__ Bh, const u16* __restrict__ Bl,
    float* __restrict__ C, u16* __restrict__ Oh, u16* __restrict__ Ol,
    const float* __restrict__ sq, float* __restrict__ pdot){
  int tid=threadIdx.x, w=tid>>6, lane=tid&63, L=lane&15, q=lane>>4;
  int colBase=blockIdx.x<<6, rowBase=blockIdx.y<<6;
  const u16* ahp = Ah + (size_t)((rowBase>>4)+w)*4096 + (size_t)lane*8;
  const u16* alp = Al + (size_t)((rowBase>>4)+w)*4096 + (size_t)lane*8;
  f4v z4={0.f,0.f,0.f,0.f};
  f4v acc[4]={z4,z4,z4,z4};
  #pragma unroll
  for (int kc=0;kc<8;kc++){
    s8v ah=*(const s8v*)(ahp + kc*512), al=*(const s8v*)(alp + kc*512);
    #pragma unroll
    for (int t=0;t<4;t++){
      size_t boff = (size_t)((colBase>>4)+t)*4096 + (size_t)kc*512 + (size_t)lane*8;
      s8v bh=*(const s8v*)(Bh + boff);
      s8v bl=*(const s8v*)(Bl + boff);
      acc[t]=MFMA(ah,bh,acc[t]);
      acc[t]=MFMA(ah,bl,acc[t]);
      acc[t]=MFMA(al,bh,acc[t]);
    }
  }
  if constexpr (EPI==5){
    int b = rowBase>>10;
    float pp[4]={0.f,0.f,0.f,0.f};
    #pragma unroll
    for (int t=0;t<4;t++){
      int col = colBase + t*16 + L;
      float qv = sq[b*256 + col];
      #pragma unroll
      for (int reg=0;reg<4;reg++) pp[reg] += acc[t][reg]*qv;
    }
    #pragma unroll
    for (int off=1;off<16;off<<=1)
      #pragma unroll
      for (int reg=0;reg<4;reg++) pp[reg] += __shfl_xor(pp[reg],off);
    if (L==0){
      #pragma unroll
      for (int reg=0;reg<4;reg++){
        int row = rowBase + w*16 + q*4 + reg;
        atomicAdd(&pdot[row], pp[reg]);
      }
    }
  } else {
    #pragma unroll
    for (int t=0;t<4;t++){
      int col = colBase + t*16 + L;
      #pragma unroll
      for (int reg=0;reg<4;reg++){
        int row = rowBase + w*16 + q*4 + reg;
        float v = acc[t][reg];
        if constexpr (EPI==0){ C[(size_t)row*256 + col] = v; }
        else {
          size_t off = gpK(row, col, 256);
          u16 h = f2b(v); Oh[off]=h; Ol[off]=f2b(v - b2f(h));
        }
      }
    }
  }
}

// ---------- gram + bitpack v2: packed fragments, symmetric tile enumeration ----------
__global__ __launch_bounds__(256) void k_mconnect2(const u16* __restrict__ fahP, const u16* __restrict__ falP,
    const u8* __restrict__ sel8, u32* __restrict__ conn){
  __shared__ u8 sg[64][64];
  __shared__ u8 selI[64], selJ[64];
  int tid=threadIdx.x, w=tid>>6, lane=tid&63, L=lane&15, q=lane>>4;
  int b=blockIdx.z;
  int p=blockIdx.x;
  int i = (int)((sqrtf(8.f*p+1.f)-1.f)*0.5f);
  while ((i+1)*(i+2)/2 <= p) i++;
  while (i*(i+1)/2 > p) i--;
  int j = p - i*(i+1)/2;          // i >= j, both 0..15
  if (tid < 64)        selI[tid]     = sel8[b*NN + i*64 + tid];
  else if (tid < 128)  selJ[tid-64]  = sel8[b*NN + j*64 + (tid-64)];
  const u16* ah0 = fahP + ((size_t)(b*64 + i*4 + w))*4096 + (size_t)lane*8;
  const u16* al0 = falP + ((size_t)(b*64 + i*4 + w))*4096 + (size_t)lane*8;
  const u16* bh0 = fahP + ((size_t)(b*64 + j*4))*4096 + (size_t)lane*8;
  const u16* bl0 = falP + ((size_t)(b*64 + j*4))*4096 + (size_t)lane*8;
  f4v z4={0.f,0.f,0.f,0.f};
  f4v acc[4]={z4,z4,z4,z4};
  #pragma unroll
  for (int kc=0;kc<8;kc++){
    s8v ah = *(const s8v*)(ah0 + kc*512);
    s8v al = *(const s8v*)(al0 + kc*512);
    #pragma unroll
    for (int t=0;t<4;t++){
      s8v bh = *(const s8v*)(bh0 + (size_t)t*4096 + kc*512);
      s8v bl = *(const s8v*)(bl0 + (size_t)t*4096 + kc*512);
      acc[t]=MFMA(ah,bh,acc[t]);
      acc[t]=MFMA(ah,bl,acc[t]);
      acc[t]=MFMA(al,bh,acc[t]);
    }
  }
  #pragma unroll
  for (int t=0;t<4;t++)
    #pragma unroll
    for (int reg=0;reg<4;reg++)
      sg[w*16 + q*4 + reg][t*16 + L] = acc[t][reg] > 0.f;
  __syncthreads();
  int row=(tid&127)>>1, ww=tid&1;
  if (tid<128){
    u32 word=0;
    if (selI[row]){
      #pragma unroll 8
      for (int jj=0;jj<32;jj++)
        if (sg[row][ww*32+jj] && selJ[ww*32+jj]) word |= (1u<<jj);
    }
    conn[((size_t)b*NN + i*64+row)*32 + j*2 + ww] = word;
  } else if (i != j){
    u32 word=0;
    if (selJ[row]){
      #pragma unroll 8
      for (int jj=0;jj<32;jj++)
        if (sg[ww*32+jj][row] && selI[ww*32+jj]) word |= (1u<<jj);
    }
    conn[((size_t)b*NN + j*64+row)*32 + i*2 + ww] = word;
  }
}

// ---------- row max of s2 over connected m ----------
__global__ __launch_bounds__(256) void k_rowmax(const float* __restrict__ s2a,
    const u32* __restrict__ conn, float* __restrict__ M2a){
  int h = blockIdx.y;
  int r = blockIdx.x*4 + (threadIdx.x>>6);
  int lane = threadIdx.x&63;
  int b = r>>10;
  const float* s2p = s2a + h*BN + b*NN;
  float mx = -3.0e38f;
  #pragma unroll
  for (int t=0;t<16;t++){
    int m = lane + t*64;
    u32 wd = conn[(size_t)r*32 + (m>>5)];
    if ((wd>>(m&31))&1u) mx = fmaxf(mx, s2p[m]);
  }
  mx = wredmax(mx);
  if (lane==0) M2a[h*BN+r] = mx;
}

// ---------- MFMA GAT attention v8: P shared via LDS; V loaded EARLY (single copy) ----------
// s1/s2/M2a are prescaled by LOG2E -> bare v_exp_f32 (2^x).
// PKO: 0 = row-major output (stride oStride); else fragment-packed gpK(row,col,PKO).
template<int CT, bool SWZ, int PKO>
__global__ __launch_bounds__(256,4) void k_mattn5(const float* __restrict__ s1a, const float* __restrict__ s2a,
    const float* __restrict__ M2a, const u32* __restrict__ conn,
    const u16* __restrict__ P, int headMul, u16* __restrict__ Out, int oStride){
  __shared__ __align__(16) u16 Pb[2][4][512];
  __shared__ float Srow[64];
  int tid=threadIdx.x, w=tid>>6, lane=tid&63, L=lane&15, q=lane>>4;
  int h, rowBlk;
  if constexpr (SWZ){ h = blockIdx.y & 7; rowBlk = (blockIdx.y>>3) + (blockIdx.z<<4); }
  else             { h = blockIdx.z;     rowBlk = blockIdx.y; }
  int rowBase = rowBlk*64;
  int hOff = h*headMul, sOff = h*BN;
  int b = rowBase>>10;
  size_t bOff = (size_t)b*NN;
  int r = rowBase + w*16 + L;             // own row for P-build
  float s1v = s1a[sOff+r];
  float rmv = leakyf(s1v + M2a[sOff+r]);
  const float* s2p = s2a + sOff + bOff;
  const u32* cp = conn + (size_t)r*32;
  int tile0 = blockIdx.x*(4*CT) + w*CT;   // first col-tile owned by this wave
  const u16* vp = P + (size_t)((hOff>>4) + tile0)*131072 + (size_t)b*16384 + (size_t)lane*8;
  f4v z4={0.f,0.f,0.f,0.f};
  f4v acc[4][CT];
  #pragma unroll
  for (int g=0;g<4;g++)
    #pragma unroll
    for (int t=0;t<CT;t++) acc[g][t]=z4;
  float sumP = 0.f;
  for (int k0=0;k0<NN;k0+=32){
    int cur=(k0>>5)&1;
    u32 cw = cp[k0>>5];
    // issue THIS chunk's V loads first — latency hidden under P-build + barrier
    s8v vf[CT];
    {
      const u16* vk = vp + (size_t)(k0>>5)*512;
      #pragma unroll
      for (int t=0;t<CT;t++) vf[t] = *(const s8v*)(vk + (size_t)t*131072);
    }
    float4 sA = *(const float4*)(s2p + k0 + q*8);
    float4 sB = *(const float4*)(s2p + k0 + q*8 + 4);
    float s2v[8] = {sA.x,sA.y,sA.z,sA.w,sB.x,sB.y,sB.z,sB.w};
    float p[8];
    #pragma unroll
    for (int j=0;j<8;j++){
      float z = s1v + s2v[j];
      float ev = fmaxf(z, 0.2f*z);                      // leaky = max(z, 0.2z) (scaled)
      ev = ((cw>>(q*8+j))&1u) ? ev : -9.0e15f;          // mask BEFORE exp (uniform rows!)
      p[j] = exp2z(ev - rmv);                            // bare v_exp (2^x), prescaled
      sumP += p[j];
    }
    union{ s8v v; u32 u[4]; } pk;
    #pragma unroll
    for (int jj=0;jj<4;jj++)
      pk.u[jj] = pk2(p[2*jj], p[2*jj+1]);
    *(s8v*)&Pb[cur][w][lane*8] = pk.v;    // ds_write_b128, contiguous
    __syncthreads();                       // all P fragments for this chunk visible
    s8v pa[4];
    #pragma unroll
    for (int g=0;g<4;g++) pa[g] = *(const s8v*)&Pb[cur][g][lane*8];
    #pragma unroll
    for (int t=0;t<CT;t++)
      #pragma unroll
      for (int g=0;g<4;g++) acc[g][t] = MFMA(pa[g], vf[t], acc[g][t]);
  }
  sumP += __shfl_xor(sumP,16);
  sumP += __shfl_xor(sumP,32);
  if (lane<16) Srow[w*16+lane] = sumP;
  __syncthreads();
  #pragma unroll
  for (int g=0;g<4;g++){
    float4 sv = *(const float4*)&Srow[g*16 + q*4];
    float rsi[4] = {1.f/sv.x, 1.f/sv.y, 1.f/sv.z, 1.f/sv.w};
    #pragma unroll
    for (int t=0;t<CT;t++){
      int col = hOff + (tile0+t)*16 + L;
      #pragma unroll
      for (int reg=0;reg<4;reg++){
        int row = rowBase + g*16 + q*4 + reg;
        float ov = eluf(acc[g][t][reg]*rsi[reg]);
        if constexpr (PKO) Out[gpK(row, col, PKO)] = f2b(ov);
        else               Out[(size_t)row*oStride + col] = f2b(ov);
      }
    }
  }
}

// ---------- LayerNorms (packed gpK-256 output) ----------
__global__ __launch_bounds__(256) void k_ln_x(const float* __restrict__ x, const float* __restrict__ g,
                                              const float* __restrict__ bb, u16* __restrict__ out){
  int r = blockIdx.x*4 + (threadIdx.x>>6);
  int lane=threadIdx.x&63;
  float4 v = *(const float4*)(x + (size_t)r*DD + lane*4);
  float s = v.x+v.y+v.z+v.w;
  float s2 = v.x*v.x+v.y*v.y+v.z*v.z+v.w*v.w;
  s = wredsum(s); s2 = wredsum(s2);
  float mean = s*(1.f/256.f);
  float var = s2*(1.f/256.f) - mean*mean;
  float rstd = rsqrtf(var + 1e-5f);
  float4 gv = *(const float4*)(g+lane*4), bv = *(const float4*)(bb+lane*4);
  u16 t[4];
  t[0]=f2b((v.x-mean)*rstd*gv.x+bv.x); t[1]=f2b((v.y-mean)*rstd*gv.y+bv.y);
  t[2]=f2b((v.z-mean)*rstd*gv.z+bv.z); t[3]=f2b((v.w-mean)*rstd*gv.w+bv.w);
  *(uint2*)(out + gpK(r, lane*4, 256)) = *(uint2*)&t[0];
}

__global__ __launch_bounds__(256) void k_ln_kv(const u16* __restrict__ gout, const float* __restrict__ pe,
    const u8* __restrict__ sel8, const float* __restrict__ g, const float* __restrict__ bb,
    u16* __restrict__ out){
  int r = blockIdx.x*4 + (threadIdx.x>>6);
  int lane=threadIdx.x&63;
  int n = r & 1023;
  float4 v = make_float4(0.f,0.f,0.f,0.f);
  if (sel8[r]){
    float4 gv = ld4bf(gout + (size_t)r*DD + lane*4);
    float4 pv = *(const float4*)(pe + (size_t)n*DD + lane*4);
    v = make_float4(gv.x+pv.x, gv.y+pv.y, gv.z+pv.z, gv.w+pv.w);
  }
  float s = v.x+v.y+v.z+v.w;
  float s2 = v.x*v.x+v.y*v.y+v.z*v.z+v.w*v.w;
  s = wredsum(s); s2 = wredsum(s2);
  float mean = s*(1.f/256.f);
  float var = s2*(1.f/256.f) - mean*mean;
  float rstd = rsqrtf(var + 1e-5f);
  float4 gv = *(const float4*)(g+lane*4), bv = *(const float4*)(bb+lane*4);
  u16 t[4];
  t[0]=f2b((v.x-mean)*rstd*gv.x+bv.x); t[1]=f2b((v.y-mean)*rstd*gv.y+bv.y);
  t[2]=f2b((v.z-mean)*rstd*gv.z+bv.z); t[3]=f2b((v.w-mean)*rstd*gv.w+bv.w);
  *(uint2*)(out + gpK(r, lane*4, 256)) = *(uint2*)&t[0];
}

// ---------- CA attention v3: barrier-free flash; direct fragment loads ----------
__global__ __launch_bounds__(256) void k_mca_av3(const u16* __restrict__ q, const u16* __restrict__ k,
    const u16* __restrict__ v, const u8* __restrict__ sel8, u16* __restrict__ O){
  __shared__ __align__(16) u16 Pw[4][16][72];
  int tid=threadIdx.x;
  int w = tid>>6, lane = tid&63, L = lane&15, qd = lane>>4;
  int b=blockIdx.z, h=blockIdx.y, rowBase=blockIdx.x*64;
  size_t bOff = (size_t)b*NN;
  const u16* qbase = q + (size_t)((bOff + rowBase + w*16)>>4)*4096 + (size_t)lane*8;
  s8v af0 = *(const s8v*)(qbase + (size_t)(h*2+0)*512);
  s8v af1 = *(const s8v*)(qbase + (size_t)(h*2+1)*512);
  float rm[4], sp[4];
  #pragma unroll
  for (int reg=0;reg<4;reg++){ rm[reg] = -3.0e38f; sp[reg] = 0.f; }
  f4v zero = {0.f,0.f,0.f,0.f};
  f4v acc[4] = {zero,zero,zero,zero};
  for (int m0=0;m0<NN;m0+=64){
    s8v bt[4][2];
    #pragma unroll
    for (int t=0;t<4;t++){
      const u16* kb = k + (size_t)((bOff + m0 + t*16)>>4)*4096 + (size_t)lane*8;
      bt[t][0] = *(const s8v*)(kb + (size_t)(h*2+0)*512);
      bt[t][1] = *(const s8v*)(kb + (size_t)(h*2+1)*512);
    }
    s8v vf[4][2];
    #pragma unroll
    for (int t=0;t<4;t++){
      const u16* vb = v + (size_t)(((h*4+t)*8 + b)*32 + (m0>>5))*512 + (size_t)lane*8;
      vf[t][0] = *(const s8v*)vb;
      vf[t][1] = *(const s8v*)(vb + 512);
    }
    f4v sa[4] = {zero,zero,zero,zero};
    #pragma unroll
    for (int t=0;t<4;t++){
      sa[t] = MFMA(af0, bt[t][0], sa[t]);
      sa[t] = MFMA(af1, bt[t][1], sa[t]);
    }
    float vals[4][4];
    float tmax[4];
    #pragma unroll
    for (int reg=0;reg<4;reg++) tmax[reg] = -3.0e38f;
    #pragma unroll
    for (int t=0;t<4;t++){
      int m = m0 + t*16 + L;
      bool sl = sel8[b*NN+m];
      #pragma unroll
      for (int reg=0;reg<4;reg++){
        float val = sl ? sa[t][reg]*0.125f : -1.0e9f;
        vals[t][reg] = val;
        tmax[reg] = fmaxf(tmax[reg], val);
      }
    }
    #pragma unroll
    for (int off=1;off<16;off<<=1)
      #pragma unroll
      for (int reg=0;reg<4;reg++) tmax[reg] = fmaxf(tmax[reg], __shfl_xor(tmax[reg],off));
    float sc[4];
    #pragma unroll
    for (int reg=0;reg<4;reg++){
      float nm = fmaxf(rm[reg], tmax[reg]);
      sc[reg] = exp0(rm[reg] - nm);
      rm[reg] = nm;
      sp[reg] *= sc[reg];
    }
    #pragma unroll
    for (int t=0;t<4;t++){
      #pragma unroll
      for (int reg=0;reg<4;reg++){
        float pv = exp0(vals[t][reg] - rm[reg]);
        sp[reg] += pv;
        Pw[w][qd*4 + reg][t*16 + L] = f2b(pv);   // intra-wave slice, no barrier
      }
    }
    #pragma unroll
    for (int t=0;t<4;t++)
      #pragma unroll
      for (int reg=0;reg<4;reg++) acc[t][reg] *= sc[reg];
    #pragma unroll
    for (int mc2=0;mc2<2;mc2++){
      s8v pf = *(const s8v*)&Pw[w][L][mc2*32 + qd*8];
      #pragma unroll
      for (int t=0;t<4;t++)
        acc[t] = MFMA(pf, vf[t][mc2], acc[t]);
    }
  }
  #pragma unroll
  for (int off=1;off<16;off<<=1)
    #pragma unroll
    for (int reg=0;reg<4;reg++) sp[reg] += __shfl_xor(sp[reg],off);
  float ri[4];
  #pragma unroll
  for (int reg=0;reg<4;reg++) ri[reg] = 1.f/sp[reg];
  #pragma unroll
  for (int t=0;t<4;t++){
    int col = h*64 + t*16 + L;
    #pragma unroll
    for (int reg=0;reg<4;reg++){
      int row = (int)bOff + rowBase + w*16 + qd*4 + reg;
      O[gpK(row, col, 256)] = f2b(acc[t][reg]*ri[reg]);
    }
  }
}

extern "C" void kernel_launch(void* const* d_in, const int* in_sizes, int n_in,
                              void* d_out, int out_size, void* d_ws, size_t ws_size,
                              hipStream_t stream) {
  (void)in_sizes; (void)n_in; (void)out_size;
  const float* x      = (const float*)d_in[0];
  const int*   mask   = (const int*  )d_in[1];
  const float* pe     = (const float*)d_in[2];
  const float* sim_Wx = (const float*)d_in[3];
  const float* sim_Wq = (const float*)d_in[4];
  const float* adj_W  = (const float*)d_in[5];
  const float* gat_W  = (const float*)d_in[6];
  const float* gat_a1 = (const float*)d_in[7];
  const float* gat_a2 = (const float*)d_in[8];
  const float* gat_Wo = (const float*)d_in[9];
  const float* gat_ao1= (const float*)d_in[10];
  const float* gat_ao2= (const float*)d_in[11];
  const float* ln3_g  = (const float*)d_in[12];
  const float* ln3_b  = (const float*)d_in[13];
  const float* ln4_g  = (const float*)d_in[14];
  const float* ln4_b  = (const float*)d_in[15];
  const float* ca_Wq  = (const float*)d_in[16];
  const float* ca_Wk  = (const float*)d_in[17];
  const float* ca_Wv  = (const float*)d_in[18];
  const float* ca_Wp  = (const float*)d_in[19];
  const float* gamma  = (const float*)d_in[20];
  float* out    = (float*)d_out;
  float* simOut = out + (size_t)BN*DD;

  const size_t MB = 1024*1024;
  bool big = ws_size >= 98*MB;
  char* W = (char*)d_ws;
  float* pq   = (float*)W;
  float* cnt  = pq + 2048;
  float* sq   = cnt + 16;
  float* s1a  = (float*)(W + 64*1024);
  float* s2a  = (float*)(W + 320*1024);
  float* M2a  = (float*)(W + 576*1024);
  float* pdot = (float*)(W + 1216*1024);
  u8*    sel8 = (u8*)(W + 1400*1024);
  u32*   conn = (u32*)(W + 2*MB);
  u16*   WT0  = (u16*)(W + 3*MB);
  u16*   WoT  = (u16*)(W + 4*MB);
  u16*   WQT  = (u16*)(W + 5*MB);
  u16*   WPT  = WQT + 3*65536;
  u16*   sWxh = (u16*)(W + 5*MB + 512*1024);
  u16*   sWxl = sWxh + 65536;
  u16*   aWh  = sWxl + 65536;
  u16*   aWl  = aWh + 65536;
  u16*   xh   = (u16*)(W + 6*MB);
  u16*   xl   = (u16*)(W + 10*MB);
  float* S0   = (float*)(W + 14*MB);
  u16*   fah  = (u16*)(W + 22*MB);
  u16*   fal  = (u16*)(W + 26*MB);
  u16*   T2   = (u16*)(W + 30*MB);

  // prep (everything fragment-packed)
  k_split<<<BN*DD/2048,256,0,stream>>>(x, xh, xl);
  k_transpose<<<dim3(4,4,HG),256,0,stream>>>(gat_W, WT0, 256, 65536, 256);
  k_transpose<<<dim3(4,32,1),256,0,stream>>>(gat_Wo, WoT, 2048, 0, 2048);
  k_transpose4<<<dim3(4,4,4),256,0,stream>>>(ca_Wq, ca_Wk, ca_Wv, ca_Wp, WQT);
  k_transp_split<<<dim3(4,4,1),256,0,stream>>>(sim_Wx, sWxh, sWxl);
  k_transp_split<<<dim3(4,4,1),256,0,stream>>>(adj_W, aWh, aWl);

  hipMemsetAsync(pq, 0, (2048+16+2048)*sizeof(float), stream);   // pq + cnt + sq
  hipMemsetAsync(pdot, 0, BN*sizeof(float), stream);
  k_posq<<<dim3(BB,64),256,0,stream>>>(x, mask, pq, cnt);
  k_sq<<<dim3(BB,16),256,0,stream>>>(pq, cnt, sim_Wq, sq);
  k_msgemm<5><<<dim3(4,128),256,0,stream>>>(xh, xl, sWxh, sWxl, nullptr, nullptr, nullptr, sq, pdot); // y-dot fold
  k_simsel2<<<BN/256,256,0,stream>>>(pdot, simOut, sel8);
  k_msgemm<4><<<dim3(4,128),256,0,stream>>>(xh, xl, aWh, aWl, nullptr, fah, fal, nullptr, nullptr);   // fa gram-packed
  k_mconnect2<<<dim3(136,1,BB),256,0,stream>>>(fah, fal, sel8, conn);

  if (big){
    u16* WhP   = (u16*)(W + 66*MB);   // attention-packed Wh_cat, 32MB
    u16* htcat = (u16*)(W + 34*MB);   // fragment-packed (gpK 2048) ht_cat, 32MB
    u16* S0P   = (u16*)(W + 22*MB);   // attention-packed Who, 4MB (fah dead after mconnect)
    u16* qx = (u16*)(W + 34*MB);      // after htcat consumed
    u16* kv = (u16*)(W + 38*MB);
    u16* qb = (u16*)(W + 42*MB);
    u16* vb = (u16*)(W + 50*MB);
    u16* Ob = (u16*)(W + 54*MB);

    hipMemsetAsync(s1a, 0, 512*1024, stream);  // s1a(256K) + s2a(256K) contiguous
    k_mgemm<7,1,1><<<dim3(32,128),256,0,stream>>>(xh, WT0, 256, 256, 0, nullptr, nullptr, nullptr, nullptr,
                                                  WhP, gat_a1, gat_a2, s1a, s2a);  // WhP pack + s1s2 fold (×log2e)
    k_rowmax<<<dim3(BN/4,HG),256,0,stream>>>(s2a, conn, M2a);
    k_mattn5<4,true,2048><<<dim3(1,128,HG),256,0,stream>>>(s1a, s2a, M2a, conn, WhP, 256, htcat, 2048);
    hipMemsetAsync(s1a, 0, BN*sizeof(float), stream);
    hipMemsetAsync(s2a, 0, BN*sizeof(float), stream);
    k_mgemm<8,1,1,4><<<dim3(4,128),256,0,stream>>>(htcat, WoT, 2048, 2048, 0, nullptr, nullptr, nullptr, nullptr,
                                                   S0P, gat_ao1, gat_ao2, s1a, s2a);  // S0P pack + s1s2 fold (×log2e)
    k_rowmax<<<dim3(BN/4,1),256,0,stream>>>(s2a, conn, M2a);
    k_mattn5<1,false,0><<<dim3(4,128,1),256,0,stream>>>(s1a, s2a, M2a, conn, S0P, 0, T2, 256);  // gout

    k_ln_x<<<BN/4,256,0,stream>>>(x, ln3_g, ln3_b, qx);
    k_ln_kv<<<BN/4,256,0,stream>>>(T2, pe, sel8, ln4_g, ln4_b, kv);
    k_mgemm3<<<dim3(4,128,3),256,0,stream>>>(qx, kv, WQT, qb);     // qb,kb gpK; vb packIdx
    k_mca_av3<<<dim3(16,HC,BB),256,0,stream>>>(qb, qb + 2097152, vb, sel8, Ob);
    k_mgemm<2,1,1,4><<<dim3(4,128),256,0,stream>>>(Ob, WPT, 256, 256, 0, out, x, gamma, nullptr, nullptr,
                                                   nullptr, nullptr, nullptr, nullptr);
  } else {
    // small-ws fallback: per-head loop, packed kernels (rarely taken)
    u16* T0 = fah;
    u16* T1 = fal;
    u16* S0b = (u16*)S0;
    hipMemsetAsync(s1a, 0, 512*1024, stream);
    for (int h=0;h<HG;h++){
      hipMemsetAsync(s1a, 0, BN*sizeof(float), stream);
      hipMemsetAsync(s2a, 0, BN*sizeof(float), stream);
      k_mgemm<8,1,1><<<dim3(4,128),256,0,stream>>>(xh, WT0 + (size_t)h*65536, 256, 256, 0,
                                                   nullptr, nullptr, nullptr, nullptr, T0,
                                                   gat_a1 + h*DD, gat_a2 + h*DD, s1a, s2a);
      k_rowmax<<<dim3(BN/4,1),256,0,stream>>>(s2a, conn, M2a);
      k_mattn5<1,false,0><<<dim3(4,128,1),256,0,stream>>>(s1a, s2a, M2a, conn, T0, 0, T1, 256);
      k_mgemm<1,0,1><<<dim3(4,128),256,0,stream>>>(T1, WoT, 256, 2048, h*256, S0, nullptr, nullptr, nullptr, nullptr,
                                                   nullptr, nullptr, nullptr, nullptr);
    }
    hipMemsetAsync(s1a, 0, BN*sizeof(float), stream);
    hipMemsetAsync(s2a, 0, BN*sizeof(float), stream);
    k_mattn5<1,false,0><<<dim3(4,128,1),256,0,stream>>>(s1a, s2a, M2a, conn, (u16*)S0, 0, T2, 256);
    k_ln_x<<<BN/4,256,0,stream>>>(x, ln3_g, ln3_b, T1);
    k_ln_kv<<<BN/4,256,0,stream>>>(T2, pe, sel8, ln4_g, ln4_b, T0);
    k_mgemm3<<<dim3(4,128,3),256,0,stream>>>(T1, T0, WQT, S0b);
    k_mca_av3<<<dim3(16,HC,BB),256,0,stream>>>(S0b, S0b + 2097152, S0b + 4194304, sel8, T0);
    k_mgemm<2,1,1><<<dim3(4,128),256,0,stream>>>(T0, WPT, 256, 256, 0, out, x, gamma, nullptr, nullptr,
                                                 nullptr, nullptr, nullptr, nullptr);
  }
}

// Round 17
// 445.727 us; speedup vs baseline: 1.2182x; 1.0026x over previous
//
#include <hip/hip_runtime.h>
#include <hip/hip_bf16.h>

// GATFusionBlockPosOnly: B=8, N=1024, D=256, 8 GAT heads, 4 CA heads.
// Round 26:
//  - R25 post-mortem: total 463->447 (posq/sq). mattn5 62->64 with VALUBusy
//    55->49 — exp2 prescale removed VALU but dur flat => NOT VALU-bound;
//    barrier-locked phase alignment (P-build vs MFMA) is the limiter.
//  - k_mattn5: s_setprio(1) around MFMA cluster (T5: phase-diverse blocks/CU
//    exist -> scheduler can prefer MFMA-phase waves). Zero-risk.
//  - k_mgemm<7,1,1> -> UNR=2 (likely hidden #2; 28->~70 VGPR keeps 7 waves/SIMD).

#define BB 8
#define NN 1024
#define DD 256
#define HG 8
#define HC 4
#define BN (BB*NN)
#define LOG2E 1.44269504088896f

typedef unsigned short u16;
typedef unsigned int u32;
typedef unsigned char u8;
typedef __attribute__((ext_vector_type(8))) short s8v;   // 8 bf16
typedef __attribute__((ext_vector_type(4))) float f4v;   // 4 fp32 acc
#define MFMA(a,b,c) __builtin_amdgcn_mfma_f32_16x16x32_bf16((a),(b),(c),0,0,0)

__device__ __forceinline__ u16 f2b(float x){
  union{ float f; unsigned u; } a; a.f = x;
  unsigned r = a.u + 0x7fff + ((a.u>>16)&1);
  return (u16)(r>>16);
}
__device__ __forceinline__ float b2f(u16 b){ return __uint_as_float(((unsigned)b)<<16); }
__device__ __forceinline__ float4 ld4bf(const u16* p){
  uint2 u = *(const uint2*)p;
  float4 r;
  r.x=__uint_as_float(u.x<<16); r.y=__uint_as_float(u.x&0xffff0000u);
  r.z=__uint_as_float(u.y<<16); r.w=__uint_as_float(u.y&0xffff0000u);
  return r;
}
__device__ __forceinline__ void load8(const float* p, float* v){
  float4 a=*(const float4*)p, b=*(const float4*)(p+4);
  v[0]=a.x;v[1]=a.y;v[2]=a.z;v[3]=a.w;v[4]=b.x;v[5]=b.y;v[6]=b.z;v[7]=b.w;
}
__device__ __forceinline__ float wredsum(float v){
  #pragma unroll
  for(int o=32;o>0;o>>=1) v += __shfl_xor(v,o);
  return v;
}
__device__ __forceinline__ float wredmax(float v){
  #pragma unroll
  for(int o=32;o>0;o>>=1) v = fmaxf(v,__shfl_xor(v,o));
  return v;
}
__device__ __forceinline__ float eluf(float x){ return x>0.f ? x : __expf(x)-1.f; }
__device__ __forceinline__ float leakyf(float z){ return z>=0.f ? z : 0.2f*z; }
__device__ __forceinline__ float exp0(float a){ return __expf(fminf(a, 0.f)); }
__device__ __forceinline__ float exp2z(float a){   // 2^min(a,0), bare v_exp
  float x = fminf(a, 0.f), r;
  asm("v_exp_f32 %0, %1" : "=v"(r) : "v"(x));
  return r;
}
__device__ __forceinline__ float flushf(float v){ return (fabsf(v) < 1.0e30f) ? v : 0.f; }
__device__ __forceinline__ u32 pk2(float lo, float hi){
  u32 r;
  asm("v_cvt_pk_bf16_f32 %0, %1, %2" : "=v"(r) : "v"(lo), "v"(hi));
  return r;
}

// packed index for element (col, m) of the attention-V pack:  b=m>>10, kk=m&1023
__device__ __forceinline__ size_t packIdx(int col, int row){
  int kk = row & 1023;
  return ((((size_t)(col>>4))*8 + (row>>10))*32 + (kk>>5))*512
       + (size_t)(((((kk>>3)&3)*16) + (col&15))*8 + (kk&7));
}

// fragment-pack: element (row, k) of a [rows][KK] operand -> fragment order.
__device__ __forceinline__ size_t gpK(int row, int k, int KK){
  return (size_t)(row>>4)*((size_t)16*KK) + (size_t)(k>>5)*512
       + (size_t)(((((k>>3)&3)*16) + (row&15))*8 + (k&7));
}

// ---------- fp32 -> (hi,lo) bf16 split, packed output (gpK, KK=256) ----------
__global__ __launch_bounds__(256) void k_split(const float* __restrict__ X, u16* __restrict__ H, u16* __restrict__ Lo){
  size_t i = ((size_t)blockIdx.x*256 + threadIdx.x)*8;
  float v[8]; load8(X+i, v);
  u16 hh[8], ll[8];
  #pragma unroll
  for (int j=0;j<8;j++){ hh[j]=f2b(v[j]); ll[j]=f2b(v[j]-b2f(hh[j])); }
  int row = (int)(i>>8), col = (int)(i&255);
  size_t off = gpK(row, col, 256);
  *(uint4*)(H+off)=*(uint4*)&hh[0];
  *(uint4*)(Lo+off)=*(uint4*)&ll[0];
}

// ---------- transpose fp32 [R][C] -> bf16; pkKK=0: row-major [C][R]; else gpK packed ----------
__global__ __launch_bounds__(256) void k_transpose(const float* __restrict__ S, u16* __restrict__ D,
                                                   int R, int sliceElems, int pkKK){
  __shared__ float tl[64][65];
  const float* src = S + (size_t)blockIdx.z*sliceElems;
  u16* dst = D + (size_t)blockIdx.z*sliceElems;
  int C = gridDim.x*64;
  int bx=blockIdx.x*64, by=blockIdx.y*64;
  int tid=threadIdx.x, r=tid>>2, c0=(tid&3)*16;
  #pragma unroll
  for (int i=0;i<16;i+=4){
    float4 v = *(const float4*)(src + (size_t)(by+r)*C + bx + c0 + i);
    tl[r][c0+i]=v.x; tl[r][c0+i+1]=v.y; tl[r][c0+i+2]=v.z; tl[r][c0+i+3]=v.w;
  }
  __syncthreads();
  u16 tmp[16];
  #pragma unroll
  for (int i=0;i<16;i++) tmp[i] = f2b(tl[c0+i][r]);
  if (pkKK){
    *(uint4*)(dst + gpK(bx+r, by+c0,     pkKK)) = *(uint4*)&tmp[0];
    *(uint4*)(dst + gpK(bx+r, by+c0+8,   pkKK)) = *(uint4*)&tmp[8];
  } else {
    *(uint4*)(dst + (size_t)(bx+r)*R + by + c0)     = *(uint4*)&tmp[0];
    *(uint4*)(dst + (size_t)(bx+r)*R + by + c0 + 8) = *(uint4*)&tmp[8];
  }
}

// ---------- 4x 256x256 transposes, PACKED (gpK 256) output; grid (4,4,4) ----------
__global__ __launch_bounds__(256) void k_transpose4(const float* __restrict__ Sa, const float* __restrict__ Sb,
    const float* __restrict__ Sc, const float* __restrict__ Sd, u16* __restrict__ D){
  __shared__ float tl[64][65];
  const float* src = blockIdx.z==0 ? Sa : blockIdx.z==1 ? Sb : blockIdx.z==2 ? Sc : Sd;
  u16* dst = D + (size_t)blockIdx.z*65536;
  int bx=blockIdx.x*64, by=blockIdx.y*64;
  int tid=threadIdx.x, r=tid>>2, c0=(tid&3)*16;
  #pragma unroll
  for (int i=0;i<16;i+=4){
    float4 v = *(const float4*)(src + (size_t)(by+r)*256 + bx + c0 + i);
    tl[r][c0+i]=v.x; tl[r][c0+i+1]=v.y; tl[r][c0+i+2]=v.z; tl[r][c0+i+3]=v.w;
  }
  __syncthreads();
  u16 tmp[16];
  #pragma unroll
  for (int i=0;i<16;i++) tmp[i] = f2b(tl[c0+i][r]);
  *(uint4*)(dst + gpK(bx+r, by+c0,   256)) = *(uint4*)&tmp[0];
  *(uint4*)(dst + gpK(bx+r, by+c0+8, 256)) = *(uint4*)&tmp[8];
}

// ---------- transpose + split: fp32 [256][256] -> hi/lo bf16 PACKED (gpK 256) ----------
__global__ __launch_bounds__(256) void k_transp_split(const float* __restrict__ S, u16* __restrict__ DH, u16* __restrict__ DL){
  __shared__ float tl[64][65];
  int bx=blockIdx.x*64, by=blockIdx.y*64;
  int tid=threadIdx.x, r=tid>>2, c0=(tid&3)*16;
  #pragma unroll
  for (int i=0;i<16;i+=4){
    float4 v = *(const float4*)(S + (size_t)(by+r)*256 + bx + c0 + i);
    tl[r][c0+i]=v.x; tl[r][c0+i+1]=v.y; tl[r][c0+i+2]=v.z; tl[r][c0+i+3]=v.w;
  }
  __syncthreads();
  u16 th[16], tll[16];
  #pragma unroll
  for (int i=0;i<16;i++){
    float v = tl[c0+i][r];
    th[i]=f2b(v); tll[i]=f2b(v - b2f(th[i]));
  }
  size_t o0 = gpK(bx+r, by+c0,   256);
  size_t o1 = gpK(bx+r, by+c0+8, 256);
  *(uint4*)(DH + o0) = *(uint4*)&th[0];
  *(uint4*)(DH + o1) = *(uint4*)&th[8];
  *(uint4*)(DL + o0) = *(uint4*)&tll[0];
  *(uint4*)(DL + o1) = *(uint4*)&tll[8];
}

// ---------- pos_query: grid (BB, 64), 16 rows per block ----------
__global__ __launch_bounds__(256) void k_posq(const float* __restrict__ x, const int* __restrict__ mask,
                                              float* __restrict__ pq, float* __restrict__ cnt){
  int b = blockIdx.x, chunk = blockIdx.y;
  int d = threadIdx.x;
  int n0 = chunk*16;
  float acc = 0.f; float c = 0.f;
  for (int i=0;i<16;i++){
    int n = n0+i;
    if (mask[b*NN+n]==1){ acc += x[((size_t)(b*NN+n))*DD + d]; c += 1.f; }
  }
  atomicAdd(&pq[b*DD+d], acc);
  if (d==0) atomicAdd(&cnt[b], c);
}

// ---------- sq: grid (BB, 16), 16 d-rows per block, atomic accumulate ----------
__global__ __launch_bounds__(256) void k_sq(const float* __restrict__ pq, const float* __restrict__ cnt,
                                            const float* __restrict__ Wq, float* __restrict__ sq){
  int b = blockIdx.x, dq = blockIdx.y;
  int e = threadIdx.x;
  float inv = 1.f / fmaxf(cnt[b], 1.f);
  float acc=0.f;
  for (int i=0;i<16;i++){
    int d0 = dq*16 + i;
    acc += pq[b*DD+d0] * Wq[d0*DD+e];
  }
  atomicAdd(&sq[b*DD+e], acc*inv);
}

// ---------- sigmoid + threshold from folded dot ----------
__global__ __launch_bounds__(256) void k_simsel2(const float* __restrict__ pdot,
                                                 float* __restrict__ simOut, u8* __restrict__ sel8){
  int r = blockIdx.x*256 + threadIdx.x;
  float s = pdot[r] * 0.0625f;
  float sim = 1.f/(1.f+expf(-s));
  simOut[r] = sim;
  sel8[r] = (sim > 0.97f) ? 1 : 0;
}

// ---------- no-LDS MFMA GEMM: out[8192, OC] = A[8192,KK] @ BT[OC,KK]^T ----------
// APK: A fragment-packed (gpK, KK). BPK: BT fragment-packed (gpK, ldB total K; kOff = K start).
// UNR: load-batch depth.
// EPI: 0=C fp32, 1=C+=, 2=residual+gamma, 3=O bf16,
//      7=Pk pack + s1/s2 fold (head=colBase>>8), 8=Pk pack + s1/s2 fold (single head)
// EPI 7/8: a1/a2 prescaled by LOG2E so consumers use bare 2^x.
template<int EPI, int APK, int BPK, int UNR=1>
__global__ __launch_bounds__(256) void k_mgemm(const u16* __restrict__ A, const u16* __restrict__ BT,
    int KK, int ldB, int kOff, float* __restrict__ C, const float* __restrict__ Xres,
    const float* __restrict__ gamma, u16* __restrict__ O, u16* __restrict__ Pk,
    const float* __restrict__ A1, const float* __restrict__ A2,
    float* __restrict__ s1g, float* __restrict__ s2g){
  int tid=threadIdx.x, w=tid>>6, lane=tid&63, L=lane&15, q=lane>>4;
  int OC = gridDim.x<<6;
  int colBase=blockIdx.x<<6, rowBase=blockIdx.y<<6;
  const u16* ap;
  if constexpr (APK) ap = A + (size_t)((rowBase>>4)+w)*((size_t)16*KK) + (size_t)lane*8;
  else               ap = A + (size_t)(rowBase + w*16 + L)*KK + q*8;
  const u16* bp[4];
  #pragma unroll
  for (int t=0;t<4;t++){
    if constexpr (BPK) bp[t] = BT + (size_t)((colBase>>4)+t)*((size_t)16*ldB) + (size_t)(kOff>>5)*512 + (size_t)lane*8;
    else               bp[t] = BT + (size_t)(colBase + t*16 + L)*ldB + q*8 + kOff;
  }
  f4v z4={0.f,0.f,0.f,0.f};
  f4v acc[4]={z4,z4,z4,z4};
  int nk = KK>>5;
  for (int kc0=0;kc0<nk;kc0+=UNR){
    s8v a0[UNR], bt[UNR][4];
    #pragma unroll
    for (int u=0;u<UNR;u++){
      int kc = kc0 + u;
      if constexpr (APK) a0[u] = *(const s8v*)(ap + (size_t)kc*512);
      else               a0[u] = *(const s8v*)(ap + kc*32);
      #pragma unroll
      for (int t=0;t<4;t++){
        if constexpr (BPK) bt[u][t] = *(const s8v*)(bp[t] + (size_t)kc*512);
        else               bt[u][t] = *(const s8v*)(bp[t] + kc*32);
      }
    }
    #pragma unroll
    for (int u=0;u<UNR;u++)
      #pragma unroll
      for (int t=0;t<4;t++)
        acc[t]=MFMA(a0[u],bt[u][t],acc[t]);
  }
  if constexpr (EPI<=3){
    #pragma unroll
    for (int t=0;t<4;t++){
      int col = colBase + t*16 + L;
      #pragma unroll
      for (int reg=0;reg<4;reg++){
        int row = rowBase + w*16 + q*4 + reg;
        size_t off = (size_t)row*OC + col;
        float v = acc[t][reg];
        if constexpr (EPI==0){ C[off] = v; }
        else if constexpr (EPI==1){ C[off] += v; }
        else if constexpr (EPI==2){ C[off] = flushf(Xres[off] + gamma[col]*v); }
        else { O[off] = f2b(v); }
      }
    }
  } else {
    // s1/s2 fold (prescaled by LOG2E for exp2 consumers)
    float s1p[4]={0.f,0.f,0.f,0.f}, s2p[4]={0.f,0.f,0.f,0.f};
    #pragma unroll
    for (int t=0;t<4;t++){
      int col = colBase + t*16 + L;
      float a1v = A1[col]*LOG2E, a2v = A2[col]*LOG2E;
      #pragma unroll
      for (int reg=0;reg<4;reg++){
        float v = acc[t][reg];
        s1p[reg] += v*a1v;
        s2p[reg] += v*a2v;
      }
    }
    #pragma unroll
    for (int off=1;off<16;off<<=1)
      #pragma unroll
      for (int reg=0;reg<4;reg++){
        s1p[reg] += __shfl_xor(s1p[reg],off);
        s2p[reg] += __shfl_xor(s2p[reg],off);
      }
    if (L==0){
      int sOff = (EPI==7) ? (colBase>>8)*BN : 0;
      #pragma unroll
      for (int reg=0;reg<4;reg++){
        int row = rowBase + w*16 + q*4 + reg;
        atomicAdd(&s1g[sOff+row], s1p[reg]);
        atomicAdd(&s2g[sOff+row], s2p[reg]);
      }
    }
    // coalesced pack store (16B per lane, 8 consecutive rows of one column)
    int pq_ = q&1;
    int m0 = rowBase + w*16 + (q>>1)*8;
    #pragma unroll
    for (int tp=0;tp<2;tp++){
      f4v accA = acc[2*tp], accB = acc[2*tp+1];
      f4v mine   = pq_ ? accB : accA;
      f4v theirs = pq_ ? accA : accB;
      u32 k0 = pk2(mine[0],  mine[1]);
      u32 k1 = pk2(mine[2],  mine[3]);
      u32 s0 = pk2(theirs[0],theirs[1]);
      u32 s1 = pk2(theirs[2],theirs[3]);
      u32 r0 = (u32)__shfl_xor((int)s0,16);
      u32 r1 = (u32)__shfl_xor((int)s1,16);
      uint4 val = pq_==0 ? make_uint4(k0,k1,r0,r1) : make_uint4(r0,r1,k0,k1);
      int t = 2*tp + pq_;
      int col = colBase + t*16 + L;
      *(uint4*)(Pk + packIdx(col, m0)) = val;
    }
  }
}

// ---------- fused q/k/v projections, packed A+B (gpK 256); outputs packed:
// z=0 (q) and z=1 (k): gpK(row,col,256); z=2 (v): packIdx(col,row) ----------
__global__ __launch_bounds__(256) void k_mgemm3(const u16* __restrict__ Aq, const u16* __restrict__ Akv,
    const u16* __restrict__ BT0, u16* __restrict__ O0){
  int tid=threadIdx.x, w=tid>>6, lane=tid&63, L=lane&15, q=lane>>4;
  const u16* A = blockIdx.z==0 ? Aq : Akv;
  const u16* BT = BT0 + (size_t)blockIdx.z*65536;
  u16* O = O0 + (size_t)blockIdx.z*2097152;
  int colBase=blockIdx.x<<6, rowBase=blockIdx.y<<6;
  const u16* ap = A + (size_t)((rowBase>>4)+w)*4096 + (size_t)lane*8;
  f4v z4={0.f,0.f,0.f,0.f};
  f4v acc[4]={z4,z4,z4,z4};
  #pragma unroll
  for (int kc=0;kc<8;kc++){
    s8v a0 = *(const s8v*)(ap + kc*512);
    #pragma unroll
    for (int t=0;t<4;t++){
      s8v bt = *(const s8v*)(BT + (size_t)((colBase>>4)+t)*4096 + (size_t)kc*512 + (size_t)lane*8);
      acc[t]=MFMA(a0,bt,acc[t]);
    }
  }
  bool isV = (blockIdx.z==2);
  #pragma unroll
  for (int t=0;t<4;t++){
    int col = colBase + t*16 + L;
    #pragma unroll
    for (int reg=0;reg<4;reg++){
      int row = rowBase + w*16 + q*4 + reg;
      u16 hv = f2b(acc[t][reg]);
      if (isV) O[packIdx(col, row)] = hv;
      else     O[gpK(row, col, 256)] = hv;
    }
  }
}

// ---------- split (3-term) MFMA GEMM, packed A and B (gpK 256): KK=256, OC=256 ----------
// EPI 4: hi/lo bf16 gram-packed out.  EPI 5: sq-dot fold -> pdot.
template<int EPI>
__global__ __launch_bounds__(256) void k_msgemm(const u16* __restrict__ Ah, const u16* __restrict__ Al,
    const u16* __restrict__ Bh, const u16* __restrict__ Bl,
    float* __restrict__ C, u16* __restrict__ Oh, u16* __restrict__ Ol,
    const float* __restrict__ sq, float* __restrict__ pdot){
  int tid=threadIdx.x, w=tid>>6, lane=tid&63, L=lane&15, q=lane>>4;
  int colBase=blockIdx.x<<6, rowBase=blockIdx.y<<6;
  const u16* ahp = Ah + (size_t)((rowBase>>4)+w)*4096 + (size_t)lane*8;
  const u16* alp = Al + (size_t)((rowBase>>4)+w)*4096 + (size_t)lane*8;
  f4v z4={0.f,0.f,0.f,0.f};
  f4v acc[4]={z4,z4,z4,z4};
  #pragma unroll
  for (int kc=0;kc<8;kc++){
    s8v ah=*(const s8v*)(ahp + kc*512), al=*(const s8v*)(alp + kc*512);
    #pragma unroll
    for (int t=0;t<4;t++){
      size_t boff = (size_t)((colBase>>4)+t)*4096 + (size_t)kc*512 + (size_t)lane*8;
      s8v bh=*(const s8v*)(Bh + boff);
      s8v bl=*(const s8v*)(Bl + boff);
      acc[t]=MFMA(ah,bh,acc[t]);
      acc[t]=MFMA(ah,bl,acc[t]);
      acc[t]=MFMA(al,bh,acc[t]);
    }
  }
  if constexpr (EPI==5){
    int b = rowBase>>10;
    float pp[4]={0.f,0.f,0.f,0.f};
    #pragma unroll
    for (int t=0;t<4;t++){
      int col = colBase + t*16 + L;
      float qv = sq[b*256 + col];
      #pragma unroll
      for (int reg=0;reg<4;reg++) pp[reg] += acc[t][reg]*qv;
    }
    #pragma unroll
    for (int off=1;off<16;off<<=1)
      #pragma unroll
      for (int reg=0;reg<4;reg++) pp[reg] += __shfl_xor(pp[reg],off);
    if (L==0){
      #pragma unroll
      for (int reg=0;reg<4;reg++){
        int row = rowBase + w*16 + q*4 + reg;
        atomicAdd(&pdot[row], pp[reg]);
      }
    }
  } else {
    #pragma unroll
    for (int t=0;t<4;t++){
      int col = colBase + t*16 + L;
      #pragma unroll
      for (int reg=0;reg<4;reg++){
        int row = rowBase + w*16 + q*4 + reg;
        float v = acc[t][reg];
        if constexpr (EPI==0){ C[(size_t)row*256 + col] = v; }
        else {
          size_t off = gpK(row, col, 256);
          u16 h = f2b(v); Oh[off]=h; Ol[off]=f2b(v - b2f(h));
        }
      }
    }
  }
}

// ---------- gram + bitpack v2: packed fragments, symmetric tile enumeration ----------
__global__ __launch_bounds__(256) void k_mconnect2(const u16* __restrict__ fahP, const u16* __restrict__ falP,
    const u8* __restrict__ sel8, u32* __restrict__ conn){
  __shared__ u8 sg[64][64];
  __shared__ u8 selI[64], selJ[64];
  int tid=threadIdx.x, w=tid>>6, lane=tid&63, L=lane&15, q=lane>>4;
  int b=blockIdx.z;
  int p=blockIdx.x;
  int i = (int)((sqrtf(8.f*p+1.f)-1.f)*0.5f);
  while ((i+1)*(i+2)/2 <= p) i++;
  while (i*(i+1)/2 > p) i--;
  int j = p - i*(i+1)/2;          // i >= j, both 0..15
  if (tid < 64)        selI[tid]     = sel8[b*NN + i*64 + tid];
  else if (tid < 128)  selJ[tid-64]  = sel8[b*NN + j*64 + (tid-64)];
  const u16* ah0 = fahP + ((size_t)(b*64 + i*4 + w))*4096 + (size_t)lane*8;
  const u16* al0 = falP + ((size_t)(b*64 + i*4 + w))*4096 + (size_t)lane*8;
  const u16* bh0 = fahP + ((size_t)(b*64 + j*4))*4096 + (size_t)lane*8;
  const u16* bl0 = falP + ((size_t)(b*64 + j*4))*4096 + (size_t)lane*8;
  f4v z4={0.f,0.f,0.f,0.f};
  f4v acc[4]={z4,z4,z4,z4};
  #pragma unroll
  for (int kc=0;kc<8;kc++){
    s8v ah = *(const s8v*)(ah0 + kc*512);
    s8v al = *(const s8v*)(al0 + kc*512);
    #pragma unroll
    for (int t=0;t<4;t++){
      s8v bh = *(const s8v*)(bh0 + (size_t)t*4096 + kc*512);
      s8v bl = *(const s8v*)(bl0 + (size_t)t*4096 + kc*512);
      acc[t]=MFMA(ah,bh,acc[t]);
      acc[t]=MFMA(ah,bl,acc[t]);
      acc[t]=MFMA(al,bh,acc[t]);
    }
  }
  #pragma unroll
  for (int t=0;t<4;t++)
    #pragma unroll
    for (int reg=0;reg<4;reg++)
      sg[w*16 + q*4 + reg][t*16 + L] = acc[t][reg] > 0.f;
  __syncthreads();
  int row=(tid&127)>>1, ww=tid&1;
  if (tid<128){
    u32 word=0;
    if (selI[row]){
      #pragma unroll 8
      for (int jj=0;jj<32;jj++)
        if (sg[row][ww*32+jj] && selJ[ww*32+jj]) word |= (1u<<jj);
    }
    conn[((size_t)b*NN + i*64+row)*32 + j*2 + ww] = word;
  } else if (i != j){
    u32 word=0;
    if (selJ[row]){
      #pragma unroll 8
      for (int jj=0;jj<32;jj++)
        if (sg[ww*32+jj][row] && selI[ww*32+jj]) word |= (1u<<jj);
    }
    conn[((size_t)b*NN + j*64+row)*32 + i*2 + ww] = word;
  }
}

// ---------- row max of s2 over connected m ----------
__global__ __launch_bounds__(256) void k_rowmax(const float* __restrict__ s2a,
    const u32* __restrict__ conn, float* __restrict__ M2a){
  int h = blockIdx.y;
  int r = blockIdx.x*4 + (threadIdx.x>>6);
  int lane = threadIdx.x&63;
  int b = r>>10;
  const float* s2p = s2a + h*BN + b*NN;
  float mx = -3.0e38f;
  #pragma unroll
  for (int t=0;t<16;t++){
    int m = lane + t*64;
    u32 wd = conn[(size_t)r*32 + (m>>5)];
    if ((wd>>(m&31))&1u) mx = fmaxf(mx, s2p[m]);
  }
  mx = wredmax(mx);
  if (lane==0) M2a[h*BN+r] = mx;
}

// ---------- MFMA GAT attention v8: P shared via LDS; V loaded EARLY; setprio MFMA ----------
// s1/s2/M2a are prescaled by LOG2E -> bare v_exp_f32 (2^x).
// PKO: 0 = row-major output (stride oStride); else fragment-packed gpK(row,col,PKO).
template<int CT, bool SWZ, int PKO>
__global__ __launch_bounds__(256,4) void k_mattn5(const float* __restrict__ s1a, const float* __restrict__ s2a,
    const float* __restrict__ M2a, const u32* __restrict__ conn,
    const u16* __restrict__ P, int headMul, u16* __restrict__ Out, int oStride){
  __shared__ __align__(16) u16 Pb[2][4][512];
  __shared__ float Srow[64];
  int tid=threadIdx.x, w=tid>>6, lane=tid&63, L=lane&15, q=lane>>4;
  int h, rowBlk;
  if constexpr (SWZ){ h = blockIdx.y & 7; rowBlk = (blockIdx.y>>3) + (blockIdx.z<<4); }
  else             { h = blockIdx.z;     rowBlk = blockIdx.y; }
  int rowBase = rowBlk*64;
  int hOff = h*headMul, sOff = h*BN;
  int b = rowBase>>10;
  size_t bOff = (size_t)b*NN;
  int r = rowBase + w*16 + L;             // own row for P-build
  float s1v = s1a[sOff+r];
  float rmv = leakyf(s1v + M2a[sOff+r]);
  const float* s2p = s2a + sOff + bOff;
  const u32* cp = conn + (size_t)r*32;
  int tile0 = blockIdx.x*(4*CT) + w*CT;   // first col-tile owned by this wave
  const u16* vp = P + (size_t)((hOff>>4) + tile0)*131072 + (size_t)b*16384 + (size_t)lane*8;
  f4v z4={0.f,0.f,0.f,0.f};
  f4v acc[4][CT];
  #pragma unroll
  for (int g=0;g<4;g++)
    #pragma unroll
    for (int t=0;t<CT;t++) acc[g][t]=z4;
  float sumP = 0.f;
  for (int k0=0;k0<NN;k0+=32){
    int cur=(k0>>5)&1;
    u32 cw = cp[k0>>5];
    // issue THIS chunk's V loads first — latency hidden under P-build + barrier
    s8v vf[CT];
    {
      const u16* vk = vp + (size_t)(k0>>5)*512;
      #pragma unroll
      for (int t=0;t<CT;t++) vf[t] = *(const s8v*)(vk + (size_t)t*131072);
    }
    float4 sA = *(const float4*)(s2p + k0 + q*8);
    float4 sB = *(const float4*)(s2p + k0 + q*8 + 4);
    float s2v[8] = {sA.x,sA.y,sA.z,sA.w,sB.x,sB.y,sB.z,sB.w};
    float p[8];
    #pragma unroll
    for (int j=0;j<8;j++){
      float z = s1v + s2v[j];
      float ev = fmaxf(z, 0.2f*z);                      // leaky = max(z, 0.2z) (scaled)
      ev = ((cw>>(q*8+j))&1u) ? ev : -9.0e15f;          // mask BEFORE exp (uniform rows!)
      p[j] = exp2z(ev - rmv);                            // bare v_exp (2^x), prescaled
      sumP += p[j];
    }
    union{ s8v v; u32 u[4]; } pk;
    #pragma unroll
    for (int jj=0;jj<4;jj++)
      pk.u[jj] = pk2(p[2*jj], p[2*jj+1]);
    *(s8v*)&Pb[cur][w][lane*8] = pk.v;    // ds_write_b128, contiguous
    __syncthreads();                       // all P fragments for this chunk visible
    s8v pa[4];
    #pragma unroll
    for (int g=0;g<4;g++) pa[g] = *(const s8v*)&Pb[cur][g][lane*8];
    __builtin_amdgcn_s_setprio(1);
    #pragma unroll
    for (int t=0;t<CT;t++)
      #pragma unroll
      for (int g=0;g<4;g++) acc[g][t] = MFMA(pa[g], vf[t], acc[g][t]);
    __builtin_amdgcn_s_setprio(0);
  }
  sumP += __shfl_xor(sumP,16);
  sumP += __shfl_xor(sumP,32);
  if (lane<16) Srow[w*16+lane] = sumP;
  __syncthreads();
  #pragma unroll
  for (int g=0;g<4;g++){
    float4 sv = *(const float4*)&Srow[g*16 + q*4];
    float rsi[4] = {1.f/sv.x, 1.f/sv.y, 1.f/sv.z, 1.f/sv.w};
    #pragma unroll
    for (int t=0;t<CT;t++){
      int col = hOff + (tile0+t)*16 + L;
      #pragma unroll
      for (int reg=0;reg<4;reg++){
        int row = rowBase + g*16 + q*4 + reg;
        float ov = eluf(acc[g][t][reg]*rsi[reg]);
        if constexpr (PKO) Out[gpK(row, col, PKO)] = f2b(ov);
        else               Out[(size_t)row*oStride + col] = f2b(ov);
      }
    }
  }
}

// ---------- LayerNorms (packed gpK-256 output) ----------
__global__ __launch_bounds__(256) void k_ln_x(const float* __restrict__ x, const float* __restrict__ g,
                                              const float* __restrict__ bb, u16* __restrict__ out){
  int r = blockIdx.x*4 + (threadIdx.x>>6);
  int lane=threadIdx.x&63;
  float4 v = *(const float4*)(x + (size_t)r*DD + lane*4);
  float s = v.x+v.y+v.z+v.w;
  float s2 = v.x*v.x+v.y*v.y+v.z*v.z+v.w*v.w;
  s = wredsum(s); s2 = wredsum(s2);
  float mean = s*(1.f/256.f);
  float var = s2*(1.f/256.f) - mean*mean;
  float rstd = rsqrtf(var + 1e-5f);
  float4 gv = *(const float4*)(g+lane*4), bv = *(const float4*)(bb+lane*4);
  u16 t[4];
  t[0]=f2b((v.x-mean)*rstd*gv.x+bv.x); t[1]=f2b((v.y-mean)*rstd*gv.y+bv.y);
  t[2]=f2b((v.z-mean)*rstd*gv.z+bv.z); t[3]=f2b((v.w-mean)*rstd*gv.w+bv.w);
  *(uint2*)(out + gpK(r, lane*4, 256)) = *(uint2*)&t[0];
}

__global__ __launch_bounds__(256) void k_ln_kv(const u16* __restrict__ gout, const float* __restrict__ pe,
    const u8* __restrict__ sel8, const float* __restrict__ g, const float* __restrict__ bb,
    u16* __restrict__ out){
  int r = blockIdx.x*4 + (threadIdx.x>>6);
  int lane=threadIdx.x&63;
  int n = r & 1023;
  float4 v = make_float4(0.f,0.f,0.f,0.f);
  if (sel8[r]){
    float4 gv = ld4bf(gout + (size_t)r*DD + lane*4);
    float4 pv = *(const float4*)(pe + (size_t)n*DD + lane*4);
    v = make_float4(gv.x+pv.x, gv.y+pv.y, gv.z+pv.z, gv.w+pv.w);
  }
  float s = v.x+v.y+v.z+v.w;
  float s2 = v.x*v.x+v.y*v.y+v.z*v.z+v.w*v.w;
  s = wredsum(s); s2 = wredsum(s2);
  float mean = s*(1.f/256.f);
  float var = s2*(1.f/256.f) - mean*mean;
  float rstd = rsqrtf(var + 1e-5f);
  float4 gv = *(const float4*)(g+lane*4), bv = *(const float4*)(bb+lane*4);
  u16 t[4];
  t[0]=f2b((v.x-mean)*rstd*gv.x+bv.x); t[1]=f2b((v.y-mean)*rstd*gv.y+bv.y);
  t[2]=f2b((v.z-mean)*rstd*gv.z+bv.z); t[3]=f2b((v.w-mean)*rstd*gv.w+bv.w);
  *(uint2*)(out + gpK(r, lane*4, 256)) = *(uint2*)&t[0];
}

// ---------- CA attention v3: barrier-free flash; direct fragment loads ----------
__global__ __launch_bounds__(256) void k_mca_av3(const u16* __restrict__ q, const u16* __restrict__ k,
    const u16* __restrict__ v, const u8* __restrict__ sel8, u16* __restrict__ O){
  __shared__ __align__(16) u16 Pw[4][16][72];
  int tid=threadIdx.x;
  int w = tid>>6, lane = tid&63, L = lane&15, qd = lane>>4;
  int b=blockIdx.z, h=blockIdx.y, rowBase=blockIdx.x*64;
  size_t bOff = (size_t)b*NN;
  const u16* qbase = q + (size_t)((bOff + rowBase + w*16)>>4)*4096 + (size_t)lane*8;
  s8v af0 = *(const s8v*)(qbase + (size_t)(h*2+0)*512);
  s8v af1 = *(const s8v*)(qbase + (size_t)(h*2+1)*512);
  float rm[4], sp[4];
  #pragma unroll
  for (int reg=0;reg<4;reg++){ rm[reg] = -3.0e38f; sp[reg] = 0.f; }
  f4v zero = {0.f,0.f,0.f,0.f};
  f4v acc[4] = {zero,zero,zero,zero};
  for (int m0=0;m0<NN;m0+=64){
    s8v bt[4][2];
    #pragma unroll
    for (int t=0;t<4;t++){
      const u16* kb = k + (size_t)((bOff + m0 + t*16)>>4)*4096 + (size_t)lane*8;
      bt[t][0] = *(const s8v*)(kb + (size_t)(h*2+0)*512);
      bt[t][1] = *(const s8v*)(kb + (size_t)(h*2+1)*512);
    }
    s8v vf[4][2];
    #pragma unroll
    for (int t=0;t<4;t++){
      const u16* vb = v + (size_t)(((h*4+t)*8 + b)*32 + (m0>>5))*512 + (size_t)lane*8;
      vf[t][0] = *(const s8v*)vb;
      vf[t][1] = *(const s8v*)(vb + 512);
    }
    f4v sa[4] = {zero,zero,zero,zero};
    #pragma unroll
    for (int t=0;t<4;t++){
      sa[t] = MFMA(af0, bt[t][0], sa[t]);
      sa[t] = MFMA(af1, bt[t][1], sa[t]);
    }
    float vals[4][4];
    float tmax[4];
    #pragma unroll
    for (int reg=0;reg<4;reg++) tmax[reg] = -3.0e38f;
    #pragma unroll
    for (int t=0;t<4;t++){
      int m = m0 + t*16 + L;
      bool sl = sel8[b*NN+m];
      #pragma unroll
      for (int reg=0;reg<4;reg++){
        float val = sl ? sa[t][reg]*0.125f : -1.0e9f;
        vals[t][reg] = val;
        tmax[reg] = fmaxf(tmax[reg], val);
      }
    }
    #pragma unroll
    for (int off=1;off<16;off<<=1)
      #pragma unroll
      for (int reg=0;reg<4;reg++) tmax[reg] = fmaxf(tmax[reg], __shfl_xor(tmax[reg],off));
    float sc[4];
    #pragma unroll
    for (int reg=0;reg<4;reg++){
      float nm = fmaxf(rm[reg], tmax[reg]);
      sc[reg] = exp0(rm[reg] - nm);
      rm[reg] = nm;
      sp[reg] *= sc[reg];
    }
    #pragma unroll
    for (int t=0;t<4;t++){
      #pragma unroll
      for (int reg=0;reg<4;reg++){
        float pv = exp0(vals[t][reg] - rm[reg]);
        sp[reg] += pv;
        Pw[w][qd*4 + reg][t*16 + L] = f2b(pv);   // intra-wave slice, no barrier
      }
    }
    #pragma unroll
    for (int t=0;t<4;t++)
      #pragma unroll
      for (int reg=0;reg<4;reg++) acc[t][reg] *= sc[reg];
    #pragma unroll
    for (int mc2=0;mc2<2;mc2++){
      s8v pf = *(const s8v*)&Pw[w][L][mc2*32 + qd*8];
      #pragma unroll
      for (int t=0;t<4;t++)
        acc[t] = MFMA(pf, vf[t][mc2], acc[t]);
    }
  }
  #pragma unroll
  for (int off=1;off<16;off<<=1)
    #pragma unroll
    for (int reg=0;reg<4;reg++) sp[reg] += __shfl_xor(sp[reg],off);
  float ri[4];
  #pragma unroll
  for (int reg=0;reg<4;reg++) ri[reg] = 1.f/sp[reg];
  #pragma unroll
  for (int t=0;t<4;t++){
    int col = h*64 + t*16 + L;
    #pragma unroll
    for (int reg=0;reg<4;reg++){
      int row = (int)bOff + rowBase + w*16 + qd*4 + reg;
      O[gpK(row, col, 256)] = f2b(acc[t][reg]*ri[reg]);
    }
  }
}

extern "C" void kernel_launch(void* const* d_in, const int* in_sizes, int n_in,
                              void* d_out, int out_size, void* d_ws, size_t ws_size,
                              hipStream_t stream) {
  (void)in_sizes; (void)n_in; (void)out_size;
  const float* x      = (const float*)d_in[0];
  const int*   mask   = (const int*  )d_in[1];
  const float* pe     = (const float*)d_in[2];
  const float* sim_Wx = (const float*)d_in[3];
  const float* sim_Wq = (const float*)d_in[4];
  const float* adj_W  = (const float*)d_in[5];
  const float* gat_W  = (const float*)d_in[6];
  const float* gat_a1 = (const float*)d_in[7];
  const float* gat_a2 = (const float*)d_in[8];
  const float* gat_Wo = (const float*)d_in[9];
  const float* gat_ao1= (const float*)d_in[10];
  const float* gat_ao2= (const float*)d_in[11];
  const float* ln3_g  = (const float*)d_in[12];
  const float* ln3_b  = (const float*)d_in[13];
  const float* ln4_g  = (const float*)d_in[14];
  const float* ln4_b  = (const float*)d_in[15];
  const float* ca_Wq  = (const float*)d_in[16];
  const float* ca_Wk  = (const float*)d_in[17];
  const float* ca_Wv  = (const float*)d_in[18];
  const float* ca_Wp  = (const float*)d_in[19];
  const float* gamma  = (const float*)d_in[20];
  float* out    = (float*)d_out;
  float* simOut = out + (size_t)BN*DD;

  const size_t MB = 1024*1024;
  bool big = ws_size >= 98*MB;
  char* W = (char*)d_ws;
  float* pq   = (float*)W;
  float* cnt  = pq + 2048;
  float* sq   = cnt + 16;
  float* s1a  = (float*)(W + 64*1024);
  float* s2a  = (float*)(W + 320*1024);
  float* M2a  = (float*)(W + 576*1024);
  float* pdot = (float*)(W + 1216*1024);
  u8*    sel8 = (u8*)(W + 1400*1024);
  u32*   conn = (u32*)(W + 2*MB);
  u16*   WT0  = (u16*)(W + 3*MB);
  u16*   WoT  = (u16*)(W + 4*MB);
  u16*   WQT  = (u16*)(W + 5*MB);
  u16*   WPT  = WQT + 3*65536;
  u16*   sWxh = (u16*)(W + 5*MB + 512*1024);
  u16*   sWxl = sWxh + 65536;
  u16*   aWh  = sWxl + 65536;
  u16*   aWl  = aWh + 65536;
  u16*   xh   = (u16*)(W + 6*MB);
  u16*   xl   = (u16*)(W + 10*MB);
  float* S0   = (float*)(W + 14*MB);
  u16*   fah  = (u16*)(W + 22*MB);
  u16*   fal  = (u16*)(W + 26*MB);
  u16*   T2   = (u16*)(W + 30*MB);

  // prep (everything fragment-packed)
  k_split<<<BN*DD/2048,256,0,stream>>>(x, xh, xl);
  k_transpose<<<dim3(4,4,HG),256,0,stream>>>(gat_W, WT0, 256, 65536, 256);
  k_transpose<<<dim3(4,32,1),256,0,stream>>>(gat_Wo, WoT, 2048, 0, 2048);
  k_transpose4<<<dim3(4,4,4),256,0,stream>>>(ca_Wq, ca_Wk, ca_Wv, ca_Wp, WQT);
  k_transp_split<<<dim3(4,4,1),256,0,stream>>>(sim_Wx, sWxh, sWxl);
  k_transp_split<<<dim3(4,4,1),256,0,stream>>>(adj_W, aWh, aWl);

  hipMemsetAsync(pq, 0, (2048+16+2048)*sizeof(float), stream);   // pq + cnt + sq
  hipMemsetAsync(pdot, 0, BN*sizeof(float), stream);
  k_posq<<<dim3(BB,64),256,0,stream>>>(x, mask, pq, cnt);
  k_sq<<<dim3(BB,16),256,0,stream>>>(pq, cnt, sim_Wq, sq);
  k_msgemm<5><<<dim3(4,128),256,0,stream>>>(xh, xl, sWxh, sWxl, nullptr, nullptr, nullptr, sq, pdot); // y-dot fold
  k_simsel2<<<BN/256,256,0,stream>>>(pdot, simOut, sel8);
  k_msgemm<4><<<dim3(4,128),256,0,stream>>>(xh, xl, aWh, aWl, nullptr, fah, fal, nullptr, nullptr);   // fa gram-packed
  k_mconnect2<<<dim3(136,1,BB),256,0,stream>>>(fah, fal, sel8, conn);

  if (big){
    u16* WhP   = (u16*)(W + 66*MB);   // attention-packed Wh_cat, 32MB
    u16* htcat = (u16*)(W + 34*MB);   // fragment-packed (gpK 2048) ht_cat, 32MB
    u16* S0P   = (u16*)(W + 22*MB);   // attention-packed Who, 4MB (fah dead after mconnect)
    u16* qx = (u16*)(W + 34*MB);      // after htcat consumed
    u16* kv = (u16*)(W + 38*MB);
    u16* qb = (u16*)(W + 42*MB);
    u16* vb = (u16*)(W + 50*MB);
    u16* Ob = (u16*)(W + 54*MB);

    hipMemsetAsync(s1a, 0, 512*1024, stream);  // s1a(256K) + s2a(256K) contiguous
    k_mgemm<7,1,1,2><<<dim3(32,128),256,0,stream>>>(xh, WT0, 256, 256, 0, nullptr, nullptr, nullptr, nullptr,
                                                    WhP, gat_a1, gat_a2, s1a, s2a);  // WhP pack + s1s2 fold (×log2e)
    k_rowmax<<<dim3(BN/4,HG),256,0,stream>>>(s2a, conn, M2a);
    k_mattn5<4,true,2048><<<dim3(1,128,HG),256,0,stream>>>(s1a, s2a, M2a, conn, WhP, 256, htcat, 2048);
    hipMemsetAsync(s1a, 0, BN*sizeof(float), stream);
    hipMemsetAsync(s2a, 0, BN*sizeof(float), stream);
    k_mgemm<8,1,1,4><<<dim3(4,128),256,0,stream>>>(htcat, WoT, 2048, 2048, 0, nullptr, nullptr, nullptr, nullptr,
                                                   S0P, gat_ao1, gat_ao2, s1a, s2a);  // S0P pack + s1s2 fold (×log2e)
    k_rowmax<<<dim3(BN/4,1),256,0,stream>>>(s2a, conn, M2a);
    k_mattn5<1,false,0><<<dim3(4,128,1),256,0,stream>>>(s1a, s2a, M2a, conn, S0P, 0, T2, 256);  // gout

    k_ln_x<<<BN/4,256,0,stream>>>(x, ln3_g, ln3_b, qx);
    k_ln_kv<<<BN/4,256,0,stream>>>(T2, pe, sel8, ln4_g, ln4_b, kv);
    k_mgemm3<<<dim3(4,128,3),256,0,stream>>>(qx, kv, WQT, qb);     // qb,kb gpK; vb packIdx
    k_mca_av3<<<dim3(16,HC,BB),256,0,stream>>>(qb, qb + 2097152, vb, sel8, Ob);
    k_mgemm<2,1,1,4><<<dim3(4,128),256,0,stream>>>(Ob, WPT, 256, 256, 0, out, x, gamma, nullptr, nullptr,
                                                   nullptr, nullptr, nullptr, nullptr);
  } else {
    // small-ws fallback: per-head loop, packed kernels (rarely taken)
    u16* T0 = fah;
    u16* T1 = fal;
    u16* S0b = (u16*)S0;
    hipMemsetAsync(s1a, 0, 512*1024, stream);
    for (int h=0;h<HG;h++){
      hipMemsetAsync(s1a, 0, BN*sizeof(float), stream);
      hipMemsetAsync(s2a, 0, BN*sizeof(float), stream);
      k_mgemm<8,1,1><<<dim3(4,128),256,0,stream>>>(xh, WT0 + (size_t)h*65536, 256, 256, 0,
                                                   nullptr, nullptr, nullptr, nullptr, T0,
                                                   gat_a1 + h*DD, gat_a2 + h*DD, s1a, s2a);
      k_rowmax<<<dim3(BN/4,1),256,0,stream>>>(s2a, conn, M2a);
      k_mattn5<1,false,0><<<dim3(4,128,1),256,0,stream>>>(s1a, s2a, M2a, conn, T0, 0, T1, 256);
      k_mgemm<1,0,1><<<dim3(4,128),256,0,stream>>>(T1, WoT, 256, 2048, h*256, S0, nullptr, nullptr, nullptr, nullptr,
                                                   nullptr, nullptr, nullptr, nullptr);
    }
    hipMemsetAsync(s1a, 0, BN*sizeof(float), stream);
    hipMemsetAsync(s2a, 0, BN*sizeof(float), stream);
    k_mattn5<1,false,0><<<dim3(4,128,1),256,0,stream>>>(s1a, s2a, M2a, conn, (u16*)S0, 0, T2, 256);
    k_ln_x<<<BN/4,256,0,stream>>>(x, ln3_g, ln3_b, T1);
    k_ln_kv<<<BN/4,256,0,stream>>>(T2, pe, sel8, ln4_g, ln4_b, T0);
    k_mgemm3<<<dim3(4,128,3),256,0,stream>>>(T1, T0, WQT, S0b);
    k_mca_av3<<<dim3(16,HC,BB),256,0,stream>>>(S0b, S0b + 2097152, S0b + 4194304, sel8, T0);
    k_mgemm<2,1,1><<<dim3(4,128),256,0,stream>>>(T0, WPT, 256, 256, 0, out, x, gamma, nullptr, nullptr,
                                                 nullptr, nullptr, nullptr, nullptr);
  }
}

// Round 18
// 445.051 us; speedup vs baseline: 1.2200x; 1.0015x over previous
//
#include <hip/hip_runtime.h>
#include <hip/hip_bf16.h>

// GATFusionBlockPosOnly: B=8, N=1024, D=256, 8 GAT heads, 4 CA heads.
// Round 27:
//  - R26 post-mortem: setprio+UNR2 ~neutral (447->445.7). mattn5 still 63us,
//    not VALU/MFMA/HBM bound -> the __syncthreads vmcnt(0) drain is the
//    structural serializer (m97-style): V loads can never span the barrier.
//  - k_mattn5: lgkmcnt-only barrier (asm s_waitcnt lgkmcnt(0) + s_barrier)
//    instead of __syncthreads. Only cross-wave dep is the LDS P-write; V/s2
//    loads stay in flight across the barrier (T4 minimal form).
//    NOTE: Pb double-buffer is now load-bearing (single buffer would race).

#define BB 8
#define NN 1024
#define DD 256
#define HG 8
#define HC 4
#define BN (BB*NN)
#define LOG2E 1.44269504088896f

typedef unsigned short u16;
typedef unsigned int u32;
typedef unsigned char u8;
typedef __attribute__((ext_vector_type(8))) short s8v;   // 8 bf16
typedef __attribute__((ext_vector_type(4))) float f4v;   // 4 fp32 acc
#define MFMA(a,b,c) __builtin_amdgcn_mfma_f32_16x16x32_bf16((a),(b),(c),0,0,0)

__device__ __forceinline__ u16 f2b(float x){
  union{ float f; unsigned u; } a; a.f = x;
  unsigned r = a.u + 0x7fff + ((a.u>>16)&1);
  return (u16)(r>>16);
}
__device__ __forceinline__ float b2f(u16 b){ return __uint_as_float(((unsigned)b)<<16); }
__device__ __forceinline__ float4 ld4bf(const u16* p){
  uint2 u = *(const uint2*)p;
  float4 r;
  r.x=__uint_as_float(u.x<<16); r.y=__uint_as_float(u.x&0xffff0000u);
  r.z=__uint_as_float(u.y<<16); r.w=__uint_as_float(u.y&0xffff0000u);
  return r;
}
__device__ __forceinline__ void load8(const float* p, float* v){
  float4 a=*(const float4*)p, b=*(const float4*)(p+4);
  v[0]=a.x;v[1]=a.y;v[2]=a.z;v[3]=a.w;v[4]=b.x;v[5]=b.y;v[6]=b.z;v[7]=b.w;
}
__device__ __forceinline__ float wredsum(float v){
  #pragma unroll
  for(int o=32;o>0;o>>=1) v += __shfl_xor(v,o);
  return v;
}
__device__ __forceinline__ float wredmax(float v){
  #pragma unroll
  for(int o=32;o>0;o>>=1) v = fmaxf(v,__shfl_xor(v,o));
  return v;
}
__device__ __forceinline__ float eluf(float x){ return x>0.f ? x : __expf(x)-1.f; }
__device__ __forceinline__ float leakyf(float z){ return z>=0.f ? z : 0.2f*z; }
__device__ __forceinline__ float exp0(float a){ return __expf(fminf(a, 0.f)); }
__device__ __forceinline__ float exp2z(float a){   // 2^min(a,0), bare v_exp
  float x = fminf(a, 0.f), r;
  asm("v_exp_f32 %0, %1" : "=v"(r) : "v"(x));
  return r;
}
__device__ __forceinline__ float flushf(float v){ return (fabsf(v) < 1.0e30f) ? v : 0.f; }
__device__ __forceinline__ u32 pk2(float lo, float hi){
  u32 r;
  asm("v_cvt_pk_bf16_f32 %0, %1, %2" : "=v"(r) : "v"(lo), "v"(hi));
  return r;
}

// packed index for element (col, m) of the attention-V pack:  b=m>>10, kk=m&1023
__device__ __forceinline__ size_t packIdx(int col, int row){
  int kk = row & 1023;
  return ((((size_t)(col>>4))*8 + (row>>10))*32 + (kk>>5))*512
       + (size_t)(((((kk>>3)&3)*16) + (col&15))*8 + (kk&7));
}

// fragment-pack: element (row, k) of a [rows][KK] operand -> fragment order.
__device__ __forceinline__ size_t gpK(int row, int k, int KK){
  return (size_t)(row>>4)*((size_t)16*KK) + (size_t)(k>>5)*512
       + (size_t)(((((k>>3)&3)*16) + (row&15))*8 + (k&7));
}

// ---------- fp32 -> (hi,lo) bf16 split, packed output (gpK, KK=256) ----------
__global__ __launch_bounds__(256) void k_split(const float* __restrict__ X, u16* __restrict__ H, u16* __restrict__ Lo){
  size_t i = ((size_t)blockIdx.x*256 + threadIdx.x)*8;
  float v[8]; load8(X+i, v);
  u16 hh[8], ll[8];
  #pragma unroll
  for (int j=0;j<8;j++){ hh[j]=f2b(v[j]); ll[j]=f2b(v[j]-b2f(hh[j])); }
  int row = (int)(i>>8), col = (int)(i&255);
  size_t off = gpK(row, col, 256);
  *(uint4*)(H+off)=*(uint4*)&hh[0];
  *(uint4*)(Lo+off)=*(uint4*)&ll[0];
}

// ---------- transpose fp32 [R][C] -> bf16; pkKK=0: row-major [C][R]; else gpK packed ----------
__global__ __launch_bounds__(256) void k_transpose(const float* __restrict__ S, u16* __restrict__ D,
                                                   int R, int sliceElems, int pkKK){
  __shared__ float tl[64][65];
  const float* src = S + (size_t)blockIdx.z*sliceElems;
  u16* dst = D + (size_t)blockIdx.z*sliceElems;
  int C = gridDim.x*64;
  int bx=blockIdx.x*64, by=blockIdx.y*64;
  int tid=threadIdx.x, r=tid>>2, c0=(tid&3)*16;
  #pragma unroll
  for (int i=0;i<16;i+=4){
    float4 v = *(const float4*)(src + (size_t)(by+r)*C + bx + c0 + i);
    tl[r][c0+i]=v.x; tl[r][c0+i+1]=v.y; tl[r][c0+i+2]=v.z; tl[r][c0+i+3]=v.w;
  }
  __syncthreads();
  u16 tmp[16];
  #pragma unroll
  for (int i=0;i<16;i++) tmp[i] = f2b(tl[c0+i][r]);
  if (pkKK){
    *(uint4*)(dst + gpK(bx+r, by+c0,     pkKK)) = *(uint4*)&tmp[0];
    *(uint4*)(dst + gpK(bx+r, by+c0+8,   pkKK)) = *(uint4*)&tmp[8];
  } else {
    *(uint4*)(dst + (size_t)(bx+r)*R + by + c0)     = *(uint4*)&tmp[0];
    *(uint4*)(dst + (size_t)(bx+r)*R + by + c0 + 8) = *(uint4*)&tmp[8];
  }
}

// ---------- 4x 256x256 transposes, PACKED (gpK 256) output; grid (4,4,4) ----------
__global__ __launch_bounds__(256) void k_transpose4(const float* __restrict__ Sa, const float* __restrict__ Sb,
    const float* __restrict__ Sc, const float* __restrict__ Sd, u16* __restrict__ D){
  __shared__ float tl[64][65];
  const float* src = blockIdx.z==0 ? Sa : blockIdx.z==1 ? Sb : blockIdx.z==2 ? Sc : Sd;
  u16* dst = D + (size_t)blockIdx.z*65536;
  int bx=blockIdx.x*64, by=blockIdx.y*64;
  int tid=threadIdx.x, r=tid>>2, c0=(tid&3)*16;
  #pragma unroll
  for (int i=0;i<16;i+=4){
    float4 v = *(const float4*)(src + (size_t)(by+r)*256 + bx + c0 + i);
    tl[r][c0+i]=v.x; tl[r][c0+i+1]=v.y; tl[r][c0+i+2]=v.z; tl[r][c0+i+3]=v.w;
  }
  __syncthreads();
  u16 tmp[16];
  #pragma unroll
  for (int i=0;i<16;i++) tmp[i] = f2b(tl[c0+i][r]);
  *(uint4*)(dst + gpK(bx+r, by+c0,   256)) = *(uint4*)&tmp[0];
  *(uint4*)(dst + gpK(bx+r, by+c0+8, 256)) = *(uint4*)&tmp[8];
}

// ---------- transpose + split: fp32 [256][256] -> hi/lo bf16 PACKED (gpK 256) ----------
__global__ __launch_bounds__(256) void k_transp_split(const float* __restrict__ S, u16* __restrict__ DH, u16* __restrict__ DL){
  __shared__ float tl[64][65];
  int bx=blockIdx.x*64, by=blockIdx.y*64;
  int tid=threadIdx.x, r=tid>>2, c0=(tid&3)*16;
  #pragma unroll
  for (int i=0;i<16;i+=4){
    float4 v = *(const float4*)(S + (size_t)(by+r)*256 + bx + c0 + i);
    tl[r][c0+i]=v.x; tl[r][c0+i+1]=v.y; tl[r][c0+i+2]=v.z; tl[r][c0+i+3]=v.w;
  }
  __syncthreads();
  u16 th[16], tll[16];
  #pragma unroll
  for (int i=0;i<16;i++){
    float v = tl[c0+i][r];
    th[i]=f2b(v); tll[i]=f2b(v - b2f(th[i]));
  }
  size_t o0 = gpK(bx+r, by+c0,   256);
  size_t o1 = gpK(bx+r, by+c0+8, 256);
  *(uint4*)(DH + o0) = *(uint4*)&th[0];
  *(uint4*)(DH + o1) = *(uint4*)&th[8];
  *(uint4*)(DL + o0) = *(uint4*)&tll[0];
  *(uint4*)(DL + o1) = *(uint4*)&tll[8];
}

// ---------- pos_query: grid (BB, 64), 16 rows per block ----------
__global__ __launch_bounds__(256) void k_posq(const float* __restrict__ x, const int* __restrict__ mask,
                                              float* __restrict__ pq, float* __restrict__ cnt){
  int b = blockIdx.x, chunk = blockIdx.y;
  int d = threadIdx.x;
  int n0 = chunk*16;
  float acc = 0.f; float c = 0.f;
  for (int i=0;i<16;i++){
    int n = n0+i;
    if (mask[b*NN+n]==1){ acc += x[((size_t)(b*NN+n))*DD + d]; c += 1.f; }
  }
  atomicAdd(&pq[b*DD+d], acc);
  if (d==0) atomicAdd(&cnt[b], c);
}

// ---------- sq: grid (BB, 16), 16 d-rows per block, atomic accumulate ----------
__global__ __launch_bounds__(256) void k_sq(const float* __restrict__ pq, const float* __restrict__ cnt,
                                            const float* __restrict__ Wq, float* __restrict__ sq){
  int b = blockIdx.x, dq = blockIdx.y;
  int e = threadIdx.x;
  float inv = 1.f / fmaxf(cnt[b], 1.f);
  float acc=0.f;
  for (int i=0;i<16;i++){
    int d0 = dq*16 + i;
    acc += pq[b*DD+d0] * Wq[d0*DD+e];
  }
  atomicAdd(&sq[b*DD+e], acc*inv);
}

// ---------- sigmoid + threshold from folded dot ----------
__global__ __launch_bounds__(256) void k_simsel2(const float* __restrict__ pdot,
                                                 float* __restrict__ simOut, u8* __restrict__ sel8){
  int r = blockIdx.x*256 + threadIdx.x;
  float s = pdot[r] * 0.0625f;
  float sim = 1.f/(1.f+expf(-s));
  simOut[r] = sim;
  sel8[r] = (sim > 0.97f) ? 1 : 0;
}

// ---------- no-LDS MFMA GEMM: out[8192, OC] = A[8192,KK] @ BT[OC,KK]^T ----------
// APK: A fragment-packed (gpK, KK). BPK: BT fragment-packed (gpK, ldB total K; kOff = K start).
// UNR: load-batch depth.
// EPI: 0=C fp32, 1=C+=, 2=residual+gamma, 3=O bf16,
//      7=Pk pack + s1/s2 fold (head=colBase>>8), 8=Pk pack + s1/s2 fold (single head)
// EPI 7/8: a1/a2 prescaled by LOG2E so consumers use bare 2^x.
template<int EPI, int APK, int BPK, int UNR=1>
__global__ __launch_bounds__(256) void k_mgemm(const u16* __restrict__ A, const u16* __restrict__ BT,
    int KK, int ldB, int kOff, float* __restrict__ C, const float* __restrict__ Xres,
    const float* __restrict__ gamma, u16* __restrict__ O, u16* __restrict__ Pk,
    const float* __restrict__ A1, const float* __restrict__ A2,
    float* __restrict__ s1g, float* __restrict__ s2g){
  int tid=threadIdx.x, w=tid>>6, lane=tid&63, L=lane&15, q=lane>>4;
  int OC = gridDim.x<<6;
  int colBase=blockIdx.x<<6, rowBase=blockIdx.y<<6;
  const u16* ap;
  if constexpr (APK) ap = A + (size_t)((rowBase>>4)+w)*((size_t)16*KK) + (size_t)lane*8;
  else               ap = A + (size_t)(rowBase + w*16 + L)*KK + q*8;
  const u16* bp[4];
  #pragma unroll
  for (int t=0;t<4;t++){
    if constexpr (BPK) bp[t] = BT + (size_t)((colBase>>4)+t)*((size_t)16*ldB) + (size_t)(kOff>>5)*512 + (size_t)lane*8;
    else               bp[t] = BT + (size_t)(colBase + t*16 + L)*ldB + q*8 + kOff;
  }
  f4v z4={0.f,0.f,0.f,0.f};
  f4v acc[4]={z4,z4,z4,z4};
  int nk = KK>>5;
  for (int kc0=0;kc0<nk;kc0+=UNR){
    s8v a0[UNR], bt[UNR][4];
    #pragma unroll
    for (int u=0;u<UNR;u++){
      int kc = kc0 + u;
      if constexpr (APK) a0[u] = *(const s8v*)(ap + (size_t)kc*512);
      else               a0[u] = *(const s8v*)(ap + kc*32);
      #pragma unroll
      for (int t=0;t<4;t++){
        if constexpr (BPK) bt[u][t] = *(const s8v*)(bp[t] + (size_t)kc*512);
        else               bt[u][t] = *(const s8v*)(bp[t] + kc*32);
      }
    }
    #pragma unroll
    for (int u=0;u<UNR;u++)
      #pragma unroll
      for (int t=0;t<4;t++)
        acc[t]=MFMA(a0[u],bt[u][t],acc[t]);
  }
  if constexpr (EPI<=3){
    #pragma unroll
    for (int t=0;t<4;t++){
      int col = colBase + t*16 + L;
      #pragma unroll
      for (int reg=0;reg<4;reg++){
        int row = rowBase + w*16 + q*4 + reg;
        size_t off = (size_t)row*OC + col;
        float v = acc[t][reg];
        if constexpr (EPI==0){ C[off] = v; }
        else if constexpr (EPI==1){ C[off] += v; }
        else if constexpr (EPI==2){ C[off] = flushf(Xres[off] + gamma[col]*v); }
        else { O[off] = f2b(v); }
      }
    }
  } else {
    // s1/s2 fold (prescaled by LOG2E for exp2 consumers)
    float s1p[4]={0.f,0.f,0.f,0.f}, s2p[4]={0.f,0.f,0.f,0.f};
    #pragma unroll
    for (int t=0;t<4;t++){
      int col = colBase + t*16 + L;
      float a1v = A1[col]*LOG2E, a2v = A2[col]*LOG2E;
      #pragma unroll
      for (int reg=0;reg<4;reg++){
        float v = acc[t][reg];
        s1p[reg] += v*a1v;
        s2p[reg] += v*a2v;
      }
    }
    #pragma unroll
    for (int off=1;off<16;off<<=1)
      #pragma unroll
      for (int reg=0;reg<4;reg++){
        s1p[reg] += __shfl_xor(s1p[reg],off);
        s2p[reg] += __shfl_xor(s2p[reg],off);
      }
    if (L==0){
      int sOff = (EPI==7) ? (colBase>>8)*BN : 0;
      #pragma unroll
      for (int reg=0;reg<4;reg++){
        int row = rowBase + w*16 + q*4 + reg;
        atomicAdd(&s1g[sOff+row], s1p[reg]);
        atomicAdd(&s2g[sOff+row], s2p[reg]);
      }
    }
    // coalesced pack store (16B per lane, 8 consecutive rows of one column)
    int pq_ = q&1;
    int m0 = rowBase + w*16 + (q>>1)*8;
    #pragma unroll
    for (int tp=0;tp<2;tp++){
      f4v accA = acc[2*tp], accB = acc[2*tp+1];
      f4v mine   = pq_ ? accB : accA;
      f4v theirs = pq_ ? accA : accB;
      u32 k0 = pk2(mine[0],  mine[1]);
      u32 k1 = pk2(mine[2],  mine[3]);
      u32 s0 = pk2(theirs[0],theirs[1]);
      u32 s1 = pk2(theirs[2],theirs[3]);
      u32 r0 = (u32)__shfl_xor((int)s0,16);
      u32 r1 = (u32)__shfl_xor((int)s1,16);
      uint4 val = pq_==0 ? make_uint4(k0,k1,r0,r1) : make_uint4(r0,r1,k0,k1);
      int t = 2*tp + pq_;
      int col = colBase + t*16 + L;
      *(uint4*)(Pk + packIdx(col, m0)) = val;
    }
  }
}

// ---------- fused q/k/v projections, packed A+B (gpK 256); outputs packed:
// z=0 (q) and z=1 (k): gpK(row,col,256); z=2 (v): packIdx(col,row) ----------
__global__ __launch_bounds__(256) void k_mgemm3(const u16* __restrict__ Aq, const u16* __restrict__ Akv,
    const u16* __restrict__ BT0, u16* __restrict__ O0){
  int tid=threadIdx.x, w=tid>>6, lane=tid&63, L=lane&15, q=lane>>4;
  const u16* A = blockIdx.z==0 ? Aq : Akv;
  const u16* BT = BT0 + (size_t)blockIdx.z*65536;
  u16* O = O0 + (size_t)blockIdx.z*2097152;
  int colBase=blockIdx.x<<6, rowBase=blockIdx.y<<6;
  const u16* ap = A + (size_t)((rowBase>>4)+w)*4096 + (size_t)lane*8;
  f4v z4={0.f,0.f,0.f,0.f};
  f4v acc[4]={z4,z4,z4,z4};
  #pragma unroll
  for (int kc=0;kc<8;kc++){
    s8v a0 = *(const s8v*)(ap + kc*512);
    #pragma unroll
    for (int t=0;t<4;t++){
      s8v bt = *(const s8v*)(BT + (size_t)((colBase>>4)+t)*4096 + (size_t)kc*512 + (size_t)lane*8);
      acc[t]=MFMA(a0,bt,acc[t]);
    }
  }
  bool isV = (blockIdx.z==2);
  #pragma unroll
  for (int t=0;t<4;t++){
    int col = colBase + t*16 + L;
    #pragma unroll
    for (int reg=0;reg<4;reg++){
      int row = rowBase + w*16 + q*4 + reg;
      u16 hv = f2b(acc[t][reg]);
      if (isV) O[packIdx(col, row)] = hv;
      else     O[gpK(row, col, 256)] = hv;
    }
  }
}

// ---------- split (3-term) MFMA GEMM, packed A and B (gpK 256): KK=256, OC=256 ----------
// EPI 4: hi/lo bf16 gram-packed out.  EPI 5: sq-dot fold -> pdot.
template<int EPI>
__global__ __launch_bounds__(256) void k_msgemm(const u16* __restrict__ Ah, const u16* __restrict__ Al,
    const u16* __restrict__ Bh, const u16* __restrict__ Bl,
    float* __restrict__ C, u16* __restrict__ Oh, u16* __restrict__ Ol,
    const float* __restrict__ sq, float* __restrict__ pdot){
  int tid=threadIdx.x, w=tid>>6, lane=tid&63, L=lane&15, q=lane>>4;
  int colBase=blockIdx.x<<6, rowBase=blockIdx.y<<6;
  const u16* ahp = Ah + (size_t)((rowBase>>4)+w)*4096 + (size_t)lane*8;
  const u16* alp = Al + (size_t)((rowBase>>4)+w)*4096 + (size_t)lane*8;
  f4v z4={0.f,0.f,0.f,0.f};
  f4v acc[4]={z4,z4,z4,z4};
  #pragma unroll
  for (int kc=0;kc<8;kc++){
    s8v ah=*(const s8v*)(ahp + kc*512), al=*(const s8v*)(alp + kc*512);
    #pragma unroll
    for (int t=0;t<4;t++){
      size_t boff = (size_t)((colBase>>4)+t)*4096 + (size_t)kc*512 + (size_t)lane*8;
      s8v bh=*(const s8v*)(Bh + boff);
      s8v bl=*(const s8v*)(Bl + boff);
      acc[t]=MFMA(ah,bh,acc[t]);
      acc[t]=MFMA(ah,bl,acc[t]);
      acc[t]=MFMA(al,bh,acc[t]);
    }
  }
  if constexpr (EPI==5){
    int b = rowBase>>10;
    float pp[4]={0.f,0.f,0.f,0.f};
    #pragma unroll
    for (int t=0;t<4;t++){
      int col = colBase + t*16 + L;
      float qv = sq[b*256 + col];
      #pragma unroll
      for (int reg=0;reg<4;reg++) pp[reg] += acc[t][reg]*qv;
    }
    #pragma unroll
    for (int off=1;off<16;off<<=1)
      #pragma unroll
      for (int reg=0;reg<4;reg++) pp[reg] += __shfl_xor(pp[reg],off);
    if (L==0){
      #pragma unroll
      for (int reg=0;reg<4;reg++){
        int row = rowBase + w*16 + q*4 + reg;
        atomicAdd(&pdot[row], pp[reg]);
      }
    }
  } else {
    #pragma unroll
    for (int t=0;t<4;t++){
      int col = colBase + t*16 + L;
      #pragma unroll
      for (int reg=0;reg<4;reg++){
        int row = rowBase + w*16 + q*4 + reg;
        float v = acc[t][reg];
        if constexpr (EPI==0){ C[(size_t)row*256 + col] = v; }
        else {
          size_t off = gpK(row, col, 256);
          u16 h = f2b(v); Oh[off]=h; Ol[off]=f2b(v - b2f(h));
        }
      }
    }
  }
}

// ---------- gram + bitpack v2: packed fragments, symmetric tile enumeration ----------
__global__ __launch_bounds__(256) void k_mconnect2(const u16* __restrict__ fahP, const u16* __restrict__ falP,
    const u8* __restrict__ sel8, u32* __restrict__ conn){
  __shared__ u8 sg[64][64];
  __shared__ u8 selI[64], selJ[64];
  int tid=threadIdx.x, w=tid>>6, lane=tid&63, L=lane&15, q=lane>>4;
  int b=blockIdx.z;
  int p=blockIdx.x;
  int i = (int)((sqrtf(8.f*p+1.f)-1.f)*0.5f);
  while ((i+1)*(i+2)/2 <= p) i++;
  while (i*(i+1)/2 > p) i--;
  int j = p - i*(i+1)/2;          // i >= j, both 0..15
  if (tid < 64)        selI[tid]     = sel8[b*NN + i*64 + tid];
  else if (tid < 128)  selJ[tid-64]  = sel8[b*NN + j*64 + (tid-64)];
  const u16* ah0 = fahP + ((size_t)(b*64 + i*4 + w))*4096 + (size_t)lane*8;
  const u16* al0 = falP + ((size_t)(b*64 + i*4 + w))*4096 + (size_t)lane*8;
  const u16* bh0 = fahP + ((size_t)(b*64 + j*4))*4096 + (size_t)lane*8;
  const u16* bl0 = falP + ((size_t)(b*64 + j*4))*4096 + (size_t)lane*8;
  f4v z4={0.f,0.f,0.f,0.f};
  f4v acc[4]={z4,z4,z4,z4};
  #pragma unroll
  for (int kc=0;kc<8;kc++){
    s8v ah = *(const s8v*)(ah0 + kc*512);
    s8v al = *(const s8v*)(al0 + kc*512);
    #pragma unroll
    for (int t=0;t<4;t++){
      s8v bh = *(const s8v*)(bh0 + (size_t)t*4096 + kc*512);
      s8v bl = *(const s8v*)(bl0 + (size_t)t*4096 + kc*512);
      acc[t]=MFMA(ah,bh,acc[t]);
      acc[t]=MFMA(ah,bl,acc[t]);
      acc[t]=MFMA(al,bh,acc[t]);
    }
  }
  #pragma unroll
  for (int t=0;t<4;t++)
    #pragma unroll
    for (int reg=0;reg<4;reg++)
      sg[w*16 + q*4 + reg][t*16 + L] = acc[t][reg] > 0.f;
  __syncthreads();
  int row=(tid&127)>>1, ww=tid&1;
  if (tid<128){
    u32 word=0;
    if (selI[row]){
      #pragma unroll 8
      for (int jj=0;jj<32;jj++)
        if (sg[row][ww*32+jj] && selJ[ww*32+jj]) word |= (1u<<jj);
    }
    conn[((size_t)b*NN + i*64+row)*32 + j*2 + ww] = word;
  } else if (i != j){
    u32 word=0;
    if (selJ[row]){
      #pragma unroll 8
      for (int jj=0;jj<32;jj++)
        if (sg[ww*32+jj][row] && selI[ww*32+jj]) word |= (1u<<jj);
    }
    conn[((size_t)b*NN + j*64+row)*32 + i*2 + ww] = word;
  }
}

// ---------- row max of s2 over connected m ----------
__global__ __launch_bounds__(256) void k_rowmax(const float* __restrict__ s2a,
    const u32* __restrict__ conn, float* __restrict__ M2a){
  int h = blockIdx.y;
  int r = blockIdx.x*4 + (threadIdx.x>>6);
  int lane = threadIdx.x&63;
  int b = r>>10;
  const float* s2p = s2a + h*BN + b*NN;
  float mx = -3.0e38f;
  #pragma unroll
  for (int t=0;t<16;t++){
    int m = lane + t*64;
    u32 wd = conn[(size_t)r*32 + (m>>5)];
    if ((wd>>(m&31))&1u) mx = fmaxf(mx, s2p[m]);
  }
  mx = wredmax(mx);
  if (lane==0) M2a[h*BN+r] = mx;
}

// ---------- MFMA GAT attention v9: lgkmcnt-only barrier (V loads span it) ----------
// s1/s2/M2a are prescaled by LOG2E -> bare v_exp_f32 (2^x).
// PKO: 0 = row-major output (stride oStride); else fragment-packed gpK(row,col,PKO).
template<int CT, bool SWZ, int PKO>
__global__ __launch_bounds__(256,4) void k_mattn5(const float* __restrict__ s1a, const float* __restrict__ s2a,
    const float* __restrict__ M2a, const u32* __restrict__ conn,
    const u16* __restrict__ P, int headMul, u16* __restrict__ Out, int oStride){
  __shared__ __align__(16) u16 Pb[2][4][512];
  __shared__ float Srow[64];
  int tid=threadIdx.x, w=tid>>6, lane=tid&63, L=lane&15, q=lane>>4;
  int h, rowBlk;
  if constexpr (SWZ){ h = blockIdx.y & 7; rowBlk = (blockIdx.y>>3) + (blockIdx.z<<4); }
  else             { h = blockIdx.z;     rowBlk = blockIdx.y; }
  int rowBase = rowBlk*64;
  int hOff = h*headMul, sOff = h*BN;
  int b = rowBase>>10;
  size_t bOff = (size_t)b*NN;
  int r = rowBase + w*16 + L;             // own row for P-build
  float s1v = s1a[sOff+r];
  float rmv = leakyf(s1v + M2a[sOff+r]);
  const float* s2p = s2a + sOff + bOff;
  const u32* cp = conn + (size_t)r*32;
  int tile0 = blockIdx.x*(4*CT) + w*CT;   // first col-tile owned by this wave
  const u16* vp = P + (size_t)((hOff>>4) + tile0)*131072 + (size_t)b*16384 + (size_t)lane*8;
  f4v z4={0.f,0.f,0.f,0.f};
  f4v acc[4][CT];
  #pragma unroll
  for (int g=0;g<4;g++)
    #pragma unroll
    for (int t=0;t<CT;t++) acc[g][t]=z4;
  float sumP = 0.f;
  for (int k0=0;k0<NN;k0+=32){
    int cur=(k0>>5)&1;
    u32 cw = cp[k0>>5];
    // issue THIS chunk's V loads first — they now stay in flight ACROSS the
    // barrier (lgkmcnt-only), completing under the MFMA wait of the consumer.
    s8v vf[CT];
    {
      const u16* vk = vp + (size_t)(k0>>5)*512;
      #pragma unroll
      for (int t=0;t<CT;t++) vf[t] = *(const s8v*)(vk + (size_t)t*131072);
    }
    float4 sA = *(const float4*)(s2p + k0 + q*8);
    float4 sB = *(const float4*)(s2p + k0 + q*8 + 4);
    float s2v[8] = {sA.x,sA.y,sA.z,sA.w,sB.x,sB.y,sB.z,sB.w};
    float p[8];
    #pragma unroll
    for (int j=0;j<8;j++){
      float z = s1v + s2v[j];
      float ev = fmaxf(z, 0.2f*z);                      // leaky = max(z, 0.2z) (scaled)
      ev = ((cw>>(q*8+j))&1u) ? ev : -9.0e15f;          // mask BEFORE exp (uniform rows!)
      p[j] = exp2z(ev - rmv);                            // bare v_exp (2^x), prescaled
      sumP += p[j];
    }
    union{ s8v v; u32 u[4]; } pk;
    #pragma unroll
    for (int jj=0;jj<4;jj++)
      pk.u[jj] = pk2(p[2*jj], p[2*jj+1]);
    *(s8v*)&Pb[cur][w][lane*8] = pk.v;    // ds_write_b128, contiguous
    // lgkmcnt-only barrier: own LDS write retired, then block-wide barrier.
    // Does NOT drain vmcnt — V/s2/conn loads stay outstanding (T4 minimal).
    // Pb[2] double-buffer is REQUIRED for correctness with this barrier.
    asm volatile("s_waitcnt lgkmcnt(0)" ::: "memory");
    __builtin_amdgcn_s_barrier();
    asm volatile("" ::: "memory");
    s8v pa[4];
    #pragma unroll
    for (int g=0;g<4;g++) pa[g] = *(const s8v*)&Pb[cur][g][lane*8];
    __builtin_amdgcn_s_setprio(1);
    #pragma unroll
    for (int t=0;t<CT;t++)
      #pragma unroll
      for (int g=0;g<4;g++) acc[g][t] = MFMA(pa[g], vf[t], acc[g][t]);
    __builtin_amdgcn_s_setprio(0);
  }
  sumP += __shfl_xor(sumP,16);
  sumP += __shfl_xor(sumP,32);
  if (lane<16) Srow[w*16+lane] = sumP;
  __syncthreads();
  #pragma unroll
  for (int g=0;g<4;g++){
    float4 sv = *(const float4*)&Srow[g*16 + q*4];
    float rsi[4] = {1.f/sv.x, 1.f/sv.y, 1.f/sv.z, 1.f/sv.w};
    #pragma unroll
    for (int t=0;t<CT;t++){
      int col = hOff + (tile0+t)*16 + L;
      #pragma unroll
      for (int reg=0;reg<4;reg++){
        int row = rowBase + g*16 + q*4 + reg;
        float ov = eluf(acc[g][t][reg]*rsi[reg]);
        if constexpr (PKO) Out[gpK(row, col, PKO)] = f2b(ov);
        else               Out[(size_t)row*oStride + col] = f2b(ov);
      }
    }
  }
}

// ---------- LayerNorms (packed gpK-256 output) ----------
__global__ __launch_bounds__(256) void k_ln_x(const float* __restrict__ x, const float* __restrict__ g,
                                              const float* __restrict__ bb, u16* __restrict__ out){
  int r = blockIdx.x*4 + (threadIdx.x>>6);
  int lane=threadIdx.x&63;
  float4 v = *(const float4*)(x + (size_t)r*DD + lane*4);
  float s = v.x+v.y+v.z+v.w;
  float s2 = v.x*v.x+v.y*v.y+v.z*v.z+v.w*v.w;
  s = wredsum(s); s2 = wredsum(s2);
  float mean = s*(1.f/256.f);
  float var = s2*(1.f/256.f) - mean*mean;
  float rstd = rsqrtf(var + 1e-5f);
  float4 gv = *(const float4*)(g+lane*4), bv = *(const float4*)(bb+lane*4);
  u16 t[4];
  t[0]=f2b((v.x-mean)*rstd*gv.x+bv.x); t[1]=f2b((v.y-mean)*rstd*gv.y+bv.y);
  t[2]=f2b((v.z-mean)*rstd*gv.z+bv.z); t[3]=f2b((v.w-mean)*rstd*gv.w+bv.w);
  *(uint2*)(out + gpK(r, lane*4, 256)) = *(uint2*)&t[0];
}

__global__ __launch_bounds__(256) void k_ln_kv(const u16* __restrict__ gout, const float* __restrict__ pe,
    const u8* __restrict__ sel8, const float* __restrict__ g, const float* __restrict__ bb,
    u16* __restrict__ out){
  int r = blockIdx.x*4 + (threadIdx.x>>6);
  int lane=threadIdx.x&63;
  int n = r & 1023;
  float4 v = make_float4(0.f,0.f,0.f,0.f);
  if (sel8[r]){
    float4 gv = ld4bf(gout + (size_t)r*DD + lane*4);
    float4 pv = *(const float4*)(pe + (size_t)n*DD + lane*4);
    v = make_float4(gv.x+pv.x, gv.y+pv.y, gv.z+pv.z, gv.w+pv.w);
  }
  float s = v.x+v.y+v.z+v.w;
  float s2 = v.x*v.x+v.y*v.y+v.z*v.z+v.w*v.w;
  s = wredsum(s); s2 = wredsum(s2);
  float mean = s*(1.f/256.f);
  float var = s2*(1.f/256.f) - mean*mean;
  float rstd = rsqrtf(var + 1e-5f);
  float4 gv = *(const float4*)(g+lane*4), bv = *(const float4*)(bb+lane*4);
  u16 t[4];
  t[0]=f2b((v.x-mean)*rstd*gv.x+bv.x); t[1]=f2b((v.y-mean)*rstd*gv.y+bv.y);
  t[2]=f2b((v.z-mean)*rstd*gv.z+bv.z); t[3]=f2b((v.w-mean)*rstd*gv.w+bv.w);
  *(uint2*)(out + gpK(r, lane*4, 256)) = *(uint2*)&t[0];
}

// ---------- CA attention v3: barrier-free flash; direct fragment loads ----------
__global__ __launch_bounds__(256) void k_mca_av3(const u16* __restrict__ q, const u16* __restrict__ k,
    const u16* __restrict__ v, const u8* __restrict__ sel8, u16* __restrict__ O){
  __shared__ __align__(16) u16 Pw[4][16][72];
  int tid=threadIdx.x;
  int w = tid>>6, lane = tid&63, L = lane&15, qd = lane>>4;
  int b=blockIdx.z, h=blockIdx.y, rowBase=blockIdx.x*64;
  size_t bOff = (size_t)b*NN;
  const u16* qbase = q + (size_t)((bOff + rowBase + w*16)>>4)*4096 + (size_t)lane*8;
  s8v af0 = *(const s8v*)(qbase + (size_t)(h*2+0)*512);
  s8v af1 = *(const s8v*)(qbase + (size_t)(h*2+1)*512);
  float rm[4], sp[4];
  #pragma unroll
  for (int reg=0;reg<4;reg++){ rm[reg] = -3.0e38f; sp[reg] = 0.f; }
  f4v zero = {0.f,0.f,0.f,0.f};
  f4v acc[4] = {zero,zero,zero,zero};
  for (int m0=0;m0<NN;m0+=64){
    s8v bt[4][2];
    #pragma unroll
    for (int t=0;t<4;t++){
      const u16* kb = k + (size_t)((bOff + m0 + t*16)>>4)*4096 + (size_t)lane*8;
      bt[t][0] = *(const s8v*)(kb + (size_t)(h*2+0)*512);
      bt[t][1] = *(const s8v*)(kb + (size_t)(h*2+1)*512);
    }
    s8v vf[4][2];
    #pragma unroll
    for (int t=0;t<4;t++){
      const u16* vb = v + (size_t)(((h*4+t)*8 + b)*32 + (m0>>5))*512 + (size_t)lane*8;
      vf[t][0] = *(const s8v*)vb;
      vf[t][1] = *(const s8v*)(vb + 512);
    }
    f4v sa[4] = {zero,zero,zero,zero};
    #pragma unroll
    for (int t=0;t<4;t++){
      sa[t] = MFMA(af0, bt[t][0], sa[t]);
      sa[t] = MFMA(af1, bt[t][1], sa[t]);
    }
    float vals[4][4];
    float tmax[4];
    #pragma unroll
    for (int reg=0;reg<4;reg++) tmax[reg] = -3.0e38f;
    #pragma unroll
    for (int t=0;t<4;t++){
      int m = m0 + t*16 + L;
      bool sl = sel8[b*NN+m];
      #pragma unroll
      for (int reg=0;reg<4;reg++){
        float val = sl ? sa[t][reg]*0.125f : -1.0e9f;
        vals[t][reg] = val;
        tmax[reg] = fmaxf(tmax[reg], val);
      }
    }
    #pragma unroll
    for (int off=1;off<16;off<<=1)
      #pragma unroll
      for (int reg=0;reg<4;reg++) tmax[reg] = fmaxf(tmax[reg], __shfl_xor(tmax[reg],off));
    float sc[4];
    #pragma unroll
    for (int reg=0;reg<4;reg++){
      float nm = fmaxf(rm[reg], tmax[reg]);
      sc[reg] = exp0(rm[reg] - nm);
      rm[reg] = nm;
      sp[reg] *= sc[reg];
    }
    #pragma unroll
    for (int t=0;t<4;t++){
      #pragma unroll
      for (int reg=0;reg<4;reg++){
        float pv = exp0(vals[t][reg] - rm[reg]);
        sp[reg] += pv;
        Pw[w][qd*4 + reg][t*16 + L] = f2b(pv);   // intra-wave slice, no barrier
      }
    }
    #pragma unroll
    for (int t=0;t<4;t++)
      #pragma unroll
      for (int reg=0;reg<4;reg++) acc[t][reg] *= sc[reg];
    #pragma unroll
    for (int mc2=0;mc2<2;mc2++){
      s8v pf = *(const s8v*)&Pw[w][L][mc2*32 + qd*8];
      #pragma unroll
      for (int t=0;t<4;t++)
        acc[t] = MFMA(pf, vf[t][mc2], acc[t]);
    }
  }
  #pragma unroll
  for (int off=1;off<16;off<<=1)
    #pragma unroll
    for (int reg=0;reg<4;reg++) sp[reg] += __shfl_xor(sp[reg],off);
  float ri[4];
  #pragma unroll
  for (int reg=0;reg<4;reg++) ri[reg] = 1.f/sp[reg];
  #pragma unroll
  for (int t=0;t<4;t++){
    int col = h*64 + t*16 + L;
    #pragma unroll
    for (int reg=0;reg<4;reg++){
      int row = (int)bOff + rowBase + w*16 + qd*4 + reg;
      O[gpK(row, col, 256)] = f2b(acc[t][reg]*ri[reg]);
    }
  }
}

extern "C" void kernel_launch(void* const* d_in, const int* in_sizes, int n_in,
                              void* d_out, int out_size, void* d_ws, size_t ws_size,
                              hipStream_t stream) {
  (void)in_sizes; (void)n_in; (void)out_size;
  const float* x      = (const float*)d_in[0];
  const int*   mask   = (const int*  )d_in[1];
  const float* pe     = (const float*)d_in[2];
  const float* sim_Wx = (const float*)d_in[3];
  const float* sim_Wq = (const float*)d_in[4];
  const float* adj_W  = (const float*)d_in[5];
  const float* gat_W  = (const float*)d_in[6];
  const float* gat_a1 = (const float*)d_in[7];
  const float* gat_a2 = (const float*)d_in[8];
  const float* gat_Wo = (const float*)d_in[9];
  const float* gat_ao1= (const float*)d_in[10];
  const float* gat_ao2= (const float*)d_in[11];
  const float* ln3_g  = (const float*)d_in[12];
  const float* ln3_b  = (const float*)d_in[13];
  const float* ln4_g  = (const float*)d_in[14];
  const float* ln4_b  = (const float*)d_in[15];
  const float* ca_Wq  = (const float*)d_in[16];
  const float* ca_Wk  = (const float*)d_in[17];
  const float* ca_Wv  = (const float*)d_in[18];
  const float* ca_Wp  = (const float*)d_in[19];
  const float* gamma  = (const float*)d_in[20];
  float* out    = (float*)d_out;
  float* simOut = out + (size_t)BN*DD;

  const size_t MB = 1024*1024;
  bool big = ws_size >= 98*MB;
  char* W = (char*)d_ws;
  float* pq   = (float*)W;
  float* cnt  = pq + 2048;
  float* sq   = cnt + 16;
  float* s1a  = (float*)(W + 64*1024);
  float* s2a  = (float*)(W + 320*1024);
  float* M2a  = (float*)(W + 576*1024);
  float* pdot = (float*)(W + 1216*1024);
  u8*    sel8 = (u8*)(W + 1400*1024);
  u32*   conn = (u32*)(W + 2*MB);
  u16*   WT0  = (u16*)(W + 3*MB);
  u16*   WoT  = (u16*)(W + 4*MB);
  u16*   WQT  = (u16*)(W + 5*MB);
  u16*   WPT  = WQT + 3*65536;
  u16*   sWxh = (u16*)(W + 5*MB + 512*1024);
  u16*   sWxl = sWxh + 65536;
  u16*   aWh  = sWxl + 65536;
  u16*   aWl  = aWh + 65536;
  u16*   xh   = (u16*)(W + 6*MB);
  u16*   xl   = (u16*)(W + 10*MB);
  float* S0   = (float*)(W + 14*MB);
  u16*   fah  = (u16*)(W + 22*MB);
  u16*   fal  = (u16*)(W + 26*MB);
  u16*   T2   = (u16*)(W + 30*MB);

  // prep (everything fragment-packed)
  k_split<<<BN*DD/2048,256,0,stream>>>(x, xh, xl);
  k_transpose<<<dim3(4,4,HG),256,0,stream>>>(gat_W, WT0, 256, 65536, 256);
  k_transpose<<<dim3(4,32,1),256,0,stream>>>(gat_Wo, WoT, 2048, 0, 2048);
  k_transpose4<<<dim3(4,4,4),256,0,stream>>>(ca_Wq, ca_Wk, ca_Wv, ca_Wp, WQT);
  k_transp_split<<<dim3(4,4,1),256,0,stream>>>(sim_Wx, sWxh, sWxl);
  k_transp_split<<<dim3(4,4,1),256,0,stream>>>(adj_W, aWh, aWl);

  hipMemsetAsync(pq, 0, (2048+16+2048)*sizeof(float), stream);   // pq + cnt + sq
  hipMemsetAsync(pdot, 0, BN*sizeof(float), stream);
  k_posq<<<dim3(BB,64),256,0,stream>>>(x, mask, pq, cnt);
  k_sq<<<dim3(BB,16),256,0,stream>>>(pq, cnt, sim_Wq, sq);
  k_msgemm<5><<<dim3(4,128),256,0,stream>>>(xh, xl, sWxh, sWxl, nullptr, nullptr, nullptr, sq, pdot); // y-dot fold
  k_simsel2<<<BN/256,256,0,stream>>>(pdot, simOut, sel8);
  k_msgemm<4><<<dim3(4,128),256,0,stream>>>(xh, xl, aWh, aWl, nullptr, fah, fal, nullptr, nullptr);   // fa gram-packed
  k_mconnect2<<<dim3(136,1,BB),256,0,stream>>>(fah, fal, sel8, conn);

  if (big){
    u16* WhP   = (u16*)(W + 66*MB);   // attention-packed Wh_cat, 32MB
    u16* htcat = (u16*)(W + 34*MB);   // fragment-packed (gpK 2048) ht_cat, 32MB
    u16* S0P   = (u16*)(W + 22*MB);   // attention-packed Who, 4MB (fah dead after mconnect)
    u16* qx = (u16*)(W + 34*MB);      // after htcat consumed
    u16* kv = (u16*)(W + 38*MB);
    u16* qb = (u16*)(W + 42*MB);
    u16* vb = (u16*)(W + 50*MB);
    u16* Ob = (u16*)(W + 54*MB);

    hipMemsetAsync(s1a, 0, 512*1024, stream);  // s1a(256K) + s2a(256K) contiguous
    k_mgemm<7,1,1,2><<<dim3(32,128),256,0,stream>>>(xh, WT0, 256, 256, 0, nullptr, nullptr, nullptr, nullptr,
                                                    WhP, gat_a1, gat_a2, s1a, s2a);  // WhP pack + s1s2 fold (×log2e)
    k_rowmax<<<dim3(BN/4,HG),256,0,stream>>>(s2a, conn, M2a);
    k_mattn5<4,true,2048><<<dim3(1,128,HG),256,0,stream>>>(s1a, s2a, M2a, conn, WhP, 256, htcat, 2048);
    hipMemsetAsync(s1a, 0, BN*sizeof(float), stream);
    hipMemsetAsync(s2a, 0, BN*sizeof(float), stream);
    k_mgemm<8,1,1,4><<<dim3(4,128),256,0,stream>>>(htcat, WoT, 2048, 2048, 0, nullptr, nullptr, nullptr, nullptr,
                                                   S0P, gat_ao1, gat_ao2, s1a, s2a);  // S0P pack + s1s2 fold (×log2e)
    k_rowmax<<<dim3(BN/4,1),256,0,stream>>>(s2a, conn, M2a);
    k_mattn5<1,false,0><<<dim3(4,128,1),256,0,stream>>>(s1a, s2a, M2a, conn, S0P, 0, T2, 256);  // gout

    k_ln_x<<<BN/4,256,0,stream>>>(x, ln3_g, ln3_b, qx);
    k_ln_kv<<<BN/4,256,0,stream>>>(T2, pe, sel8, ln4_g, ln4_b, kv);
    k_mgemm3<<<dim3(4,128,3),256,0,stream>>>(qx, kv, WQT, qb);     // qb,kb gpK; vb packIdx
    k_mca_av3<<<dim3(16,HC,BB),256,0,stream>>>(qb, qb + 2097152, vb, sel8, Ob);
    k_mgemm<2,1,1,4><<<dim3(4,128),256,0,stream>>>(Ob, WPT, 256, 256, 0, out, x, gamma, nullptr, nullptr,
                                                   nullptr, nullptr, nullptr, nullptr);
  } else {
    // small-ws fallback: per-head loop, packed kernels (rarely taken)
    u16* T0 = fah;
    u16* T1 = fal;
    u16* S0b = (u16*)S0;
    hipMemsetAsync(s1a, 0, 512*1024, stream);
    for (int h=0;h<HG;h++){
      hipMemsetAsync(s1a, 0, BN*sizeof(float), stream);
      hipMemsetAsync(s2a, 0, BN*sizeof(float), stream);
      k_mgemm<8,1,1><<<dim3(4,128),256,0,stream>>>(xh, WT0 + (size_t)h*65536, 256, 256, 0,
                                                   nullptr, nullptr, nullptr, nullptr, T0,
                                                   gat_a1 + h*DD, gat_a2 + h*DD, s1a, s2a);
      k_rowmax<<<dim3(BN/4,1),256,0,stream>>>(s2a, conn, M2a);
      k_mattn5<1,false,0><<<dim3(4,128,1),256,0,stream>>>(s1a, s2a, M2a, conn, T0, 0, T1, 256);
      k_mgemm<1,0,1><<<dim3(4,128),256,0,stream>>>(T1, WoT, 256, 2048, h*256, S0, nullptr, nullptr, nullptr, nullptr,
                                                   nullptr, nullptr, nullptr, nullptr);
    }
    hipMemsetAsync(s1a, 0, BN*sizeof(float), stream);
    hipMemsetAsync(s2a, 0, BN*sizeof(float), stream);
    k_mattn5<1,false,0><<<dim3(4,128,1),256,0,stream>>>(s1a, s2a, M2a, conn, (u16*)S0, 0, T2, 256);
    k_ln_x<<<BN/4,256,0,stream>>>(x, ln3_g, ln3_b, T1);
    k_ln_kv<<<BN/4,256,0,stream>>>(T2, pe, sel8, ln4_g, ln4_b, T0);
    k_mgemm3<<<dim3(4,128,3),256,0,stream>>>(T1, T0, WQT, S0b);
    k_mca_av3<<<dim3(16,HC,BB),256,0,stream>>>(S0b, S0b + 2097152, S0b + 4194304, sel8, T0);
    k_mgemm<2,1,1><<<dim3(4,128),256,0,stream>>>(T0, WPT, 256, 256, 0, out, x, gamma, nullptr, nullptr,
                                                 nullptr, nullptr, nullptr, nullptr);
  }
}

// Round 19
// 388.011 us; speedup vs baseline: 1.3994x; 1.1470x over previous
//
#include <hip/hip_runtime.h>
#include <hip/hip_bf16.h>

// GATFusionBlockPosOnly: B=8, N=1024, D=256, 8 GAT heads, 4 CA heads.
// Round 28:
//  - R27 post-mortem: lgkmcnt-only barrier flat (445.1). mattn5's 63us is the
//    honest cost of the structure; stop polishing the loop.
//  - DEFER-MAX (T13, THR=inf): softmax is shift-invariant and exponents are
//    bounded (|s1+s2|*log2e <~ 30 << 127), so drop the row-max entirely:
//    * both k_rowmax launches deleted, M2a buffer dead;
//    * mattn5: p = bare v_exp(ev) (no rmv subtract, no fmin clamp);
//    * all-masked rows (= non-selected rows, since conn diagonal is always set
//      for selected rows) now give sumP=0 -> guarded rsi=0 -> output 0 (finite;
//      those rows are provably discarded downstream, and P=0 x finite = 0 in
//      PV, unlike 0 x NaN).

#define BB 8
#define NN 1024
#define DD 256
#define HG 8
#define HC 4
#define BN (BB*NN)
#define LOG2E 1.44269504088896f

typedef unsigned short u16;
typedef unsigned int u32;
typedef unsigned char u8;
typedef __attribute__((ext_vector_type(8))) short s8v;   // 8 bf16
typedef __attribute__((ext_vector_type(4))) float f4v;   // 4 fp32 acc
#define MFMA(a,b,c) __builtin_amdgcn_mfma_f32_16x16x32_bf16((a),(b),(c),0,0,0)

__device__ __forceinline__ u16 f2b(float x){
  union{ float f; unsigned u; } a; a.f = x;
  unsigned r = a.u + 0x7fff + ((a.u>>16)&1);
  return (u16)(r>>16);
}
__device__ __forceinline__ float b2f(u16 b){ return __uint_as_float(((unsigned)b)<<16); }
__device__ __forceinline__ float4 ld4bf(const u16* p){
  uint2 u = *(const uint2*)p;
  float4 r;
  r.x=__uint_as_float(u.x<<16); r.y=__uint_as_float(u.x&0xffff0000u);
  r.z=__uint_as_float(u.y<<16); r.w=__uint_as_float(u.y&0xffff0000u);
  return r;
}
__device__ __forceinline__ void load8(const float* p, float* v){
  float4 a=*(const float4*)p, b=*(const float4*)(p+4);
  v[0]=a.x;v[1]=a.y;v[2]=a.z;v[3]=a.w;v[4]=b.x;v[5]=b.y;v[6]=b.z;v[7]=b.w;
}
__device__ __forceinline__ float wredsum(float v){
  #pragma unroll
  for(int o=32;o>0;o>>=1) v += __shfl_xor(v,o);
  return v;
}
__device__ __forceinline__ float wredmax(float v){
  #pragma unroll
  for(int o=32;o>0;o>>=1) v = fmaxf(v,__shfl_xor(v,o));
  return v;
}
__device__ __forceinline__ float eluf(float x){ return x>0.f ? x : __expf(x)-1.f; }
__device__ __forceinline__ float leakyf(float z){ return z>=0.f ? z : 0.2f*z; }
__device__ __forceinline__ float exp0(float a){ return __expf(fminf(a, 0.f)); }
__device__ __forceinline__ float exp2r(float a){   // bare v_exp_f32 (2^a), no clamp
  float r;
  asm("v_exp_f32 %0, %1" : "=v"(r) : "v"(a));
  return r;
}
__device__ __forceinline__ float flushf(float v){ return (fabsf(v) < 1.0e30f) ? v : 0.f; }
__device__ __forceinline__ u32 pk2(float lo, float hi){
  u32 r;
  asm("v_cvt_pk_bf16_f32 %0, %1, %2" : "=v"(r) : "v"(lo), "v"(hi));
  return r;
}

// packed index for element (col, m) of the attention-V pack:  b=m>>10, kk=m&1023
__device__ __forceinline__ size_t packIdx(int col, int row){
  int kk = row & 1023;
  return ((((size_t)(col>>4))*8 + (row>>10))*32 + (kk>>5))*512
       + (size_t)(((((kk>>3)&3)*16) + (col&15))*8 + (kk&7));
}

// fragment-pack: element (row, k) of a [rows][KK] operand -> fragment order.
__device__ __forceinline__ size_t gpK(int row, int k, int KK){
  return (size_t)(row>>4)*((size_t)16*KK) + (size_t)(k>>5)*512
       + (size_t)(((((k>>3)&3)*16) + (row&15))*8 + (k&7));
}

// ---------- fp32 -> (hi,lo) bf16 split, packed output (gpK, KK=256) ----------
__global__ __launch_bounds__(256) void k_split(const float* __restrict__ X, u16* __restrict__ H, u16* __restrict__ Lo){
  size_t i = ((size_t)blockIdx.x*256 + threadIdx.x)*8;
  float v[8]; load8(X+i, v);
  u16 hh[8], ll[8];
  #pragma unroll
  for (int j=0;j<8;j++){ hh[j]=f2b(v[j]); ll[j]=f2b(v[j]-b2f(hh[j])); }
  int row = (int)(i>>8), col = (int)(i&255);
  size_t off = gpK(row, col, 256);
  *(uint4*)(H+off)=*(uint4*)&hh[0];
  *(uint4*)(Lo+off)=*(uint4*)&ll[0];
}

// ---------- transpose fp32 [R][C] -> bf16; pkKK=0: row-major [C][R]; else gpK packed ----------
__global__ __launch_bounds__(256) void k_transpose(const float* __restrict__ S, u16* __restrict__ D,
                                                   int R, int sliceElems, int pkKK){
  __shared__ float tl[64][65];
  const float* src = S + (size_t)blockIdx.z*sliceElems;
  u16* dst = D + (size_t)blockIdx.z*sliceElems;
  int C = gridDim.x*64;
  int bx=blockIdx.x*64, by=blockIdx.y*64;
  int tid=threadIdx.x, r=tid>>2, c0=(tid&3)*16;
  #pragma unroll
  for (int i=0;i<16;i+=4){
    float4 v = *(const float4*)(src + (size_t)(by+r)*C + bx + c0 + i);
    tl[r][c0+i]=v.x; tl[r][c0+i+1]=v.y; tl[r][c0+i+2]=v.z; tl[r][c0+i+3]=v.w;
  }
  __syncthreads();
  u16 tmp[16];
  #pragma unroll
  for (int i=0;i<16;i++) tmp[i] = f2b(tl[c0+i][r]);
  if (pkKK){
    *(uint4*)(dst + gpK(bx+r, by+c0,     pkKK)) = *(uint4*)&tmp[0];
    *(uint4*)(dst + gpK(bx+r, by+c0+8,   pkKK)) = *(uint4*)&tmp[8];
  } else {
    *(uint4*)(dst + (size_t)(bx+r)*R + by + c0)     = *(uint4*)&tmp[0];
    *(uint4*)(dst + (size_t)(bx+r)*R + by + c0 + 8) = *(uint4*)&tmp[8];
  }
}

// ---------- 4x 256x256 transposes, PACKED (gpK 256) output; grid (4,4,4) ----------
__global__ __launch_bounds__(256) void k_transpose4(const float* __restrict__ Sa, const float* __restrict__ Sb,
    const float* __restrict__ Sc, const float* __restrict__ Sd, u16* __restrict__ D){
  __shared__ float tl[64][65];
  const float* src = blockIdx.z==0 ? Sa : blockIdx.z==1 ? Sb : blockIdx.z==2 ? Sc : Sd;
  u16* dst = D + (size_t)blockIdx.z*65536;
  int bx=blockIdx.x*64, by=blockIdx.y*64;
  int tid=threadIdx.x, r=tid>>2, c0=(tid&3)*16;
  #pragma unroll
  for (int i=0;i<16;i+=4){
    float4 v = *(const float4*)(src + (size_t)(by+r)*256 + bx + c0 + i);
    tl[r][c0+i]=v.x; tl[r][c0+i+1]=v.y; tl[r][c0+i+2]=v.z; tl[r][c0+i+3]=v.w;
  }
  __syncthreads();
  u16 tmp[16];
  #pragma unroll
  for (int i=0;i<16;i++) tmp[i] = f2b(tl[c0+i][r]);
  *(uint4*)(dst + gpK(bx+r, by+c0,   256)) = *(uint4*)&tmp[0];
  *(uint4*)(dst + gpK(bx+r, by+c0+8, 256)) = *(uint4*)&tmp[8];
}

// ---------- transpose + split: fp32 [256][256] -> hi/lo bf16 PACKED (gpK 256) ----------
__global__ __launch_bounds__(256) void k_transp_split(const float* __restrict__ S, u16* __restrict__ DH, u16* __restrict__ DL){
  __shared__ float tl[64][65];
  int bx=blockIdx.x*64, by=blockIdx.y*64;
  int tid=threadIdx.x, r=tid>>2, c0=(tid&3)*16;
  #pragma unroll
  for (int i=0;i<16;i+=4){
    float4 v = *(const float4*)(S + (size_t)(by+r)*256 + bx + c0 + i);
    tl[r][c0+i]=v.x; tl[r][c0+i+1]=v.y; tl[r][c0+i+2]=v.z; tl[r][c0+i+3]=v.w;
  }
  __syncthreads();
  u16 th[16], tll[16];
  #pragma unroll
  for (int i=0;i<16;i++){
    float v = tl[c0+i][r];
    th[i]=f2b(v); tll[i]=f2b(v - b2f(th[i]));
  }
  size_t o0 = gpK(bx+r, by+c0,   256);
  size_t o1 = gpK(bx+r, by+c0+8, 256);
  *(uint4*)(DH + o0) = *(uint4*)&th[0];
  *(uint4*)(DH + o1) = *(uint4*)&th[8];
  *(uint4*)(DL + o0) = *(uint4*)&tll[0];
  *(uint4*)(DL + o1) = *(uint4*)&tll[8];
}

// ---------- pos_query: grid (BB, 64), 16 rows per block ----------
__global__ __launch_bounds__(256) void k_posq(const float* __restrict__ x, const int* __restrict__ mask,
                                              float* __restrict__ pq, float* __restrict__ cnt){
  int b = blockIdx.x, chunk = blockIdx.y;
  int d = threadIdx.x;
  int n0 = chunk*16;
  float acc = 0.f; float c = 0.f;
  for (int i=0;i<16;i++){
    int n = n0+i;
    if (mask[b*NN+n]==1){ acc += x[((size_t)(b*NN+n))*DD + d]; c += 1.f; }
  }
  atomicAdd(&pq[b*DD+d], acc);
  if (d==0) atomicAdd(&cnt[b], c);
}

// ---------- sq: grid (BB, 16), 16 d-rows per block, atomic accumulate ----------
__global__ __launch_bounds__(256) void k_sq(const float* __restrict__ pq, const float* __restrict__ cnt,
                                            const float* __restrict__ Wq, float* __restrict__ sq){
  int b = blockIdx.x, dq = blockIdx.y;
  int e = threadIdx.x;
  float inv = 1.f / fmaxf(cnt[b], 1.f);
  float acc=0.f;
  for (int i=0;i<16;i++){
    int d0 = dq*16 + i;
    acc += pq[b*DD+d0] * Wq[d0*DD+e];
  }
  atomicAdd(&sq[b*DD+e], acc*inv);
}

// ---------- sigmoid + threshold from folded dot ----------
__global__ __launch_bounds__(256) void k_simsel2(const float* __restrict__ pdot,
                                                 float* __restrict__ simOut, u8* __restrict__ sel8){
  int r = blockIdx.x*256 + threadIdx.x;
  float s = pdot[r] * 0.0625f;
  float sim = 1.f/(1.f+expf(-s));
  simOut[r] = sim;
  sel8[r] = (sim > 0.97f) ? 1 : 0;
}

// ---------- no-LDS MFMA GEMM: out[8192, OC] = A[8192,KK] @ BT[OC,KK]^T ----------
// APK: A fragment-packed (gpK, KK). BPK: BT fragment-packed (gpK, ldB total K; kOff = K start).
// UNR: load-batch depth.
// EPI: 0=C fp32, 1=C+=, 2=residual+gamma, 3=O bf16,
//      7=Pk pack + s1/s2 fold (head=colBase>>8), 8=Pk pack + s1/s2 fold (single head)
// EPI 7/8: a1/a2 prescaled by LOG2E so consumers use bare 2^x.
template<int EPI, int APK, int BPK, int UNR=1>
__global__ __launch_bounds__(256) void k_mgemm(const u16* __restrict__ A, const u16* __restrict__ BT,
    int KK, int ldB, int kOff, float* __restrict__ C, const float* __restrict__ Xres,
    const float* __restrict__ gamma, u16* __restrict__ O, u16* __restrict__ Pk,
    const float* __restrict__ A1, const float* __restrict__ A2,
    float* __restrict__ s1g, float* __restrict__ s2g){
  int tid=threadIdx.x, w=tid>>6, lane=tid&63, L=lane&15, q=lane>>4;
  int OC = gridDim.x<<6;
  int colBase=blockIdx.x<<6, rowBase=blockIdx.y<<6;
  const u16* ap;
  if constexpr (APK) ap = A + (size_t)((rowBase>>4)+w)*((size_t)16*KK) + (size_t)lane*8;
  else               ap = A + (size_t)(rowBase + w*16 + L)*KK + q*8;
  const u16* bp[4];
  #pragma unroll
  for (int t=0;t<4;t++){
    if constexpr (BPK) bp[t] = BT + (size_t)((colBase>>4)+t)*((size_t)16*ldB) + (size_t)(kOff>>5)*512 + (size_t)lane*8;
    else               bp[t] = BT + (size_t)(colBase + t*16 + L)*ldB + q*8 + kOff;
  }
  f4v z4={0.f,0.f,0.f,0.f};
  f4v acc[4]={z4,z4,z4,z4};
  int nk = KK>>5;
  for (int kc0=0;kc0<nk;kc0+=UNR){
    s8v a0[UNR], bt[UNR][4];
    #pragma unroll
    for (int u=0;u<UNR;u++){
      int kc = kc0 + u;
      if constexpr (APK) a0[u] = *(const s8v*)(ap + (size_t)kc*512);
      else               a0[u] = *(const s8v*)(ap + kc*32);
      #pragma unroll
      for (int t=0;t<4;t++){
        if constexpr (BPK) bt[u][t] = *(const s8v*)(bp[t] + (size_t)kc*512);
        else               bt[u][t] = *(const s8v*)(bp[t] + kc*32);
      }
    }
    #pragma unroll
    for (int u=0;u<UNR;u++)
      #pragma unroll
      for (int t=0;t<4;t++)
        acc[t]=MFMA(a0[u],bt[u][t],acc[t]);
  }
  if constexpr (EPI<=3){
    #pragma unroll
    for (int t=0;t<4;t++){
      int col = colBase + t*16 + L;
      #pragma unroll
      for (int reg=0;reg<4;reg++){
        int row = rowBase + w*16 + q*4 + reg;
        size_t off = (size_t)row*OC + col;
        float v = acc[t][reg];
        if constexpr (EPI==0){ C[off] = v; }
        else if constexpr (EPI==1){ C[off] += v; }
        else if constexpr (EPI==2){ C[off] = flushf(Xres[off] + gamma[col]*v); }
        else { O[off] = f2b(v); }
      }
    }
  } else {
    // s1/s2 fold (prescaled by LOG2E for exp2 consumers)
    float s1p[4]={0.f,0.f,0.f,0.f}, s2p[4]={0.f,0.f,0.f,0.f};
    #pragma unroll
    for (int t=0;t<4;t++){
      int col = colBase + t*16 + L;
      float a1v = A1[col]*LOG2E, a2v = A2[col]*LOG2E;
      #pragma unroll
      for (int reg=0;reg<4;reg++){
        float v = acc[t][reg];
        s1p[reg] += v*a1v;
        s2p[reg] += v*a2v;
      }
    }
    #pragma unroll
    for (int off=1;off<16;off<<=1)
      #pragma unroll
      for (int reg=0;reg<4;reg++){
        s1p[reg] += __shfl_xor(s1p[reg],off);
        s2p[reg] += __shfl_xor(s2p[reg],off);
      }
    if (L==0){
      int sOff = (EPI==7) ? (colBase>>8)*BN : 0;
      #pragma unroll
      for (int reg=0;reg<4;reg++){
        int row = rowBase + w*16 + q*4 + reg;
        atomicAdd(&s1g[sOff+row], s1p[reg]);
        atomicAdd(&s2g[sOff+row], s2p[reg]);
      }
    }
    // coalesced pack store (16B per lane, 8 consecutive rows of one column)
    int pq_ = q&1;
    int m0 = rowBase + w*16 + (q>>1)*8;
    #pragma unroll
    for (int tp=0;tp<2;tp++){
      f4v accA = acc[2*tp], accB = acc[2*tp+1];
      f4v mine   = pq_ ? accB : accA;
      f4v theirs = pq_ ? accA : accB;
      u32 k0 = pk2(mine[0],  mine[1]);
      u32 k1 = pk2(mine[2],  mine[3]);
      u32 s0 = pk2(theirs[0],theirs[1]);
      u32 s1 = pk2(theirs[2],theirs[3]);
      u32 r0 = (u32)__shfl_xor((int)s0,16);
      u32 r1 = (u32)__shfl_xor((int)s1,16);
      uint4 val = pq_==0 ? make_uint4(k0,k1,r0,r1) : make_uint4(r0,r1,k0,k1);
      int t = 2*tp + pq_;
      int col = colBase + t*16 + L;
      *(uint4*)(Pk + packIdx(col, m0)) = val;
    }
  }
}

// ---------- fused q/k/v projections, packed A+B (gpK 256); outputs packed:
// z=0 (q) and z=1 (k): gpK(row,col,256); z=2 (v): packIdx(col,row) ----------
__global__ __launch_bounds__(256) void k_mgemm3(const u16* __restrict__ Aq, const u16* __restrict__ Akv,
    const u16* __restrict__ BT0, u16* __restrict__ O0){
  int tid=threadIdx.x, w=tid>>6, lane=tid&63, L=lane&15, q=lane>>4;
  const u16* A = blockIdx.z==0 ? Aq : Akv;
  const u16* BT = BT0 + (size_t)blockIdx.z*65536;
  u16* O = O0 + (size_t)blockIdx.z*2097152;
  int colBase=blockIdx.x<<6, rowBase=blockIdx.y<<6;
  const u16* ap = A + (size_t)((rowBase>>4)+w)*4096 + (size_t)lane*8;
  f4v z4={0.f,0.f,0.f,0.f};
  f4v acc[4]={z4,z4,z4,z4};
  #pragma unroll
  for (int kc=0;kc<8;kc++){
    s8v a0 = *(const s8v*)(ap + kc*512);
    #pragma unroll
    for (int t=0;t<4;t++){
      s8v bt = *(const s8v*)(BT + (size_t)((colBase>>4)+t)*4096 + (size_t)kc*512 + (size_t)lane*8);
      acc[t]=MFMA(a0,bt,acc[t]);
    }
  }
  bool isV = (blockIdx.z==2);
  #pragma unroll
  for (int t=0;t<4;t++){
    int col = colBase + t*16 + L;
    #pragma unroll
    for (int reg=0;reg<4;reg++){
      int row = rowBase + w*16 + q*4 + reg;
      u16 hv = f2b(acc[t][reg]);
      if (isV) O[packIdx(col, row)] = hv;
      else     O[gpK(row, col, 256)] = hv;
    }
  }
}

// ---------- split (3-term) MFMA GEMM, packed A and B (gpK 256): KK=256, OC=256 ----------
// EPI 4: hi/lo bf16 gram-packed out.  EPI 5: sq-dot fold -> pdot.
template<int EPI>
__global__ __launch_bounds__(256) void k_msgemm(const u16* __restrict__ Ah, const u16* __restrict__ Al,
    const u16* __restrict__ Bh, const u16* __restrict__ Bl,
    float* __restrict__ C, u16* __restrict__ Oh, u16* __restrict__ Ol,
    const float* __restrict__ sq, float* __restrict__ pdot){
  int tid=threadIdx.x, w=tid>>6, lane=tid&63, L=lane&15, q=lane>>4;
  int colBase=blockIdx.x<<6, rowBase=blockIdx.y<<6;
  const u16* ahp = Ah + (size_t)((rowBase>>4)+w)*4096 + (size_t)lane*8;
  const u16* alp = Al + (size_t)((rowBase>>4)+w)*4096 + (size_t)lane*8;
  f4v z4={0.f,0.f,0.f,0.f};
  f4v acc[4]={z4,z4,z4,z4};
  #pragma unroll
  for (int kc=0;kc<8;kc++){
    s8v ah=*(const s8v*)(ahp + kc*512), al=*(const s8v*)(alp + kc*512);
    #pragma unroll
    for (int t=0;t<4;t++){
      size_t boff = (size_t)((colBase>>4)+t)*4096 + (size_t)kc*512 + (size_t)lane*8;
      s8v bh=*(const s8v*)(Bh + boff);
      s8v bl=*(const s8v*)(Bl + boff);
      acc[t]=MFMA(ah,bh,acc[t]);
      acc[t]=MFMA(ah,bl,acc[t]);
      acc[t]=MFMA(al,bh,acc[t]);
    }
  }
  if constexpr (EPI==5){
    int b = rowBase>>10;
    float pp[4]={0.f,0.f,0.f,0.f};
    #pragma unroll
    for (int t=0;t<4;t++){
      int col = colBase + t*16 + L;
      float qv = sq[b*256 + col];
      #pragma unroll
      for (int reg=0;reg<4;reg++) pp[reg] += acc[t][reg]*qv;
    }
    #pragma unroll
    for (int off=1;off<16;off<<=1)
      #pragma unroll
      for (int reg=0;reg<4;reg++) pp[reg] += __shfl_xor(pp[reg],off);
    if (L==0){
      #pragma unroll
      for (int reg=0;reg<4;reg++){
        int row = rowBase + w*16 + q*4 + reg;
        atomicAdd(&pdot[row], pp[reg]);
      }
    }
  } else {
    #pragma unroll
    for (int t=0;t<4;t++){
      int col = colBase + t*16 + L;
      #pragma unroll
      for (int reg=0;reg<4;reg++){
        int row = rowBase + w*16 + q*4 + reg;
        float v = acc[t][reg];
        if constexpr (EPI==0){ C[(size_t)row*256 + col] = v; }
        else {
          size_t off = gpK(row, col, 256);
          u16 h = f2b(v); Oh[off]=h; Ol[off]=f2b(v - b2f(h));
        }
      }
    }
  }
}

// ---------- gram + bitpack v2: packed fragments, symmetric tile enumeration ----------
__global__ __launch_bounds__(256) void k_mconnect2(const u16* __restrict__ fahP, const u16* __restrict__ falP,
    const u8* __restrict__ sel8, u32* __restrict__ conn){
  __shared__ u8 sg[64][64];
  __shared__ u8 selI[64], selJ[64];
  int tid=threadIdx.x, w=tid>>6, lane=tid&63, L=lane&15, q=lane>>4;
  int b=blockIdx.z;
  int p=blockIdx.x;
  int i = (int)((sqrtf(8.f*p+1.f)-1.f)*0.5f);
  while ((i+1)*(i+2)/2 <= p) i++;
  while (i*(i+1)/2 > p) i--;
  int j = p - i*(i+1)/2;          // i >= j, both 0..15
  if (tid < 64)        selI[tid]     = sel8[b*NN + i*64 + tid];
  else if (tid < 128)  selJ[tid-64]  = sel8[b*NN + j*64 + (tid-64)];
  const u16* ah0 = fahP + ((size_t)(b*64 + i*4 + w))*4096 + (size_t)lane*8;
  const u16* al0 = falP + ((size_t)(b*64 + i*4 + w))*4096 + (size_t)lane*8;
  const u16* bh0 = fahP + ((size_t)(b*64 + j*4))*4096 + (size_t)lane*8;
  const u16* bl0 = falP + ((size_t)(b*64 + j*4))*4096 + (size_t)lane*8;
  f4v z4={0.f,0.f,0.f,0.f};
  f4v acc[4]={z4,z4,z4,z4};
  #pragma unroll
  for (int kc=0;kc<8;kc++){
    s8v ah = *(const s8v*)(ah0 + kc*512);
    s8v al = *(const s8v*)(al0 + kc*512);
    #pragma unroll
    for (int t=0;t<4;t++){
      s8v bh = *(const s8v*)(bh0 + (size_t)t*4096 + kc*512);
      s8v bl = *(const s8v*)(bl0 + (size_t)t*4096 + kc*512);
      acc[t]=MFMA(ah,bh,acc[t]);
      acc[t]=MFMA(ah,bl,acc[t]);
      acc[t]=MFMA(al,bh,acc[t]);
    }
  }
  #pragma unroll
  for (int t=0;t<4;t++)
    #pragma unroll
    for (int reg=0;reg<4;reg++)
      sg[w*16 + q*4 + reg][t*16 + L] = acc[t][reg] > 0.f;
  __syncthreads();
  int row=(tid&127)>>1, ww=tid&1;
  if (tid<128){
    u32 word=0;
    if (selI[row]){
      #pragma unroll 8
      for (int jj=0;jj<32;jj++)
        if (sg[row][ww*32+jj] && selJ[ww*32+jj]) word |= (1u<<jj);
    }
    conn[((size_t)b*NN + i*64+row)*32 + j*2 + ww] = word;
  } else if (i != j){
    u32 word=0;
    if (selJ[row]){
      #pragma unroll 8
      for (int jj=0;jj<32;jj++)
        if (sg[ww*32+jj][row] && selI[ww*32+jj]) word |= (1u<<jj);
    }
    conn[((size_t)b*NN + j*64+row)*32 + i*2 + ww] = word;
  }
}

// ---------- MFMA GAT attention v10: defer-max (no M2a), lgkmcnt-only barrier ----------
// s1/s2 are prescaled by LOG2E -> bare v_exp_f32 (2^x). No row-max subtraction:
// softmax is shift-invariant and |s1+s2|*log2e is bounded (~30) << fp32 range.
// All-masked rows -> sumP=0 -> guarded rsi=0 -> finite 0 output (rows discarded
// downstream; P=0 keeps PV exact).
// PKO: 0 = row-major output (stride oStride); else fragment-packed gpK(row,col,PKO).
template<int CT, bool SWZ, int PKO>
__global__ __launch_bounds__(256,4) void k_mattn5(const float* __restrict__ s1a, const float* __restrict__ s2a,
    const u32* __restrict__ conn,
    const u16* __restrict__ P, int headMul, u16* __restrict__ Out, int oStride){
  __shared__ __align__(16) u16 Pb[2][4][512];
  __shared__ float Srow[64];
  int tid=threadIdx.x, w=tid>>6, lane=tid&63, L=lane&15, q=lane>>4;
  int h, rowBlk;
  if constexpr (SWZ){ h = blockIdx.y & 7; rowBlk = (blockIdx.y>>3) + (blockIdx.z<<4); }
  else             { h = blockIdx.z;     rowBlk = blockIdx.y; }
  int rowBase = rowBlk*64;
  int hOff = h*headMul, sOff = h*BN;
  int b = rowBase>>10;
  size_t bOff = (size_t)b*NN;
  int r = rowBase + w*16 + L;             // own row for P-build
  float s1v = s1a[sOff+r];
  const float* s2p = s2a + sOff + bOff;
  const u32* cp = conn + (size_t)r*32;
  int tile0 = blockIdx.x*(4*CT) + w*CT;   // first col-tile owned by this wave
  const u16* vp = P + (size_t)((hOff>>4) + tile0)*131072 + (size_t)b*16384 + (size_t)lane*8;
  f4v z4={0.f,0.f,0.f,0.f};
  f4v acc[4][CT];
  #pragma unroll
  for (int g=0;g<4;g++)
    #pragma unroll
    for (int t=0;t<CT;t++) acc[g][t]=z4;
  float sumP = 0.f;
  for (int k0=0;k0<NN;k0+=32){
    int cur=(k0>>5)&1;
    u32 cw = cp[k0>>5];
    // issue THIS chunk's V loads first — they stay in flight ACROSS the
    // barrier (lgkmcnt-only), completing under the MFMA wait of the consumer.
    s8v vf[CT];
    {
      const u16* vk = vp + (size_t)(k0>>5)*512;
      #pragma unroll
      for (int t=0;t<CT;t++) vf[t] = *(const s8v*)(vk + (size_t)t*131072);
    }
    float4 sA = *(const float4*)(s2p + k0 + q*8);
    float4 sB = *(const float4*)(s2p + k0 + q*8 + 4);
    float s2v[8] = {sA.x,sA.y,sA.z,sA.w,sB.x,sB.y,sB.z,sB.w};
    float p[8];
    #pragma unroll
    for (int j=0;j<8;j++){
      float z = s1v + s2v[j];
      float ev = fmaxf(z, 0.2f*z);                      // leaky = max(z, 0.2z) (scaled)
      ev = ((cw>>(q*8+j))&1u) ? ev : -9.0e15f;          // mask BEFORE exp; 2^-9e15 = 0
      p[j] = exp2r(ev);                                  // bare v_exp (2^x), no max-sub
      sumP += p[j];
    }
    union{ s8v v; u32 u[4]; } pk;
    #pragma unroll
    for (int jj=0;jj<4;jj++)
      pk.u[jj] = pk2(p[2*jj], p[2*jj+1]);
    *(s8v*)&Pb[cur][w][lane*8] = pk.v;    // ds_write_b128, contiguous
    // lgkmcnt-only barrier: own LDS write retired, then block-wide barrier.
    // Does NOT drain vmcnt — V/s2/conn loads stay outstanding (T4 minimal).
    // Pb[2] double-buffer is REQUIRED for correctness with this barrier.
    asm volatile("s_waitcnt lgkmcnt(0)" ::: "memory");
    __builtin_amdgcn_s_barrier();
    asm volatile("" ::: "memory");
    s8v pa[4];
    #pragma unroll
    for (int g=0;g<4;g++) pa[g] = *(const s8v*)&Pb[cur][g][lane*8];
    __builtin_amdgcn_s_setprio(1);
    #pragma unroll
    for (int t=0;t<CT;t++)
      #pragma unroll
      for (int g=0;g<4;g++) acc[g][t] = MFMA(pa[g], vf[t], acc[g][t]);
    __builtin_amdgcn_s_setprio(0);
  }
  sumP += __shfl_xor(sumP,16);
  sumP += __shfl_xor(sumP,32);
  if (lane<16) Srow[w*16+lane] = sumP;
  __syncthreads();
  #pragma unroll
  for (int g=0;g<4;g++){
    float4 sv = *(const float4*)&Srow[g*16 + q*4];
    // guard: all-masked row -> sumP==0 -> emit 0 (finite), not inf/NaN
    float rsi[4] = {sv.x>0.f ? 1.f/sv.x : 0.f, sv.y>0.f ? 1.f/sv.y : 0.f,
                    sv.z>0.f ? 1.f/sv.z : 0.f, sv.w>0.f ? 1.f/sv.w : 0.f};
    #pragma unroll
    for (int t=0;t<CT;t++){
      int col = hOff + (tile0+t)*16 + L;
      #pragma unroll
      for (int reg=0;reg<4;reg++){
        int row = rowBase + g*16 + q*4 + reg;
        float ov = eluf(acc[g][t][reg]*rsi[reg]);
        if constexpr (PKO) Out[gpK(row, col, PKO)] = f2b(ov);
        else               Out[(size_t)row*oStride + col] = f2b(ov);
      }
    }
  }
}

// ---------- LayerNorms (packed gpK-256 output) ----------
__global__ __launch_bounds__(256) void k_ln_x(const float* __restrict__ x, const float* __restrict__ g,
                                              const float* __restrict__ bb, u16* __restrict__ out){
  int r = blockIdx.x*4 + (threadIdx.x>>6);
  int lane=threadIdx.x&63;
  float4 v = *(const float4*)(x + (size_t)r*DD + lane*4);
  float s = v.x+v.y+v.z+v.w;
  float s2 = v.x*v.x+v.y*v.y+v.z*v.z+v.w*v.w;
  s = wredsum(s); s2 = wredsum(s2);
  float mean = s*(1.f/256.f);
  float var = s2*(1.f/256.f) - mean*mean;
  float rstd = rsqrtf(var + 1e-5f);
  float4 gv = *(const float4*)(g+lane*4), bv = *(const float4*)(bb+lane*4);
  u16 t[4];
  t[0]=f2b((v.x-mean)*rstd*gv.x+bv.x); t[1]=f2b((v.y-mean)*rstd*gv.y+bv.y);
  t[2]=f2b((v.z-mean)*rstd*gv.z+bv.z); t[3]=f2b((v.w-mean)*rstd*gv.w+bv.w);
  *(uint2*)(out + gpK(r, lane*4, 256)) = *(uint2*)&t[0];
}

__global__ __launch_bounds__(256) void k_ln_kv(const u16* __restrict__ gout, const float* __restrict__ pe,
    const u8* __restrict__ sel8, const float* __restrict__ g, const float* __restrict__ bb,
    u16* __restrict__ out){
  int r = blockIdx.x*4 + (threadIdx.x>>6);
  int lane=threadIdx.x&63;
  int n = r & 1023;
  float4 v = make_float4(0.f,0.f,0.f,0.f);
  if (sel8[r]){
    float4 gv = ld4bf(gout + (size_t)r*DD + lane*4);
    float4 pv = *(const float4*)(pe + (size_t)n*DD + lane*4);
    v = make_float4(gv.x+pv.x, gv.y+pv.y, gv.z+pv.z, gv.w+pv.w);
  }
  float s = v.x+v.y+v.z+v.w;
  float s2 = v.x*v.x+v.y*v.y+v.z*v.z+v.w*v.w;
  s = wredsum(s); s2 = wredsum(s2);
  float mean = s*(1.f/256.f);
  float var = s2*(1.f/256.f) - mean*mean;
  float rstd = rsqrtf(var + 1e-5f);
  float4 gv = *(const float4*)(g+lane*4), bv = *(const float4*)(bb+lane*4);
  u16 t[4];
  t[0]=f2b((v.x-mean)*rstd*gv.x+bv.x); t[1]=f2b((v.y-mean)*rstd*gv.y+bv.y);
  t[2]=f2b((v.z-mean)*rstd*gv.z+bv.z); t[3]=f2b((v.w-mean)*rstd*gv.w+bv.w);
  *(uint2*)(out + gpK(r, lane*4, 256)) = *(uint2*)&t[0];
}

// ---------- CA attention v3: barrier-free flash; direct fragment loads ----------
__global__ __launch_bounds__(256) void k_mca_av3(const u16* __restrict__ q, const u16* __restrict__ k,
    const u16* __restrict__ v, const u8* __restrict__ sel8, u16* __restrict__ O){
  __shared__ __align__(16) u16 Pw[4][16][72];
  int tid=threadIdx.x;
  int w = tid>>6, lane = tid&63, L = lane&15, qd = lane>>4;
  int b=blockIdx.z, h=blockIdx.y, rowBase=blockIdx.x*64;
  size_t bOff = (size_t)b*NN;
  const u16* qbase = q + (size_t)((bOff + rowBase + w*16)>>4)*4096 + (size_t)lane*8;
  s8v af0 = *(const s8v*)(qbase + (size_t)(h*2+0)*512);
  s8v af1 = *(const s8v*)(qbase + (size_t)(h*2+1)*512);
  float rm[4], sp[4];
  #pragma unroll
  for (int reg=0;reg<4;reg++){ rm[reg] = -3.0e38f; sp[reg] = 0.f; }
  f4v zero = {0.f,0.f,0.f,0.f};
  f4v acc[4] = {zero,zero,zero,zero};
  for (int m0=0;m0<NN;m0+=64){
    s8v bt[4][2];
    #pragma unroll
    for (int t=0;t<4;t++){
      const u16* kb = k + (size_t)((bOff + m0 + t*16)>>4)*4096 + (size_t)lane*8;
      bt[t][0] = *(const s8v*)(kb + (size_t)(h*2+0)*512);
      bt[t][1] = *(const s8v*)(kb + (size_t)(h*2+1)*512);
    }
    s8v vf[4][2];
    #pragma unroll
    for (int t=0;t<4;t++){
      const u16* vb = v + (size_t)(((h*4+t)*8 + b)*32 + (m0>>5))*512 + (size_t)lane*8;
      vf[t][0] = *(const s8v*)vb;
      vf[t][1] = *(const s8v*)(vb + 512);
    }
    f4v sa[4] = {zero,zero,zero,zero};
    #pragma unroll
    for (int t=0;t<4;t++){
      sa[t] = MFMA(af0, bt[t][0], sa[t]);
      sa[t] = MFMA(af1, bt[t][1], sa[t]);
    }
    float vals[4][4];
    float tmax[4];
    #pragma unroll
    for (int reg=0;reg<4;reg++) tmax[reg] = -3.0e38f;
    #pragma unroll
    for (int t=0;t<4;t++){
      int m = m0 + t*16 + L;
      bool sl = sel8[b*NN+m];
      #pragma unroll
      for (int reg=0;reg<4;reg++){
        float val = sl ? sa[t][reg]*0.125f : -1.0e9f;
        vals[t][reg] = val;
        tmax[reg] = fmaxf(tmax[reg], val);
      }
    }
    #pragma unroll
    for (int off=1;off<16;off<<=1)
      #pragma unroll
      for (int reg=0;reg<4;reg++) tmax[reg] = fmaxf(tmax[reg], __shfl_xor(tmax[reg],off));
    float sc[4];
    #pragma unroll
    for (int reg=0;reg<4;reg++){
      float nm = fmaxf(rm[reg], tmax[reg]);
      sc[reg] = exp0(rm[reg] - nm);
      rm[reg] = nm;
      sp[reg] *= sc[reg];
    }
    #pragma unroll
    for (int t=0;t<4;t++){
      #pragma unroll
      for (int reg=0;reg<4;reg++){
        float pv = exp0(vals[t][reg] - rm[reg]);
        sp[reg] += pv;
        Pw[w][qd*4 + reg][t*16 + L] = f2b(pv);   // intra-wave slice, no barrier
      }
    }
    #pragma unroll
    for (int t=0;t<4;t++)
      #pragma unroll
      for (int reg=0;reg<4;reg++) acc[t][reg] *= sc[reg];
    #pragma unroll
    for (int mc2=0;mc2<2;mc2++){
      s8v pf = *(const s8v*)&Pw[w][L][mc2*32 + qd*8];
      #pragma unroll
      for (int t=0;t<4;t++)
        acc[t] = MFMA(pf, vf[t][mc2], acc[t]);
    }
  }
  #pragma unroll
  for (int off=1;off<16;off<<=1)
    #pragma unroll
    for (int reg=0;reg<4;reg++) sp[reg] += __shfl_xor(sp[reg],off);
  float ri[4];
  #pragma unroll
  for (int reg=0;reg<4;reg++) ri[reg] = 1.f/sp[reg];
  #pragma unroll
  for (int t=0;t<4;t++){
    int col = h*64 + t*16 + L;
    #pragma unroll
    for (int reg=0;reg<4;reg++){
      int row = (int)bOff + rowBase + w*16 + qd*4 + reg;
      O[gpK(row, col, 256)] = f2b(acc[t][reg]*ri[reg]);
    }
  }
}

extern "C" void kernel_launch(void* const* d_in, const int* in_sizes, int n_in,
                              void* d_out, int out_size, void* d_ws, size_t ws_size,
                              hipStream_t stream) {
  (void)in_sizes; (void)n_in; (void)out_size;
  const float* x      = (const float*)d_in[0];
  const int*   mask   = (const int*  )d_in[1];
  const float* pe     = (const float*)d_in[2];
  const float* sim_Wx = (const float*)d_in[3];
  const float* sim_Wq = (const float*)d_in[4];
  const float* adj_W  = (const float*)d_in[5];
  const float* gat_W  = (const float*)d_in[6];
  const float* gat_a1 = (const float*)d_in[7];
  const float* gat_a2 = (const float*)d_in[8];
  const float* gat_Wo = (const float*)d_in[9];
  const float* gat_ao1= (const float*)d_in[10];
  const float* gat_ao2= (const float*)d_in[11];
  const float* ln3_g  = (const float*)d_in[12];
  const float* ln3_b  = (const float*)d_in[13];
  const float* ln4_g  = (const float*)d_in[14];
  const float* ln4_b  = (const float*)d_in[15];
  const float* ca_Wq  = (const float*)d_in[16];
  const float* ca_Wk  = (const float*)d_in[17];
  const float* ca_Wv  = (const float*)d_in[18];
  const float* ca_Wp  = (const float*)d_in[19];
  const float* gamma  = (const float*)d_in[20];
  float* out    = (float*)d_out;
  float* simOut = out + (size_t)BN*DD;

  const size_t MB = 1024*1024;
  bool big = ws_size >= 98*MB;
  char* W = (char*)d_ws;
  float* pq   = (float*)W;
  float* cnt  = pq + 2048;
  float* sq   = cnt + 16;
  float* s1a  = (float*)(W + 64*1024);
  float* s2a  = (float*)(W + 320*1024);
  float* pdot = (float*)(W + 1216*1024);
  u8*    sel8 = (u8*)(W + 1400*1024);
  u32*   conn = (u32*)(W + 2*MB);
  u16*   WT0  = (u16*)(W + 3*MB);
  u16*   WoT  = (u16*)(W + 4*MB);
  u16*   WQT  = (u16*)(W + 5*MB);
  u16*   WPT  = WQT + 3*65536;
  u16*   sWxh = (u16*)(W + 5*MB + 512*1024);
  u16*   sWxl = sWxh + 65536;
  u16*   aWh  = sWxl + 65536;
  u16*   aWl  = aWh + 65536;
  u16*   xh   = (u16*)(W + 6*MB);
  u16*   xl   = (u16*)(W + 10*MB);
  float* S0   = (float*)(W + 14*MB);
  u16*   fah  = (u16*)(W + 22*MB);
  u16*   fal  = (u16*)(W + 26*MB);
  u16*   T2   = (u16*)(W + 30*MB);

  // prep (everything fragment-packed)
  k_split<<<BN*DD/2048,256,0,stream>>>(x, xh, xl);
  k_transpose<<<dim3(4,4,HG),256,0,stream>>>(gat_W, WT0, 256, 65536, 256);
  k_transpose<<<dim3(4,32,1),256,0,stream>>>(gat_Wo, WoT, 2048, 0, 2048);
  k_transpose4<<<dim3(4,4,4),256,0,stream>>>(ca_Wq, ca_Wk, ca_Wv, ca_Wp, WQT);
  k_transp_split<<<dim3(4,4,1),256,0,stream>>>(sim_Wx, sWxh, sWxl);
  k_transp_split<<<dim3(4,4,1),256,0,stream>>>(adj_W, aWh, aWl);

  hipMemsetAsync(pq, 0, (2048+16+2048)*sizeof(float), stream);   // pq + cnt + sq
  hipMemsetAsync(pdot, 0, BN*sizeof(float), stream);
  k_posq<<<dim3(BB,64),256,0,stream>>>(x, mask, pq, cnt);
  k_sq<<<dim3(BB,16),256,0,stream>>>(pq, cnt, sim_Wq, sq);
  k_msgemm<5><<<dim3(4,128),256,0,stream>>>(xh, xl, sWxh, sWxl, nullptr, nullptr, nullptr, sq, pdot); // y-dot fold
  k_simsel2<<<BN/256,256,0,stream>>>(pdot, simOut, sel8);
  k_msgemm<4><<<dim3(4,128),256,0,stream>>>(xh, xl, aWh, aWl, nullptr, fah, fal, nullptr, nullptr);   // fa gram-packed
  k_mconnect2<<<dim3(136,1,BB),256,0,stream>>>(fah, fal, sel8, conn);

  if (big){
    u16* WhP   = (u16*)(W + 66*MB);   // attention-packed Wh_cat, 32MB
    u16* htcat = (u16*)(W + 34*MB);   // fragment-packed (gpK 2048) ht_cat, 32MB
    u16* S0P   = (u16*)(W + 22*MB);   // attention-packed Who, 4MB (fah dead after mconnect)
    u16* qx = (u16*)(W + 34*MB);      // after htcat consumed
    u16* kv = (u16*)(W + 38*MB);
    u16* qb = (u16*)(W + 42*MB);
    u16* vb = (u16*)(W + 50*MB);
    u16* Ob = (u16*)(W + 54*MB);

    hipMemsetAsync(s1a, 0, 512*1024, stream);  // s1a(256K) + s2a(256K) contiguous
    k_mgemm<7,1,1,2><<<dim3(32,128),256,0,stream>>>(xh, WT0, 256, 256, 0, nullptr, nullptr, nullptr, nullptr,
                                                    WhP, gat_a1, gat_a2, s1a, s2a);  // WhP pack + s1s2 fold (×log2e)
    k_mattn5<4,true,2048><<<dim3(1,128,HG),256,0,stream>>>(s1a, s2a, conn, WhP, 256, htcat, 2048);
    hipMemsetAsync(s1a, 0, BN*sizeof(float), stream);
    hipMemsetAsync(s2a, 0, BN*sizeof(float), stream);
    k_mgemm<8,1,1,4><<<dim3(4,128),256,0,stream>>>(htcat, WoT, 2048, 2048, 0, nullptr, nullptr, nullptr, nullptr,
                                                   S0P, gat_ao1, gat_ao2, s1a, s2a);  // S0P pack + s1s2 fold (×log2e)
    k_mattn5<1,false,0><<<dim3(4,128,1),256,0,stream>>>(s1a, s2a, conn, S0P, 0, T2, 256);  // gout

    k_ln_x<<<BN/4,256,0,stream>>>(x, ln3_g, ln3_b, qx);
    k_ln_kv<<<BN/4,256,0,stream>>>(T2, pe, sel8, ln4_g, ln4_b, kv);
    k_mgemm3<<<dim3(4,128,3),256,0,stream>>>(qx, kv, WQT, qb);     // qb,kb gpK; vb packIdx
    k_mca_av3<<<dim3(16,HC,BB),256,0,stream>>>(qb, qb + 2097152, vb, sel8, Ob);
    k_mgemm<2,1,1,4><<<dim3(4,128),256,0,stream>>>(Ob, WPT, 256, 256, 0, out, x, gamma, nullptr, nullptr,
                                                   nullptr, nullptr, nullptr, nullptr);
  } else {
    // small-ws fallback: per-head loop, packed kernels (rarely taken)
    u16* T0 = fah;
    u16* T1 = fal;
    u16* S0b = (u16*)S0;
    hipMemsetAsync(s1a, 0, 512*1024, stream);
    for (int h=0;h<HG;h++){
      hipMemsetAsync(s1a, 0, BN*sizeof(float), stream);
      hipMemsetAsync(s2a, 0, BN*sizeof(float), stream);
      k_mgemm<8,1,1><<<dim3(4,128),256,0,stream>>>(xh, WT0 + (size_t)h*65536, 256, 256, 0,
                                                   nullptr, nullptr, nullptr, nullptr, T0,
                                                   gat_a1 + h*DD, gat_a2 + h*DD, s1a, s2a);
      k_mattn5<1,false,0><<<dim3(4,128,1),256,0,stream>>>(s1a, s2a, conn, T0, 0, T1, 256);
      k_mgemm<1,0,1><<<dim3(4,128),256,0,stream>>>(T1, WoT, 256, 2048, h*256, S0, nullptr, nullptr, nullptr, nullptr,
                                                   nullptr, nullptr, nullptr, nullptr);
    }
    hipMemsetAsync(s1a, 0, BN*sizeof(float), stream);
    hipMemsetAsync(s2a, 0, BN*sizeof(float), stream);
    k_mattn5<1,false,0><<<dim3(4,128,1),256,0,stream>>>(s1a, s2a, conn, (u16*)S0, 0, T2, 256);
    k_ln_x<<<BN/4,256,0,stream>>>(x, ln3_g, ln3_b, T1);
    k_ln_kv<<<BN/4,256,0,stream>>>(T2, pe, sel8, ln4_g, ln4_b, T0);
    k_mgemm3<<<dim3(4,128,3),256,0,stream>>>(T1, T0, WQT, S0b);
    k_mca_av3<<<dim3(16,HC,BB),256,0,stream>>>(S0b, S0b + 2097152, S0b + 4194304, sel8, T0);
    k_mgemm<2,1,1><<<dim3(4,128),256,0,stream>>>(T0, WPT, 256, 256, 0, out, x, gamma, nullptr, nullptr,
                                                 nullptr, nullptr, nullptr, nullptr);
  }
}

// Round 20
// 382.452 us; speedup vs baseline: 1.4197x; 1.0145x over previous
//
#include <hip/hip_runtime.h>
#include <hip/hip_bf16.h>

// GATFusionBlockPosOnly: B=8, N=1024, D=256, 8 GAT heads, 4 CA heads.
// Round 29:
//  - R28 landed BIG: defer-max 445->388us (rowmax deleted, bare v_exp, M2a dead).
//  - mattn5 L1 (60us, Mfma22/VALU46) accepted for now (3 structural attempts flat).
//  - Target hidden #2/#3: the 512-block grid-capped GEMMs run at 2 blocks/CU
//    -> VGPR budget 256/thread; UNR=4 (~120) uses half. UNR=8 (~195, no spill)
//    doubles load-batch ILP: k_mgemm<8> (Who, 64 kc) and k_mgemm<2> (final CA,
//    nk=8 fully unrolled).
//  - Merged the two mid-pipeline 32KB memsets into one 512KB covering both.

#define BB 8
#define NN 1024
#define DD 256
#define HG 8
#define HC 4
#define BN (BB*NN)
#define LOG2E 1.44269504088896f

typedef unsigned short u16;
typedef unsigned int u32;
typedef unsigned char u8;
typedef __attribute__((ext_vector_type(8))) short s8v;   // 8 bf16
typedef __attribute__((ext_vector_type(4))) float f4v;   // 4 fp32 acc
#define MFMA(a,b,c) __builtin_amdgcn_mfma_f32_16x16x32_bf16((a),(b),(c),0,0,0)

__device__ __forceinline__ u16 f2b(float x){
  union{ float f; unsigned u; } a; a.f = x;
  unsigned r = a.u + 0x7fff + ((a.u>>16)&1);
  return (u16)(r>>16);
}
__device__ __forceinline__ float b2f(u16 b){ return __uint_as_float(((unsigned)b)<<16); }
__device__ __forceinline__ float4 ld4bf(const u16* p){
  uint2 u = *(const uint2*)p;
  float4 r;
  r.x=__uint_as_float(u.x<<16); r.y=__uint_as_float(u.x&0xffff0000u);
  r.z=__uint_as_float(u.y<<16); r.w=__uint_as_float(u.y&0xffff0000u);
  return r;
}
__device__ __forceinline__ void load8(const float* p, float* v){
  float4 a=*(const float4*)p, b=*(const float4*)(p+4);
  v[0]=a.x;v[1]=a.y;v[2]=a.z;v[3]=a.w;v[4]=b.x;v[5]=b.y;v[6]=b.z;v[7]=b.w;
}
__device__ __forceinline__ float wredsum(float v){
  #pragma unroll
  for(int o=32;o>0;o>>=1) v += __shfl_xor(v,o);
  return v;
}
__device__ __forceinline__ float wredmax(float v){
  #pragma unroll
  for(int o=32;o>0;o>>=1) v = fmaxf(v,__shfl_xor(v,o));
  return v;
}
__device__ __forceinline__ float eluf(float x){ return x>0.f ? x : __expf(x)-1.f; }
__device__ __forceinline__ float leakyf(float z){ return z>=0.f ? z : 0.2f*z; }
__device__ __forceinline__ float exp0(float a){ return __expf(fminf(a, 0.f)); }
__device__ __forceinline__ float exp2r(float a){   // bare v_exp_f32 (2^a), no clamp
  float r;
  asm("v_exp_f32 %0, %1" : "=v"(r) : "v"(a));
  return r;
}
__device__ __forceinline__ float flushf(float v){ return (fabsf(v) < 1.0e30f) ? v : 0.f; }
__device__ __forceinline__ u32 pk2(float lo, float hi){
  u32 r;
  asm("v_cvt_pk_bf16_f32 %0, %1, %2" : "=v"(r) : "v"(lo), "v"(hi));
  return r;
}

// packed index for element (col, m) of the attention-V pack:  b=m>>10, kk=m&1023
__device__ __forceinline__ size_t packIdx(int col, int row){
  int kk = row & 1023;
  return ((((size_t)(col>>4))*8 + (row>>10))*32 + (kk>>5))*512
       + (size_t)(((((kk>>3)&3)*16) + (col&15))*8 + (kk&7));
}

// fragment-pack: element (row, k) of a [rows][KK] operand -> fragment order.
__device__ __forceinline__ size_t gpK(int row, int k, int KK){
  return (size_t)(row>>4)*((size_t)16*KK) + (size_t)(k>>5)*512
       + (size_t)(((((k>>3)&3)*16) + (row&15))*8 + (k&7));
}

// ---------- fp32 -> (hi,lo) bf16 split, packed output (gpK, KK=256) ----------
__global__ __launch_bounds__(256) void k_split(const float* __restrict__ X, u16* __restrict__ H, u16* __restrict__ Lo){
  size_t i = ((size_t)blockIdx.x*256 + threadIdx.x)*8;
  float v[8]; load8(X+i, v);
  u16 hh[8], ll[8];
  #pragma unroll
  for (int j=0;j<8;j++){ hh[j]=f2b(v[j]); ll[j]=f2b(v[j]-b2f(hh[j])); }
  int row = (int)(i>>8), col = (int)(i&255);
  size_t off = gpK(row, col, 256);
  *(uint4*)(H+off)=*(uint4*)&hh[0];
  *(uint4*)(Lo+off)=*(uint4*)&ll[0];
}

// ---------- transpose fp32 [R][C] -> bf16; pkKK=0: row-major [C][R]; else gpK packed ----------
__global__ __launch_bounds__(256) void k_transpose(const float* __restrict__ S, u16* __restrict__ D,
                                                   int R, int sliceElems, int pkKK){
  __shared__ float tl[64][65];
  const float* src = S + (size_t)blockIdx.z*sliceElems;
  u16* dst = D + (size_t)blockIdx.z*sliceElems;
  int C = gridDim.x*64;
  int bx=blockIdx.x*64, by=blockIdx.y*64;
  int tid=threadIdx.x, r=tid>>2, c0=(tid&3)*16;
  #pragma unroll
  for (int i=0;i<16;i+=4){
    float4 v = *(const float4*)(src + (size_t)(by+r)*C + bx + c0 + i);
    tl[r][c0+i]=v.x; tl[r][c0+i+1]=v.y; tl[r][c0+i+2]=v.z; tl[r][c0+i+3]=v.w;
  }
  __syncthreads();
  u16 tmp[16];
  #pragma unroll
  for (int i=0;i<16;i++) tmp[i] = f2b(tl[c0+i][r]);
  if (pkKK){
    *(uint4*)(dst + gpK(bx+r, by+c0,     pkKK)) = *(uint4*)&tmp[0];
    *(uint4*)(dst + gpK(bx+r, by+c0+8,   pkKK)) = *(uint4*)&tmp[8];
  } else {
    *(uint4*)(dst + (size_t)(bx+r)*R + by + c0)     = *(uint4*)&tmp[0];
    *(uint4*)(dst + (size_t)(bx+r)*R + by + c0 + 8) = *(uint4*)&tmp[8];
  }
}

// ---------- 4x 256x256 transposes, PACKED (gpK 256) output; grid (4,4,4) ----------
__global__ __launch_bounds__(256) void k_transpose4(const float* __restrict__ Sa, const float* __restrict__ Sb,
    const float* __restrict__ Sc, const float* __restrict__ Sd, u16* __restrict__ D){
  __shared__ float tl[64][65];
  const float* src = blockIdx.z==0 ? Sa : blockIdx.z==1 ? Sb : blockIdx.z==2 ? Sc : Sd;
  u16* dst = D + (size_t)blockIdx.z*65536;
  int bx=blockIdx.x*64, by=blockIdx.y*64;
  int tid=threadIdx.x, r=tid>>2, c0=(tid&3)*16;
  #pragma unroll
  for (int i=0;i<16;i+=4){
    float4 v = *(const float4*)(src + (size_t)(by+r)*256 + bx + c0 + i);
    tl[r][c0+i]=v.x; tl[r][c0+i+1]=v.y; tl[r][c0+i+2]=v.z; tl[r][c0+i+3]=v.w;
  }
  __syncthreads();
  u16 tmp[16];
  #pragma unroll
  for (int i=0;i<16;i++) tmp[i] = f2b(tl[c0+i][r]);
  *(uint4*)(dst + gpK(bx+r, by+c0,   256)) = *(uint4*)&tmp[0];
  *(uint4*)(dst + gpK(bx+r, by+c0+8, 256)) = *(uint4*)&tmp[8];
}

// ---------- transpose + split: fp32 [256][256] -> hi/lo bf16 PACKED (gpK 256) ----------
__global__ __launch_bounds__(256) void k_transp_split(const float* __restrict__ S, u16* __restrict__ DH, u16* __restrict__ DL){
  __shared__ float tl[64][65];
  int bx=blockIdx.x*64, by=blockIdx.y*64;
  int tid=threadIdx.x, r=tid>>2, c0=(tid&3)*16;
  #pragma unroll
  for (int i=0;i<16;i+=4){
    float4 v = *(const float4*)(S + (size_t)(by+r)*256 + bx + c0 + i);
    tl[r][c0+i]=v.x; tl[r][c0+i+1]=v.y; tl[r][c0+i+2]=v.z; tl[r][c0+i+3]=v.w;
  }
  __syncthreads();
  u16 th[16], tll[16];
  #pragma unroll
  for (int i=0;i<16;i++){
    float v = tl[c0+i][r];
    th[i]=f2b(v); tll[i]=f2b(v - b2f(th[i]));
  }
  size_t o0 = gpK(bx+r, by+c0,   256);
  size_t o1 = gpK(bx+r, by+c0+8, 256);
  *(uint4*)(DH + o0) = *(uint4*)&th[0];
  *(uint4*)(DH + o1) = *(uint4*)&th[8];
  *(uint4*)(DL + o0) = *(uint4*)&tll[0];
  *(uint4*)(DL + o1) = *(uint4*)&tll[8];
}

// ---------- pos_query: grid (BB, 64), 16 rows per block ----------
__global__ __launch_bounds__(256) void k_posq(const float* __restrict__ x, const int* __restrict__ mask,
                                              float* __restrict__ pq, float* __restrict__ cnt){
  int b = blockIdx.x, chunk = blockIdx.y;
  int d = threadIdx.x;
  int n0 = chunk*16;
  float acc = 0.f; float c = 0.f;
  for (int i=0;i<16;i++){
    int n = n0+i;
    if (mask[b*NN+n]==1){ acc += x[((size_t)(b*NN+n))*DD + d]; c += 1.f; }
  }
  atomicAdd(&pq[b*DD+d], acc);
  if (d==0) atomicAdd(&cnt[b], c);
}

// ---------- sq: grid (BB, 16), 16 d-rows per block, atomic accumulate ----------
__global__ __launch_bounds__(256) void k_sq(const float* __restrict__ pq, const float* __restrict__ cnt,
                                            const float* __restrict__ Wq, float* __restrict__ sq){
  int b = blockIdx.x, dq = blockIdx.y;
  int e = threadIdx.x;
  float inv = 1.f / fmaxf(cnt[b], 1.f);
  float acc=0.f;
  for (int i=0;i<16;i++){
    int d0 = dq*16 + i;
    acc += pq[b*DD+d0] * Wq[d0*DD+e];
  }
  atomicAdd(&sq[b*DD+e], acc*inv);
}

// ---------- sigmoid + threshold from folded dot ----------
__global__ __launch_bounds__(256) void k_simsel2(const float* __restrict__ pdot,
                                                 float* __restrict__ simOut, u8* __restrict__ sel8){
  int r = blockIdx.x*256 + threadIdx.x;
  float s = pdot[r] * 0.0625f;
  float sim = 1.f/(1.f+expf(-s));
  simOut[r] = sim;
  sel8[r] = (sim > 0.97f) ? 1 : 0;
}

// ---------- no-LDS MFMA GEMM: out[8192, OC] = A[8192,KK] @ BT[OC,KK]^T ----------
// APK: A fragment-packed (gpK, KK). BPK: BT fragment-packed (gpK, ldB total K; kOff = K start).
// UNR: load-batch depth (UNR=8 only on 512-block grid-capped GEMMs: 2 blocks/CU
//      -> 256 VGPR budget; ~195 used, no spill).
// EPI: 0=C fp32, 1=C+=, 2=residual+gamma, 3=O bf16,
//      7=Pk pack + s1/s2 fold (head=colBase>>8), 8=Pk pack + s1/s2 fold (single head)
// EPI 7/8: a1/a2 prescaled by LOG2E so consumers use bare 2^x.
template<int EPI, int APK, int BPK, int UNR=1>
__global__ __launch_bounds__(256) void k_mgemm(const u16* __restrict__ A, const u16* __restrict__ BT,
    int KK, int ldB, int kOff, float* __restrict__ C, const float* __restrict__ Xres,
    const float* __restrict__ gamma, u16* __restrict__ O, u16* __restrict__ Pk,
    const float* __restrict__ A1, const float* __restrict__ A2,
    float* __restrict__ s1g, float* __restrict__ s2g){
  int tid=threadIdx.x, w=tid>>6, lane=tid&63, L=lane&15, q=lane>>4;
  int OC = gridDim.x<<6;
  int colBase=blockIdx.x<<6, rowBase=blockIdx.y<<6;
  const u16* ap;
  if constexpr (APK) ap = A + (size_t)((rowBase>>4)+w)*((size_t)16*KK) + (size_t)lane*8;
  else               ap = A + (size_t)(rowBase + w*16 + L)*KK + q*8;
  const u16* bp[4];
  #pragma unroll
  for (int t=0;t<4;t++){
    if constexpr (BPK) bp[t] = BT + (size_t)((colBase>>4)+t)*((size_t)16*ldB) + (size_t)(kOff>>5)*512 + (size_t)lane*8;
    else               bp[t] = BT + (size_t)(colBase + t*16 + L)*ldB + q*8 + kOff;
  }
  f4v z4={0.f,0.f,0.f,0.f};
  f4v acc[4]={z4,z4,z4,z4};
  int nk = KK>>5;
  for (int kc0=0;kc0<nk;kc0+=UNR){
    s8v a0[UNR], bt[UNR][4];
    #pragma unroll
    for (int u=0;u<UNR;u++){
      int kc = kc0 + u;
      if constexpr (APK) a0[u] = *(const s8v*)(ap + (size_t)kc*512);
      else               a0[u] = *(const s8v*)(ap + kc*32);
      #pragma unroll
      for (int t=0;t<4;t++){
        if constexpr (BPK) bt[u][t] = *(const s8v*)(bp[t] + (size_t)kc*512);
        else               bt[u][t] = *(const s8v*)(bp[t] + kc*32);
      }
    }
    #pragma unroll
    for (int u=0;u<UNR;u++)
      #pragma unroll
      for (int t=0;t<4;t++)
        acc[t]=MFMA(a0[u],bt[u][t],acc[t]);
  }
  if constexpr (EPI<=3){
    #pragma unroll
    for (int t=0;t<4;t++){
      int col = colBase + t*16 + L;
      #pragma unroll
      for (int reg=0;reg<4;reg++){
        int row = rowBase + w*16 + q*4 + reg;
        size_t off = (size_t)row*OC + col;
        float v = acc[t][reg];
        if constexpr (EPI==0){ C[off] = v; }
        else if constexpr (EPI==1){ C[off] += v; }
        else if constexpr (EPI==2){ C[off] = flushf(Xres[off] + gamma[col]*v); }
        else { O[off] = f2b(v); }
      }
    }
  } else {
    // s1/s2 fold (prescaled by LOG2E for exp2 consumers)
    float s1p[4]={0.f,0.f,0.f,0.f}, s2p[4]={0.f,0.f,0.f,0.f};
    #pragma unroll
    for (int t=0;t<4;t++){
      int col = colBase + t*16 + L;
      float a1v = A1[col]*LOG2E, a2v = A2[col]*LOG2E;
      #pragma unroll
      for (int reg=0;reg<4;reg++){
        float v = acc[t][reg];
        s1p[reg] += v*a1v;
        s2p[reg] += v*a2v;
      }
    }
    #pragma unroll
    for (int off=1;off<16;off<<=1)
      #pragma unroll
      for (int reg=0;reg<4;reg++){
        s1p[reg] += __shfl_xor(s1p[reg],off);
        s2p[reg] += __shfl_xor(s2p[reg],off);
      }
    if (L==0){
      int sOff = (EPI==7) ? (colBase>>8)*BN : 0;
      #pragma unroll
      for (int reg=0;reg<4;reg++){
        int row = rowBase + w*16 + q*4 + reg;
        atomicAdd(&s1g[sOff+row], s1p[reg]);
        atomicAdd(&s2g[sOff+row], s2p[reg]);
      }
    }
    // coalesced pack store (16B per lane, 8 consecutive rows of one column)
    int pq_ = q&1;
    int m0 = rowBase + w*16 + (q>>1)*8;
    #pragma unroll
    for (int tp=0;tp<2;tp++){
      f4v accA = acc[2*tp], accB = acc[2*tp+1];
      f4v mine   = pq_ ? accB : accA;
      f4v theirs = pq_ ? accA : accB;
      u32 k0 = pk2(mine[0],  mine[1]);
      u32 k1 = pk2(mine[2],  mine[3]);
      u32 s0 = pk2(theirs[0],theirs[1]);
      u32 s1 = pk2(theirs[2],theirs[3]);
      u32 r0 = (u32)__shfl_xor((int)s0,16);
      u32 r1 = (u32)__shfl_xor((int)s1,16);
      uint4 val = pq_==0 ? make_uint4(k0,k1,r0,r1) : make_uint4(r0,r1,k0,k1);
      int t = 2*tp + pq_;
      int col = colBase + t*16 + L;
      *(uint4*)(Pk + packIdx(col, m0)) = val;
    }
  }
}

// ---------- fused q/k/v projections, packed A+B (gpK 256); outputs packed:
// z=0 (q) and z=1 (k): gpK(row,col,256); z=2 (v): packIdx(col,row) ----------
__global__ __launch_bounds__(256) void k_mgemm3(const u16* __restrict__ Aq, const u16* __restrict__ Akv,
    const u16* __restrict__ BT0, u16* __restrict__ O0){
  int tid=threadIdx.x, w=tid>>6, lane=tid&63, L=lane&15, q=lane>>4;
  const u16* A = blockIdx.z==0 ? Aq : Akv;
  const u16* BT = BT0 + (size_t)blockIdx.z*65536;
  u16* O = O0 + (size_t)blockIdx.z*2097152;
  int colBase=blockIdx.x<<6, rowBase=blockIdx.y<<6;
  const u16* ap = A + (size_t)((rowBase>>4)+w)*4096 + (size_t)lane*8;
  f4v z4={0.f,0.f,0.f,0.f};
  f4v acc[4]={z4,z4,z4,z4};
  #pragma unroll
  for (int kc=0;kc<8;kc++){
    s8v a0 = *(const s8v*)(ap + kc*512);
    #pragma unroll
    for (int t=0;t<4;t++){
      s8v bt = *(const s8v*)(BT + (size_t)((colBase>>4)+t)*4096 + (size_t)kc*512 + (size_t)lane*8);
      acc[t]=MFMA(a0,bt,acc[t]);
    }
  }
  bool isV = (blockIdx.z==2);
  #pragma unroll
  for (int t=0;t<4;t++){
    int col = colBase + t*16 + L;
    #pragma unroll
    for (int reg=0;reg<4;reg++){
      int row = rowBase + w*16 + q*4 + reg;
      u16 hv = f2b(acc[t][reg]);
      if (isV) O[packIdx(col, row)] = hv;
      else     O[gpK(row, col, 256)] = hv;
    }
  }
}

// ---------- split (3-term) MFMA GEMM, packed A and B (gpK 256): KK=256, OC=256 ----------
// EPI 4: hi/lo bf16 gram-packed out.  EPI 5: sq-dot fold -> pdot.
template<int EPI>
__global__ __launch_bounds__(256) void k_msgemm(const u16* __restrict__ Ah, const u16* __restrict__ Al,
    const u16* __restrict__ Bh, const u16* __restrict__ Bl,
    float* __restrict__ C, u16* __restrict__ Oh, u16* __restrict__ Ol,
    const float* __restrict__ sq, float* __restrict__ pdot){
  int tid=threadIdx.x, w=tid>>6, lane=tid&63, L=lane&15, q=lane>>4;
  int colBase=blockIdx.x<<6, rowBase=blockIdx.y<<6;
  const u16* ahp = Ah + (size_t)((rowBase>>4)+w)*4096 + (size_t)lane*8;
  const u16* alp = Al + (size_t)((rowBase>>4)+w)*4096 + (size_t)lane*8;
  f4v z4={0.f,0.f,0.f,0.f};
  f4v acc[4]={z4,z4,z4,z4};
  #pragma unroll
  for (int kc=0;kc<8;kc++){
    s8v ah=*(const s8v*)(ahp + kc*512), al=*(const s8v*)(alp + kc*512);
    #pragma unroll
    for (int t=0;t<4;t++){
      size_t boff = (size_t)((colBase>>4)+t)*4096 + (size_t)kc*512 + (size_t)lane*8;
      s8v bh=*(const s8v*)(Bh + boff);
      s8v bl=*(const s8v*)(Bl + boff);
      acc[t]=MFMA(ah,bh,acc[t]);
      acc[t]=MFMA(ah,bl,acc[t]);
      acc[t]=MFMA(al,bh,acc[t]);
    }
  }
  if constexpr (EPI==5){
    int b = rowBase>>10;
    float pp[4]={0.f,0.f,0.f,0.f};
    #pragma unroll
    for (int t=0;t<4;t++){
      int col = colBase + t*16 + L;
      float qv = sq[b*256 + col];
      #pragma unroll
      for (int reg=0;reg<4;reg++) pp[reg] += acc[t][reg]*qv;
    }
    #pragma unroll
    for (int off=1;off<16;off<<=1)
      #pragma unroll
      for (int reg=0;reg<4;reg++) pp[reg] += __shfl_xor(pp[reg],off);
    if (L==0){
      #pragma unroll
      for (int reg=0;reg<4;reg++){
        int row = rowBase + w*16 + q*4 + reg;
        atomicAdd(&pdot[row], pp[reg]);
      }
    }
  } else {
    #pragma unroll
    for (int t=0;t<4;t++){
      int col = colBase + t*16 + L;
      #pragma unroll
      for (int reg=0;reg<4;reg++){
        int row = rowBase + w*16 + q*4 + reg;
        float v = acc[t][reg];
        if constexpr (EPI==0){ C[(size_t)row*256 + col] = v; }
        else {
          size_t off = gpK(row, col, 256);
          u16 h = f2b(v); Oh[off]=h; Ol[off]=f2b(v - b2f(h));
        }
      }
    }
  }
}

// ---------- gram + bitpack v2: packed fragments, symmetric tile enumeration ----------
__global__ __launch_bounds__(256) void k_mconnect2(const u16* __restrict__ fahP, const u16* __restrict__ falP,
    const u8* __restrict__ sel8, u32* __restrict__ conn){
  __shared__ u8 sg[64][64];
  __shared__ u8 selI[64], selJ[64];
  int tid=threadIdx.x, w=tid>>6, lane=tid&63, L=lane&15, q=lane>>4;
  int b=blockIdx.z;
  int p=blockIdx.x;
  int i = (int)((sqrtf(8.f*p+1.f)-1.f)*0.5f);
  while ((i+1)*(i+2)/2 <= p) i++;
  while (i*(i+1)/2 > p) i--;
  int j = p - i*(i+1)/2;          // i >= j, both 0..15
  if (tid < 64)        selI[tid]     = sel8[b*NN + i*64 + tid];
  else if (tid < 128)  selJ[tid-64]  = sel8[b*NN + j*64 + (tid-64)];
  const u16* ah0 = fahP + ((size_t)(b*64 + i*4 + w))*4096 + (size_t)lane*8;
  const u16* al0 = falP + ((size_t)(b*64 + i*4 + w))*4096 + (size_t)lane*8;
  const u16* bh0 = fahP + ((size_t)(b*64 + j*4))*4096 + (size_t)lane*8;
  const u16* bl0 = falP + ((size_t)(b*64 + j*4))*4096 + (size_t)lane*8;
  f4v z4={0.f,0.f,0.f,0.f};
  f4v acc[4]={z4,z4,z4,z4};
  #pragma unroll
  for (int kc=0;kc<8;kc++){
    s8v ah = *(const s8v*)(ah0 + kc*512);
    s8v al = *(const s8v*)(al0 + kc*512);
    #pragma unroll
    for (int t=0;t<4;t++){
      s8v bh = *(const s8v*)(bh0 + (size_t)t*4096 + kc*512);
      s8v bl = *(const s8v*)(bl0 + (size_t)t*4096 + kc*512);
      acc[t]=MFMA(ah,bh,acc[t]);
      acc[t]=MFMA(ah,bl,acc[t]);
      acc[t]=MFMA(al,bh,acc[t]);
    }
  }
  #pragma unroll
  for (int t=0;t<4;t++)
    #pragma unroll
    for (int reg=0;reg<4;reg++)
      sg[w*16 + q*4 + reg][t*16 + L] = acc[t][reg] > 0.f;
  __syncthreads();
  int row=(tid&127)>>1, ww=tid&1;
  if (tid<128){
    u32 word=0;
    if (selI[row]){
      #pragma unroll 8
      for (int jj=0;jj<32;jj++)
        if (sg[row][ww*32+jj] && selJ[ww*32+jj]) word |= (1u<<jj);
    }
    conn[((size_t)b*NN + i*64+row)*32 + j*2 + ww] = word;
  } else if (i != j){
    u32 word=0;
    if (selJ[row]){
      #pragma unroll 8
      for (int jj=0;jj<32;jj++)
        if (sg[ww*32+jj][row] && selI[ww*32+jj]) word |= (1u<<jj);
    }
    conn[((size_t)b*NN + j*64+row)*32 + i*2 + ww] = word;
  }
}

// ---------- MFMA GAT attention v10: defer-max (no M2a), lgkmcnt-only barrier ----------
// s1/s2 are prescaled by LOG2E -> bare v_exp_f32 (2^x). No row-max subtraction:
// softmax is shift-invariant and |s1+s2|*log2e is bounded (~30) << fp32 range.
// All-masked rows -> sumP=0 -> guarded rsi=0 -> finite 0 output (rows discarded
// downstream; P=0 keeps PV exact).
// PKO: 0 = row-major output (stride oStride); else fragment-packed gpK(row,col,PKO).
template<int CT, bool SWZ, int PKO>
__global__ __launch_bounds__(256,4) void k_mattn5(const float* __restrict__ s1a, const float* __restrict__ s2a,
    const u32* __restrict__ conn,
    const u16* __restrict__ P, int headMul, u16* __restrict__ Out, int oStride){
  __shared__ __align__(16) u16 Pb[2][4][512];
  __shared__ float Srow[64];
  int tid=threadIdx.x, w=tid>>6, lane=tid&63, L=lane&15, q=lane>>4;
  int h, rowBlk;
  if constexpr (SWZ){ h = blockIdx.y & 7; rowBlk = (blockIdx.y>>3) + (blockIdx.z<<4); }
  else             { h = blockIdx.z;     rowBlk = blockIdx.y; }
  int rowBase = rowBlk*64;
  int hOff = h*headMul, sOff = h*BN;
  int b = rowBase>>10;
  size_t bOff = (size_t)b*NN;
  int r = rowBase + w*16 + L;             // own row for P-build
  float s1v = s1a[sOff+r];
  const float* s2p = s2a + sOff + bOff;
  const u32* cp = conn + (size_t)r*32;
  int tile0 = blockIdx.x*(4*CT) + w*CT;   // first col-tile owned by this wave
  const u16* vp = P + (size_t)((hOff>>4) + tile0)*131072 + (size_t)b*16384 + (size_t)lane*8;
  f4v z4={0.f,0.f,0.f,0.f};
  f4v acc[4][CT];
  #pragma unroll
  for (int g=0;g<4;g++)
    #pragma unroll
    for (int t=0;t<CT;t++) acc[g][t]=z4;
  float sumP = 0.f;
  for (int k0=0;k0<NN;k0+=32){
    int cur=(k0>>5)&1;
    u32 cw = cp[k0>>5];
    // issue THIS chunk's V loads first — they stay in flight ACROSS the
    // barrier (lgkmcnt-only), completing under the MFMA wait of the consumer.
    s8v vf[CT];
    {
      const u16* vk = vp + (size_t)(k0>>5)*512;
      #pragma unroll
      for (int t=0;t<CT;t++) vf[t] = *(const s8v*)(vk + (size_t)t*131072);
    }
    float4 sA = *(const float4*)(s2p + k0 + q*8);
    float4 sB = *(const float4*)(s2p + k0 + q*8 + 4);
    float s2v[8] = {sA.x,sA.y,sA.z,sA.w,sB.x,sB.y,sB.z,sB.w};
    float p[8];
    #pragma unroll
    for (int j=0;j<8;j++){
      float z = s1v + s2v[j];
      float ev = fmaxf(z, 0.2f*z);                      // leaky = max(z, 0.2z) (scaled)
      ev = ((cw>>(q*8+j))&1u) ? ev : -9.0e15f;          // mask BEFORE exp; 2^-9e15 = 0
      p[j] = exp2r(ev);                                  // bare v_exp (2^x), no max-sub
      sumP += p[j];
    }
    union{ s8v v; u32 u[4]; } pk;
    #pragma unroll
    for (int jj=0;jj<4;jj++)
      pk.u[jj] = pk2(p[2*jj], p[2*jj+1]);
    *(s8v*)&Pb[cur][w][lane*8] = pk.v;    // ds_write_b128, contiguous
    // lgkmcnt-only barrier: own LDS write retired, then block-wide barrier.
    // Does NOT drain vmcnt — V/s2/conn loads stay outstanding (T4 minimal).
    // Pb[2] double-buffer is REQUIRED for correctness with this barrier.
    asm volatile("s_waitcnt lgkmcnt(0)" ::: "memory");
    __builtin_amdgcn_s_barrier();
    asm volatile("" ::: "memory");
    s8v pa[4];
    #pragma unroll
    for (int g=0;g<4;g++) pa[g] = *(const s8v*)&Pb[cur][g][lane*8];
    __builtin_amdgcn_s_setprio(1);
    #pragma unroll
    for (int t=0;t<CT;t++)
      #pragma unroll
      for (int g=0;g<4;g++) acc[g][t] = MFMA(pa[g], vf[t], acc[g][t]);
    __builtin_amdgcn_s_setprio(0);
  }
  sumP += __shfl_xor(sumP,16);
  sumP += __shfl_xor(sumP,32);
  if (lane<16) Srow[w*16+lane] = sumP;
  __syncthreads();
  #pragma unroll
  for (int g=0;g<4;g++){
    float4 sv = *(const float4*)&Srow[g*16 + q*4];
    // guard: all-masked row -> sumP==0 -> emit 0 (finite), not inf/NaN
    float rsi[4] = {sv.x>0.f ? 1.f/sv.x : 0.f, sv.y>0.f ? 1.f/sv.y : 0.f,
                    sv.z>0.f ? 1.f/sv.z : 0.f, sv.w>0.f ? 1.f/sv.w : 0.f};
    #pragma unroll
    for (int t=0;t<CT;t++){
      int col = hOff + (tile0+t)*16 + L;
      #pragma unroll
      for (int reg=0;reg<4;reg++){
        int row = rowBase + g*16 + q*4 + reg;
        float ov = eluf(acc[g][t][reg]*rsi[reg]);
        if constexpr (PKO) Out[gpK(row, col, PKO)] = f2b(ov);
        else               Out[(size_t)row*oStride + col] = f2b(ov);
      }
    }
  }
}

// ---------- LayerNorms (packed gpK-256 output) ----------
__global__ __launch_bounds__(256) void k_ln_x(const float* __restrict__ x, const float* __restrict__ g,
                                              const float* __restrict__ bb, u16* __restrict__ out){
  int r = blockIdx.x*4 + (threadIdx.x>>6);
  int lane=threadIdx.x&63;
  float4 v = *(const float4*)(x + (size_t)r*DD + lane*4);
  float s = v.x+v.y+v.z+v.w;
  float s2 = v.x*v.x+v.y*v.y+v.z*v.z+v.w*v.w;
  s = wredsum(s); s2 = wredsum(s2);
  float mean = s*(1.f/256.f);
  float var = s2*(1.f/256.f) - mean*mean;
  float rstd = rsqrtf(var + 1e-5f);
  float4 gv = *(const float4*)(g+lane*4), bv = *(const float4*)(bb+lane*4);
  u16 t[4];
  t[0]=f2b((v.x-mean)*rstd*gv.x+bv.x); t[1]=f2b((v.y-mean)*rstd*gv.y+bv.y);
  t[2]=f2b((v.z-mean)*rstd*gv.z+bv.z); t[3]=f2b((v.w-mean)*rstd*gv.w+bv.w);
  *(uint2*)(out + gpK(r, lane*4, 256)) = *(uint2*)&t[0];
}

__global__ __launch_bounds__(256) void k_ln_kv(const u16* __restrict__ gout, const float* __restrict__ pe,
    const u8* __restrict__ sel8, const float* __restrict__ g, const float* __restrict__ bb,
    u16* __restrict__ out){
  int r = blockIdx.x*4 + (threadIdx.x>>6);
  int lane=threadIdx.x&63;
  int n = r & 1023;
  float4 v = make_float4(0.f,0.f,0.f,0.f);
  if (sel8[r]){
    float4 gv = ld4bf(gout + (size_t)r*DD + lane*4);
    float4 pv = *(const float4*)(pe + (size_t)n*DD + lane*4);
    v = make_float4(gv.x+pv.x, gv.y+pv.y, gv.z+pv.z, gv.w+pv.w);
  }
  float s = v.x+v.y+v.z+v.w;
  float s2 = v.x*v.x+v.y*v.y+v.z*v.z+v.w*v.w;
  s = wredsum(s); s2 = wredsum(s2);
  float mean = s*(1.f/256.f);
  float var = s2*(1.f/256.f) - mean*mean;
  float rstd = rsqrtf(var + 1e-5f);
  float4 gv = *(const float4*)(g+lane*4), bv = *(const float4*)(bb+lane*4);
  u16 t[4];
  t[0]=f2b((v.x-mean)*rstd*gv.x+bv.x); t[1]=f2b((v.y-mean)*rstd*gv.y+bv.y);
  t[2]=f2b((v.z-mean)*rstd*gv.z+bv.z); t[3]=f2b((v.w-mean)*rstd*gv.w+bv.w);
  *(uint2*)(out + gpK(r, lane*4, 256)) = *(uint2*)&t[0];
}

// ---------- CA attention v3: barrier-free flash; direct fragment loads ----------
__global__ __launch_bounds__(256) void k_mca_av3(const u16* __restrict__ q, const u16* __restrict__ k,
    const u16* __restrict__ v, const u8* __restrict__ sel8, u16* __restrict__ O){
  __shared__ __align__(16) u16 Pw[4][16][72];
  int tid=threadIdx.x;
  int w = tid>>6, lane = tid&63, L = lane&15, qd = lane>>4;
  int b=blockIdx.z, h=blockIdx.y, rowBase=blockIdx.x*64;
  size_t bOff = (size_t)b*NN;
  const u16* qbase = q + (size_t)((bOff + rowBase + w*16)>>4)*4096 + (size_t)lane*8;
  s8v af0 = *(const s8v*)(qbase + (size_t)(h*2+0)*512);
  s8v af1 = *(const s8v*)(qbase + (size_t)(h*2+1)*512);
  float rm[4], sp[4];
  #pragma unroll
  for (int reg=0;reg<4;reg++){ rm[reg] = -3.0e38f; sp[reg] = 0.f; }
  f4v zero = {0.f,0.f,0.f,0.f};
  f4v acc[4] = {zero,zero,zero,zero};
  for (int m0=0;m0<NN;m0+=64){
    s8v bt[4][2];
    #pragma unroll
    for (int t=0;t<4;t++){
      const u16* kb = k + (size_t)((bOff + m0 + t*16)>>4)*4096 + (size_t)lane*8;
      bt[t][0] = *(const s8v*)(kb + (size_t)(h*2+0)*512);
      bt[t][1] = *(const s8v*)(kb + (size_t)(h*2+1)*512);
    }
    s8v vf[4][2];
    #pragma unroll
    for (int t=0;t<4;t++){
      const u16* vb = v + (size_t)(((h*4+t)*8 + b)*32 + (m0>>5))*512 + (size_t)lane*8;
      vf[t][0] = *(const s8v*)vb;
      vf[t][1] = *(const s8v*)(vb + 512);
    }
    f4v sa[4] = {zero,zero,zero,zero};
    #pragma unroll
    for (int t=0;t<4;t++){
      sa[t] = MFMA(af0, bt[t][0], sa[t]);
      sa[t] = MFMA(af1, bt[t][1], sa[t]);
    }
    float vals[4][4];
    float tmax[4];
    #pragma unroll
    for (int reg=0;reg<4;reg++) tmax[reg] = -3.0e38f;
    #pragma unroll
    for (int t=0;t<4;t++){
      int m = m0 + t*16 + L;
      bool sl = sel8[b*NN+m];
      #pragma unroll
      for (int reg=0;reg<4;reg++){
        float val = sl ? sa[t][reg]*0.125f : -1.0e9f;
        vals[t][reg] = val;
        tmax[reg] = fmaxf(tmax[reg], val);
      }
    }
    #pragma unroll
    for (int off=1;off<16;off<<=1)
      #pragma unroll
      for (int reg=0;reg<4;reg++) tmax[reg] = fmaxf(tmax[reg], __shfl_xor(tmax[reg],off));
    float sc[4];
    #pragma unroll
    for (int reg=0;reg<4;reg++){
      float nm = fmaxf(rm[reg], tmax[reg]);
      sc[reg] = exp0(rm[reg] - nm);
      rm[reg] = nm;
      sp[reg] *= sc[reg];
    }
    #pragma unroll
    for (int t=0;t<4;t++){
      #pragma unroll
      for (int reg=0;reg<4;reg++){
        float pv = exp0(vals[t][reg] - rm[reg]);
        sp[reg] += pv;
        Pw[w][qd*4 + reg][t*16 + L] = f2b(pv);   // intra-wave slice, no barrier
      }
    }
    #pragma unroll
    for (int t=0;t<4;t++)
      #pragma unroll
      for (int reg=0;reg<4;reg++) acc[t][reg] *= sc[reg];
    #pragma unroll
    for (int mc2=0;mc2<2;mc2++){
      s8v pf = *(const s8v*)&Pw[w][L][mc2*32 + qd*8];
      #pragma unroll
      for (int t=0;t<4;t++)
        acc[t] = MFMA(pf, vf[t][mc2], acc[t]);
    }
  }
  #pragma unroll
  for (int off=1;off<16;off<<=1)
    #pragma unroll
    for (int reg=0;reg<4;reg++) sp[reg] += __shfl_xor(sp[reg],off);
  float ri[4];
  #pragma unroll
  for (int reg=0;reg<4;reg++) ri[reg] = 1.f/sp[reg];
  #pragma unroll
  for (int t=0;t<4;t++){
    int col = h*64 + t*16 + L;
    #pragma unroll
    for (int reg=0;reg<4;reg++){
      int row = (int)bOff + rowBase + w*16 + qd*4 + reg;
      O[gpK(row, col, 256)] = f2b(acc[t][reg]*ri[reg]);
    }
  }
}

extern "C" void kernel_launch(void* const* d_in, const int* in_sizes, int n_in,
                              void* d_out, int out_size, void* d_ws, size_t ws_size,
                              hipStream_t stream) {
  (void)in_sizes; (void)n_in; (void)out_size;
  const float* x      = (const float*)d_in[0];
  const int*   mask   = (const int*  )d_in[1];
  const float* pe     = (const float*)d_in[2];
  const float* sim_Wx = (const float*)d_in[3];
  const float* sim_Wq = (const float*)d_in[4];
  const float* adj_W  = (const float*)d_in[5];
  const float* gat_W  = (const float*)d_in[6];
  const float* gat_a1 = (const float*)d_in[7];
  const float* gat_a2 = (const float*)d_in[8];
  const float* gat_Wo = (const float*)d_in[9];
  const float* gat_ao1= (const float*)d_in[10];
  const float* gat_ao2= (const float*)d_in[11];
  const float* ln3_g  = (const float*)d_in[12];
  const float* ln3_b  = (const float*)d_in[13];
  const float* ln4_g  = (const float*)d_in[14];
  const float* ln4_b  = (const float*)d_in[15];
  const float* ca_Wq  = (const float*)d_in[16];
  const float* ca_Wk  = (const float*)d_in[17];
  const float* ca_Wv  = (const float*)d_in[18];
  const float* ca_Wp  = (const float*)d_in[19];
  const float* gamma  = (const float*)d_in[20];
  float* out    = (float*)d_out;
  float* simOut = out + (size_t)BN*DD;

  const size_t MB = 1024*1024;
  bool big = ws_size >= 98*MB;
  char* W = (char*)d_ws;
  float* pq   = (float*)W;
  float* cnt  = pq + 2048;
  float* sq   = cnt + 16;
  float* s1a  = (float*)(W + 64*1024);
  float* s2a  = (float*)(W + 320*1024);
  float* pdot = (float*)(W + 1216*1024);
  u8*    sel8 = (u8*)(W + 1400*1024);
  u32*   conn = (u32*)(W + 2*MB);
  u16*   WT0  = (u16*)(W + 3*MB);
  u16*   WoT  = (u16*)(W + 4*MB);
  u16*   WQT  = (u16*)(W + 5*MB);
  u16*   WPT  = WQT + 3*65536;
  u16*   sWxh = (u16*)(W + 5*MB + 512*1024);
  u16*   sWxl = sWxh + 65536;
  u16*   aWh  = sWxl + 65536;
  u16*   aWl  = aWh + 65536;
  u16*   xh   = (u16*)(W + 6*MB);
  u16*   xl   = (u16*)(W + 10*MB);
  float* S0   = (float*)(W + 14*MB);
  u16*   fah  = (u16*)(W + 22*MB);
  u16*   fal  = (u16*)(W + 26*MB);
  u16*   T2   = (u16*)(W + 30*MB);

  // prep (everything fragment-packed)
  k_split<<<BN*DD/2048,256,0,stream>>>(x, xh, xl);
  k_transpose<<<dim3(4,4,HG),256,0,stream>>>(gat_W, WT0, 256, 65536, 256);
  k_transpose<<<dim3(4,32,1),256,0,stream>>>(gat_Wo, WoT, 2048, 0, 2048);
  k_transpose4<<<dim3(4,4,4),256,0,stream>>>(ca_Wq, ca_Wk, ca_Wv, ca_Wp, WQT);
  k_transp_split<<<dim3(4,4,1),256,0,stream>>>(sim_Wx, sWxh, sWxl);
  k_transp_split<<<dim3(4,4,1),256,0,stream>>>(adj_W, aWh, aWl);

  hipMemsetAsync(pq, 0, (2048+16+2048)*sizeof(float), stream);   // pq + cnt + sq
  hipMemsetAsync(pdot, 0, BN*sizeof(float), stream);
  k_posq<<<dim3(BB,64),256,0,stream>>>(x, mask, pq, cnt);
  k_sq<<<dim3(BB,16),256,0,stream>>>(pq, cnt, sim_Wq, sq);
  k_msgemm<5><<<dim3(4,128),256,0,stream>>>(xh, xl, sWxh, sWxl, nullptr, nullptr, nullptr, sq, pdot); // y-dot fold
  k_simsel2<<<BN/256,256,0,stream>>>(pdot, simOut, sel8);
  k_msgemm<4><<<dim3(4,128),256,0,stream>>>(xh, xl, aWh, aWl, nullptr, fah, fal, nullptr, nullptr);   // fa gram-packed
  k_mconnect2<<<dim3(136,1,BB),256,0,stream>>>(fah, fal, sel8, conn);

  if (big){
    u16* WhP   = (u16*)(W + 66*MB);   // attention-packed Wh_cat, 32MB
    u16* htcat = (u16*)(W + 34*MB);   // fragment-packed (gpK 2048) ht_cat, 32MB
    u16* S0P   = (u16*)(W + 22*MB);   // attention-packed Who, 4MB (fah dead after mconnect)
    u16* qx = (u16*)(W + 34*MB);      // after htcat consumed
    u16* kv = (u16*)(W + 38*MB);
    u16* qb = (u16*)(W + 42*MB);
    u16* vb = (u16*)(W + 50*MB);
    u16* Ob = (u16*)(W + 54*MB);

    hipMemsetAsync(s1a, 0, 512*1024, stream);  // s1a(256K) + s2a(256K) contiguous
    k_mgemm<7,1,1,2><<<dim3(32,128),256,0,stream>>>(xh, WT0, 256, 256, 0, nullptr, nullptr, nullptr, nullptr,
                                                    WhP, gat_a1, gat_a2, s1a, s2a);  // WhP pack + s1s2 fold (×log2e)
    k_mattn5<4,true,2048><<<dim3(1,128,HG),256,0,stream>>>(s1a, s2a, conn, WhP, 256, htcat, 2048);
    hipMemsetAsync(s1a, 0, 512*1024, stream);  // re-zero s1a+s2a regions (one node)
    k_mgemm<8,1,1,8><<<dim3(4,128),256,0,stream>>>(htcat, WoT, 2048, 2048, 0, nullptr, nullptr, nullptr, nullptr,
                                                   S0P, gat_ao1, gat_ao2, s1a, s2a);  // S0P pack + s1s2 fold (×log2e)
    k_mattn5<1,false,0><<<dim3(4,128,1),256,0,stream>>>(s1a, s2a, conn, S0P, 0, T2, 256);  // gout

    k_ln_x<<<BN/4,256,0,stream>>>(x, ln3_g, ln3_b, qx);
    k_ln_kv<<<BN/4,256,0,stream>>>(T2, pe, sel8, ln4_g, ln4_b, kv);
    k_mgemm3<<<dim3(4,128,3),256,0,stream>>>(qx, kv, WQT, qb);     // qb,kb gpK; vb packIdx
    k_mca_av3<<<dim3(16,HC,BB),256,0,stream>>>(qb, qb + 2097152, vb, sel8, Ob);
    k_mgemm<2,1,1,8><<<dim3(4,128),256,0,stream>>>(Ob, WPT, 256, 256, 0, out, x, gamma, nullptr, nullptr,
                                                   nullptr, nullptr, nullptr, nullptr);
  } else {
    // small-ws fallback: per-head loop, packed kernels (rarely taken)
    u16* T0 = fah;
    u16* T1 = fal;
    u16* S0b = (u16*)S0;
    hipMemsetAsync(s1a, 0, 512*1024, stream);
    for (int h=0;h<HG;h++){
      hipMemsetAsync(s1a, 0, BN*sizeof(float), stream);
      hipMemsetAsync(s2a, 0, BN*sizeof(float), stream);
      k_mgemm<8,1,1><<<dim3(4,128),256,0,stream>>>(xh, WT0 + (size_t)h*65536, 256, 256, 0,
                                                   nullptr, nullptr, nullptr, nullptr, T0,
                                                   gat_a1 + h*DD, gat_a2 + h*DD, s1a, s2a);
      k_mattn5<1,false,0><<<dim3(4,128,1),256,0,stream>>>(s1a, s2a, conn, T0, 0, T1, 256);
      k_mgemm<1,0,1><<<dim3(4,128),256,0,stream>>>(T1, WoT, 256, 2048, h*256, S0, nullptr, nullptr, nullptr, nullptr,
                                                   nullptr, nullptr, nullptr, nullptr);
    }
    hipMemsetAsync(s1a, 0, BN*sizeof(float), stream);
    hipMemsetAsync(s2a, 0, BN*sizeof(float), stream);
    k_mattn5<1,false,0><<<dim3(4,128,1),256,0,stream>>>(s1a, s2a, conn, (u16*)S0, 0, T2, 256);
    k_ln_x<<<BN/4,256,0,stream>>>(x, ln3_g, ln3_b, T1);
    k_ln_kv<<<BN/4,256,0,stream>>>(T2, pe, sel8, ln4_g, ln4_b, T0);
    k_mgemm3<<<dim3(4,128,3),256,0,stream>>>(T1, T0, WQT, S0b);
    k_mca_av3<<<dim3(16,HC,BB),256,0,stream>>>(S0b, S0b + 2097152, S0b + 4194304, sel8, T0);
    k_mgemm<2,1,1><<<dim3(4,128),256,0,stream>>>(T0, WPT, 256, 256, 0, out, x, gamma, nullptr, nullptr,
                                                 nullptr, nullptr, nullptr, nullptr);
  }
}